// Round 3
// baseline (1653.551 us; speedup 1.0000x reference)
//
#include <hip/hip_runtime.h>
#include <hip/hip_bf16.h>
#include <cstdint>

#define D_STATE 16
#define D_INNER 2048
#define DT_RANK 64
#define SEQ 2048
#define BL 4096   // B * L

__device__ __forceinline__ float siluf(float x) { return x / (1.f + expf(-x)); }

// ---------------- GEMM: C[M,N] = A[M,K] * B[N,K]^T, 128x128 tile, fp32 ----------------
// M, N multiples of 128; K multiple of 16. Strided (lda/ldb/ldc in elements).
__global__ __launch_bounds__(256) void gemm128(const float* __restrict__ A,
                                               const float* __restrict__ B,
                                               float* __restrict__ C,
                                               int M, int N, int K,
                                               int lda, int ldb, int ldc) {
  __shared__ __align__(16) float As[16][128];
  __shared__ __align__(16) float Bs[16][128];
  const int tid = threadIdx.x;
  const int tx = tid & 15, ty = tid >> 4;
  const int m0 = blockIdx.y * 128, n0 = blockIdx.x * 128;
  const int lrow = tid >> 2;        // 0..63
  const int lc4  = (tid & 3) * 4;   // 0,4,8,12

  float acc[8][8];
#pragma unroll
  for (int i = 0; i < 8; ++i)
#pragma unroll
    for (int j = 0; j < 8; ++j) acc[i][j] = 0.f;

  for (int k0 = 0; k0 < K; k0 += 16) {
    __syncthreads();
#pragma unroll
    for (int g = 0; g < 2; ++g) {
      const int row = lrow + g * 64;
      float4 av = *reinterpret_cast<const float4*>(&A[(size_t)(m0 + row) * lda + k0 + lc4]);
      As[lc4 + 0][row] = av.x; As[lc4 + 1][row] = av.y;
      As[lc4 + 2][row] = av.z; As[lc4 + 3][row] = av.w;
      float4 bv = *reinterpret_cast<const float4*>(&B[(size_t)(n0 + row) * ldb + k0 + lc4]);
      Bs[lc4 + 0][row] = bv.x; Bs[lc4 + 1][row] = bv.y;
      Bs[lc4 + 2][row] = bv.z; Bs[lc4 + 3][row] = bv.w;
    }
    __syncthreads();
#pragma unroll
    for (int kk = 0; kk < 16; ++kk) {
      float4 a0 = *reinterpret_cast<const float4*>(&As[kk][ty * 8]);
      float4 a1 = *reinterpret_cast<const float4*>(&As[kk][ty * 8 + 4]);
      float4 b0 = *reinterpret_cast<const float4*>(&Bs[kk][tx * 8]);
      float4 b1 = *reinterpret_cast<const float4*>(&Bs[kk][tx * 8 + 4]);
      float a[8] = {a0.x, a0.y, a0.z, a0.w, a1.x, a1.y, a1.z, a1.w};
      float b[8] = {b0.x, b0.y, b0.z, b0.w, b1.x, b1.y, b1.z, b1.w};
#pragma unroll
      for (int i = 0; i < 8; ++i)
#pragma unroll
        for (int j = 0; j < 8; ++j) acc[i][j] = fmaf(a[i], b[j], acc[i][j]);
    }
  }

#pragma unroll
  for (int i = 0; i < 8; ++i) {
    const size_t row = (size_t)(m0 + ty * 8 + i) * ldc + n0 + tx * 8;
#pragma unroll
    for (int j = 0; j < 8; ++j) C[row + j] = acc[i][j];
  }
}

// ---------------- Guarded GEMM: 64x64 tile, arbitrary N, K multiple of 16 ----------------
__global__ __launch_bounds__(256) void gemm64g(const float* __restrict__ A,
                                               const float* __restrict__ B,
                                               float* __restrict__ C,
                                               int M, int N, int K,
                                               int lda, int ldb, int ldc) {
  __shared__ __align__(16) float As[16][64];
  __shared__ __align__(16) float Bs[16][64];
  const int tid = threadIdx.x;
  const int tx = tid & 15, ty = tid >> 4;
  const int m0 = blockIdx.y * 64, n0 = blockIdx.x * 64;
  const int lrow = tid >> 2;
  const int lc4  = (tid & 3) * 4;

  float acc[4][4];
#pragma unroll
  for (int i = 0; i < 4; ++i)
#pragma unroll
    for (int j = 0; j < 4; ++j) acc[i][j] = 0.f;

  for (int k0 = 0; k0 < K; k0 += 16) {
    __syncthreads();
    {
      float4 av = make_float4(0.f, 0.f, 0.f, 0.f);
      if (m0 + lrow < M)
        av = *reinterpret_cast<const float4*>(&A[(size_t)(m0 + lrow) * lda + k0 + lc4]);
      As[lc4 + 0][lrow] = av.x; As[lc4 + 1][lrow] = av.y;
      As[lc4 + 2][lrow] = av.z; As[lc4 + 3][lrow] = av.w;
      float4 bv = make_float4(0.f, 0.f, 0.f, 0.f);
      if (n0 + lrow < N)
        bv = *reinterpret_cast<const float4*>(&B[(size_t)(n0 + lrow) * ldb + k0 + lc4]);
      Bs[lc4 + 0][lrow] = bv.x; Bs[lc4 + 1][lrow] = bv.y;
      Bs[lc4 + 2][lrow] = bv.z; Bs[lc4 + 3][lrow] = bv.w;
    }
    __syncthreads();
#pragma unroll
    for (int kk = 0; kk < 16; ++kk) {
      float4 a = *reinterpret_cast<const float4*>(&As[kk][ty * 4]);
      float4 b = *reinterpret_cast<const float4*>(&Bs[kk][tx * 4]);
      float av[4] = {a.x, a.y, a.z, a.w};
      float bv[4] = {b.x, b.y, b.z, b.w};
#pragma unroll
      for (int i = 0; i < 4; ++i)
#pragma unroll
        for (int j = 0; j < 4; ++j) acc[i][j] = fmaf(av[i], bv[j], acc[i][j]);
    }
  }

#pragma unroll
  for (int i = 0; i < 4; ++i) {
    int m = m0 + ty * 4 + i;
    if (m >= M) continue;
#pragma unroll
    for (int j = 0; j < 4; ++j) {
      int n = n0 + tx * 4 + j;
      if (n < N) C[(size_t)m * ldc + n] = acc[i][j];
    }
  }
}

// ---------------- depthwise causal conv1d (width 4) + bias + silu ----------------
__global__ __launch_bounds__(256) void conv_silu_kernel(const float* __restrict__ xz,
                                                        const float* __restrict__ conv_w,
                                                        const float* __restrict__ conv_b,
                                                        float* __restrict__ x_act) {
  const int idx = blockIdx.x * 256 + threadIdx.x;   // over BL * D_INNER
  const int d = idx & (D_INNER - 1);
  const int bl = idx >> 11;
  const int l = bl & (SEQ - 1);
  float acc = conv_b[d];
#pragma unroll
  for (int k = 0; k < 4; ++k) {
    const int ll = l + k - 3;
    if (ll >= 0)
      acc = fmaf(xz[(size_t)(bl + k - 3) * 4096 + d], conv_w[d * 4 + k], acc);
  }
  x_act[idx] = siluf(acc);
}

// ---------------- delta = softplus(delta_raw + dt_proj_b), in place at stride 4096 ------
__global__ __launch_bounds__(256) void softplus_bias_kernel(float* delta,  // xz region
                                                            const float* __restrict__ dt_proj_b) {
  const int idx = blockIdx.x * 256 + threadIdx.x;   // over BL * D_INNER
  const int d = idx & (D_INNER - 1);
  const int bl = idx >> 11;
  const size_t a = (size_t)bl * 4096 + d;
  const float v = delta[a] + dt_proj_b[d];
  delta[a] = fmaxf(v, 0.f) + log1pf(expf(-fabsf(v)));
}

// ---------------- selective scan: thread per (b, d, n); writes y over delta in place ----
// dxy: the xz buffer; delta lives at cols 0..2047 (stride 4096); y overwrites it in place.
__global__ __launch_bounds__(256) void scan_kernel(float* dxy,   // NOT restrict: read delta / write y, same addresses
                                                   const float* __restrict__ x_act,
                                                   const float* __restrict__ x_dbl,
                                                   const float* __restrict__ A_log) {
  const int t = blockIdx.x * 256 + threadIdx.x;   // 65536 threads
  const int n = t & 15;
  const int pair = t >> 4;        // b * D_INNER + d
  const int d = pair & (D_INNER - 1);
  const int b = pair >> 11;
  const float Aval = -expf(A_log[d * D_STATE + n]);

  float* dp = dxy + (size_t)b * SEQ * 4096 + d;            // delta in, y out (same addresses)
  const float* up = x_act + (size_t)b * SEQ * D_INNER + d;
  const float* xb = x_dbl + (size_t)b * SEQ * 96 + DT_RANK + n;
  const float* xc = x_dbl + (size_t)b * SEQ * 96 + DT_RANK + D_STATE + n;

  float h = 0.f;
  float dv = dp[0];
  float uv = up[0];
  float Bv = xb[0];
  float Cv = xc[0];
  for (int l = 0; l < SEQ; ++l) {
    // depth-1 prefetch of next iteration (issued before this iteration's store)
    float dv2 = 0.f, uv2 = 0.f, Bv2 = 0.f, Cv2 = 0.f;
    if (l + 1 < SEQ) {
      dv2 = dp[(size_t)(l + 1) * 4096];
      uv2 = up[(size_t)(l + 1) * D_INNER];
      Bv2 = xb[(size_t)(l + 1) * 96];
      Cv2 = xc[(size_t)(l + 1) * 96];
    }
    const float dA = expf(dv * Aval);
    h = fmaf(dA, h, dv * uv * Bv);
    float p = h * Cv;
    p += __shfl_xor(p, 8);
    p += __shfl_xor(p, 4);
    p += __shfl_xor(p, 2);
    p += __shfl_xor(p, 1);
    if (n == 0) dp[(size_t)l * 4096] = p;   // y over delta, in place
    dv = dv2; uv = uv2; Bv = Bv2; Cv = Cv2;
  }
}

// ---------------- gate: y = (y + x_act * D_skip) * silu(z), y at xz cols 0..2047 --------
__global__ __launch_bounds__(256) void gate_kernel(float* xz,    // y in place at cols 0..2047; z at 2048..4095
                                                   const float* __restrict__ x_act,
                                                   const float* __restrict__ D_skip) {
  const int idx = blockIdx.x * 256 + threadIdx.x;   // over BL * D_INNER
  const int d = idx & (D_INNER - 1);
  const int bl = idx >> 11;
  const size_t ya = (size_t)bl * 4096 + d;
  const float zv = xz[(size_t)bl * 4096 + D_INNER + d];
  xz[ya] = (xz[ya] + x_act[idx] * D_skip[d]) * siluf(zv);
}

extern "C" void kernel_launch(void* const* d_in, const int* in_sizes, int n_in,
                              void* d_out, int out_size, void* d_ws, size_t ws_size,
                              hipStream_t stream) {
  const float* x          = (const float*)d_in[0];
  const float* in_proj_w  = (const float*)d_in[1];
  const float* conv_w     = (const float*)d_in[2];
  const float* conv_b     = (const float*)d_in[3];
  const float* x_proj_w   = (const float*)d_in[4];
  const float* dt_proj_w  = (const float*)d_in[5];
  const float* dt_proj_b  = (const float*)d_in[6];
  const float* A_log      = (const float*)d_in[7];
  const float* D_skip     = (const float*)d_in[8];
  const float* out_proj_w = (const float*)d_in[9];
  float* out = (float*)d_out;   // reference output dtype is float32

  // Workspace layout (total 102,236,160 bytes):
  //   xz    : BL x 4096 fp32 = 67,108,864 B   (cols 0..2047: x_in -> delta -> y ; cols 2048..4095: z)
  //   x_act : BL x 2048 fp32 = 33,554,432 B
  //   x_dbl : BL x   96 fp32 =  1,572,864 B
  char* ws = (char*)d_ws;
  float* xz    = (float*)(ws);
  float* x_act = (float*)(ws + 67108864);
  float* x_dbl = (float*)(ws + 100663296);

  // 1. xz = x @ in_proj_w^T           (4096 x 4096, K=1024)
  gemm128<<<dim3(32, 32), 256, 0, stream>>>(x, in_proj_w, xz, BL, 4096, 1024,
                                            1024, 1024, 4096);

  // 2. depthwise causal conv + bias + silu -> x_act
  conv_silu_kernel<<<(BL * D_INNER) / 256, 256, 0, stream>>>(xz, conv_w, conv_b, x_act);

  // 3. x_dbl = x_act @ x_proj_w^T     (4096 x 96, K=2048)
  gemm64g<<<dim3(2, 64), 256, 0, stream>>>(x_act, x_proj_w, x_dbl, BL, 96, 2048,
                                           2048, 2048, 96);

  // 4. delta_raw = dt_low @ dt_proj_w^T  (4096 x 2048, K=64), written into xz cols 0..2047
  gemm64g<<<dim3(32, 64), 256, 0, stream>>>(x_dbl, dt_proj_w, xz, BL, 2048, 64,
                                            96, 64, 4096);

  // 5. delta = softplus(delta_raw + dt_proj_b), in place (stride 4096)
  softplus_bias_kernel<<<(BL * D_INNER) / 256, 256, 0, stream>>>(xz, dt_proj_b);

  // 6. selective scan -> y over delta, in place in xz cols 0..2047
  scan_kernel<<<256, 256, 0, stream>>>(xz, x_act, x_dbl, A_log);

  // 7. gate: y = (y + x_act * D_skip) * silu(z), in place
  gate_kernel<<<(BL * D_INNER) / 256, 256, 0, stream>>>(xz, x_act, D_skip);

  // 8. out = y @ out_proj_w^T  (4096 x 1024, K=2048), fp32 output
  gemm128<<<dim3(8, 32), 256, 0, stream>>>(xz, out_proj_w, out, BL, 1024, 2048,
                                           4096, 2048, 1024);
}

// Round 4
// 651.879 us; speedup vs baseline: 2.5366x; 2.5366x over previous
//
#include <hip/hip_runtime.h>
#include <hip/hip_bf16.h>
#include <cstdint>

#define D_STATE 16
#define D_INNER 2048
#define DT_RANK 64
#define SEQ 2048
#define BL 4096      // B * L
#define NCHUNK 8
#define CHUNK 256    // SEQ / NCHUNK

typedef short bf16x8 __attribute__((ext_vector_type(8)));
typedef float f32x4 __attribute__((ext_vector_type(4)));

__device__ __forceinline__ float siluf(float x) { return x / (1.f + expf(-x)); }

__device__ __forceinline__ void gload_lds16(const void* g, void* l) {
  __builtin_amdgcn_global_load_lds((const __attribute__((address_space(1))) unsigned int*)g,
                                   (__attribute__((address_space(3))) unsigned int*)l,
                                   16, 0, 0);
}

// ---------------- fp32 -> bf16 conversion (n multiple of 1024) ----------------
__global__ __launch_bounds__(256) void f2bf_kernel(const float* __restrict__ in,
                                                   __hip_bfloat16* __restrict__ out) {
  const int i = (blockIdx.x * 256 + threadIdx.x) * 4;
  float4 v = *reinterpret_cast<const float4*>(&in[i]);
  out[i + 0] = __float2bfloat16(v.x);
  out[i + 1] = __float2bfloat16(v.y);
  out[i + 2] = __float2bfloat16(v.z);
  out[i + 3] = __float2bfloat16(v.w);
}

// ---------------- MFMA bf16 GEMM: C[M,N] = A[M,K] * B[N,K]^T ----------------
// 128x128 tile, 4 waves (2x2), BK=32, mfma_f32_16x16x32_bf16.
// M,N multiples of 128; K multiple of 32. lda/ldb/ldc in elements.
template <typename OutT>
__global__ __launch_bounds__(256) void gemm_bt_bf16(const __hip_bfloat16* __restrict__ A,
                                                    const __hip_bfloat16* __restrict__ B,
                                                    OutT* __restrict__ C,
                                                    int M, int N, int K,
                                                    int lda, int ldb, int ldc) {
  __shared__ __align__(16) unsigned short Alds[128 * 32];
  __shared__ __align__(16) unsigned short Blds[128 * 32];
  const int tid = threadIdx.x;
  const int wv = tid >> 6, lane = tid & 63;
  const int wr = wv >> 1, wc = wv & 1;          // wave grid 2x2, each wave 64x64 out
  const int m0 = blockIdx.y * 128, n0 = blockIdx.x * 128;
  const int sr = tid >> 2;                      // staging row 0..63
  const int sk = (tid & 3) * 8;                 // staging k-col (bf16 elems)
  const int frow = lane & 15;                   // fragment row/col within 16
  const int fk = (lane >> 4) * 8;               // fragment k offset

  f32x4 acc[4][4];
#pragma unroll
  for (int i = 0; i < 4; ++i)
#pragma unroll
    for (int j = 0; j < 4; ++j) acc[i][j] = {0.f, 0.f, 0.f, 0.f};

  const unsigned short* Ag = (const unsigned short*)A;
  const unsigned short* Bg = (const unsigned short*)B;

  for (int k0 = 0; k0 < K; k0 += 32) {
    // stage A[128][32] and B[128][32] into LDS (linear, global_load_lds x16B)
    gload_lds16(&Ag[(size_t)(m0 + sr) * lda + k0 + sk],       &Alds[wv * 512]);
    gload_lds16(&Ag[(size_t)(m0 + sr + 64) * lda + k0 + sk],  &Alds[2048 + wv * 512]);
    gload_lds16(&Bg[(size_t)(n0 + sr) * ldb + k0 + sk],       &Blds[wv * 512]);
    gload_lds16(&Bg[(size_t)(n0 + sr + 64) * ldb + k0 + sk],  &Blds[2048 + wv * 512]);
    __syncthreads();   // compiler drains vmcnt before barrier

    bf16x8 af[4], bfr[4];
#pragma unroll
    for (int mi = 0; mi < 4; ++mi)
      af[mi] = *reinterpret_cast<const bf16x8*>(&Alds[(wr * 64 + mi * 16 + frow) * 32 + fk]);
#pragma unroll
    for (int ni = 0; ni < 4; ++ni)
      bfr[ni] = *reinterpret_cast<const bf16x8*>(&Blds[(wc * 64 + ni * 16 + frow) * 32 + fk]);
#pragma unroll
    for (int mi = 0; mi < 4; ++mi)
#pragma unroll
      for (int ni = 0; ni < 4; ++ni)
        acc[mi][ni] = __builtin_amdgcn_mfma_f32_16x16x32_bf16(af[mi], bfr[ni], acc[mi][ni], 0, 0, 0);
    __syncthreads();
  }

  // C/D layout (m89-verified): col = lane&15, row = (lane>>4)*4 + reg
  const int crow = (lane >> 4) * 4;
  const int ccol = lane & 15;
#pragma unroll
  for (int mi = 0; mi < 4; ++mi)
#pragma unroll
    for (int ni = 0; ni < 4; ++ni) {
      const int gcol = n0 + wc * 64 + ni * 16 + ccol;
#pragma unroll
      for (int j = 0; j < 4; ++j) {
        const int grow = m0 + wr * 64 + mi * 16 + crow + j;
        if constexpr (sizeof(OutT) == 2) {
          C[(size_t)grow * ldc + gcol] = __float2bfloat16(acc[mi][ni][j]);
        } else {
          C[(size_t)grow * ldc + gcol] = acc[mi][ni][j];
        }
      }
    }
}

// ---------------- Guarded fp32 GEMM: 64x64 tile (small projections) ----------------
__global__ __launch_bounds__(256) void gemm64g(const float* __restrict__ A,
                                               const float* __restrict__ B,
                                               float* __restrict__ C,
                                               int M, int N, int K,
                                               int lda, int ldb, int ldc) {
  __shared__ __align__(16) float As[16][64];
  __shared__ __align__(16) float Bs[16][64];
  const int tid = threadIdx.x;
  const int tx = tid & 15, ty = tid >> 4;
  const int m0 = blockIdx.y * 64, n0 = blockIdx.x * 64;
  const int lrow = tid >> 2;
  const int lc4  = (tid & 3) * 4;

  float acc[4][4];
#pragma unroll
  for (int i = 0; i < 4; ++i)
#pragma unroll
    for (int j = 0; j < 4; ++j) acc[i][j] = 0.f;

  for (int k0 = 0; k0 < K; k0 += 16) {
    __syncthreads();
    {
      float4 av = make_float4(0.f, 0.f, 0.f, 0.f);
      if (m0 + lrow < M)
        av = *reinterpret_cast<const float4*>(&A[(size_t)(m0 + lrow) * lda + k0 + lc4]);
      As[lc4 + 0][lrow] = av.x; As[lc4 + 1][lrow] = av.y;
      As[lc4 + 2][lrow] = av.z; As[lc4 + 3][lrow] = av.w;
      float4 bv = make_float4(0.f, 0.f, 0.f, 0.f);
      if (n0 + lrow < N)
        bv = *reinterpret_cast<const float4*>(&B[(size_t)(n0 + lrow) * ldb + k0 + lc4]);
      Bs[lc4 + 0][lrow] = bv.x; Bs[lc4 + 1][lrow] = bv.y;
      Bs[lc4 + 2][lrow] = bv.z; Bs[lc4 + 3][lrow] = bv.w;
    }
    __syncthreads();
#pragma unroll
    for (int kk = 0; kk < 16; ++kk) {
      float4 a = *reinterpret_cast<const float4*>(&As[kk][ty * 4]);
      float4 b = *reinterpret_cast<const float4*>(&Bs[kk][tx * 4]);
      float av[4] = {a.x, a.y, a.z, a.w};
      float bv[4] = {b.x, b.y, b.z, b.w};
#pragma unroll
      for (int i = 0; i < 4; ++i)
#pragma unroll
        for (int j = 0; j < 4; ++j) acc[i][j] = fmaf(av[i], bv[j], acc[i][j]);
    }
  }

#pragma unroll
  for (int i = 0; i < 4; ++i) {
    int m = m0 + ty * 4 + i;
    if (m >= M) continue;
#pragma unroll
    for (int j = 0; j < 4; ++j) {
      int n = n0 + tx * 4 + j;
      if (n < N) C[(size_t)m * ldc + n] = acc[i][j];
    }
  }
}

// ---------------- depthwise causal conv1d (w=4) + bias + silu; bf16 in, fp32 out ----
__global__ __launch_bounds__(256) void conv_silu_kernel(const __hip_bfloat16* __restrict__ xz_bf,
                                                        const float* __restrict__ conv_w,
                                                        const float* __restrict__ conv_b,
                                                        float* __restrict__ x_act) {
  const int idx = blockIdx.x * 256 + threadIdx.x;   // over BL * D_INNER
  const int d = idx & (D_INNER - 1);
  const int bl = idx >> 11;
  const int l = bl & (SEQ - 1);
  float acc = conv_b[d];
#pragma unroll
  for (int k = 0; k < 4; ++k) {
    const int ll = l + k - 3;
    if (ll >= 0)
      acc = fmaf(__bfloat162float(xz_bf[(size_t)(bl + k - 3) * 4096 + d]), conv_w[d * 4 + k], acc);
  }
  x_act[idx] = siluf(acc);
}

// ---------------- delta = softplus(delta_raw + dt_proj_b), dense [BL][2048] ----------
__global__ __launch_bounds__(256) void softplus_bias_kernel(float* delta,
                                                            const float* __restrict__ dt_proj_b) {
  const int idx = blockIdx.x * 256 + threadIdx.x;
  const int d = idx & (D_INNER - 1);
  const float v = delta[idx] + dt_proj_b[d];
  delta[idx] = fmaxf(v, 0.f) + log1pf(expf(-fabsf(v)));
}

// ---------------- scan pass 1: per-chunk (prod dA, h_end) with h0=0 ----------------
// thread t -> (b, chunk, d, n): n=t&15, d=(t>>4)&2047, c=(t>>15)&7, b=t>>18
__global__ __launch_bounds__(256) void scan_pass1(const float* __restrict__ delta,
                                                  const float* __restrict__ x_act,
                                                  const float* __restrict__ x_dbl,
                                                  const float* __restrict__ A_log,
                                                  float* __restrict__ chunkA,
                                                  float* __restrict__ chunkH) {
  const int t = blockIdx.x * 256 + threadIdx.x;
  const int n = t & 15;
  const int d = (t >> 4) & (D_INNER - 1);
  const int c = (t >> 15) & (NCHUNK - 1);
  const int b = t >> 18;
  const float Aval = -expf(A_log[d * D_STATE + n]);
  const int l0 = c * CHUNK;

  const float* dp = delta + ((size_t)(b * SEQ + l0)) * D_INNER + d;
  const float* up = x_act + ((size_t)(b * SEQ + l0)) * D_INNER + d;
  const float* xb = x_dbl + ((size_t)(b * SEQ + l0)) * 96 + DT_RANK + n;

  float h = 0.f, aP = 1.f;
  float dv = dp[0], uv = up[0], Bv = xb[0];
  for (int l = 0; l < CHUNK; ++l) {
    float dv2 = 0.f, uv2 = 0.f, Bv2 = 0.f;
    if (l + 1 < CHUNK) {
      dv2 = dp[(size_t)(l + 1) * D_INNER];
      uv2 = up[(size_t)(l + 1) * D_INNER];
      Bv2 = xb[(size_t)(l + 1) * 96];
    }
    const float dA = expf(dv * Aval);
    h = fmaf(dA, h, dv * uv * Bv);
    aP *= dA;
    dv = dv2; uv = uv2; Bv = Bv2;
  }
  chunkA[t] = aP;
  chunkH[t] = h;
}

// ---------------- scan pass 2: combine chunk prefixes (h0 per chunk) ----------------
// chunkH0 aliases chunkA (read-then-overwrite same slot is safe within a thread).
__global__ __launch_bounds__(256) void scan_pass2(const float* __restrict__ chunkH,
                                                  float* chunkAH0) {
  const int s = blockIdx.x * 256 + threadIdx.x;   // 65536 = (b, d, n)
  const int lo = s & 32767;                        // d*16+n
  const int b = s >> 15;
  float H = 0.f;
  for (int c = 0; c < NCHUNK; ++c) {
    const int idx = (b * NCHUNK + c) * 32768 + lo;
    const float aP = chunkAH0[idx];
    const float hE = chunkH[idx];
    chunkAH0[idx] = H;           // h0 for this chunk
    H = fmaf(aP, H, hE);
  }
}

// ---------------- scan pass 3: rescan with h0, fuse D-skip + silu(z) gate, emit bf16 --
__global__ __launch_bounds__(256) void scan_pass3(const float* __restrict__ delta,
                                                  const float* __restrict__ x_act,
                                                  const float* __restrict__ x_dbl,
                                                  const float* __restrict__ A_log,
                                                  const float* __restrict__ chunkH0,
                                                  const float* __restrict__ D_skip,
                                                  __hip_bfloat16* xz_bf) {
  const int t = blockIdx.x * 256 + threadIdx.x;
  const int n = t & 15;
  const int d = (t >> 4) & (D_INNER - 1);
  const int c = (t >> 15) & (NCHUNK - 1);
  const int b = t >> 18;
  const float Aval = -expf(A_log[d * D_STATE + n]);
  const int l0 = c * CHUNK;

  const float* dp = delta + ((size_t)(b * SEQ + l0)) * D_INNER + d;
  const float* up = x_act + ((size_t)(b * SEQ + l0)) * D_INNER + d;
  const float* xb = x_dbl + ((size_t)(b * SEQ + l0)) * 96 + DT_RANK + n;
  const float* xc = x_dbl + ((size_t)(b * SEQ + l0)) * 96 + DT_RANK + D_STATE + n;
  const float Dv = D_skip[d];

  float h = chunkH0[t];
  float dv = dp[0], uv = up[0], Bv = xb[0], Cv = xc[0];
  for (int l = 0; l < CHUNK; ++l) {
    float dv2 = 0.f, uv2 = 0.f, Bv2 = 0.f, Cv2 = 0.f;
    if (l + 1 < CHUNK) {
      dv2 = dp[(size_t)(l + 1) * D_INNER];
      uv2 = up[(size_t)(l + 1) * D_INNER];
      Bv2 = xb[(size_t)(l + 1) * 96];
      Cv2 = xc[(size_t)(l + 1) * 96];
    }
    const float dA = expf(dv * Aval);
    h = fmaf(dA, h, dv * uv * Bv);
    float p = h * Cv;
    p += __shfl_xor(p, 8);
    p += __shfl_xor(p, 4);
    p += __shfl_xor(p, 2);
    p += __shfl_xor(p, 1);
    if (n == 0) {
      const size_t bl = (size_t)(b * SEQ + l0 + l);
      const float zv = __bfloat162float(xz_bf[bl * 4096 + D_INNER + d]);
      const float yv = (p + uv * Dv) * siluf(zv);
      xz_bf[bl * 4096 + d] = __float2bfloat16(yv);   // y_bf over dead x_in half
    }
    dv = dv2; uv = uv2; Bv = Bv2; Cv = Cv2;
  }
}

extern "C" void kernel_launch(void* const* d_in, const int* in_sizes, int n_in,
                              void* d_out, int out_size, void* d_ws, size_t ws_size,
                              hipStream_t stream) {
  const float* x          = (const float*)d_in[0];
  const float* in_proj_w  = (const float*)d_in[1];
  const float* conv_w     = (const float*)d_in[2];
  const float* conv_b     = (const float*)d_in[3];
  const float* x_proj_w   = (const float*)d_in[4];
  const float* dt_proj_w  = (const float*)d_in[5];
  const float* dt_proj_b  = (const float*)d_in[6];
  const float* A_log      = (const float*)d_in[7];
  const float* D_skip     = (const float*)d_in[8];
  const float* out_proj_w = (const float*)d_in[9];
  float* out = (float*)d_out;   // fp32 output

  // Workspace layout (peak 106,430,464 B):
  //   xz_bf   @0          33,554,432  bf16 [4096][4096]; cols 0..2047 x_in -> y_bf, cols 2048..4095 z
  //   x_act   @33554432   33,554,432  fp32 [4096][2048]
  //   delta   @67108864   33,554,432  fp32 [4096][2048]
  //     (before delta live: x_bf @67108864 8MB, inw_bf @75497472 8MB;
  //      after delta dead:  outw_bf @67108864 4MB)
  //   x_dbl   @100663296   1,572,864  fp32 [4096][96]
  //   chunkA/H0 @102236160 2,097,152
  //   chunkH  @104333312   2,097,152
  char* ws = (char*)d_ws;
  __hip_bfloat16* xz_bf  = (__hip_bfloat16*)(ws);
  float* x_act           = (float*)(ws + 33554432);
  float* delta           = (float*)(ws + 67108864);
  __hip_bfloat16* x_bf   = (__hip_bfloat16*)(ws + 67108864);
  __hip_bfloat16* inw_bf = (__hip_bfloat16*)(ws + 75497472);
  __hip_bfloat16* outw_bf= (__hip_bfloat16*)(ws + 67108864);
  float* x_dbl           = (float*)(ws + 100663296);
  float* chunkAH0        = (float*)(ws + 102236160);
  float* chunkH          = (float*)(ws + 104333312);

  // 1-2. bf16 conversions for in_proj operands
  f2bf_kernel<<<4096, 256, 0, stream>>>(x, x_bf);            // 4096x1024
  f2bf_kernel<<<4096, 256, 0, stream>>>(in_proj_w, inw_bf);  // 4096x1024

  // 3. xz = x @ in_proj_w^T  (M=4096, N=4096, K=1024), bf16 out
  gemm_bt_bf16<__hip_bfloat16><<<dim3(32, 32), 256, 0, stream>>>(
      x_bf, inw_bf, xz_bf, BL, 4096, 1024, 1024, 1024, 4096);

  // 4. depthwise causal conv + bias + silu -> x_act (fp32)
  conv_silu_kernel<<<(BL * D_INNER) / 256, 256, 0, stream>>>(xz_bf, conv_w, conv_b, x_act);

  // 5. x_dbl = x_act @ x_proj_w^T  (4096 x 96, K=2048)
  gemm64g<<<dim3(2, 64), 256, 0, stream>>>(x_act, x_proj_w, x_dbl, BL, 96, 2048,
                                           2048, 2048, 96);

  // 6. delta_raw = dt_low @ dt_proj_w^T  (4096 x 2048, K=64)
  gemm64g<<<dim3(32, 64), 256, 0, stream>>>(x_dbl, dt_proj_w, delta, BL, 2048, 64,
                                            96, 64, 2048);

  // 7. delta = softplus(delta_raw + dt_proj_b)
  softplus_bias_kernel<<<(BL * D_INNER) / 256, 256, 0, stream>>>(delta, dt_proj_b);

  // 8-10. chunked selective scan (+fused gate, bf16 y into xz cols 0..2047)
  scan_pass1<<<2048, 256, 0, stream>>>(delta, x_act, x_dbl, A_log, chunkAH0, chunkH);
  scan_pass2<<<256, 256, 0, stream>>>(chunkH, chunkAH0);
  scan_pass3<<<2048, 256, 0, stream>>>(delta, x_act, x_dbl, A_log, chunkAH0, D_skip, xz_bf);

  // 11. out_proj weights -> bf16 (delta region is dead now)
  f2bf_kernel<<<2048, 256, 0, stream>>>(out_proj_w, outw_bf); // 1024x2048

  // 12. out = y @ out_proj_w^T  (M=4096, N=1024, K=2048), fp32 out
  gemm_bt_bf16<float><<<dim3(8, 32), 256, 0, stream>>>(
      xz_bf, outw_bf, out, BL, 1024, 2048, 4096, 2048, 1024);
}

// Round 6
// 593.858 us; speedup vs baseline: 2.7844x; 1.0977x over previous
//
#include <hip/hip_runtime.h>
#include <hip/hip_bf16.h>
#include <cstdint>

#define D_STATE 16
#define D_INNER 2048
#define DT_RANK 64
#define SEQ 2048
#define BL 4096      // B * L
#define NCHUNK 8
#define CHUNK 256    // SEQ / NCHUNK

typedef short bf16x8 __attribute__((ext_vector_type(8)));
typedef float f32x4 __attribute__((ext_vector_type(4)));

__device__ __forceinline__ float siluf(float x) {
  return __fdividef(x, 1.f + __expf(-x));
}

// xor-butterfly add over 16-lane groups via ds_swizzle (imm pattern via template const)
template <int PAT>
__device__ __forceinline__ float swzadd(float p) {
  return p + __int_as_float(__builtin_amdgcn_ds_swizzle(__float_as_int(p), PAT));
}

__device__ __forceinline__ void gload_lds16(const void* g, void* l) {
  __builtin_amdgcn_global_load_lds((const __attribute__((address_space(1))) unsigned int*)g,
                                   (__attribute__((address_space(3))) unsigned int*)l,
                                   16, 0, 0);
}

// ---------------- fp32 -> bf16 conversion (n multiple of 1024) ----------------
__global__ __launch_bounds__(256) void f2bf_kernel(const float* __restrict__ in,
                                                   __hip_bfloat16* __restrict__ out) {
  const int i = (blockIdx.x * 256 + threadIdx.x) * 4;
  float4 v = *reinterpret_cast<const float4*>(&in[i]);
  out[i + 0] = __float2bfloat16(v.x);
  out[i + 1] = __float2bfloat16(v.y);
  out[i + 2] = __float2bfloat16(v.z);
  out[i + 3] = __float2bfloat16(v.w);
}

// ---------------- MFMA bf16 GEMM: C[M,N] = A[M,K] * B[N,K]^T ----------------
// 128x128 tile, 4 waves (2x2), BK=32, mfma_f32_16x16x32_bf16.
// M,N multiples of 128; K multiple of 32. lda/ldb/ldc in elements.
template <typename OutT>
__global__ __launch_bounds__(256) void gemm_bt_bf16(const __hip_bfloat16* __restrict__ A,
                                                    const __hip_bfloat16* __restrict__ B,
                                                    OutT* __restrict__ C,
                                                    int M, int N, int K,
                                                    int lda, int ldb, int ldc) {
  __shared__ __align__(16) unsigned short Alds[128 * 32];
  __shared__ __align__(16) unsigned short Blds[128 * 32];
  const int tid = threadIdx.x;
  const int wv = tid >> 6, lane = tid & 63;
  const int wr = wv >> 1, wc = wv & 1;          // wave grid 2x2, each wave 64x64 out
  const int m0 = blockIdx.y * 128, n0 = blockIdx.x * 128;
  const int sr = tid >> 2;                      // staging row 0..63
  const int sk = (tid & 3) * 8;                 // staging k-col (bf16 elems)
  const int frow = lane & 15;                   // fragment row/col within 16
  const int fk = (lane >> 4) * 8;               // fragment k offset

  f32x4 acc[4][4];
#pragma unroll
  for (int i = 0; i < 4; ++i)
#pragma unroll
    for (int j = 0; j < 4; ++j) acc[i][j] = {0.f, 0.f, 0.f, 0.f};

  const unsigned short* Ag = (const unsigned short*)A;
  const unsigned short* Bg = (const unsigned short*)B;

  for (int k0 = 0; k0 < K; k0 += 32) {
    // stage A[128][32] and B[128][32] into LDS (linear, global_load_lds x16B)
    gload_lds16(&Ag[(size_t)(m0 + sr) * lda + k0 + sk],       &Alds[wv * 512]);
    gload_lds16(&Ag[(size_t)(m0 + sr + 64) * lda + k0 + sk],  &Alds[2048 + wv * 512]);
    gload_lds16(&Bg[(size_t)(n0 + sr) * ldb + k0 + sk],       &Blds[wv * 512]);
    gload_lds16(&Bg[(size_t)(n0 + sr + 64) * ldb + k0 + sk],  &Blds[2048 + wv * 512]);
    __syncthreads();   // compiler drains vmcnt before barrier

    bf16x8 af[4], bfr[4];
#pragma unroll
    for (int mi = 0; mi < 4; ++mi)
      af[mi] = *reinterpret_cast<const bf16x8*>(&Alds[(wr * 64 + mi * 16 + frow) * 32 + fk]);
#pragma unroll
    for (int ni = 0; ni < 4; ++ni)
      bfr[ni] = *reinterpret_cast<const bf16x8*>(&Blds[(wc * 64 + ni * 16 + frow) * 32 + fk]);
#pragma unroll
    for (int mi = 0; mi < 4; ++mi)
#pragma unroll
      for (int ni = 0; ni < 4; ++ni)
        acc[mi][ni] = __builtin_amdgcn_mfma_f32_16x16x32_bf16(af[mi], bfr[ni], acc[mi][ni], 0, 0, 0);
    __syncthreads();
  }

  // C/D layout (m89-verified): col = lane&15, row = (lane>>4)*4 + reg
  const int crow = (lane >> 4) * 4;
  const int ccol = lane & 15;
#pragma unroll
  for (int mi = 0; mi < 4; ++mi)
#pragma unroll
    for (int ni = 0; ni < 4; ++ni) {
      const int gcol = n0 + wc * 64 + ni * 16 + ccol;
#pragma unroll
      for (int j = 0; j < 4; ++j) {
        const int grow = m0 + wr * 64 + mi * 16 + crow + j;
        if constexpr (sizeof(OutT) == 2) {
          C[(size_t)grow * ldc + gcol] = __float2bfloat16(acc[mi][ni][j]);
        } else {
          C[(size_t)grow * ldc + gcol] = acc[mi][ni][j];
        }
      }
    }
}

// ---------------- Guarded fp32 GEMM: 64x64 tile (small projections) ----------------
__global__ __launch_bounds__(256) void gemm64g(const float* __restrict__ A,
                                               const float* __restrict__ B,
                                               float* __restrict__ C,
                                               int M, int N, int K,
                                               int lda, int ldb, int ldc) {
  __shared__ __align__(16) float As[16][64];
  __shared__ __align__(16) float Bs[16][64];
  const int tid = threadIdx.x;
  const int tx = tid & 15, ty = tid >> 4;
  const int m0 = blockIdx.y * 64, n0 = blockIdx.x * 64;
  const int lrow = tid >> 2;
  const int lc4  = (tid & 3) * 4;

  float acc[4][4];
#pragma unroll
  for (int i = 0; i < 4; ++i)
#pragma unroll
    for (int j = 0; j < 4; ++j) acc[i][j] = 0.f;

  for (int k0 = 0; k0 < K; k0 += 16) {
    __syncthreads();
    {
      float4 av = make_float4(0.f, 0.f, 0.f, 0.f);
      if (m0 + lrow < M)
        av = *reinterpret_cast<const float4*>(&A[(size_t)(m0 + lrow) * lda + k0 + lc4]);
      As[lc4 + 0][lrow] = av.x; As[lc4 + 1][lrow] = av.y;
      As[lc4 + 2][lrow] = av.z; As[lc4 + 3][lrow] = av.w;
      float4 bv = make_float4(0.f, 0.f, 0.f, 0.f);
      if (n0 + lrow < N)
        bv = *reinterpret_cast<const float4*>(&B[(size_t)(n0 + lrow) * ldb + k0 + lc4]);
      Bs[lc4 + 0][lrow] = bv.x; Bs[lc4 + 1][lrow] = bv.y;
      Bs[lc4 + 2][lrow] = bv.z; Bs[lc4 + 3][lrow] = bv.w;
    }
    __syncthreads();
#pragma unroll
    for (int kk = 0; kk < 16; ++kk) {
      float4 a = *reinterpret_cast<const float4*>(&As[kk][ty * 4]);
      float4 b = *reinterpret_cast<const float4*>(&Bs[kk][tx * 4]);
      float av[4] = {a.x, a.y, a.z, a.w};
      float bv[4] = {b.x, b.y, b.z, b.w};
#pragma unroll
      for (int i = 0; i < 4; ++i)
#pragma unroll
        for (int j = 0; j < 4; ++j) acc[i][j] = fmaf(av[i], bv[j], acc[i][j]);
    }
  }

#pragma unroll
  for (int i = 0; i < 4; ++i) {
    int m = m0 + ty * 4 + i;
    if (m >= M) continue;
#pragma unroll
    for (int j = 0; j < 4; ++j) {
      int n = n0 + tx * 4 + j;
      if (n < N) C[(size_t)m * ldc + n] = acc[i][j];
    }
  }
}

// ---------------- depthwise causal conv1d (w=4) + bias + silu; bf16 in, fp32 out ----
__global__ __launch_bounds__(256) void conv_silu_kernel(const __hip_bfloat16* __restrict__ xz_bf,
                                                        const float* __restrict__ conv_w,
                                                        const float* __restrict__ conv_b,
                                                        float* __restrict__ x_act) {
  const int idx = blockIdx.x * 256 + threadIdx.x;   // over BL * D_INNER
  const int d = idx & (D_INNER - 1);
  const int bl = idx >> 11;
  const int l = bl & (SEQ - 1);
  float acc = conv_b[d];
#pragma unroll
  for (int k = 0; k < 4; ++k) {
    const int ll = l + k - 3;
    if (ll >= 0)
      acc = fmaf(__bfloat162float(xz_bf[(size_t)(bl + k - 3) * 4096 + d]), conv_w[d * 4 + k], acc);
  }
  x_act[idx] = siluf(acc);
}

// ---------------- delta = softplus(delta_raw + dt_proj_b), dense [BL][2048] ----------
__global__ __launch_bounds__(256) void softplus_bias_kernel(float* delta,
                                                            const float* __restrict__ dt_proj_b) {
  const int idx = blockIdx.x * 256 + threadIdx.x;
  const int d = idx & (D_INNER - 1);
  const float v = delta[idx] + dt_proj_b[d];
  delta[idx] = fmaxf(v, 0.f) + __logf(1.f + __expf(-fabsf(v)));
}

// ---------------- scan pass 1: per-chunk (prod dA, h_end) with h0=0 ----------------
// thread t -> (b, chunk, d, n): n=t&15, d=(t>>4)&2047, c=(t>>15)&7, b=t>>18
__global__ __launch_bounds__(256) void scan_pass1(const float* __restrict__ delta,
                                                  const float* __restrict__ x_act,
                                                  const float* __restrict__ x_dbl,
                                                  const float* __restrict__ A_log,
                                                  float* __restrict__ chunkA,
                                                  float* __restrict__ chunkH) {
  const int t = blockIdx.x * 256 + threadIdx.x;
  const int n = t & 15;
  const int d = (t >> 4) & (D_INNER - 1);
  const int c = (t >> 15) & (NCHUNK - 1);
  const int b = t >> 18;
  const float Aval = -expf(A_log[d * D_STATE + n]);
  const int base = b * SEQ + c * CHUNK;

  const float* dp = delta + (size_t)base * D_INNER + d;
  const float* up = x_act + (size_t)base * D_INNER + d;
  const float* xb = x_dbl + (size_t)base * 96 + DT_RANK + n;

  float h = 0.f, aP = 1.f;
  for (int l = 0; l < CHUNK; ++l) {
    const float dv = *dp; dp += D_INNER;
    const float uv = *up; up += D_INNER;
    const float Bv = *xb; xb += 96;
    const float dA = __expf(dv * Aval);
    aP *= dA;
    h = fmaf(dA, h, dv * uv * Bv);
  }
  chunkA[t] = aP;
  chunkH[t] = h;
}

// ---------------- scan pass 2: combine chunk prefixes (h0 per chunk) ----------------
// chunkAH0 aliases chunkA (read-then-overwrite same slot is safe within a thread).
__global__ __launch_bounds__(256) void scan_pass2(const float* __restrict__ chunkH,
                                                  float* chunkAH0) {
  const int s = blockIdx.x * 256 + threadIdx.x;   // 65536 = (b, d, n)
  const int lo = s & 32767;                        // d*16+n
  const int b = s >> 15;
  float H = 0.f;
  for (int c = 0; c < NCHUNK; ++c) {
    const int idx = (b * NCHUNK + c) * 32768 + lo;
    const float aP = chunkAH0[idx];
    const float hE = chunkH[idx];
    chunkAH0[idx] = H;           // h0 for this chunk
    H = fmaf(aP, H, hE);
  }
}

// ---------------- scan pass 3: rescan with h0, fuse D-skip + silu(z) gate, emit bf16 --
__global__ __launch_bounds__(256) void scan_pass3(const float* __restrict__ delta,
                                                  const float* __restrict__ x_act,
                                                  const float* __restrict__ x_dbl,
                                                  const float* __restrict__ A_log,
                                                  const float* __restrict__ chunkH0,
                                                  const float* __restrict__ D_skip,
                                                  __hip_bfloat16* xz_bf) {
  const int t = blockIdx.x * 256 + threadIdx.x;
  const int n = t & 15;
  const int d = (t >> 4) & (D_INNER - 1);
  const int c = (t >> 15) & (NCHUNK - 1);
  const int b = t >> 18;
  const float Aval = -expf(A_log[d * D_STATE + n]);
  const int base = b * SEQ + c * CHUNK;

  const float* dp = delta + (size_t)base * D_INNER + d;
  const float* up = x_act + (size_t)base * D_INNER + d;
  const float* xb = x_dbl + (size_t)base * 96 + DT_RANK + n;     // B at [0], C at [16]
  __hip_bfloat16* zp = xz_bf + (size_t)base * 4096 + D_INNER + d; // z load; y store at zp[-2048]
  const float Dv = D_skip[d];

  float h = chunkH0[t];
  for (int l = 0; l < CHUNK; ++l) {
    const float dv = *dp; dp += D_INNER;
    const float uv = *up; up += D_INNER;
    const float Bv = xb[0];
    const float Cv = xb[16]; xb += 96;
    const float dA = __expf(dv * Aval);
    h = fmaf(dA, h, dv * uv * Bv);
    float p = h * Cv;
    // 16-lane group sum: xor 1,2,4,8 butterflies on the DS pipe
    p = swzadd<0x041F>(p);
    p = swzadd<0x081F>(p);
    p = swzadd<0x101F>(p);
    p = swzadd<0x201F>(p);
    if (n == 0) {
      const float zv = __bfloat162float(zp[0]);
      const float yv = (p + uv * Dv) * siluf(zv);
      zp[-(int)D_INNER] = __float2bfloat16(yv);   // y_bf over dead x_in half
    }
    zp += 4096;
  }
}

extern "C" void kernel_launch(void* const* d_in, const int* in_sizes, int n_in,
                              void* d_out, int out_size, void* d_ws, size_t ws_size,
                              hipStream_t stream) {
  const float* x          = (const float*)d_in[0];
  const float* in_proj_w  = (const float*)d_in[1];
  const float* conv_w     = (const float*)d_in[2];
  const float* conv_b     = (const float*)d_in[3];
  const float* x_proj_w   = (const float*)d_in[4];
  const float* dt_proj_w  = (const float*)d_in[5];
  const float* dt_proj_b  = (const float*)d_in[6];
  const float* A_log      = (const float*)d_in[7];
  const float* D_skip     = (const float*)d_in[8];
  const float* out_proj_w = (const float*)d_in[9];
  float* out = (float*)d_out;   // fp32 output

  // Workspace layout (peak 106,430,464 B):
  //   xz_bf   @0          33,554,432  bf16 [4096][4096]; cols 0..2047 x_in -> y_bf, cols 2048..4095 z
  //   x_act   @33554432   33,554,432  fp32 [4096][2048]
  //   delta   @67108864   33,554,432  fp32 [4096][2048]
  //     (before delta live: x_bf @67108864 8MB, inw_bf @75497472 8MB;
  //      after delta dead:  outw_bf @67108864 4MB)
  //   x_dbl   @100663296   1,572,864  fp32 [4096][96]
  //   chunkA/H0 @102236160 2,097,152
  //   chunkH  @104333312   2,097,152
  char* ws = (char*)d_ws;
  __hip_bfloat16* xz_bf  = (__hip_bfloat16*)(ws);
  float* x_act           = (float*)(ws + 33554432);
  float* delta           = (float*)(ws + 67108864);
  __hip_bfloat16* x_bf   = (__hip_bfloat16*)(ws + 67108864);
  __hip_bfloat16* inw_bf = (__hip_bfloat16*)(ws + 75497472);
  __hip_bfloat16* outw_bf= (__hip_bfloat16*)(ws + 67108864);
  float* x_dbl           = (float*)(ws + 100663296);
  float* chunkAH0        = (float*)(ws + 102236160);
  float* chunkH          = (float*)(ws + 104333312);

  // 1-2. bf16 conversions for in_proj operands
  f2bf_kernel<<<4096, 256, 0, stream>>>(x, x_bf);            // 4096x1024
  f2bf_kernel<<<4096, 256, 0, stream>>>(in_proj_w, inw_bf);  // 4096x1024

  // 3. xz = x @ in_proj_w^T  (M=4096, N=4096, K=1024), bf16 out
  gemm_bt_bf16<__hip_bfloat16><<<dim3(32, 32), 256, 0, stream>>>(
      x_bf, inw_bf, xz_bf, BL, 4096, 1024, 1024, 1024, 4096);

  // 4. depthwise causal conv + bias + silu -> x_act (fp32)
  conv_silu_kernel<<<(BL * D_INNER) / 256, 256, 0, stream>>>(xz_bf, conv_w, conv_b, x_act);

  // 5. x_dbl = x_act @ x_proj_w^T  (4096 x 96, K=2048)
  gemm64g<<<dim3(2, 64), 256, 0, stream>>>(x_act, x_proj_w, x_dbl, BL, 96, 2048,
                                           2048, 2048, 96);

  // 6. delta_raw = dt_low @ dt_proj_w^T  (4096 x 2048, K=64)
  gemm64g<<<dim3(32, 64), 256, 0, stream>>>(x_dbl, dt_proj_w, delta, BL, 2048, 64,
                                            96, 64, 2048);

  // 7. delta = softplus(delta_raw + dt_proj_b)
  softplus_bias_kernel<<<(BL * D_INNER) / 256, 256, 0, stream>>>(delta, dt_proj_b);

  // 8-10. chunked selective scan (+fused gate, bf16 y into xz cols 0..2047)
  scan_pass1<<<2048, 256, 0, stream>>>(delta, x_act, x_dbl, A_log, chunkAH0, chunkH);
  scan_pass2<<<256, 256, 0, stream>>>(chunkH, chunkAH0);
  scan_pass3<<<2048, 256, 0, stream>>>(delta, x_act, x_dbl, A_log, chunkAH0, D_skip, xz_bf);

  // 11. out_proj weights -> bf16 (delta region is dead now)
  f2bf_kernel<<<2048, 256, 0, stream>>>(out_proj_w, outw_bf); // 1024x2048

  // 12. out = y @ out_proj_w^T  (M=4096, N=1024, K=2048), fp32 out
  gemm_bt_bf16<float><<<dim3(8, 32), 256, 0, stream>>>(
      xz_bf, outw_bf, out, BL, 1024, 2048, 4096, 2048, 1024);
}

// Round 7
// 466.555 us; speedup vs baseline: 3.5442x; 1.2729x over previous
//
#include <hip/hip_runtime.h>
#include <hip/hip_bf16.h>
#include <cstdint>

#define D_STATE 16
#define D_INNER 2048
#define DT_RANK 64
#define SEQ 2048
#define BL 4096      // B * L
#define NCHUNK 8
#define CHUNK 256    // SEQ / NCHUNK

typedef short bf16x8 __attribute__((ext_vector_type(8)));
typedef float f32x4 __attribute__((ext_vector_type(4)));

__device__ __forceinline__ float siluf(float x) {
  return __fdividef(x, 1.f + __expf(-x));
}

// DPP-based add: p += p[lane mapped by CTRL]; stays on the VALU, no DS pipe, no waits.
template <int CTRL>
__device__ __forceinline__ float dppadd(float p) {
  int t = __builtin_amdgcn_update_dpp(0, __float_as_int(p), CTRL, 0xF, 0xF, true);
  return p + __int_as_float(t);
}

// 16-lane-group allreduce sum: quad xor1, quad xor2, half_mirror (i^7), row_mirror (i^15).
// After the two quad stages lanes are quad-uniform, so the mirrors combine 4->8->16.
__device__ __forceinline__ float group16_sum(float p) {
  p = dppadd<0x0B1>(p);   // quad_perm [1,0,3,2]
  p = dppadd<0x04E>(p);   // quad_perm [2,3,0,1]
  p = dppadd<0x141>(p);   // row_half_mirror
  p = dppadd<0x140>(p);   // row_mirror
  return p;
}

__device__ __forceinline__ void gload_lds16(const void* g, void* l) {
  __builtin_amdgcn_global_load_lds((const __attribute__((address_space(1))) unsigned int*)g,
                                   (__attribute__((address_space(3))) unsigned int*)l,
                                   16, 0, 0);
}

// ---------------- fp32 -> bf16 conversion (n multiple of 1024) ----------------
__global__ __launch_bounds__(256) void f2bf_kernel(const float* __restrict__ in,
                                                   __hip_bfloat16* __restrict__ out) {
  const int i = (blockIdx.x * 256 + threadIdx.x) * 4;
  float4 v = *reinterpret_cast<const float4*>(&in[i]);
  out[i + 0] = __float2bfloat16(v.x);
  out[i + 1] = __float2bfloat16(v.y);
  out[i + 2] = __float2bfloat16(v.z);
  out[i + 3] = __float2bfloat16(v.w);
}

// ---------------- MFMA bf16 GEMM: C[M,N] = A[M,K] * B[N,K]^T ----------------
// 128x128 tile, 4 waves (2x2), BK=32, mfma_f32_16x16x32_bf16.
// M,N multiples of 128; K multiple of 32. lda/ldb/ldc in elements.
template <typename OutT>
__global__ __launch_bounds__(256) void gemm_bt_bf16(const __hip_bfloat16* __restrict__ A,
                                                    const __hip_bfloat16* __restrict__ B,
                                                    OutT* __restrict__ C,
                                                    int M, int N, int K,
                                                    int lda, int ldb, int ldc) {
  __shared__ __align__(16) unsigned short Alds[128 * 32];
  __shared__ __align__(16) unsigned short Blds[128 * 32];
  const int tid = threadIdx.x;
  const int wv = tid >> 6, lane = tid & 63;
  const int wr = wv >> 1, wc = wv & 1;          // wave grid 2x2, each wave 64x64 out
  const int m0 = blockIdx.y * 128, n0 = blockIdx.x * 128;
  const int sr = tid >> 2;                      // staging row 0..63
  const int sk = (tid & 3) * 8;                 // staging k-col (bf16 elems)
  const int frow = lane & 15;                   // fragment row/col within 16
  const int fk = (lane >> 4) * 8;               // fragment k offset

  f32x4 acc[4][4];
#pragma unroll
  for (int i = 0; i < 4; ++i)
#pragma unroll
    for (int j = 0; j < 4; ++j) acc[i][j] = {0.f, 0.f, 0.f, 0.f};

  const unsigned short* Ag = (const unsigned short*)A;
  const unsigned short* Bg = (const unsigned short*)B;

  for (int k0 = 0; k0 < K; k0 += 32) {
    // stage A[128][32] and B[128][32] into LDS (linear, global_load_lds x16B)
    gload_lds16(&Ag[(size_t)(m0 + sr) * lda + k0 + sk],       &Alds[wv * 512]);
    gload_lds16(&Ag[(size_t)(m0 + sr + 64) * lda + k0 + sk],  &Alds[2048 + wv * 512]);
    gload_lds16(&Bg[(size_t)(n0 + sr) * ldb + k0 + sk],       &Blds[wv * 512]);
    gload_lds16(&Bg[(size_t)(n0 + sr + 64) * ldb + k0 + sk],  &Blds[2048 + wv * 512]);
    __syncthreads();   // compiler drains vmcnt before barrier

    bf16x8 af[4], bfr[4];
#pragma unroll
    for (int mi = 0; mi < 4; ++mi)
      af[mi] = *reinterpret_cast<const bf16x8*>(&Alds[(wr * 64 + mi * 16 + frow) * 32 + fk]);
#pragma unroll
    for (int ni = 0; ni < 4; ++ni)
      bfr[ni] = *reinterpret_cast<const bf16x8*>(&Blds[(wc * 64 + ni * 16 + frow) * 32 + fk]);
#pragma unroll
    for (int mi = 0; mi < 4; ++mi)
#pragma unroll
      for (int ni = 0; ni < 4; ++ni)
        acc[mi][ni] = __builtin_amdgcn_mfma_f32_16x16x32_bf16(af[mi], bfr[ni], acc[mi][ni], 0, 0, 0);
    __syncthreads();
  }

  // C/D layout (m89-verified): col = lane&15, row = (lane>>4)*4 + reg
  const int crow = (lane >> 4) * 4;
  const int ccol = lane & 15;
#pragma unroll
  for (int mi = 0; mi < 4; ++mi)
#pragma unroll
    for (int ni = 0; ni < 4; ++ni) {
      const int gcol = n0 + wc * 64 + ni * 16 + ccol;
#pragma unroll
      for (int j = 0; j < 4; ++j) {
        const int grow = m0 + wr * 64 + mi * 16 + crow + j;
        if constexpr (sizeof(OutT) == 2) {
          C[(size_t)grow * ldc + gcol] = __float2bfloat16(acc[mi][ni][j]);
        } else {
          C[(size_t)grow * ldc + gcol] = acc[mi][ni][j];
        }
      }
    }
}

// ---------------- Guarded fp32 GEMM: 64x64 tile (small projections) ----------------
__global__ __launch_bounds__(256) void gemm64g(const float* __restrict__ A,
                                               const float* __restrict__ B,
                                               float* __restrict__ C,
                                               int M, int N, int K,
                                               int lda, int ldb, int ldc) {
  __shared__ __align__(16) float As[16][64];
  __shared__ __align__(16) float Bs[16][64];
  const int tid = threadIdx.x;
  const int tx = tid & 15, ty = tid >> 4;
  const int m0 = blockIdx.y * 64, n0 = blockIdx.x * 64;
  const int lrow = tid >> 2;
  const int lc4  = (tid & 3) * 4;

  float acc[4][4];
#pragma unroll
  for (int i = 0; i < 4; ++i)
#pragma unroll
    for (int j = 0; j < 4; ++j) acc[i][j] = 0.f;

  for (int k0 = 0; k0 < K; k0 += 16) {
    __syncthreads();
    {
      float4 av = make_float4(0.f, 0.f, 0.f, 0.f);
      if (m0 + lrow < M)
        av = *reinterpret_cast<const float4*>(&A[(size_t)(m0 + lrow) * lda + k0 + lc4]);
      As[lc4 + 0][lrow] = av.x; As[lc4 + 1][lrow] = av.y;
      As[lc4 + 2][lrow] = av.z; As[lc4 + 3][lrow] = av.w;
      float4 bv = make_float4(0.f, 0.f, 0.f, 0.f);
      if (n0 + lrow < N)
        bv = *reinterpret_cast<const float4*>(&B[(size_t)(n0 + lrow) * ldb + k0 + lc4]);
      Bs[lc4 + 0][lrow] = bv.x; Bs[lc4 + 1][lrow] = bv.y;
      Bs[lc4 + 2][lrow] = bv.z; Bs[lc4 + 3][lrow] = bv.w;
    }
    __syncthreads();
#pragma unroll
    for (int kk = 0; kk < 16; ++kk) {
      float4 a = *reinterpret_cast<const float4*>(&As[kk][ty * 4]);
      float4 b = *reinterpret_cast<const float4*>(&Bs[kk][tx * 4]);
      float av[4] = {a.x, a.y, a.z, a.w};
      float bv[4] = {b.x, b.y, b.z, b.w};
#pragma unroll
      for (int i = 0; i < 4; ++i)
#pragma unroll
        for (int j = 0; j < 4; ++j) acc[i][j] = fmaf(av[i], bv[j], acc[i][j]);
    }
  }

#pragma unroll
  for (int i = 0; i < 4; ++i) {
    int m = m0 + ty * 4 + i;
    if (m >= M) continue;
#pragma unroll
    for (int j = 0; j < 4; ++j) {
      int n = n0 + tx * 4 + j;
      if (n < N) C[(size_t)m * ldc + n] = acc[i][j];
    }
  }
}

// ---------------- depthwise causal conv1d (w=4) + bias + silu; bf16 in, fp32 out ----
__global__ __launch_bounds__(256) void conv_silu_kernel(const __hip_bfloat16* __restrict__ xz_bf,
                                                        const float* __restrict__ conv_w,
                                                        const float* __restrict__ conv_b,
                                                        float* __restrict__ x_act) {
  const int idx = blockIdx.x * 256 + threadIdx.x;   // over BL * D_INNER
  const int d = idx & (D_INNER - 1);
  const int bl = idx >> 11;
  const int l = bl & (SEQ - 1);
  float acc = conv_b[d];
#pragma unroll
  for (int k = 0; k < 4; ++k) {
    const int ll = l + k - 3;
    if (ll >= 0)
      acc = fmaf(__bfloat162float(xz_bf[(size_t)(bl + k - 3) * 4096 + d]), conv_w[d * 4 + k], acc);
  }
  x_act[idx] = siluf(acc);
}

// ---------------- delta = softplus(delta_raw + dt_proj_b), dense [BL][2048] ----------
__global__ __launch_bounds__(256) void softplus_bias_kernel(float* delta,
                                                            const float* __restrict__ dt_proj_b) {
  const int idx = blockIdx.x * 256 + threadIdx.x;
  const int d = idx & (D_INNER - 1);
  const float v = delta[idx] + dt_proj_b[d];
  delta[idx] = fmaxf(v, 0.f) + __logf(1.f + __expf(-fabsf(v)));
}

// ---------------- scan pass 1: per-chunk (prod dA, h_end) with h0=0 ----------------
// thread t -> (b, chunk, d, n): n=t&15, d=(t>>4)&2047, c=(t>>15)&7, b=t>>18
__global__ __launch_bounds__(256) void scan_pass1(const float* __restrict__ delta,
                                                  const float* __restrict__ x_act,
                                                  const float* __restrict__ x_dbl,
                                                  const float* __restrict__ A_log,
                                                  float* __restrict__ chunkA,
                                                  float* __restrict__ chunkH) {
  const int t = blockIdx.x * 256 + threadIdx.x;
  const int n = t & 15;
  const int d = (t >> 4) & (D_INNER - 1);
  const int c = (t >> 15) & (NCHUNK - 1);
  const int b = t >> 18;
  const float Aval = -expf(A_log[d * D_STATE + n]);
  const int base = b * SEQ + c * CHUNK;

  const float* dp = delta + (size_t)base * D_INNER + d;
  const float* up = x_act + (size_t)base * D_INNER + d;
  const float* xb = x_dbl + (size_t)base * 96 + DT_RANK + n;

  float h = 0.f, aP = 1.f;
  for (int l = 0; l < CHUNK; ++l) {
    const float dv = *dp; dp += D_INNER;
    const float uv = *up; up += D_INNER;
    const float Bv = *xb; xb += 96;
    const float dA = __expf(dv * Aval);
    aP *= dA;
    h = fmaf(dA, h, dv * uv * Bv);
  }
  chunkA[t] = aP;
  chunkH[t] = h;
}

// ---------------- scan pass 2: combine chunk prefixes (h0 per chunk) ----------------
// chunkAH0 aliases chunkA (read-then-overwrite same slot is safe within a thread).
__global__ __launch_bounds__(256) void scan_pass2(const float* __restrict__ chunkH,
                                                  float* chunkAH0) {
  const int s = blockIdx.x * 256 + threadIdx.x;   // 65536 = (b, d, n)
  const int lo = s & 32767;                        // d*16+n
  const int b = s >> 15;
  float H = 0.f;
  for (int c = 0; c < NCHUNK; ++c) {
    const int idx = (b * NCHUNK + c) * 32768 + lo;
    const float aP = chunkAH0[idx];
    const float hE = chunkH[idx];
    chunkAH0[idx] = H;           // h0 for this chunk
    H = fmaf(aP, H, hE);
  }
}

// ---------------- scan pass 3: rescan with h0, fuse D-skip + silu(z) gate, emit bf16 --
// DPP allreduce (no DS pipe); epilogue batched: lane n latches p at (l&15)==n, every 16
// steps all 16 lanes do z-load + silu + gate + store for their owned l.
__global__ __launch_bounds__(256) void scan_pass3(const float* __restrict__ delta,
                                                  const float* __restrict__ x_act,
                                                  const float* __restrict__ x_dbl,
                                                  const float* __restrict__ A_log,
                                                  const float* __restrict__ chunkH0,
                                                  const float* __restrict__ D_skip,
                                                  __hip_bfloat16* xz_bf) {
  const int t = blockIdx.x * 256 + threadIdx.x;
  const int n = t & 15;
  const int d = (t >> 4) & (D_INNER - 1);
  const int c = (t >> 15) & (NCHUNK - 1);
  const int b = t >> 18;
  const float Aval = -expf(A_log[d * D_STATE + n]);
  const int base = b * SEQ + c * CHUNK;

  const float* dp = delta + (size_t)base * D_INNER + d;
  const float* up = x_act + (size_t)base * D_INNER + d;
  const float* xb = x_dbl + (size_t)base * 96 + DT_RANK + n;      // B at [0], C at [16]
  __hip_bfloat16* zp = xz_bf + (size_t)base * 4096 + D_INNER + d; // z at zp[l*4096]; y at -2048
  const float Dv = D_skip[d];

  float h = chunkH0[t];
  float psave = 0.f;
  for (int lb = 0; lb < CHUNK; lb += 16) {
#pragma unroll
    for (int j = 0; j < 16; ++j) {
      const float dv = *dp; dp += D_INNER;
      const float uv = *up; up += D_INNER;
      const float Bv = xb[0];
      const float Cv = xb[16]; xb += 96;
      const float dA = __expf(dv * Aval);
      h = fmaf(dA, h, dv * uv * Bv);
      float p = group16_sum(h * Cv);
      p = fmaf(uv, Dv, p);          // + D-skip (uv is this l's value, all lanes)
      psave = (j == n) ? p : psave; // lane n owns l = lb + n
    }
    // batched epilogue: 16 lanes handle 16 consecutive l's
    const size_t zi = (size_t)(lb + n) * 4096;
    const float zv = __bfloat162float(zp[zi]);
    zp[zi - D_INNER] = __float2bfloat16(psave * siluf(zv));
  }
}

extern "C" void kernel_launch(void* const* d_in, const int* in_sizes, int n_in,
                              void* d_out, int out_size, void* d_ws, size_t ws_size,
                              hipStream_t stream) {
  const float* x          = (const float*)d_in[0];
  const float* in_proj_w  = (const float*)d_in[1];
  const float* conv_w     = (const float*)d_in[2];
  const float* conv_b     = (const float*)d_in[3];
  const float* x_proj_w   = (const float*)d_in[4];
  const float* dt_proj_w  = (const float*)d_in[5];
  const float* dt_proj_b  = (const float*)d_in[6];
  const float* A_log      = (const float*)d_in[7];
  const float* D_skip     = (const float*)d_in[8];
  const float* out_proj_w = (const float*)d_in[9];
  float* out = (float*)d_out;   // fp32 output

  // Workspace layout (peak 106,430,464 B):
  //   xz_bf   @0          33,554,432  bf16 [4096][4096]; cols 0..2047 x_in -> y_bf, cols 2048..4095 z
  //   x_act   @33554432   33,554,432  fp32 [4096][2048]
  //   delta   @67108864   33,554,432  fp32 [4096][2048]
  //     (before delta live: x_bf @67108864 8MB, inw_bf @75497472 8MB;
  //      after delta dead:  outw_bf @67108864 4MB)
  //   x_dbl   @100663296   1,572,864  fp32 [4096][96]
  //   chunkA/H0 @102236160 2,097,152
  //   chunkH  @104333312   2,097,152
  char* ws = (char*)d_ws;
  __hip_bfloat16* xz_bf  = (__hip_bfloat16*)(ws);
  float* x_act           = (float*)(ws + 33554432);
  float* delta           = (float*)(ws + 67108864);
  __hip_bfloat16* x_bf   = (__hip_bfloat16*)(ws + 67108864);
  __hip_bfloat16* inw_bf = (__hip_bfloat16*)(ws + 75497472);
  __hip_bfloat16* outw_bf= (__hip_bfloat16*)(ws + 67108864);
  float* x_dbl           = (float*)(ws + 100663296);
  float* chunkAH0        = (float*)(ws + 102236160);
  float* chunkH          = (float*)(ws + 104333312);

  // 1-2. bf16 conversions for in_proj operands
  f2bf_kernel<<<4096, 256, 0, stream>>>(x, x_bf);            // 4096x1024
  f2bf_kernel<<<4096, 256, 0, stream>>>(in_proj_w, inw_bf);  // 4096x1024

  // 3. xz = x @ in_proj_w^T  (M=4096, N=4096, K=1024), bf16 out
  gemm_bt_bf16<__hip_bfloat16><<<dim3(32, 32), 256, 0, stream>>>(
      x_bf, inw_bf, xz_bf, BL, 4096, 1024, 1024, 1024, 4096);

  // 4. depthwise causal conv + bias + silu -> x_act (fp32)
  conv_silu_kernel<<<(BL * D_INNER) / 256, 256, 0, stream>>>(xz_bf, conv_w, conv_b, x_act);

  // 5. x_dbl = x_act @ x_proj_w^T  (4096 x 96, K=2048)
  gemm64g<<<dim3(2, 64), 256, 0, stream>>>(x_act, x_proj_w, x_dbl, BL, 96, 2048,
                                           2048, 2048, 96);

  // 6. delta_raw = dt_low @ dt_proj_w^T  (4096 x 2048, K=64)
  gemm64g<<<dim3(32, 64), 256, 0, stream>>>(x_dbl, dt_proj_w, delta, BL, 2048, 64,
                                            96, 64, 2048);

  // 7. delta = softplus(delta_raw + dt_proj_b)
  softplus_bias_kernel<<<(BL * D_INNER) / 256, 256, 0, stream>>>(delta, dt_proj_b);

  // 8-10. chunked selective scan (+fused gate, bf16 y into xz cols 0..2047)
  scan_pass1<<<2048, 256, 0, stream>>>(delta, x_act, x_dbl, A_log, chunkAH0, chunkH);
  scan_pass2<<<256, 256, 0, stream>>>(chunkH, chunkAH0);
  scan_pass3<<<2048, 256, 0, stream>>>(delta, x_act, x_dbl, A_log, chunkAH0, D_skip, xz_bf);

  // 11. out_proj weights -> bf16 (delta region is dead now)
  f2bf_kernel<<<2048, 256, 0, stream>>>(out_proj_w, outw_bf); // 1024x2048

  // 12. out = y @ out_proj_w^T  (M=4096, N=1024, K=2048), fp32 out
  gemm_bt_bf16<float><<<dim3(8, 32), 256, 0, stream>>>(
      xz_bf, outw_bf, out, BL, 1024, 2048, 4096, 2048, 1024);
}

// Round 8
// 377.300 us; speedup vs baseline: 4.3826x; 1.2366x over previous
//
#include <hip/hip_runtime.h>
#include <hip/hip_bf16.h>
#include <cstdint>

#define D_STATE 16
#define D_INNER 2048
#define DT_RANK 64
#define SEQ 2048
#define BL 4096      // B * L
#define NCHUNK 8
#define CHUNK 256    // SEQ / NCHUNK
#define XP_N 96      // dt_rank + 2*d_state
#define XP_KS 8      // x_proj K-splits

typedef short bf16x8 __attribute__((ext_vector_type(8)));
typedef float f32x4 __attribute__((ext_vector_type(4)));

__device__ __forceinline__ float siluf(float x) {
  return __fdividef(x, 1.f + __expf(-x));
}

// DPP-based add: p += p[lane mapped by CTRL]; stays on the VALU, no DS pipe, no waits.
template <int CTRL>
__device__ __forceinline__ float dppadd(float p) {
  int t = __builtin_amdgcn_update_dpp(0, __float_as_int(p), CTRL, 0xF, 0xF, true);
  return p + __int_as_float(t);
}

// 16-lane-group allreduce sum: quad xor1, quad xor2, half_mirror (i^7), row_mirror (i^15).
__device__ __forceinline__ float group16_sum(float p) {
  p = dppadd<0x0B1>(p);   // quad_perm [1,0,3,2]
  p = dppadd<0x04E>(p);   // quad_perm [2,3,0,1]
  p = dppadd<0x141>(p);   // row_half_mirror
  p = dppadd<0x140>(p);   // row_mirror
  return p;
}

__device__ __forceinline__ void gload_lds16(const void* g, void* l) {
  __builtin_amdgcn_global_load_lds((const __attribute__((address_space(1))) unsigned int*)g,
                                   (__attribute__((address_space(3))) unsigned int*)l,
                                   16, 0, 0);
}

// ---------------- fp32 -> bf16 conversion (n multiple of 1024) ----------------
__global__ __launch_bounds__(256) void f2bf_kernel(const float* __restrict__ in,
                                                   __hip_bfloat16* __restrict__ out) {
  const int i = (blockIdx.x * 256 + threadIdx.x) * 4;
  float4 v = *reinterpret_cast<const float4*>(&in[i]);
  out[i + 0] = __float2bfloat16(v.x);
  out[i + 1] = __float2bfloat16(v.y);
  out[i + 2] = __float2bfloat16(v.z);
  out[i + 3] = __float2bfloat16(v.w);
}

// ---------------- MFMA bf16 GEMM: C[M,N] = A[M,K] * B[N,K]^T ----------------
// 128x128 tile, 4 waves (2x2), BK=32, mfma_f32_16x16x32_bf16.
template <typename OutT>
__global__ __launch_bounds__(256) void gemm_bt_bf16(const __hip_bfloat16* __restrict__ A,
                                                    const __hip_bfloat16* __restrict__ B,
                                                    OutT* __restrict__ C,
                                                    int M, int N, int K,
                                                    int lda, int ldb, int ldc) {
  __shared__ __align__(16) unsigned short Alds[128 * 32];
  __shared__ __align__(16) unsigned short Blds[128 * 32];
  const int tid = threadIdx.x;
  const int wv = tid >> 6, lane = tid & 63;
  const int wr = wv >> 1, wc = wv & 1;          // wave grid 2x2, each wave 64x64 out
  const int m0 = blockIdx.y * 128, n0 = blockIdx.x * 128;
  const int sr = tid >> 2;                      // staging row 0..63
  const int sk = (tid & 3) * 8;                 // staging k-col (bf16 elems)
  const int frow = lane & 15;                   // fragment row/col within 16
  const int fk = (lane >> 4) * 8;               // fragment k offset

  f32x4 acc[4][4];
#pragma unroll
  for (int i = 0; i < 4; ++i)
#pragma unroll
    for (int j = 0; j < 4; ++j) acc[i][j] = {0.f, 0.f, 0.f, 0.f};

  const unsigned short* Ag = (const unsigned short*)A;
  const unsigned short* Bg = (const unsigned short*)B;

  for (int k0 = 0; k0 < K; k0 += 32) {
    gload_lds16(&Ag[(size_t)(m0 + sr) * lda + k0 + sk],       &Alds[wv * 512]);
    gload_lds16(&Ag[(size_t)(m0 + sr + 64) * lda + k0 + sk],  &Alds[2048 + wv * 512]);
    gload_lds16(&Bg[(size_t)(n0 + sr) * ldb + k0 + sk],       &Blds[wv * 512]);
    gload_lds16(&Bg[(size_t)(n0 + sr + 64) * ldb + k0 + sk],  &Blds[2048 + wv * 512]);
    __syncthreads();

    bf16x8 af[4], bfr[4];
#pragma unroll
    for (int mi = 0; mi < 4; ++mi)
      af[mi] = *reinterpret_cast<const bf16x8*>(&Alds[(wr * 64 + mi * 16 + frow) * 32 + fk]);
#pragma unroll
    for (int ni = 0; ni < 4; ++ni)
      bfr[ni] = *reinterpret_cast<const bf16x8*>(&Blds[(wc * 64 + ni * 16 + frow) * 32 + fk]);
#pragma unroll
    for (int mi = 0; mi < 4; ++mi)
#pragma unroll
      for (int ni = 0; ni < 4; ++ni)
        acc[mi][ni] = __builtin_amdgcn_mfma_f32_16x16x32_bf16(af[mi], bfr[ni], acc[mi][ni], 0, 0, 0);
    __syncthreads();
  }

  const int crow = (lane >> 4) * 4;
  const int ccol = lane & 15;
#pragma unroll
  for (int mi = 0; mi < 4; ++mi)
#pragma unroll
    for (int ni = 0; ni < 4; ++ni) {
      const int gcol = n0 + wc * 64 + ni * 16 + ccol;
#pragma unroll
      for (int j = 0; j < 4; ++j) {
        const int grow = m0 + wr * 64 + mi * 16 + crow + j;
        if constexpr (sizeof(OutT) == 2) {
          C[(size_t)grow * ldc + gcol] = __float2bfloat16(acc[mi][ni][j]);
        } else {
          C[(size_t)grow * ldc + gcol] = acc[mi][ni][j];
        }
      }
    }
}

// ---------------- Guarded fp32 GEMM: 64x64 tile (dt_proj) ----------------
__global__ __launch_bounds__(256) void gemm64g(const float* __restrict__ A,
                                               const float* __restrict__ B,
                                               float* __restrict__ C,
                                               int M, int N, int K,
                                               int lda, int ldb, int ldc) {
  __shared__ __align__(16) float As[16][64];
  __shared__ __align__(16) float Bs[16][64];
  const int tid = threadIdx.x;
  const int tx = tid & 15, ty = tid >> 4;
  const int m0 = blockIdx.y * 64, n0 = blockIdx.x * 64;
  const int lrow = tid >> 2;
  const int lc4  = (tid & 3) * 4;

  float acc[4][4];
#pragma unroll
  for (int i = 0; i < 4; ++i)
#pragma unroll
    for (int j = 0; j < 4; ++j) acc[i][j] = 0.f;

  for (int k0 = 0; k0 < K; k0 += 16) {
    __syncthreads();
    {
      float4 av = make_float4(0.f, 0.f, 0.f, 0.f);
      if (m0 + lrow < M)
        av = *reinterpret_cast<const float4*>(&A[(size_t)(m0 + lrow) * lda + k0 + lc4]);
      As[lc4 + 0][lrow] = av.x; As[lc4 + 1][lrow] = av.y;
      As[lc4 + 2][lrow] = av.z; As[lc4 + 3][lrow] = av.w;
      float4 bv = make_float4(0.f, 0.f, 0.f, 0.f);
      if (n0 + lrow < N)
        bv = *reinterpret_cast<const float4*>(&B[(size_t)(n0 + lrow) * ldb + k0 + lc4]);
      Bs[lc4 + 0][lrow] = bv.x; Bs[lc4 + 1][lrow] = bv.y;
      Bs[lc4 + 2][lrow] = bv.z; Bs[lc4 + 3][lrow] = bv.w;
    }
    __syncthreads();
#pragma unroll
    for (int kk = 0; kk < 16; ++kk) {
      float4 a = *reinterpret_cast<const float4*>(&As[kk][ty * 4]);
      float4 b = *reinterpret_cast<const float4*>(&Bs[kk][tx * 4]);
      float av[4] = {a.x, a.y, a.z, a.w};
      float bv[4] = {b.x, b.y, b.z, b.w};
#pragma unroll
      for (int i = 0; i < 4; ++i)
#pragma unroll
        for (int j = 0; j < 4; ++j) acc[i][j] = fmaf(av[i], bv[j], acc[i][j]);
    }
  }

#pragma unroll
  for (int i = 0; i < 4; ++i) {
    int m = m0 + ty * 4 + i;
    if (m >= M) continue;
#pragma unroll
    for (int j = 0; j < 4; ++j) {
      int n = n0 + tx * 4 + j;
      if (n < N) C[(size_t)m * ldc + n] = acc[i][j];
    }
  }
}

// ---------------- x_proj split-K: Cpart[z][4096][96] = x_act[.][Kz] @ W[96][Kz]^T ------
// grid (XP_KS, 64): z = K-split of 256, m-tile of 64 rows. 256 thr: tx=tid&15 (6 cols
// at stride 16), ty=tid>>4 (4 rows). LDS padded (68/100) -> only free 2-way conflicts.
__global__ __launch_bounds__(256) void gemm_xproj_splitk(const float* __restrict__ A,
                                                         const float* __restrict__ B,
                                                         float* __restrict__ Cpart) {
  __shared__ __align__(16) float As[16][68];
  __shared__ __align__(16) float Bs[16][100];
  const int tid = threadIdx.x;
  const int tx = tid & 15, ty = tid >> 4;
  const int m0 = blockIdx.y * 64;
  const int kbase = blockIdx.x * (2048 / XP_KS);
  const int lrow = tid >> 2;
  const int lc4  = (tid & 3) * 4;

  float acc[4][6];
#pragma unroll
  for (int i = 0; i < 4; ++i)
#pragma unroll
    for (int j = 0; j < 6; ++j) acc[i][j] = 0.f;

  for (int ks = 0; ks < 2048 / XP_KS; ks += 16) {
    const int k0 = kbase + ks;
    __syncthreads();
    {
      float4 av = *reinterpret_cast<const float4*>(&A[(size_t)(m0 + lrow) * 2048 + k0 + lc4]);
      As[lc4 + 0][lrow] = av.x; As[lc4 + 1][lrow] = av.y;
      As[lc4 + 2][lrow] = av.z; As[lc4 + 3][lrow] = av.w;
      if (tid < 128) {   // rows 64..95 of B handled by second half-range
      }
#pragma unroll
      for (int r = lrow; r < XP_N; r += 64) {
        float4 bv = *reinterpret_cast<const float4*>(&B[(size_t)r * 2048 + k0 + lc4]);
        Bs[lc4 + 0][r] = bv.x; Bs[lc4 + 1][r] = bv.y;
        Bs[lc4 + 2][r] = bv.z; Bs[lc4 + 3][r] = bv.w;
      }
    }
    __syncthreads();
#pragma unroll
    for (int kk = 0; kk < 16; ++kk) {
      float4 a = *reinterpret_cast<const float4*>(&As[kk][ty * 4]);
      float av[4] = {a.x, a.y, a.z, a.w};
#pragma unroll
      for (int j = 0; j < 6; ++j) {
        const float bv = Bs[kk][tx + 16 * j];
#pragma unroll
        for (int i = 0; i < 4; ++i) acc[i][j] = fmaf(av[i], bv, acc[i][j]);
      }
    }
  }

  float* Cz = Cpart + (size_t)blockIdx.x * BL * XP_N;
#pragma unroll
  for (int i = 0; i < 4; ++i) {
    const size_t row = (size_t)(m0 + ty * 4 + i) * XP_N;
#pragma unroll
    for (int j = 0; j < 6; ++j) Cz[row + tx + 16 * j] = acc[i][j];
  }
}

// ---------------- x_proj reduce: x_dbl[i] = sum_z Cpart[z][i] (deterministic) ----------
__global__ __launch_bounds__(256) void xproj_reduce(const float* __restrict__ Cpart,
                                                    float* __restrict__ x_dbl) {
  const int i = blockIdx.x * 256 + threadIdx.x;    // < BL * XP_N
  float s = 0.f;
#pragma unroll
  for (int z = 0; z < XP_KS; ++z) s += Cpart[(size_t)z * BL * XP_N + i];
  x_dbl[i] = s;
}

// ---------------- depthwise causal conv1d (w=4) + bias + silu; bf16 in, fp32 out ----
__global__ __launch_bounds__(256) void conv_silu_kernel(const __hip_bfloat16* __restrict__ xz_bf,
                                                        const float* __restrict__ conv_w,
                                                        const float* __restrict__ conv_b,
                                                        float* __restrict__ x_act) {
  const int idx = blockIdx.x * 256 + threadIdx.x;   // over BL * D_INNER
  const int d = idx & (D_INNER - 1);
  const int bl = idx >> 11;
  const int l = bl & (SEQ - 1);
  float acc = conv_b[d];
#pragma unroll
  for (int k = 0; k < 4; ++k) {
    const int ll = l + k - 3;
    if (ll >= 0)
      acc = fmaf(__bfloat162float(xz_bf[(size_t)(bl + k - 3) * 4096 + d]), conv_w[d * 4 + k], acc);
  }
  x_act[idx] = siluf(acc);
}

// ---------------- delta = softplus(delta_raw + dt_proj_b), dense [BL][2048] ----------
__global__ __launch_bounds__(256) void softplus_bias_kernel(float* delta,
                                                            const float* __restrict__ dt_proj_b) {
  const int idx = blockIdx.x * 256 + threadIdx.x;
  const int d = idx & (D_INNER - 1);
  const float v = delta[idx] + dt_proj_b[d];
  delta[idx] = fmaxf(v, 0.f) + __logf(1.f + __expf(-fabsf(v)));
}

// ---------------- scan pass 1: per-chunk (prod dA, h_end) with h0=0 ----------------
__global__ __launch_bounds__(256) void scan_pass1(const float* __restrict__ delta,
                                                  const float* __restrict__ x_act,
                                                  const float* __restrict__ x_dbl,
                                                  const float* __restrict__ A_log,
                                                  float* __restrict__ chunkA,
                                                  float* __restrict__ chunkH) {
  const int t = blockIdx.x * 256 + threadIdx.x;
  const int n = t & 15;
  const int d = (t >> 4) & (D_INNER - 1);
  const int c = (t >> 15) & (NCHUNK - 1);
  const int b = t >> 18;
  const float Aval = -expf(A_log[d * D_STATE + n]);
  const int base = b * SEQ + c * CHUNK;

  const float* dp = delta + (size_t)base * D_INNER + d;
  const float* up = x_act + (size_t)base * D_INNER + d;
  const float* xb = x_dbl + (size_t)base * 96 + DT_RANK + n;

  float h = 0.f, aP = 1.f;
  for (int l = 0; l < CHUNK; ++l) {
    const float dv = *dp; dp += D_INNER;
    const float uv = *up; up += D_INNER;
    const float Bv = *xb; xb += 96;
    const float dA = __expf(dv * Aval);
    aP *= dA;
    h = fmaf(dA, h, dv * uv * Bv);
  }
  chunkA[t] = aP;
  chunkH[t] = h;
}

// ---------------- scan pass 2: combine chunk prefixes (h0 per chunk) ----------------
__global__ __launch_bounds__(256) void scan_pass2(const float* __restrict__ chunkH,
                                                  float* chunkAH0) {
  const int s = blockIdx.x * 256 + threadIdx.x;   // 65536 = (b, d, n)
  const int lo = s & 32767;                        // d*16+n
  const int b = s >> 15;
  float H = 0.f;
  for (int c = 0; c < NCHUNK; ++c) {
    const int idx = (b * NCHUNK + c) * 32768 + lo;
    const float aP = chunkAH0[idx];
    const float hE = chunkH[idx];
    chunkAH0[idx] = H;           // h0 for this chunk
    H = fmaf(aP, H, hE);
  }
}

// ---------------- scan pass 3: rescan with h0, fuse D-skip + silu(z) gate, emit bf16 --
__global__ __launch_bounds__(256) void scan_pass3(const float* __restrict__ delta,
                                                  const float* __restrict__ x_act,
                                                  const float* __restrict__ x_dbl,
                                                  const float* __restrict__ A_log,
                                                  const float* __restrict__ chunkH0,
                                                  const float* __restrict__ D_skip,
                                                  __hip_bfloat16* xz_bf) {
  const int t = blockIdx.x * 256 + threadIdx.x;
  const int n = t & 15;
  const int d = (t >> 4) & (D_INNER - 1);
  const int c = (t >> 15) & (NCHUNK - 1);
  const int b = t >> 18;
  const float Aval = -expf(A_log[d * D_STATE + n]);
  const int base = b * SEQ + c * CHUNK;

  const float* dp = delta + (size_t)base * D_INNER + d;
  const float* up = x_act + (size_t)base * D_INNER + d;
  const float* xb = x_dbl + (size_t)base * 96 + DT_RANK + n;      // B at [0], C at [16]
  __hip_bfloat16* zp = xz_bf + (size_t)base * 4096 + D_INNER + d; // z at zp[l*4096]; y at -2048
  const float Dv = D_skip[d];

  float h = chunkH0[t];
  float psave = 0.f;
  for (int lb = 0; lb < CHUNK; lb += 16) {
#pragma unroll
    for (int j = 0; j < 16; ++j) {
      const float dv = *dp; dp += D_INNER;
      const float uv = *up; up += D_INNER;
      const float Bv = xb[0];
      const float Cv = xb[16]; xb += 96;
      const float dA = __expf(dv * Aval);
      h = fmaf(dA, h, dv * uv * Bv);
      float p = group16_sum(h * Cv);
      p = fmaf(uv, Dv, p);          // + D-skip
      psave = (j == n) ? p : psave; // lane n owns l = lb + n
    }
    const size_t zi = (size_t)(lb + n) * 4096;
    const float zv = __bfloat162float(zp[zi]);
    zp[zi - D_INNER] = __float2bfloat16(psave * siluf(zv));
  }
}

extern "C" void kernel_launch(void* const* d_in, const int* in_sizes, int n_in,
                              void* d_out, int out_size, void* d_ws, size_t ws_size,
                              hipStream_t stream) {
  const float* x          = (const float*)d_in[0];
  const float* in_proj_w  = (const float*)d_in[1];
  const float* conv_w     = (const float*)d_in[2];
  const float* conv_b     = (const float*)d_in[3];
  const float* x_proj_w   = (const float*)d_in[4];
  const float* dt_proj_w  = (const float*)d_in[5];
  const float* dt_proj_b  = (const float*)d_in[6];
  const float* A_log      = (const float*)d_in[7];
  const float* D_skip     = (const float*)d_in[8];
  const float* out_proj_w = (const float*)d_in[9];
  float* out = (float*)d_out;   // fp32 output

  // Workspace layout (peak 106,430,464 B):
  //   xz_bf   @0          33,554,432  bf16 [4096][4096]
  //   x_act   @33554432   33,554,432  fp32 [4096][2048]
  //   delta   @67108864   33,554,432  fp32 [4096][2048]
  //     region 67.1-100.6MB time-shared: {x_bf, inw_bf} -> Cpart -> delta -> outw_bf
  //   x_dbl   @100663296   1,572,864
  //   chunkA/H0 @102236160 2,097,152
  //   chunkH  @104333312   2,097,152
  char* ws = (char*)d_ws;
  __hip_bfloat16* xz_bf  = (__hip_bfloat16*)(ws);
  float* x_act           = (float*)(ws + 33554432);
  float* delta           = (float*)(ws + 67108864);
  __hip_bfloat16* x_bf   = (__hip_bfloat16*)(ws + 67108864);
  __hip_bfloat16* inw_bf = (__hip_bfloat16*)(ws + 75497472);
  float* Cpart           = (float*)(ws + 67108864);   // 8*4096*96*4 = 12.6 MB
  __hip_bfloat16* outw_bf= (__hip_bfloat16*)(ws + 67108864);
  float* x_dbl           = (float*)(ws + 100663296);
  float* chunkAH0        = (float*)(ws + 102236160);
  float* chunkH          = (float*)(ws + 104333312);

  // 1-2. bf16 conversions for in_proj operands
  f2bf_kernel<<<4096, 256, 0, stream>>>(x, x_bf);            // 4096x1024
  f2bf_kernel<<<4096, 256, 0, stream>>>(in_proj_w, inw_bf);  // 4096x1024

  // 3. xz = x @ in_proj_w^T  (M=4096, N=4096, K=1024), bf16 out
  gemm_bt_bf16<__hip_bfloat16><<<dim3(32, 32), 256, 0, stream>>>(
      x_bf, inw_bf, xz_bf, BL, 4096, 1024, 1024, 1024, 4096);

  // 4. depthwise causal conv + bias + silu -> x_act (fp32)
  conv_silu_kernel<<<(BL * D_INNER) / 256, 256, 0, stream>>>(xz_bf, conv_w, conv_b, x_act);

  // 5. x_dbl = x_act @ x_proj_w^T  (4096 x 96, K=2048) via split-K + reduce
  gemm_xproj_splitk<<<dim3(XP_KS, 64), 256, 0, stream>>>(x_act, x_proj_w, Cpart);
  xproj_reduce<<<(BL * XP_N) / 256, 256, 0, stream>>>(Cpart, x_dbl);

  // 6. delta_raw = dt_low @ dt_proj_w^T  (4096 x 2048, K=64)
  gemm64g<<<dim3(32, 64), 256, 0, stream>>>(x_dbl, dt_proj_w, delta, BL, 2048, 64,
                                            96, 64, 2048);

  // 7. delta = softplus(delta_raw + dt_proj_b)
  softplus_bias_kernel<<<(BL * D_INNER) / 256, 256, 0, stream>>>(delta, dt_proj_b);

  // 8-10. chunked selective scan (+fused gate, bf16 y into xz cols 0..2047)
  scan_pass1<<<2048, 256, 0, stream>>>(delta, x_act, x_dbl, A_log, chunkAH0, chunkH);
  scan_pass2<<<256, 256, 0, stream>>>(chunkH, chunkAH0);
  scan_pass3<<<2048, 256, 0, stream>>>(delta, x_act, x_dbl, A_log, chunkAH0, D_skip, xz_bf);

  // 11. out_proj weights -> bf16 (Cpart/delta region dead now)
  f2bf_kernel<<<2048, 256, 0, stream>>>(out_proj_w, outw_bf); // 1024x2048

  // 12. out = y @ out_proj_w^T  (M=4096, N=1024, K=2048), fp32 out
  gemm_bt_bf16<float><<<dim3(8, 32), 256, 0, stream>>>(
      xz_bf, outw_bf, out, BL, 1024, 2048, 4096, 2048, 1024);
}

// Round 9
// 330.107 us; speedup vs baseline: 5.0091x; 1.1430x over previous
//
#include <hip/hip_runtime.h>
#include <hip/hip_bf16.h>
#include <cstdint>

#define D_STATE 16
#define D_INNER 2048
#define DT_RANK 64
#define SEQ 2048
#define BL 4096      // B * L
#define NCHUNK 32
#define CHUNK 64     // SEQ / NCHUNK
#define XP_N 96      // dt_rank + 2*d_state
#define XP_KS 8      // x_proj K-splits

typedef short bf16x8 __attribute__((ext_vector_type(8)));
typedef float f32x4 __attribute__((ext_vector_type(4)));

__device__ __forceinline__ float siluf(float x) {
  return __fdividef(x, 1.f + __expf(-x));
}

__device__ __forceinline__ float softplusf(float v) {
  return fmaxf(v, 0.f) + __logf(1.f + __expf(-fabsf(v)));
}

__device__ __forceinline__ void gload_lds16(const void* g, void* l) {
  __builtin_amdgcn_global_load_lds((const __attribute__((address_space(1))) unsigned int*)g,
                                   (__attribute__((address_space(3))) unsigned int*)l,
                                   16, 0, 0);
}

// ---------------- fp32 -> bf16 conversion (n multiple of 1024) ----------------
__global__ __launch_bounds__(256) void f2bf_kernel(const float* __restrict__ in,
                                                   __hip_bfloat16* __restrict__ out) {
  const int i = (blockIdx.x * 256 + threadIdx.x) * 4;
  float4 v = *reinterpret_cast<const float4*>(&in[i]);
  out[i + 0] = __float2bfloat16(v.x);
  out[i + 1] = __float2bfloat16(v.y);
  out[i + 2] = __float2bfloat16(v.z);
  out[i + 3] = __float2bfloat16(v.w);
}

// ---------------- MFMA bf16 GEMM: C[M,N] = A[M,K] * B[N,K]^T ----------------
// 128x128 tile, 4 waves (2x2), BK=32, mfma_f32_16x16x32_bf16.
template <typename OutT>
__global__ __launch_bounds__(256) void gemm_bt_bf16(const __hip_bfloat16* __restrict__ A,
                                                    const __hip_bfloat16* __restrict__ B,
                                                    OutT* __restrict__ C,
                                                    int M, int N, int K,
                                                    int lda, int ldb, int ldc) {
  __shared__ __align__(16) unsigned short Alds[128 * 32];
  __shared__ __align__(16) unsigned short Blds[128 * 32];
  const int tid = threadIdx.x;
  const int wv = tid >> 6, lane = tid & 63;
  const int wr = wv >> 1, wc = wv & 1;          // wave grid 2x2, each wave 64x64 out
  const int m0 = blockIdx.y * 128, n0 = blockIdx.x * 128;
  const int sr = tid >> 2;                      // staging row 0..63
  const int sk = (tid & 3) * 8;                 // staging k-col (bf16 elems)
  const int frow = lane & 15;                   // fragment row/col within 16
  const int fk = (lane >> 4) * 8;               // fragment k offset

  f32x4 acc[4][4];
#pragma unroll
  for (int i = 0; i < 4; ++i)
#pragma unroll
    for (int j = 0; j < 4; ++j) acc[i][j] = {0.f, 0.f, 0.f, 0.f};

  const unsigned short* Ag = (const unsigned short*)A;
  const unsigned short* Bg = (const unsigned short*)B;

  for (int k0 = 0; k0 < K; k0 += 32) {
    gload_lds16(&Ag[(size_t)(m0 + sr) * lda + k0 + sk],       &Alds[wv * 512]);
    gload_lds16(&Ag[(size_t)(m0 + sr + 64) * lda + k0 + sk],  &Alds[2048 + wv * 512]);
    gload_lds16(&Bg[(size_t)(n0 + sr) * ldb + k0 + sk],       &Blds[wv * 512]);
    gload_lds16(&Bg[(size_t)(n0 + sr + 64) * ldb + k0 + sk],  &Blds[2048 + wv * 512]);
    __syncthreads();

    bf16x8 af[4], bfr[4];
#pragma unroll
    for (int mi = 0; mi < 4; ++mi)
      af[mi] = *reinterpret_cast<const bf16x8*>(&Alds[(wr * 64 + mi * 16 + frow) * 32 + fk]);
#pragma unroll
    for (int ni = 0; ni < 4; ++ni)
      bfr[ni] = *reinterpret_cast<const bf16x8*>(&Blds[(wc * 64 + ni * 16 + frow) * 32 + fk]);
#pragma unroll
    for (int mi = 0; mi < 4; ++mi)
#pragma unroll
      for (int ni = 0; ni < 4; ++ni)
        acc[mi][ni] = __builtin_amdgcn_mfma_f32_16x16x32_bf16(af[mi], bfr[ni], acc[mi][ni], 0, 0, 0);
    __syncthreads();
  }

  const int crow = (lane >> 4) * 4;
  const int ccol = lane & 15;
#pragma unroll
  for (int mi = 0; mi < 4; ++mi)
#pragma unroll
    for (int ni = 0; ni < 4; ++ni) {
      const int gcol = n0 + wc * 64 + ni * 16 + ccol;
#pragma unroll
      for (int j = 0; j < 4; ++j) {
        const int grow = m0 + wr * 64 + mi * 16 + crow + j;
        if constexpr (sizeof(OutT) == 2) {
          C[(size_t)grow * ldc + gcol] = __float2bfloat16(acc[mi][ni][j]);
        } else {
          C[(size_t)grow * ldc + gcol] = acc[mi][ni][j];
        }
      }
    }
}

// ---------------- Guarded fp32 GEMM: 64x64 tile (dt_proj) ----------------
__global__ __launch_bounds__(256) void gemm64g(const float* __restrict__ A,
                                               const float* __restrict__ B,
                                               float* __restrict__ C,
                                               int M, int N, int K,
                                               int lda, int ldb, int ldc) {
  __shared__ __align__(16) float As[16][64];
  __shared__ __align__(16) float Bs[16][64];
  const int tid = threadIdx.x;
  const int tx = tid & 15, ty = tid >> 4;
  const int m0 = blockIdx.y * 64, n0 = blockIdx.x * 64;
  const int lrow = tid >> 2;
  const int lc4  = (tid & 3) * 4;

  float acc[4][4];
#pragma unroll
  for (int i = 0; i < 4; ++i)
#pragma unroll
    for (int j = 0; j < 4; ++j) acc[i][j] = 0.f;

  for (int k0 = 0; k0 < K; k0 += 16) {
    __syncthreads();
    {
      float4 av = make_float4(0.f, 0.f, 0.f, 0.f);
      if (m0 + lrow < M)
        av = *reinterpret_cast<const float4*>(&A[(size_t)(m0 + lrow) * lda + k0 + lc4]);
      As[lc4 + 0][lrow] = av.x; As[lc4 + 1][lrow] = av.y;
      As[lc4 + 2][lrow] = av.z; As[lc4 + 3][lrow] = av.w;
      float4 bv = make_float4(0.f, 0.f, 0.f, 0.f);
      if (n0 + lrow < N)
        bv = *reinterpret_cast<const float4*>(&B[(size_t)(n0 + lrow) * ldb + k0 + lc4]);
      Bs[lc4 + 0][lrow] = bv.x; Bs[lc4 + 1][lrow] = bv.y;
      Bs[lc4 + 2][lrow] = bv.z; Bs[lc4 + 3][lrow] = bv.w;
    }
    __syncthreads();
#pragma unroll
    for (int kk = 0; kk < 16; ++kk) {
      float4 a = *reinterpret_cast<const float4*>(&As[kk][ty * 4]);
      float4 b = *reinterpret_cast<const float4*>(&Bs[kk][tx * 4]);
      float av[4] = {a.x, a.y, a.z, a.w};
      float bv[4] = {b.x, b.y, b.z, b.w};
#pragma unroll
      for (int i = 0; i < 4; ++i)
#pragma unroll
        for (int j = 0; j < 4; ++j) acc[i][j] = fmaf(av[i], bv[j], acc[i][j]);
    }
  }

#pragma unroll
  for (int i = 0; i < 4; ++i) {
    int m = m0 + ty * 4 + i;
    if (m >= M) continue;
#pragma unroll
    for (int j = 0; j < 4; ++j) {
      int n = n0 + tx * 4 + j;
      if (n < N) C[(size_t)m * ldc + n] = acc[i][j];
    }
  }
}

// ---------------- x_proj split-K: Cpart[z][4096][96] = x_act[.][Kz] @ W[96][Kz]^T ------
__global__ __launch_bounds__(256) void gemm_xproj_splitk(const float* __restrict__ A,
                                                         const float* __restrict__ B,
                                                         float* __restrict__ Cpart) {
  __shared__ __align__(16) float As[16][68];
  __shared__ __align__(16) float Bs[16][100];
  const int tid = threadIdx.x;
  const int tx = tid & 15, ty = tid >> 4;
  const int m0 = blockIdx.y * 64;
  const int kbase = blockIdx.x * (2048 / XP_KS);
  const int lrow = tid >> 2;
  const int lc4  = (tid & 3) * 4;

  float acc[4][6];
#pragma unroll
  for (int i = 0; i < 4; ++i)
#pragma unroll
    for (int j = 0; j < 6; ++j) acc[i][j] = 0.f;

  for (int ks = 0; ks < 2048 / XP_KS; ks += 16) {
    const int k0 = kbase + ks;
    __syncthreads();
    {
      float4 av = *reinterpret_cast<const float4*>(&A[(size_t)(m0 + lrow) * 2048 + k0 + lc4]);
      As[lc4 + 0][lrow] = av.x; As[lc4 + 1][lrow] = av.y;
      As[lc4 + 2][lrow] = av.z; As[lc4 + 3][lrow] = av.w;
#pragma unroll
      for (int r = lrow; r < XP_N; r += 64) {
        float4 bv = *reinterpret_cast<const float4*>(&B[(size_t)r * 2048 + k0 + lc4]);
        Bs[lc4 + 0][r] = bv.x; Bs[lc4 + 1][r] = bv.y;
        Bs[lc4 + 2][r] = bv.z; Bs[lc4 + 3][r] = bv.w;
      }
    }
    __syncthreads();
#pragma unroll
    for (int kk = 0; kk < 16; ++kk) {
      float4 a = *reinterpret_cast<const float4*>(&As[kk][ty * 4]);
      float av[4] = {a.x, a.y, a.z, a.w};
#pragma unroll
      for (int j = 0; j < 6; ++j) {
        const float bv = Bs[kk][tx + 16 * j];
#pragma unroll
        for (int i = 0; i < 4; ++i) acc[i][j] = fmaf(av[i], bv, acc[i][j]);
      }
    }
  }

  float* Cz = Cpart + (size_t)blockIdx.x * BL * XP_N;
#pragma unroll
  for (int i = 0; i < 4; ++i) {
    const size_t row = (size_t)(m0 + ty * 4 + i) * XP_N;
#pragma unroll
    for (int j = 0; j < 6; ++j) Cz[row + tx + 16 * j] = acc[i][j];
  }
}

// ---------------- x_proj reduce ----------------
__global__ __launch_bounds__(256) void xproj_reduce(const float* __restrict__ Cpart,
                                                    float* __restrict__ x_dbl) {
  const int i = blockIdx.x * 256 + threadIdx.x;    // < BL * XP_N
  float s = 0.f;
#pragma unroll
  for (int z = 0; z < XP_KS; ++z) s += Cpart[(size_t)z * BL * XP_N + i];
  x_dbl[i] = s;
}

// ---------------- depthwise causal conv1d (w=4) + bias + silu ----------------
__global__ __launch_bounds__(256) void conv_silu_kernel(const __hip_bfloat16* __restrict__ xz_bf,
                                                        const float* __restrict__ conv_w,
                                                        const float* __restrict__ conv_b,
                                                        float* __restrict__ x_act) {
  const int idx = blockIdx.x * 256 + threadIdx.x;   // over BL * D_INNER
  const int d = idx & (D_INNER - 1);
  const int bl = idx >> 11;
  const int l = bl & (SEQ - 1);
  float acc = conv_b[d];
#pragma unroll
  for (int k = 0; k < 4; ++k) {
    const int ll = l + k - 3;
    if (ll >= 0)
      acc = fmaf(__bfloat162float(xz_bf[(size_t)(bl + k - 3) * 4096 + d]), conv_w[d * 4 + k], acc);
  }
  x_act[idx] = siluf(acc);
}

// ---------------- scan pass 1: lane owns d; 16 n-states in registers ----------------
// t -> d = t&2047, c = (t>>11)&31, b = t>>16. Computes per-chunk h_end (h0=0) and
// S = sum(softplus(delta_raw)) (chunk dA-product = exp(Aval*S), applied in pass2).
__global__ __launch_bounds__(256) void scan_pass1(const float* __restrict__ delta_raw,
                                                  const float* __restrict__ x_act,
                                                  const float* __restrict__ x_dbl,
                                                  const float* __restrict__ A_log,
                                                  const float* __restrict__ dt_proj_b,
                                                  float* __restrict__ chunkS,
                                                  float* __restrict__ chunkH) {
  const int t = blockIdx.x * 256 + threadIdx.x;
  const int d = t & (D_INNER - 1);
  const int c = (t >> 11) & (NCHUNK - 1);
  const int b = t >> 16;
  const int base = b * SEQ + c * CHUNK;

  float Av[16];
#pragma unroll
  for (int q = 0; q < 4; ++q) {
    float4 a = *reinterpret_cast<const float4*>(&A_log[d * 16 + q * 4]);
    Av[q * 4 + 0] = -__expf(a.x); Av[q * 4 + 1] = -__expf(a.y);
    Av[q * 4 + 2] = -__expf(a.z); Av[q * 4 + 3] = -__expf(a.w);
  }
  const float bias = dt_proj_b[d];

  const float* dp = delta_raw + (size_t)base * D_INNER + d;
  const float* up = x_act + (size_t)base * D_INNER + d;
  const float* xb = x_dbl + (size_t)base * 96 + DT_RANK;   // B block (16 floats)

  float h[16];
#pragma unroll
  for (int n = 0; n < 16; ++n) h[n] = 0.f;
  float S = 0.f;

  // depth-1 prefetch; tail overread stays inside d_ws (values unused)
  float dvr = *dp, uvv = *up;
  float4 b0 = *reinterpret_cast<const float4*>(xb);
  float4 b1 = *reinterpret_cast<const float4*>(xb + 4);
  float4 b2 = *reinterpret_cast<const float4*>(xb + 8);
  float4 b3 = *reinterpret_cast<const float4*>(xb + 12);
  for (int l = 0; l < CHUNK; ++l) {
    dp += D_INNER; up += D_INNER; xb += 96;
    const float ndvr = *dp, nuv = *up;
    const float4 nb0 = *reinterpret_cast<const float4*>(xb);
    const float4 nb1 = *reinterpret_cast<const float4*>(xb + 4);
    const float4 nb2 = *reinterpret_cast<const float4*>(xb + 8);
    const float4 nb3 = *reinterpret_cast<const float4*>(xb + 12);

    const float dv = softplusf(dvr + bias);
    S += dv;
    const float du = dv * uvv;
    const float Bf[16] = {b0.x, b0.y, b0.z, b0.w, b1.x, b1.y, b1.z, b1.w,
                          b2.x, b2.y, b2.z, b2.w, b3.x, b3.y, b3.z, b3.w};
#pragma unroll
    for (int n = 0; n < 16; ++n) {
      const float dA = __expf(dv * Av[n]);
      h[n] = fmaf(dA, h[n], du * Bf[n]);
    }
    dvr = ndvr; uvv = nuv; b0 = nb0; b1 = nb1; b2 = nb2; b3 = nb3;
  }

  const size_t sidx = (size_t)(b * NCHUNK + c) * D_INNER + d;
  chunkS[sidx] = S;
  float* hp = chunkH + sidx * 16;
#pragma unroll
  for (int q = 0; q < 4; ++q)
    *reinterpret_cast<float4*>(hp + q * 4) =
        make_float4(h[q * 4 + 0], h[q * 4 + 1], h[q * 4 + 2], h[q * 4 + 3]);
}

// ---------------- scan pass 2: combine chunk prefixes; chunkH becomes h0 ----------------
__global__ __launch_bounds__(256) void scan_pass2(const float* __restrict__ chunkS,
                                                  const float* __restrict__ A_log,
                                                  float* chunkH) {
  const int s = blockIdx.x * 256 + threadIdx.x;   // 65536 = (b, d, n)
  const int n = s & 15;
  const int d = (s >> 4) & (D_INNER - 1);
  const int b = s >> 15;
  const float Aval = -__expf(A_log[d * 16 + n]);
  float H = 0.f;
  for (int c = 0; c < NCHUNK; ++c) {
    const size_t sidx = (size_t)(b * NCHUNK + c) * D_INNER + d;
    const float aP = __expf(Aval * chunkS[sidx]);
    const float hE = chunkH[sidx * 16 + n];
    chunkH[sidx * 16 + n] = H;       // h0 for this chunk
    H = fmaf(aP, H, hE);
  }
}

// ---------------- scan pass 3: rescan with h0; fused D-skip + silu(z) gate -> bf16 ------
__global__ __launch_bounds__(256) void scan_pass3(const float* __restrict__ delta_raw,
                                                  const float* __restrict__ x_act,
                                                  const float* __restrict__ x_dbl,
                                                  const float* __restrict__ A_log,
                                                  const float* __restrict__ dt_proj_b,
                                                  const float* __restrict__ chunkH0,
                                                  const float* __restrict__ D_skip,
                                                  __hip_bfloat16* xz_bf) {
  const int t = blockIdx.x * 256 + threadIdx.x;
  const int d = t & (D_INNER - 1);
  const int c = (t >> 11) & (NCHUNK - 1);
  const int b = t >> 16;
  const int base = b * SEQ + c * CHUNK;

  float Av[16];
#pragma unroll
  for (int q = 0; q < 4; ++q) {
    float4 a = *reinterpret_cast<const float4*>(&A_log[d * 16 + q * 4]);
    Av[q * 4 + 0] = -__expf(a.x); Av[q * 4 + 1] = -__expf(a.y);
    Av[q * 4 + 2] = -__expf(a.z); Av[q * 4 + 3] = -__expf(a.w);
  }
  const float bias = dt_proj_b[d];
  const float Dv = D_skip[d];

  const float* dp = delta_raw + (size_t)base * D_INNER + d;
  const float* up = x_act + (size_t)base * D_INNER + d;
  const float* xb = x_dbl + (size_t)base * 96 + DT_RANK;      // B at [0..15], C at [16..31]
  __hip_bfloat16* zp = xz_bf + (size_t)base * 4096 + D_INNER + d;

  float h[16];
  {
    const float* hp = chunkH0 + ((size_t)(b * NCHUNK + c) * D_INNER + d) * 16;
#pragma unroll
    for (int q = 0; q < 4; ++q) {
      float4 v = *reinterpret_cast<const float4*>(hp + q * 4);
      h[q * 4 + 0] = v.x; h[q * 4 + 1] = v.y; h[q * 4 + 2] = v.z; h[q * 4 + 3] = v.w;
    }
  }

  float dvr = *dp, uvv = *up;
  float4 b0 = *reinterpret_cast<const float4*>(xb);
  float4 b1 = *reinterpret_cast<const float4*>(xb + 4);
  float4 b2 = *reinterpret_cast<const float4*>(xb + 8);
  float4 b3 = *reinterpret_cast<const float4*>(xb + 12);
  float4 c0 = *reinterpret_cast<const float4*>(xb + 16);
  float4 c1 = *reinterpret_cast<const float4*>(xb + 20);
  float4 c2 = *reinterpret_cast<const float4*>(xb + 24);
  float4 c3 = *reinterpret_cast<const float4*>(xb + 28);
  for (int l = 0; l < CHUNK; ++l) {
    dp += D_INNER; up += D_INNER; xb += 96;
    const float ndvr = *dp, nuv = *up;
    const float4 nb0 = *reinterpret_cast<const float4*>(xb);
    const float4 nb1 = *reinterpret_cast<const float4*>(xb + 4);
    const float4 nb2 = *reinterpret_cast<const float4*>(xb + 8);
    const float4 nb3 = *reinterpret_cast<const float4*>(xb + 12);
    const float4 nc0 = *reinterpret_cast<const float4*>(xb + 16);
    const float4 nc1 = *reinterpret_cast<const float4*>(xb + 20);
    const float4 nc2 = *reinterpret_cast<const float4*>(xb + 24);
    const float4 nc3 = *reinterpret_cast<const float4*>(xb + 28);

    const float dv = softplusf(dvr + bias);
    const float du = dv * uvv;
    const float Bf[16] = {b0.x, b0.y, b0.z, b0.w, b1.x, b1.y, b1.z, b1.w,
                          b2.x, b2.y, b2.z, b2.w, b3.x, b3.y, b3.z, b3.w};
    const float Cf[16] = {c0.x, c0.y, c0.z, c0.w, c1.x, c1.y, c1.z, c1.w,
                          c2.x, c2.y, c2.z, c2.w, c3.x, c3.y, c3.z, c3.w};
    float p = 0.f;
#pragma unroll
    for (int n = 0; n < 16; ++n) {
      const float dA = __expf(dv * Av[n]);
      h[n] = fmaf(dA, h[n], du * Bf[n]);
      p = fmaf(h[n], Cf[n], p);
    }
    const float zv = __bfloat162float(zp[0]);
    const float yv = fmaf(uvv, Dv, p) * siluf(zv);
    zp[-(int)D_INNER] = __float2bfloat16(yv);
    zp += 4096;

    dvr = ndvr; uvv = nuv;
    b0 = nb0; b1 = nb1; b2 = nb2; b3 = nb3;
    c0 = nc0; c1 = nc1; c2 = nc2; c3 = nc3;
  }
}

extern "C" void kernel_launch(void* const* d_in, const int* in_sizes, int n_in,
                              void* d_out, int out_size, void* d_ws, size_t ws_size,
                              hipStream_t stream) {
  const float* x          = (const float*)d_in[0];
  const float* in_proj_w  = (const float*)d_in[1];
  const float* conv_w     = (const float*)d_in[2];
  const float* conv_b     = (const float*)d_in[3];
  const float* x_proj_w   = (const float*)d_in[4];
  const float* dt_proj_w  = (const float*)d_in[5];
  const float* dt_proj_b  = (const float*)d_in[6];
  const float* A_log      = (const float*)d_in[7];
  const float* D_skip     = (const float*)d_in[8];
  const float* out_proj_w = (const float*)d_in[9];
  float* out = (float*)d_out;   // fp32 output

  // Workspace layout (peak ~111.1 MB; r1/r2 evidence: ws_size >= 169 MB):
  //   xz_bf     @0          33,554,432  bf16 [4096][4096]
  //   x_act     @33554432   33,554,432  fp32 [4096][2048]
  //   delta_raw @67108864   33,554,432  fp32 [4096][2048]  (region time-shared w/ x_bf/inw_bf/Cpart/outw_bf)
  //   x_dbl     @100663296   1,572,864
  //   chunkH    @102236160   8,388,608  fp32 [B*NC*D][16]  (h_end -> h0 after pass2)
  //   chunkS    @110624768     524,288  fp32 [B*NC*D]
  char* ws = (char*)d_ws;
  __hip_bfloat16* xz_bf  = (__hip_bfloat16*)(ws);
  float* x_act           = (float*)(ws + 33554432);
  float* delta_raw       = (float*)(ws + 67108864);
  __hip_bfloat16* x_bf   = (__hip_bfloat16*)(ws + 67108864);
  __hip_bfloat16* inw_bf = (__hip_bfloat16*)(ws + 75497472);
  float* Cpart           = (float*)(ws + 67108864);   // 12.6 MB
  __hip_bfloat16* outw_bf= (__hip_bfloat16*)(ws + 67108864);
  float* x_dbl           = (float*)(ws + 100663296);
  float* chunkH          = (float*)(ws + 102236160);
  float* chunkS          = (float*)(ws + 110624768);

  // 1-2. bf16 conversions for in_proj operands
  f2bf_kernel<<<4096, 256, 0, stream>>>(x, x_bf);            // 4096x1024
  f2bf_kernel<<<4096, 256, 0, stream>>>(in_proj_w, inw_bf);  // 4096x1024

  // 3. xz = x @ in_proj_w^T  (M=4096, N=4096, K=1024), bf16 out
  gemm_bt_bf16<__hip_bfloat16><<<dim3(32, 32), 256, 0, stream>>>(
      x_bf, inw_bf, xz_bf, BL, 4096, 1024, 1024, 1024, 4096);

  // 4. depthwise causal conv + bias + silu -> x_act (fp32)
  conv_silu_kernel<<<(BL * D_INNER) / 256, 256, 0, stream>>>(xz_bf, conv_w, conv_b, x_act);

  // 5. x_dbl = x_act @ x_proj_w^T  (4096 x 96, K=2048) via split-K + reduce
  gemm_xproj_splitk<<<dim3(XP_KS, 64), 256, 0, stream>>>(x_act, x_proj_w, Cpart);
  xproj_reduce<<<(BL * XP_N) / 256, 256, 0, stream>>>(Cpart, x_dbl);

  // 6. delta_raw = dt_low @ dt_proj_w^T  (4096 x 2048, K=64); softplus fused into scan
  gemm64g<<<dim3(32, 64), 256, 0, stream>>>(x_dbl, dt_proj_w, delta_raw, BL, 2048, 64,
                                            96, 64, 2048);

  // 7-9. chunked selective scan, lane-owns-d (+fused softplus, D-skip, gate)
  scan_pass1<<<512, 256, 0, stream>>>(delta_raw, x_act, x_dbl, A_log, dt_proj_b,
                                      chunkS, chunkH);
  scan_pass2<<<256, 256, 0, stream>>>(chunkS, A_log, chunkH);
  scan_pass3<<<512, 256, 0, stream>>>(delta_raw, x_act, x_dbl, A_log, dt_proj_b,
                                      chunkH, D_skip, xz_bf);

  // 10. out_proj weights -> bf16 (delta region dead now)
  f2bf_kernel<<<2048, 256, 0, stream>>>(out_proj_w, outw_bf); // 1024x2048

  // 11. out = y @ out_proj_w^T  (M=4096, N=1024, K=2048), fp32 out
  gemm_bt_bf16<float><<<dim3(8, 32), 256, 0, stream>>>(
      xz_bf, outw_bf, out, BL, 1024, 2048, 4096, 2048, 1024);
}

// Round 10
// 306.160 us; speedup vs baseline: 5.4009x; 1.0782x over previous
//
#include <hip/hip_runtime.h>
#include <hip/hip_bf16.h>
#include <cstdint>

#define D_STATE 16
#define D_INNER 2048
#define DT_RANK 64
#define SEQ 2048
#define BL 4096      // B * L
#define NCHUNK 32
#define CHUNK 64     // SEQ / NCHUNK
#define XP_N 96      // dt_rank + 2*d_state
#define XP_KS 8      // x_proj K-splits

typedef short bf16x8 __attribute__((ext_vector_type(8)));
typedef float f32x4 __attribute__((ext_vector_type(4)));

__device__ __forceinline__ float siluf(float x) {
  return __fdividef(x, 1.f + __expf(-x));
}

__device__ __forceinline__ float softplusf(float v) {
  return fmaxf(v, 0.f) + __logf(1.f + __expf(-fabsf(v)));
}

__device__ __forceinline__ void gload_lds16(const void* g, void* l) {
  __builtin_amdgcn_global_load_lds((const __attribute__((address_space(1))) unsigned int*)g,
                                   (__attribute__((address_space(3))) unsigned int*)l,
                                   16, 0, 0);
}

// ---------------- fp32 -> bf16 conversion (n multiple of 1024) ----------------
__global__ __launch_bounds__(256) void f2bf_kernel(const float* __restrict__ in,
                                                   __hip_bfloat16* __restrict__ out) {
  const int i = (blockIdx.x * 256 + threadIdx.x) * 4;
  float4 v = *reinterpret_cast<const float4*>(&in[i]);
  out[i + 0] = __float2bfloat16(v.x);
  out[i + 1] = __float2bfloat16(v.y);
  out[i + 2] = __float2bfloat16(v.z);
  out[i + 3] = __float2bfloat16(v.w);
}

// ---------------- MFMA bf16 GEMM: C = A[M,K] * B[N,K]^T, double-buffered LDS ----------
// BM x BN tile, 4 waves (2x2), BK=32, one barrier per K-step: stage(t+1) issued before
// compute(t); __syncthreads' vmcnt drain lands the prefetch after MFMA covered it.
template <int BM, int BN>
__device__ __forceinline__ void stage_tiles(const unsigned short* __restrict__ Ag,
                                            const unsigned short* __restrict__ Bg,
                                            unsigned short* buf, int m0, int n0, int k0,
                                            int lda, int ldb, int sr, int sk, int wv) {
#pragma unroll
  for (int g = 0; g < BM / 64; ++g)
    gload_lds16(&Ag[(size_t)(m0 + g * 64 + sr) * lda + k0 + sk], &buf[g * 2048 + wv * 512]);
#pragma unroll
  for (int g = 0; g < BN / 64; ++g)
    gload_lds16(&Bg[(size_t)(n0 + g * 64 + sr) * ldb + k0 + sk], &buf[BM * 32 + g * 2048 + wv * 512]);
}

template <int BM, int BN, typename OutT>
__global__ __launch_bounds__(256) void gemm_bt(const __hip_bfloat16* __restrict__ A,
                                               const __hip_bfloat16* __restrict__ B,
                                               OutT* __restrict__ C,
                                               int K, int lda, int ldb, int ldc) {
  constexpr int WM = BM / 2, WN = BN / 2;     // wave output tile
  constexpr int MI = WM / 16, NI = WN / 16;   // fragment repeats
  constexpr int BUFS = (BM + BN) * 32;        // shorts per LDS buffer
  __shared__ __align__(16) unsigned short lds[2 * BUFS];
  const int tid = threadIdx.x;
  const int wv = tid >> 6, lane = tid & 63;
  const int wr = wv >> 1, wc = wv & 1;        // wave grid 2x2
  const int m0 = blockIdx.y * BM, n0 = blockIdx.x * BN;
  const int sr = tid >> 2;                    // staging row 0..63
  const int sk = (tid & 3) * 8;               // staging k-col (bf16 elems)
  const int frow = lane & 15;
  const int fk = (lane >> 4) * 8;

  f32x4 acc[MI][NI];
#pragma unroll
  for (int i = 0; i < MI; ++i)
#pragma unroll
    for (int j = 0; j < NI; ++j) acc[i][j] = {0.f, 0.f, 0.f, 0.f};

  const unsigned short* Ag = (const unsigned short*)A;
  const unsigned short* Bg = (const unsigned short*)B;

  stage_tiles<BM, BN>(Ag, Bg, &lds[0], m0, n0, 0, lda, ldb, sr, sk, wv);
  __syncthreads();
  int sel = 0;
  for (int k0 = 0; k0 < K; k0 += 32) {
    if (k0 + 32 < K)
      stage_tiles<BM, BN>(Ag, Bg, &lds[(sel ^ 1) * BUFS], m0, n0, k0 + 32, lda, ldb, sr, sk, wv);
    const unsigned short* Abuf = &lds[sel * BUFS];
    const unsigned short* Bbuf = &lds[sel * BUFS + BM * 32];
    bf16x8 af[MI], bfr[NI];
#pragma unroll
    for (int mi = 0; mi < MI; ++mi)
      af[mi] = *reinterpret_cast<const bf16x8*>(&Abuf[(wr * WM + mi * 16 + frow) * 32 + fk]);
#pragma unroll
    for (int ni = 0; ni < NI; ++ni)
      bfr[ni] = *reinterpret_cast<const bf16x8*>(&Bbuf[(wc * WN + ni * 16 + frow) * 32 + fk]);
#pragma unroll
    for (int mi = 0; mi < MI; ++mi)
#pragma unroll
      for (int ni = 0; ni < NI; ++ni)
        acc[mi][ni] = __builtin_amdgcn_mfma_f32_16x16x32_bf16(af[mi], bfr[ni], acc[mi][ni], 0, 0, 0);
    __syncthreads();   // drains stage vmcnt; also fences buf reuse
    sel ^= 1;
  }

  // C/D layout (m89-verified): col = lane&15, row = (lane>>4)*4 + reg
  const int crow = (lane >> 4) * 4;
  const int ccol = lane & 15;
#pragma unroll
  for (int mi = 0; mi < MI; ++mi)
#pragma unroll
    for (int ni = 0; ni < NI; ++ni) {
      const int gcol = n0 + wc * WN + ni * 16 + ccol;
#pragma unroll
      for (int j = 0; j < 4; ++j) {
        const int grow = m0 + wr * WM + mi * 16 + crow + j;
        if constexpr (sizeof(OutT) == 2) {
          C[(size_t)grow * ldc + gcol] = __float2bfloat16(acc[mi][ni][j]);
        } else {
          C[(size_t)grow * ldc + gcol] = acc[mi][ni][j];
        }
      }
    }
}

// ---------------- Guarded fp32 GEMM: 64x64 tile (dt_proj) ----------------
__global__ __launch_bounds__(256) void gemm64g(const float* __restrict__ A,
                                               const float* __restrict__ B,
                                               float* __restrict__ C,
                                               int M, int N, int K,
                                               int lda, int ldb, int ldc) {
  __shared__ __align__(16) float As[16][64];
  __shared__ __align__(16) float Bs[16][64];
  const int tid = threadIdx.x;
  const int tx = tid & 15, ty = tid >> 4;
  const int m0 = blockIdx.y * 64, n0 = blockIdx.x * 64;
  const int lrow = tid >> 2;
  const int lc4  = (tid & 3) * 4;

  float acc[4][4];
#pragma unroll
  for (int i = 0; i < 4; ++i)
#pragma unroll
    for (int j = 0; j < 4; ++j) acc[i][j] = 0.f;

  for (int k0 = 0; k0 < K; k0 += 16) {
    __syncthreads();
    {
      float4 av = make_float4(0.f, 0.f, 0.f, 0.f);
      if (m0 + lrow < M)
        av = *reinterpret_cast<const float4*>(&A[(size_t)(m0 + lrow) * lda + k0 + lc4]);
      As[lc4 + 0][lrow] = av.x; As[lc4 + 1][lrow] = av.y;
      As[lc4 + 2][lrow] = av.z; As[lc4 + 3][lrow] = av.w;
      float4 bv = make_float4(0.f, 0.f, 0.f, 0.f);
      if (n0 + lrow < N)
        bv = *reinterpret_cast<const float4*>(&B[(size_t)(n0 + lrow) * ldb + k0 + lc4]);
      Bs[lc4 + 0][lrow] = bv.x; Bs[lc4 + 1][lrow] = bv.y;
      Bs[lc4 + 2][lrow] = bv.z; Bs[lc4 + 3][lrow] = bv.w;
    }
    __syncthreads();
#pragma unroll
    for (int kk = 0; kk < 16; ++kk) {
      float4 a = *reinterpret_cast<const float4*>(&As[kk][ty * 4]);
      float4 b = *reinterpret_cast<const float4*>(&Bs[kk][tx * 4]);
      float av[4] = {a.x, a.y, a.z, a.w};
      float bv[4] = {b.x, b.y, b.z, b.w};
#pragma unroll
      for (int i = 0; i < 4; ++i)
#pragma unroll
        for (int j = 0; j < 4; ++j) acc[i][j] = fmaf(av[i], bv[j], acc[i][j]);
    }
  }

#pragma unroll
  for (int i = 0; i < 4; ++i) {
    int m = m0 + ty * 4 + i;
    if (m >= M) continue;
#pragma unroll
    for (int j = 0; j < 4; ++j) {
      int n = n0 + tx * 4 + j;
      if (n < N) C[(size_t)m * ldc + n] = acc[i][j];
    }
  }
}

// ---------------- x_proj split-K: Cpart[z][4096][96] = x_act[.][Kz] @ W[96][Kz]^T ------
__global__ __launch_bounds__(256) void gemm_xproj_splitk(const float* __restrict__ A,
                                                         const float* __restrict__ B,
                                                         float* __restrict__ Cpart) {
  __shared__ __align__(16) float As[16][68];
  __shared__ __align__(16) float Bs[16][100];
  const int tid = threadIdx.x;
  const int tx = tid & 15, ty = tid >> 4;
  const int m0 = blockIdx.y * 64;
  const int kbase = blockIdx.x * (2048 / XP_KS);
  const int lrow = tid >> 2;
  const int lc4  = (tid & 3) * 4;

  float acc[4][6];
#pragma unroll
  for (int i = 0; i < 4; ++i)
#pragma unroll
    for (int j = 0; j < 6; ++j) acc[i][j] = 0.f;

  for (int ks = 0; ks < 2048 / XP_KS; ks += 16) {
    const int k0 = kbase + ks;
    __syncthreads();
    {
      float4 av = *reinterpret_cast<const float4*>(&A[(size_t)(m0 + lrow) * 2048 + k0 + lc4]);
      As[lc4 + 0][lrow] = av.x; As[lc4 + 1][lrow] = av.y;
      As[lc4 + 2][lrow] = av.z; As[lc4 + 3][lrow] = av.w;
#pragma unroll
      for (int r = lrow; r < XP_N; r += 64) {
        float4 bv = *reinterpret_cast<const float4*>(&B[(size_t)r * 2048 + k0 + lc4]);
        Bs[lc4 + 0][r] = bv.x; Bs[lc4 + 1][r] = bv.y;
        Bs[lc4 + 2][r] = bv.z; Bs[lc4 + 3][r] = bv.w;
      }
    }
    __syncthreads();
#pragma unroll
    for (int kk = 0; kk < 16; ++kk) {
      float4 a = *reinterpret_cast<const float4*>(&As[kk][ty * 4]);
      float av[4] = {a.x, a.y, a.z, a.w};
#pragma unroll
      for (int j = 0; j < 6; ++j) {
        const float bv = Bs[kk][tx + 16 * j];
#pragma unroll
        for (int i = 0; i < 4; ++i) acc[i][j] = fmaf(av[i], bv, acc[i][j]);
      }
    }
  }

  float* Cz = Cpart + (size_t)blockIdx.x * BL * XP_N;
#pragma unroll
  for (int i = 0; i < 4; ++i) {
    const size_t row = (size_t)(m0 + ty * 4 + i) * XP_N;
#pragma unroll
    for (int j = 0; j < 6; ++j) Cz[row + tx + 16 * j] = acc[i][j];
  }
}

// ---------------- x_proj reduce ----------------
__global__ __launch_bounds__(256) void xproj_reduce(const float* __restrict__ Cpart,
                                                    float* __restrict__ x_dbl) {
  const int i = blockIdx.x * 256 + threadIdx.x;    // < BL * XP_N
  float s = 0.f;
#pragma unroll
  for (int z = 0; z < XP_KS; ++z) s += Cpart[(size_t)z * BL * XP_N + i];
  x_dbl[i] = s;
}

// ---------------- depthwise causal conv1d (w=4) + bias + silu ----------------
__global__ __launch_bounds__(256) void conv_silu_kernel(const __hip_bfloat16* __restrict__ xz_bf,
                                                        const float* __restrict__ conv_w,
                                                        const float* __restrict__ conv_b,
                                                        float* __restrict__ x_act) {
  const int idx = blockIdx.x * 256 + threadIdx.x;   // over BL * D_INNER
  const int d = idx & (D_INNER - 1);
  const int bl = idx >> 11;
  const int l = bl & (SEQ - 1);
  float acc = conv_b[d];
#pragma unroll
  for (int k = 0; k < 4; ++k) {
    const int ll = l + k - 3;
    if (ll >= 0)
      acc = fmaf(__bfloat162float(xz_bf[(size_t)(bl + k - 3) * 4096 + d]), conv_w[d * 4 + k], acc);
  }
  x_act[idx] = siluf(acc);
}

// ---------------- scan pass 1: lane owns d; 16 n-states in registers ----------------
__global__ __launch_bounds__(256) void scan_pass1(const float* __restrict__ delta_raw,
                                                  const float* __restrict__ x_act,
                                                  const float* __restrict__ x_dbl,
                                                  const float* __restrict__ A_log,
                                                  const float* __restrict__ dt_proj_b,
                                                  float* __restrict__ chunkS,
                                                  float* __restrict__ chunkH) {
  const int t = blockIdx.x * 256 + threadIdx.x;
  const int d = t & (D_INNER - 1);
  const int c = (t >> 11) & (NCHUNK - 1);
  const int b = t >> 16;
  const int base = b * SEQ + c * CHUNK;

  float Av[16];
#pragma unroll
  for (int q = 0; q < 4; ++q) {
    float4 a = *reinterpret_cast<const float4*>(&A_log[d * 16 + q * 4]);
    Av[q * 4 + 0] = -__expf(a.x); Av[q * 4 + 1] = -__expf(a.y);
    Av[q * 4 + 2] = -__expf(a.z); Av[q * 4 + 3] = -__expf(a.w);
  }
  const float bias = dt_proj_b[d];

  const float* dp = delta_raw + (size_t)base * D_INNER + d;
  const float* up = x_act + (size_t)base * D_INNER + d;
  const float* xb = x_dbl + (size_t)base * 96 + DT_RANK;   // B block (16 floats)

  float h[16];
#pragma unroll
  for (int n = 0; n < 16; ++n) h[n] = 0.f;
  float S = 0.f;

  float dvr = *dp, uvv = *up;
  float4 b0 = *reinterpret_cast<const float4*>(xb);
  float4 b1 = *reinterpret_cast<const float4*>(xb + 4);
  float4 b2 = *reinterpret_cast<const float4*>(xb + 8);
  float4 b3 = *reinterpret_cast<const float4*>(xb + 12);
  for (int l = 0; l < CHUNK; ++l) {
    dp += D_INNER; up += D_INNER; xb += 96;
    const float ndvr = *dp, nuv = *up;
    const float4 nb0 = *reinterpret_cast<const float4*>(xb);
    const float4 nb1 = *reinterpret_cast<const float4*>(xb + 4);
    const float4 nb2 = *reinterpret_cast<const float4*>(xb + 8);
    const float4 nb3 = *reinterpret_cast<const float4*>(xb + 12);

    const float dv = softplusf(dvr + bias);
    S += dv;
    const float du = dv * uvv;
    const float Bf[16] = {b0.x, b0.y, b0.z, b0.w, b1.x, b1.y, b1.z, b1.w,
                          b2.x, b2.y, b2.z, b2.w, b3.x, b3.y, b3.z, b3.w};
#pragma unroll
    for (int n = 0; n < 16; ++n) {
      const float dA = __expf(dv * Av[n]);
      h[n] = fmaf(dA, h[n], du * Bf[n]);
    }
    dvr = ndvr; uvv = nuv; b0 = nb0; b1 = nb1; b2 = nb2; b3 = nb3;
  }

  const size_t sidx = (size_t)(b * NCHUNK + c) * D_INNER + d;
  chunkS[sidx] = S;
  float* hp = chunkH + sidx * 16;
#pragma unroll
  for (int q = 0; q < 4; ++q)
    *reinterpret_cast<float4*>(hp + q * 4) =
        make_float4(h[q * 4 + 0], h[q * 4 + 1], h[q * 4 + 2], h[q * 4 + 3]);
}

// ---------------- scan pass 2: combine chunk prefixes; chunkH becomes h0 ----------------
__global__ __launch_bounds__(256) void scan_pass2(const float* __restrict__ chunkS,
                                                  const float* __restrict__ A_log,
                                                  float* chunkH) {
  const int s = blockIdx.x * 256 + threadIdx.x;   // 65536 = (b, d, n)
  const int n = s & 15;
  const int d = (s >> 4) & (D_INNER - 1);
  const int b = s >> 15;
  const float Aval = -__expf(A_log[d * 16 + n]);
  float H = 0.f;
  for (int c = 0; c < NCHUNK; ++c) {
    const size_t sidx = (size_t)(b * NCHUNK + c) * D_INNER + d;
    const float aP = __expf(Aval * chunkS[sidx]);
    const float hE = chunkH[sidx * 16 + n];
    chunkH[sidx * 16 + n] = H;       // h0 for this chunk
    H = fmaf(aP, H, hE);
  }
}

// ---------------- scan pass 3: rescan with h0; fused D-skip + silu(z) gate -> bf16 ------
__global__ __launch_bounds__(256) void scan_pass3(const float* __restrict__ delta_raw,
                                                  const float* __restrict__ x_act,
                                                  const float* __restrict__ x_dbl,
                                                  const float* __restrict__ A_log,
                                                  const float* __restrict__ dt_proj_b,
                                                  const float* __restrict__ chunkH0,
                                                  const float* __restrict__ D_skip,
                                                  __hip_bfloat16* xz_bf) {
  const int t = blockIdx.x * 256 + threadIdx.x;
  const int d = t & (D_INNER - 1);
  const int c = (t >> 11) & (NCHUNK - 1);
  const int b = t >> 16;
  const int base = b * SEQ + c * CHUNK;

  float Av[16];
#pragma unroll
  for (int q = 0; q < 4; ++q) {
    float4 a = *reinterpret_cast<const float4*>(&A_log[d * 16 + q * 4]);
    Av[q * 4 + 0] = -__expf(a.x); Av[q * 4 + 1] = -__expf(a.y);
    Av[q * 4 + 2] = -__expf(a.z); Av[q * 4 + 3] = -__expf(a.w);
  }
  const float bias = dt_proj_b[d];
  const float Dv = D_skip[d];

  const float* dp = delta_raw + (size_t)base * D_INNER + d;
  const float* up = x_act + (size_t)base * D_INNER + d;
  const float* xb = x_dbl + (size_t)base * 96 + DT_RANK;      // B at [0..15], C at [16..31]
  __hip_bfloat16* zp = xz_bf + (size_t)base * 4096 + D_INNER + d;

  float h[16];
  {
    const float* hp = chunkH0 + ((size_t)(b * NCHUNK + c) * D_INNER + d) * 16;
#pragma unroll
    for (int q = 0; q < 4; ++q) {
      float4 v = *reinterpret_cast<const float4*>(hp + q * 4);
      h[q * 4 + 0] = v.x; h[q * 4 + 1] = v.y; h[q * 4 + 2] = v.z; h[q * 4 + 3] = v.w;
    }
  }

  float dvr = *dp, uvv = *up;
  float4 b0 = *reinterpret_cast<const float4*>(xb);
  float4 b1 = *reinterpret_cast<const float4*>(xb + 4);
  float4 b2 = *reinterpret_cast<const float4*>(xb + 8);
  float4 b3 = *reinterpret_cast<const float4*>(xb + 12);
  float4 c0 = *reinterpret_cast<const float4*>(xb + 16);
  float4 c1 = *reinterpret_cast<const float4*>(xb + 20);
  float4 c2 = *reinterpret_cast<const float4*>(xb + 24);
  float4 c3 = *reinterpret_cast<const float4*>(xb + 28);
  for (int l = 0; l < CHUNK; ++l) {
    dp += D_INNER; up += D_INNER; xb += 96;
    const float ndvr = *dp, nuv = *up;
    const float4 nb0 = *reinterpret_cast<const float4*>(xb);
    const float4 nb1 = *reinterpret_cast<const float4*>(xb + 4);
    const float4 nb2 = *reinterpret_cast<const float4*>(xb + 8);
    const float4 nb3 = *reinterpret_cast<const float4*>(xb + 12);
    const float4 nc0 = *reinterpret_cast<const float4*>(xb + 16);
    const float4 nc1 = *reinterpret_cast<const float4*>(xb + 20);
    const float4 nc2 = *reinterpret_cast<const float4*>(xb + 24);
    const float4 nc3 = *reinterpret_cast<const float4*>(xb + 28);

    const float dv = softplusf(dvr + bias);
    const float du = dv * uvv;
    const float Bf[16] = {b0.x, b0.y, b0.z, b0.w, b1.x, b1.y, b1.z, b1.w,
                          b2.x, b2.y, b2.z, b2.w, b3.x, b3.y, b3.z, b3.w};
    const float Cf[16] = {c0.x, c0.y, c0.z, c0.w, c1.x, c1.y, c1.z, c1.w,
                          c2.x, c2.y, c2.z, c2.w, c3.x, c3.y, c3.z, c3.w};
    float p = 0.f;
#pragma unroll
    for (int n = 0; n < 16; ++n) {
      const float dA = __expf(dv * Av[n]);
      h[n] = fmaf(dA, h[n], du * Bf[n]);
      p = fmaf(h[n], Cf[n], p);
    }
    const float zv = __bfloat162float(zp[0]);
    const float yv = fmaf(uvv, Dv, p) * siluf(zv);
    zp[-(int)D_INNER] = __float2bfloat16(yv);
    zp += 4096;

    dvr = ndvr; uvv = nuv;
    b0 = nb0; b1 = nb1; b2 = nb2; b3 = nb3;
    c0 = nc0; c1 = nc1; c2 = nc2; c3 = nc3;
  }
}

extern "C" void kernel_launch(void* const* d_in, const int* in_sizes, int n_in,
                              void* d_out, int out_size, void* d_ws, size_t ws_size,
                              hipStream_t stream) {
  const float* x          = (const float*)d_in[0];
  const float* in_proj_w  = (const float*)d_in[1];
  const float* conv_w     = (const float*)d_in[2];
  const float* conv_b     = (const float*)d_in[3];
  const float* x_proj_w   = (const float*)d_in[4];
  const float* dt_proj_w  = (const float*)d_in[5];
  const float* dt_proj_b  = (const float*)d_in[6];
  const float* A_log      = (const float*)d_in[7];
  const float* D_skip     = (const float*)d_in[8];
  const float* out_proj_w = (const float*)d_in[9];
  float* out = (float*)d_out;   // fp32 output

  // Workspace layout (peak ~111.1 MB):
  //   xz_bf     @0          33,554,432  bf16 [4096][4096]
  //   x_act     @33554432   33,554,432  fp32 [4096][2048]
  //   delta_raw @67108864   33,554,432  (time-shared w/ x_bf/inw_bf/Cpart/outw_bf)
  //   x_dbl     @100663296   1,572,864
  //   chunkH    @102236160   8,388,608
  //   chunkS    @110624768     524,288
  char* ws = (char*)d_ws;
  __hip_bfloat16* xz_bf  = (__hip_bfloat16*)(ws);
  float* x_act           = (float*)(ws + 33554432);
  float* delta_raw       = (float*)(ws + 67108864);
  __hip_bfloat16* x_bf   = (__hip_bfloat16*)(ws + 67108864);
  __hip_bfloat16* inw_bf = (__hip_bfloat16*)(ws + 75497472);
  float* Cpart           = (float*)(ws + 67108864);   // 12.6 MB
  __hip_bfloat16* outw_bf= (__hip_bfloat16*)(ws + 67108864);
  float* x_dbl           = (float*)(ws + 100663296);
  float* chunkH          = (float*)(ws + 102236160);
  float* chunkS          = (float*)(ws + 110624768);

  // 1-2. bf16 conversions for in_proj operands
  f2bf_kernel<<<4096, 256, 0, stream>>>(x, x_bf);            // 4096x1024
  f2bf_kernel<<<4096, 256, 0, stream>>>(in_proj_w, inw_bf);  // 4096x1024

  // 3. xz = x @ in_proj_w^T  (M=4096, N=4096, K=1024), bf16 out, dbuf pipeline
  gemm_bt<128, 128, __hip_bfloat16><<<dim3(32, 32), 256, 0, stream>>>(
      x_bf, inw_bf, xz_bf, 1024, 1024, 1024, 4096);

  // 4. depthwise causal conv + bias + silu -> x_act (fp32)
  conv_silu_kernel<<<(BL * D_INNER) / 256, 256, 0, stream>>>(xz_bf, conv_w, conv_b, x_act);

  // 5. x_dbl = x_act @ x_proj_w^T  (4096 x 96, K=2048) via split-K + reduce
  gemm_xproj_splitk<<<dim3(XP_KS, 64), 256, 0, stream>>>(x_act, x_proj_w, Cpart);
  xproj_reduce<<<(BL * XP_N) / 256, 256, 0, stream>>>(Cpart, x_dbl);

  // 6. delta_raw = dt_low @ dt_proj_w^T  (4096 x 2048, K=64); softplus fused into scan
  gemm64g<<<dim3(32, 64), 256, 0, stream>>>(x_dbl, dt_proj_w, delta_raw, BL, 2048, 64,
                                            96, 64, 2048);

  // 7-9. chunked selective scan, lane-owns-d (+fused softplus, D-skip, gate)
  scan_pass1<<<512, 256, 0, stream>>>(delta_raw, x_act, x_dbl, A_log, dt_proj_b,
                                      chunkS, chunkH);
  scan_pass2<<<256, 256, 0, stream>>>(chunkS, A_log, chunkH);
  scan_pass3<<<512, 256, 0, stream>>>(delta_raw, x_act, x_dbl, A_log, dt_proj_b,
                                      chunkH, D_skip, xz_bf);

  // 10. out_proj weights -> bf16 (delta region dead now)
  f2bf_kernel<<<2048, 256, 0, stream>>>(out_proj_w, outw_bf); // 1024x2048

  // 11. out = y @ out_proj_w^T  (M=4096, N=1024, K=2048), fp32 out, 128x64 tile
  gemm_bt<128, 64, float><<<dim3(16, 32), 256, 0, stream>>>(
      xz_bf, outw_bf, out, 2048, 4096, 2048, 1024);
}

// Round 11
// 293.286 us; speedup vs baseline: 5.6380x; 1.0439x over previous
//
#include <hip/hip_runtime.h>
#include <hip/hip_bf16.h>
#include <cstdint>

#define D_STATE 16
#define D_INNER 2048
#define DT_RANK 64
#define SEQ 2048
#define BL 4096      // B * L
#define NCHUNK 128
#define CHUNK 16     // SEQ / NCHUNK
#define XP_N 96      // dt_rank + 2*d_state
#define XP_KS 8      // x_proj K-splits

typedef short bf16x8 __attribute__((ext_vector_type(8)));
typedef short short8 __attribute__((ext_vector_type(8)));
typedef float f32x4 __attribute__((ext_vector_type(4)));

__device__ __forceinline__ float siluf(float x) {
  return __fdividef(x, 1.f + __expf(-x));
}

__device__ __forceinline__ float softplusf(float v) {
  return fmaxf(v, 0.f) + __logf(1.f + __expf(-fabsf(v)));
}

__device__ __forceinline__ unsigned short f2bf_bits(float x) {
  __hip_bfloat16 h = __float2bfloat16(x);
  return *reinterpret_cast<unsigned short*>(&h);
}

__device__ __forceinline__ void gload_lds16(const void* g, void* l) {
  __builtin_amdgcn_global_load_lds((const __attribute__((address_space(1))) unsigned int*)g,
                                   (__attribute__((address_space(3))) unsigned int*)l,
                                   16, 0, 0);
}

// ---------------- fp32 -> bf16 conversion, 8 elems/thread (n multiple of 2048) --------
__global__ __launch_bounds__(256) void f2bf_kernel(const float* __restrict__ in,
                                                   __hip_bfloat16* __restrict__ out) {
  const int i = (blockIdx.x * 256 + threadIdx.x) * 8;
  float4 v0 = *reinterpret_cast<const float4*>(&in[i]);
  float4 v1 = *reinterpret_cast<const float4*>(&in[i + 4]);
  short8 r;
  r[0] = f2bf_bits(v0.x); r[1] = f2bf_bits(v0.y); r[2] = f2bf_bits(v0.z); r[3] = f2bf_bits(v0.w);
  r[4] = f2bf_bits(v1.x); r[5] = f2bf_bits(v1.y); r[6] = f2bf_bits(v1.z); r[7] = f2bf_bits(v1.w);
  *reinterpret_cast<short8*>(&out[i]) = r;
}

// ---------------- MFMA bf16 GEMM: C = A[M,K] * B[N,K]^T, double-buffered LDS ----------
template <int BM, int BN>
__device__ __forceinline__ void stage_tiles(const unsigned short* __restrict__ Ag,
                                            const unsigned short* __restrict__ Bg,
                                            unsigned short* buf, int m0, int n0, int k0,
                                            int lda, int ldb, int sr, int sk, int wv) {
#pragma unroll
  for (int g = 0; g < BM / 64; ++g)
    gload_lds16(&Ag[(size_t)(m0 + g * 64 + sr) * lda + k0 + sk], &buf[g * 2048 + wv * 512]);
#pragma unroll
  for (int g = 0; g < BN / 64; ++g)
    gload_lds16(&Bg[(size_t)(n0 + g * 64 + sr) * ldb + k0 + sk], &buf[BM * 32 + g * 2048 + wv * 512]);
}

template <int BM, int BN, typename OutT>
__global__ __launch_bounds__(256) void gemm_bt(const __hip_bfloat16* __restrict__ A,
                                               const __hip_bfloat16* __restrict__ B,
                                               OutT* __restrict__ C,
                                               int K, int lda, int ldb, int ldc) {
  constexpr int WM = BM / 2, WN = BN / 2;     // wave output tile
  constexpr int MI = WM / 16, NI = WN / 16;   // fragment repeats
  constexpr int BUFS = (BM + BN) * 32;        // shorts per LDS buffer
  __shared__ __align__(16) unsigned short lds[2 * BUFS];
  const int tid = threadIdx.x;
  const int wv = tid >> 6, lane = tid & 63;
  const int wr = wv >> 1, wc = wv & 1;        // wave grid 2x2
  const int m0 = blockIdx.y * BM, n0 = blockIdx.x * BN;
  const int sr = tid >> 2;                    // staging row 0..63
  const int sk = (tid & 3) * 8;               // staging k-col (bf16 elems)
  const int frow = lane & 15;
  const int fk = (lane >> 4) * 8;

  f32x4 acc[MI][NI];
#pragma unroll
  for (int i = 0; i < MI; ++i)
#pragma unroll
    for (int j = 0; j < NI; ++j) acc[i][j] = {0.f, 0.f, 0.f, 0.f};

  const unsigned short* Ag = (const unsigned short*)A;
  const unsigned short* Bg = (const unsigned short*)B;

  stage_tiles<BM, BN>(Ag, Bg, &lds[0], m0, n0, 0, lda, ldb, sr, sk, wv);
  __syncthreads();
  int sel = 0;
  for (int k0 = 0; k0 < K; k0 += 32) {
    if (k0 + 32 < K)
      stage_tiles<BM, BN>(Ag, Bg, &lds[(sel ^ 1) * BUFS], m0, n0, k0 + 32, lda, ldb, sr, sk, wv);
    const unsigned short* Abuf = &lds[sel * BUFS];
    const unsigned short* Bbuf = &lds[sel * BUFS + BM * 32];
    bf16x8 af[MI], bfr[NI];
#pragma unroll
    for (int mi = 0; mi < MI; ++mi)
      af[mi] = *reinterpret_cast<const bf16x8*>(&Abuf[(wr * WM + mi * 16 + frow) * 32 + fk]);
#pragma unroll
    for (int ni = 0; ni < NI; ++ni)
      bfr[ni] = *reinterpret_cast<const bf16x8*>(&Bbuf[(wc * WN + ni * 16 + frow) * 32 + fk]);
#pragma unroll
    for (int mi = 0; mi < MI; ++mi)
#pragma unroll
      for (int ni = 0; ni < NI; ++ni)
        acc[mi][ni] = __builtin_amdgcn_mfma_f32_16x16x32_bf16(af[mi], bfr[ni], acc[mi][ni], 0, 0, 0);
    __syncthreads();   // drains stage vmcnt; also fences buf reuse
    sel ^= 1;
  }

  const int crow = (lane >> 4) * 4;
  const int ccol = lane & 15;
#pragma unroll
  for (int mi = 0; mi < MI; ++mi)
#pragma unroll
    for (int ni = 0; ni < NI; ++ni) {
      const int gcol = n0 + wc * WN + ni * 16 + ccol;
#pragma unroll
      for (int j = 0; j < 4; ++j) {
        const int grow = m0 + wr * WM + mi * 16 + crow + j;
        if constexpr (sizeof(OutT) == 2) {
          C[(size_t)grow * ldc + gcol] = __float2bfloat16(acc[mi][ni][j]);
        } else {
          C[(size_t)grow * ldc + gcol] = acc[mi][ni][j];
        }
      }
    }
}

// ---------------- Guarded fp32 GEMM: 64x64 tile (dt_proj) ----------------
__global__ __launch_bounds__(256) void gemm64g(const float* __restrict__ A,
                                               const float* __restrict__ B,
                                               float* __restrict__ C,
                                               int M, int N, int K,
                                               int lda, int ldb, int ldc) {
  __shared__ __align__(16) float As[16][64];
  __shared__ __align__(16) float Bs[16][64];
  const int tid = threadIdx.x;
  const int tx = tid & 15, ty = tid >> 4;
  const int m0 = blockIdx.y * 64, n0 = blockIdx.x * 64;
  const int lrow = tid >> 2;
  const int lc4  = (tid & 3) * 4;

  float acc[4][4];
#pragma unroll
  for (int i = 0; i < 4; ++i)
#pragma unroll
    for (int j = 0; j < 4; ++j) acc[i][j] = 0.f;

  for (int k0 = 0; k0 < K; k0 += 16) {
    __syncthreads();
    {
      float4 av = make_float4(0.f, 0.f, 0.f, 0.f);
      if (m0 + lrow < M)
        av = *reinterpret_cast<const float4*>(&A[(size_t)(m0 + lrow) * lda + k0 + lc4]);
      As[lc4 + 0][lrow] = av.x; As[lc4 + 1][lrow] = av.y;
      As[lc4 + 2][lrow] = av.z; As[lc4 + 3][lrow] = av.w;
      float4 bv = make_float4(0.f, 0.f, 0.f, 0.f);
      if (n0 + lrow < N)
        bv = *reinterpret_cast<const float4*>(&B[(size_t)(n0 + lrow) * ldb + k0 + lc4]);
      Bs[lc4 + 0][lrow] = bv.x; Bs[lc4 + 1][lrow] = bv.y;
      Bs[lc4 + 2][lrow] = bv.z; Bs[lc4 + 3][lrow] = bv.w;
    }
    __syncthreads();
#pragma unroll
    for (int kk = 0; kk < 16; ++kk) {
      float4 a = *reinterpret_cast<const float4*>(&As[kk][ty * 4]);
      float4 b = *reinterpret_cast<const float4*>(&Bs[kk][tx * 4]);
      float av[4] = {a.x, a.y, a.z, a.w};
      float bv[4] = {b.x, b.y, b.z, b.w};
#pragma unroll
      for (int i = 0; i < 4; ++i)
#pragma unroll
        for (int j = 0; j < 4; ++j) acc[i][j] = fmaf(av[i], bv[j], acc[i][j]);
    }
  }

#pragma unroll
  for (int i = 0; i < 4; ++i) {
    int m = m0 + ty * 4 + i;
    if (m >= M) continue;
#pragma unroll
    for (int j = 0; j < 4; ++j) {
      int n = n0 + tx * 4 + j;
      if (n < N) C[(size_t)m * ldc + n] = acc[i][j];
    }
  }
}

// ---------------- x_proj split-K: Cpart[z][4096][96] = x_act[.][Kz] @ W[96][Kz]^T ------
__global__ __launch_bounds__(256) void gemm_xproj_splitk(const float* __restrict__ A,
                                                         const float* __restrict__ B,
                                                         float* __restrict__ Cpart) {
  __shared__ __align__(16) float As[16][68];
  __shared__ __align__(16) float Bs[16][100];
  const int tid = threadIdx.x;
  const int tx = tid & 15, ty = tid >> 4;
  const int m0 = blockIdx.y * 64;
  const int kbase = blockIdx.x * (2048 / XP_KS);
  const int lrow = tid >> 2;
  const int lc4  = (tid & 3) * 4;

  float acc[4][6];
#pragma unroll
  for (int i = 0; i < 4; ++i)
#pragma unroll
    for (int j = 0; j < 6; ++j) acc[i][j] = 0.f;

  for (int ks = 0; ks < 2048 / XP_KS; ks += 16) {
    const int k0 = kbase + ks;
    __syncthreads();
    {
      float4 av = *reinterpret_cast<const float4*>(&A[(size_t)(m0 + lrow) * 2048 + k0 + lc4]);
      As[lc4 + 0][lrow] = av.x; As[lc4 + 1][lrow] = av.y;
      As[lc4 + 2][lrow] = av.z; As[lc4 + 3][lrow] = av.w;
#pragma unroll
      for (int r = lrow; r < XP_N; r += 64) {
        float4 bv = *reinterpret_cast<const float4*>(&B[(size_t)r * 2048 + k0 + lc4]);
        Bs[lc4 + 0][r] = bv.x; Bs[lc4 + 1][r] = bv.y;
        Bs[lc4 + 2][r] = bv.z; Bs[lc4 + 3][r] = bv.w;
      }
    }
    __syncthreads();
#pragma unroll
    for (int kk = 0; kk < 16; ++kk) {
      float4 a = *reinterpret_cast<const float4*>(&As[kk][ty * 4]);
      float av[4] = {a.x, a.y, a.z, a.w};
#pragma unroll
      for (int j = 0; j < 6; ++j) {
        const float bv = Bs[kk][tx + 16 * j];
#pragma unroll
        for (int i = 0; i < 4; ++i) acc[i][j] = fmaf(av[i], bv, acc[i][j]);
      }
    }
  }

  float* Cz = Cpart + (size_t)blockIdx.x * BL * XP_N;
#pragma unroll
  for (int i = 0; i < 4; ++i) {
    const size_t row = (size_t)(m0 + ty * 4 + i) * XP_N;
#pragma unroll
    for (int j = 0; j < 6; ++j) Cz[row + tx + 16 * j] = acc[i][j];
  }
}

// ---------------- x_proj reduce ----------------
__global__ __launch_bounds__(256) void xproj_reduce(const float* __restrict__ Cpart,
                                                    float* __restrict__ x_dbl) {
  const int i = blockIdx.x * 256 + threadIdx.x;    // < BL * XP_N
  float s = 0.f;
#pragma unroll
  for (int z = 0; z < XP_KS; ++z) s += Cpart[(size_t)z * BL * XP_N + i];
  x_dbl[i] = s;
}

// ---------------- depthwise causal conv1d (w=4) + bias + silu ----------------
__global__ __launch_bounds__(256) void conv_silu_kernel(const __hip_bfloat16* __restrict__ xz_bf,
                                                        const float* __restrict__ conv_w,
                                                        const float* __restrict__ conv_b,
                                                        float* __restrict__ x_act) {
  const int idx = blockIdx.x * 256 + threadIdx.x;   // over BL * D_INNER
  const int d = idx & (D_INNER - 1);
  const int bl = idx >> 11;
  const int l = bl & (SEQ - 1);
  float acc = conv_b[d];
#pragma unroll
  for (int k = 0; k < 4; ++k) {
    const int ll = l + k - 3;
    if (ll >= 0)
      acc = fmaf(__bfloat162float(xz_bf[(size_t)(bl + k - 3) * 4096 + d]), conv_w[d * 4 + k], acc);
  }
  x_act[idx] = siluf(acc);
}

// ---------------- scan pass 1: lane owns d; 16 n-states in registers ----------------
// t -> d = t&2047, c = (t>>11)&127, b = t>>18.
__global__ __launch_bounds__(256) void scan_pass1(const float* __restrict__ delta_raw,
                                                  const float* __restrict__ x_act,
                                                  const float* __restrict__ x_dbl,
                                                  const float* __restrict__ A_log,
                                                  const float* __restrict__ dt_proj_b,
                                                  float* __restrict__ chunkS,
                                                  float* __restrict__ chunkH) {
  const int t = blockIdx.x * 256 + threadIdx.x;
  const int d = t & (D_INNER - 1);
  const int c = (t >> 11) & (NCHUNK - 1);
  const int b = t >> 18;
  const int base = b * SEQ + c * CHUNK;

  float Av[16];
#pragma unroll
  for (int q = 0; q < 4; ++q) {
    float4 a = *reinterpret_cast<const float4*>(&A_log[d * 16 + q * 4]);
    Av[q * 4 + 0] = -__expf(a.x); Av[q * 4 + 1] = -__expf(a.y);
    Av[q * 4 + 2] = -__expf(a.z); Av[q * 4 + 3] = -__expf(a.w);
  }
  const float bias = dt_proj_b[d];

  const float* dp = delta_raw + (size_t)base * D_INNER + d;
  const float* up = x_act + (size_t)base * D_INNER + d;
  const float* xb = x_dbl + (size_t)base * 96 + DT_RANK;   // B block (16 floats)

  float h[16];
#pragma unroll
  for (int n = 0; n < 16; ++n) h[n] = 0.f;
  float S = 0.f;

  float dvr = *dp, uvv = *up;
  float4 b0 = *reinterpret_cast<const float4*>(xb);
  float4 b1 = *reinterpret_cast<const float4*>(xb + 4);
  float4 b2 = *reinterpret_cast<const float4*>(xb + 8);
  float4 b3 = *reinterpret_cast<const float4*>(xb + 12);
  for (int l = 0; l < CHUNK; ++l) {
    dp += D_INNER; up += D_INNER; xb += 96;
    const float ndvr = *dp, nuv = *up;
    const float4 nb0 = *reinterpret_cast<const float4*>(xb);
    const float4 nb1 = *reinterpret_cast<const float4*>(xb + 4);
    const float4 nb2 = *reinterpret_cast<const float4*>(xb + 8);
    const float4 nb3 = *reinterpret_cast<const float4*>(xb + 12);

    const float dv = softplusf(dvr + bias);
    S += dv;
    const float du = dv * uvv;
    const float Bf[16] = {b0.x, b0.y, b0.z, b0.w, b1.x, b1.y, b1.z, b1.w,
                          b2.x, b2.y, b2.z, b2.w, b3.x, b3.y, b3.z, b3.w};
#pragma unroll
    for (int n = 0; n < 16; ++n) {
      const float dA = __expf(dv * Av[n]);
      h[n] = fmaf(dA, h[n], du * Bf[n]);
    }
    dvr = ndvr; uvv = nuv; b0 = nb0; b1 = nb1; b2 = nb2; b3 = nb3;
  }

  const size_t sidx = (size_t)(b * NCHUNK + c) * D_INNER + d;
  chunkS[sidx] = S;
  float* hp = chunkH + sidx * 16;
#pragma unroll
  for (int q = 0; q < 4; ++q)
    *reinterpret_cast<float4*>(hp + q * 4) =
        make_float4(h[q * 4 + 0], h[q * 4 + 1], h[q * 4 + 2], h[q * 4 + 3]);
}

// ---------------- scan pass 2: combine chunk prefixes; chunkH becomes h0 ----------------
// Depth-1 prefetch (unguarded overread stays inside d_ws).
__global__ __launch_bounds__(256) void scan_pass2(const float* __restrict__ chunkS,
                                                  const float* __restrict__ A_log,
                                                  float* chunkH) {
  const int s = blockIdx.x * 256 + threadIdx.x;   // 65536 = (b, d, n)
  const int n = s & 15;
  const int d = (s >> 4) & (D_INNER - 1);
  const int b = s >> 15;
  const float Aval = -__expf(A_log[d * 16 + n]);

  size_t sidx = (size_t)b * NCHUNK * D_INNER + d;
  float aS = chunkS[sidx];
  float hE = chunkH[sidx * 16 + n];
  float H = 0.f;
  for (int c = 0; c < NCHUNK; ++c) {
    const size_t sidx2 = sidx + D_INNER;
    const float naS = chunkS[sidx2];            // overread at c==NC-1: inside ws
    const float nhE = chunkH[sidx2 * 16 + n];
    const float aP = __expf(Aval * aS);
    chunkH[sidx * 16 + n] = H;                  // h0 for this chunk
    H = fmaf(aP, H, hE);
    sidx = sidx2; aS = naS; hE = nhE;
  }
}

// ---------------- scan pass 3: rescan with h0; fused D-skip + silu(z) gate -> bf16 ------
__global__ __launch_bounds__(256) void scan_pass3(const float* __restrict__ delta_raw,
                                                  const float* __restrict__ x_act,
                                                  const float* __restrict__ x_dbl,
                                                  const float* __restrict__ A_log,
                                                  const float* __restrict__ dt_proj_b,
                                                  const float* __restrict__ chunkH0,
                                                  const float* __restrict__ D_skip,
                                                  __hip_bfloat16* xz_bf) {
  const int t = blockIdx.x * 256 + threadIdx.x;
  const int d = t & (D_INNER - 1);
  const int c = (t >> 11) & (NCHUNK - 1);
  const int b = t >> 18;
  const int base = b * SEQ + c * CHUNK;

  float Av[16];
#pragma unroll
  for (int q = 0; q < 4; ++q) {
    float4 a = *reinterpret_cast<const float4*>(&A_log[d * 16 + q * 4]);
    Av[q * 4 + 0] = -__expf(a.x); Av[q * 4 + 1] = -__expf(a.y);
    Av[q * 4 + 2] = -__expf(a.z); Av[q * 4 + 3] = -__expf(a.w);
  }
  const float bias = dt_proj_b[d];
  const float Dv = D_skip[d];

  const float* dp = delta_raw + (size_t)base * D_INNER + d;
  const float* up = x_act + (size_t)base * D_INNER + d;
  const float* xb = x_dbl + (size_t)base * 96 + DT_RANK;      // B at [0..15], C at [16..31]
  __hip_bfloat16* zp = xz_bf + (size_t)base * 4096 + D_INNER + d;

  float h[16];
  {
    const float* hp = chunkH0 + ((size_t)(b * NCHUNK + c) * D_INNER + d) * 16;
#pragma unroll
    for (int q = 0; q < 4; ++q) {
      float4 v = *reinterpret_cast<const float4*>(hp + q * 4);
      h[q * 4 + 0] = v.x; h[q * 4 + 1] = v.y; h[q * 4 + 2] = v.z; h[q * 4 + 3] = v.w;
    }
  }

  float dvr = *dp, uvv = *up;
  float4 b0 = *reinterpret_cast<const float4*>(xb);
  float4 b1 = *reinterpret_cast<const float4*>(xb + 4);
  float4 b2 = *reinterpret_cast<const float4*>(xb + 8);
  float4 b3 = *reinterpret_cast<const float4*>(xb + 12);
  float4 c0 = *reinterpret_cast<const float4*>(xb + 16);
  float4 c1 = *reinterpret_cast<const float4*>(xb + 20);
  float4 c2 = *reinterpret_cast<const float4*>(xb + 24);
  float4 c3 = *reinterpret_cast<const float4*>(xb + 28);
  for (int l = 0; l < CHUNK; ++l) {
    dp += D_INNER; up += D_INNER; xb += 96;
    const float ndvr = *dp, nuv = *up;
    const float4 nb0 = *reinterpret_cast<const float4*>(xb);
    const float4 nb1 = *reinterpret_cast<const float4*>(xb + 4);
    const float4 nb2 = *reinterpret_cast<const float4*>(xb + 8);
    const float4 nb3 = *reinterpret_cast<const float4*>(xb + 12);
    const float4 nc0 = *reinterpret_cast<const float4*>(xb + 16);
    const float4 nc1 = *reinterpret_cast<const float4*>(xb + 20);
    const float4 nc2 = *reinterpret_cast<const float4*>(xb + 24);
    const float4 nc3 = *reinterpret_cast<const float4*>(xb + 28);

    const float dv = softplusf(dvr + bias);
    const float du = dv * uvv;
    const float Bf[16] = {b0.x, b0.y, b0.z, b0.w, b1.x, b1.y, b1.z, b1.w,
                          b2.x, b2.y, b2.z, b2.w, b3.x, b3.y, b3.z, b3.w};
    const float Cf[16] = {c0.x, c0.y, c0.z, c0.w, c1.x, c1.y, c1.z, c1.w,
                          c2.x, c2.y, c2.z, c2.w, c3.x, c3.y, c3.z, c3.w};
    float p = 0.f;
#pragma unroll
    for (int n = 0; n < 16; ++n) {
      const float dA = __expf(dv * Av[n]);
      h[n] = fmaf(dA, h[n], du * Bf[n]);
      p = fmaf(h[n], Cf[n], p);
    }
    const float zv = __bfloat162float(zp[0]);
    const float yv = fmaf(uvv, Dv, p) * siluf(zv);
    zp[-(int)D_INNER] = __float2bfloat16(yv);
    zp += 4096;

    dvr = ndvr; uvv = nuv;
    b0 = nb0; b1 = nb1; b2 = nb2; b3 = nb3;
    c0 = nc0; c1 = nc1; c2 = nc2; c3 = nc3;
  }
}

extern "C" void kernel_launch(void* const* d_in, const int* in_sizes, int n_in,
                              void* d_out, int out_size, void* d_ws, size_t ws_size,
                              hipStream_t stream) {
  const float* x          = (const float*)d_in[0];
  const float* in_proj_w  = (const float*)d_in[1];
  const float* conv_w     = (const float*)d_in[2];
  const float* conv_b     = (const float*)d_in[3];
  const float* x_proj_w   = (const float*)d_in[4];
  const float* dt_proj_w  = (const float*)d_in[5];
  const float* dt_proj_b  = (const float*)d_in[6];
  const float* A_log      = (const float*)d_in[7];
  const float* D_skip     = (const float*)d_in[8];
  const float* out_proj_w = (const float*)d_in[9];
  float* out = (float*)d_out;   // fp32 output

  // Workspace layout (peak ~138 MB; ws evidence >= 169 MB from r1/r2):
  //   xz_bf     @0          33,554,432  bf16 [4096][4096]
  //   x_act     @33554432   33,554,432  fp32 [4096][2048]
  //   delta_raw @67108864   33,554,432  (time-shared w/ x_bf/inw_bf/Cpart/outw_bf)
  //   x_dbl     @100663296   1,572,864
  //   chunkH    @102236160  33,554,432  fp32 [B*NC*D][16]
  //   chunkS    @135790592   2,097,152
  char* ws = (char*)d_ws;
  __hip_bfloat16* xz_bf  = (__hip_bfloat16*)(ws);
  float* x_act           = (float*)(ws + 33554432);
  float* delta_raw       = (float*)(ws + 67108864);
  __hip_bfloat16* x_bf   = (__hip_bfloat16*)(ws + 67108864);
  __hip_bfloat16* inw_bf = (__hip_bfloat16*)(ws + 75497472);
  float* Cpart           = (float*)(ws + 67108864);   // 12.6 MB
  __hip_bfloat16* outw_bf= (__hip_bfloat16*)(ws + 67108864);
  float* x_dbl           = (float*)(ws + 100663296);
  float* chunkH          = (float*)(ws + 102236160);
  float* chunkS          = (float*)(ws + 135790592);

  // 1-2. bf16 conversions for in_proj operands (8 elems/thread)
  f2bf_kernel<<<2048, 256, 0, stream>>>(x, x_bf);            // 4096x1024
  f2bf_kernel<<<2048, 256, 0, stream>>>(in_proj_w, inw_bf);  // 4096x1024

  // 3. xz = x @ in_proj_w^T  (M=4096, N=4096, K=1024), bf16 out, dbuf pipeline
  gemm_bt<128, 128, __hip_bfloat16><<<dim3(32, 32), 256, 0, stream>>>(
      x_bf, inw_bf, xz_bf, 1024, 1024, 1024, 4096);

  // 4. depthwise causal conv + bias + silu -> x_act (fp32)
  conv_silu_kernel<<<(BL * D_INNER) / 256, 256, 0, stream>>>(xz_bf, conv_w, conv_b, x_act);

  // 5. x_dbl = x_act @ x_proj_w^T  (4096 x 96, K=2048) via split-K + reduce
  gemm_xproj_splitk<<<dim3(XP_KS, 64), 256, 0, stream>>>(x_act, x_proj_w, Cpart);
  xproj_reduce<<<(BL * XP_N) / 256, 256, 0, stream>>>(Cpart, x_dbl);

  // 6. delta_raw = dt_low @ dt_proj_w^T  (4096 x 2048, K=64); softplus fused into scan
  gemm64g<<<dim3(32, 64), 256, 0, stream>>>(x_dbl, dt_proj_w, delta_raw, BL, 2048, 64,
                                            96, 64, 2048);

  // 7-9. chunked selective scan, lane-owns-d, NCHUNK=128 (8 waves/SIMD)
  scan_pass1<<<2048, 256, 0, stream>>>(delta_raw, x_act, x_dbl, A_log, dt_proj_b,
                                       chunkS, chunkH);
  scan_pass2<<<256, 256, 0, stream>>>(chunkS, A_log, chunkH);
  scan_pass3<<<2048, 256, 0, stream>>>(delta_raw, x_act, x_dbl, A_log, dt_proj_b,
                                       chunkH, D_skip, xz_bf);

  // 10. out_proj weights -> bf16 (delta region dead now)
  f2bf_kernel<<<1024, 256, 0, stream>>>(out_proj_w, outw_bf); // 1024x2048

  // 11. out = y @ out_proj_w^T  (M=4096, N=1024, K=2048), fp32 out, 128x64 tile
  gemm_bt<128, 64, float><<<dim3(16, 32), 256, 0, stream>>>(
      xz_bf, outw_bf, out, 2048, 4096, 2048, 1024);
}

// Round 12
// 268.922 us; speedup vs baseline: 6.1488x; 1.0906x over previous
//
#include <hip/hip_runtime.h>
#include <hip/hip_bf16.h>
#include <cstdint>

#define D_STATE 16
#define D_INNER 2048
#define DT_RANK 64
#define SEQ 2048
#define BL 4096      // B * L
#define NCHUNK 128
#define CHUNK 16     // SEQ / NCHUNK
#define XP_N 96      // dt_rank + 2*d_state
#define XP_KS 8      // x_proj K-splits

typedef short bf16x8 __attribute__((ext_vector_type(8)));
typedef short short8 __attribute__((ext_vector_type(8)));
typedef float f32x4 __attribute__((ext_vector_type(4)));

__device__ __forceinline__ float siluf(float x) {
  return __fdividef(x, 1.f + __expf(-x));
}

__device__ __forceinline__ float softplusf(float v) {
  return fmaxf(v, 0.f) + __logf(1.f + __expf(-fabsf(v)));
}

__device__ __forceinline__ unsigned short f2bf_bits(float x) {
  __hip_bfloat16 h = __float2bfloat16(x);
  return *reinterpret_cast<unsigned short*>(&h);
}

__device__ __forceinline__ float bf2f(short u) {
  return __int_as_float(((unsigned int)(unsigned short)u) << 16);
}

__device__ __forceinline__ void gload_lds16(const void* g, void* l) {
  __builtin_amdgcn_global_load_lds((const __attribute__((address_space(1))) unsigned int*)g,
                                   (__attribute__((address_space(3))) unsigned int*)l,
                                   16, 0, 0);
}

// ---------------- fp32 -> bf16 conversion, 8 elems/thread (n multiple of 2048) --------
__global__ __launch_bounds__(256) void f2bf_kernel(const float* __restrict__ in,
                                                   __hip_bfloat16* __restrict__ out) {
  const int i = (blockIdx.x * 256 + threadIdx.x) * 8;
  float4 v0 = *reinterpret_cast<const float4*>(&in[i]);
  float4 v1 = *reinterpret_cast<const float4*>(&in[i + 4]);
  short8 r;
  r[0] = f2bf_bits(v0.x); r[1] = f2bf_bits(v0.y); r[2] = f2bf_bits(v0.z); r[3] = f2bf_bits(v0.w);
  r[4] = f2bf_bits(v1.x); r[5] = f2bf_bits(v1.y); r[6] = f2bf_bits(v1.z); r[7] = f2bf_bits(v1.w);
  *reinterpret_cast<short8*>(&out[i]) = r;
}

// ---------------- MFMA bf16 GEMM: C = A[M,K] * B[N,K]^T, double-buffered LDS ----------
// SPLITK: blockIdx.x = K-split index z (n0 = 0, K = slice length, C += z*BL*NSTORE).
// NSTORE < BN: store only cols < NSTORE (padded-B trick for small N).
template <int BM, int BN>
__device__ __forceinline__ void stage_tiles(const unsigned short* __restrict__ Ag,
                                            const unsigned short* __restrict__ Bg,
                                            unsigned short* buf, int m0, int n0, int k0,
                                            int lda, int ldb, int sr, int sk, int wv) {
#pragma unroll
  for (int g = 0; g < BM / 64; ++g)
    gload_lds16(&Ag[(size_t)(m0 + g * 64 + sr) * lda + k0 + sk], &buf[g * 2048 + wv * 512]);
#pragma unroll
  for (int g = 0; g < BN / 64; ++g)
    gload_lds16(&Bg[(size_t)(n0 + g * 64 + sr) * ldb + k0 + sk], &buf[BM * 32 + g * 2048 + wv * 512]);
}

template <int BM, int BN, int NSTORE, bool SPLITK, typename OutT>
__global__ __launch_bounds__(256) void gemm_bt(const __hip_bfloat16* __restrict__ A,
                                               const __hip_bfloat16* __restrict__ B,
                                               OutT* __restrict__ C,
                                               int K, int lda, int ldb, int ldc) {
  constexpr int WM = BM / 2, WN = BN / 2;     // wave output tile
  constexpr int MI = WM / 16, NI = WN / 16;   // fragment repeats
  constexpr int BUFS = (BM + BN) * 32;        // shorts per LDS buffer
  __shared__ __align__(16) unsigned short lds[2 * BUFS];
  const int tid = threadIdx.x;
  const int wv = tid >> 6, lane = tid & 63;
  const int wr = wv >> 1, wc = wv & 1;        // wave grid 2x2
  const int m0 = blockIdx.y * BM;
  int n0, koff;
  if constexpr (SPLITK) {
    n0 = 0;
    koff = blockIdx.x * K;
    C += (size_t)blockIdx.x * BL * NSTORE;
  } else {
    n0 = blockIdx.x * BN;
    koff = 0;
  }
  const int sr = tid >> 2;                    // staging row 0..63
  const int sk = (tid & 3) * 8;               // staging k-col (bf16 elems)
  const int frow = lane & 15;
  const int fk = (lane >> 4) * 8;

  f32x4 acc[MI][NI];
#pragma unroll
  for (int i = 0; i < MI; ++i)
#pragma unroll
    for (int j = 0; j < NI; ++j) acc[i][j] = {0.f, 0.f, 0.f, 0.f};

  const unsigned short* Ag = (const unsigned short*)A;
  const unsigned short* Bg = (const unsigned short*)B;

  stage_tiles<BM, BN>(Ag, Bg, &lds[0], m0, n0, koff, lda, ldb, sr, sk, wv);
  __syncthreads();
  int sel = 0;
  for (int k0 = 0; k0 < K; k0 += 32) {
    if (k0 + 32 < K)
      stage_tiles<BM, BN>(Ag, Bg, &lds[(sel ^ 1) * BUFS], m0, n0, koff + k0 + 32, lda, ldb, sr, sk, wv);
    const unsigned short* Abuf = &lds[sel * BUFS];
    const unsigned short* Bbuf = &lds[sel * BUFS + BM * 32];
    bf16x8 af[MI], bfr[NI];
#pragma unroll
    for (int mi = 0; mi < MI; ++mi)
      af[mi] = *reinterpret_cast<const bf16x8*>(&Abuf[(wr * WM + mi * 16 + frow) * 32 + fk]);
#pragma unroll
    for (int ni = 0; ni < NI; ++ni)
      bfr[ni] = *reinterpret_cast<const bf16x8*>(&Bbuf[(wc * WN + ni * 16 + frow) * 32 + fk]);
#pragma unroll
    for (int mi = 0; mi < MI; ++mi)
#pragma unroll
      for (int ni = 0; ni < NI; ++ni)
        acc[mi][ni] = __builtin_amdgcn_mfma_f32_16x16x32_bf16(af[mi], bfr[ni], acc[mi][ni], 0, 0, 0);
    __syncthreads();   // drains stage vmcnt; also fences buf reuse
    sel ^= 1;
  }

  const int crow = (lane >> 4) * 4;
  const int ccol = lane & 15;
#pragma unroll
  for (int mi = 0; mi < MI; ++mi)
#pragma unroll
    for (int ni = 0; ni < NI; ++ni) {
      const int gcol = n0 + wc * WN + ni * 16 + ccol;
      if constexpr (NSTORE < BN) {
        if (gcol >= NSTORE) continue;
      }
#pragma unroll
      for (int j = 0; j < 4; ++j) {
        const int grow = m0 + wr * WM + mi * 16 + crow + j;
        if constexpr (sizeof(OutT) == 2) {
          C[(size_t)grow * ldc + gcol] = __float2bfloat16(acc[mi][ni][j]);
        } else {
          C[(size_t)grow * ldc + gcol] = acc[mi][ni][j];
        }
      }
    }
}

// ---------------- Guarded fp32 GEMM: 64x64 tile (dt_proj) ----------------
__global__ __launch_bounds__(256) void gemm64g(const float* __restrict__ A,
                                               const float* __restrict__ B,
                                               float* __restrict__ C,
                                               int M, int N, int K,
                                               int lda, int ldb, int ldc) {
  __shared__ __align__(16) float As[16][64];
  __shared__ __align__(16) float Bs[16][64];
  const int tid = threadIdx.x;
  const int tx = tid & 15, ty = tid >> 4;
  const int m0 = blockIdx.y * 64, n0 = blockIdx.x * 64;
  const int lrow = tid >> 2;
  const int lc4  = (tid & 3) * 4;

  float acc[4][4];
#pragma unroll
  for (int i = 0; i < 4; ++i)
#pragma unroll
    for (int j = 0; j < 4; ++j) acc[i][j] = 0.f;

  for (int k0 = 0; k0 < K; k0 += 16) {
    __syncthreads();
    {
      float4 av = make_float4(0.f, 0.f, 0.f, 0.f);
      if (m0 + lrow < M)
        av = *reinterpret_cast<const float4*>(&A[(size_t)(m0 + lrow) * lda + k0 + lc4]);
      As[lc4 + 0][lrow] = av.x; As[lc4 + 1][lrow] = av.y;
      As[lc4 + 2][lrow] = av.z; As[lc4 + 3][lrow] = av.w;
      float4 bv = make_float4(0.f, 0.f, 0.f, 0.f);
      if (n0 + lrow < N)
        bv = *reinterpret_cast<const float4*>(&B[(size_t)(n0 + lrow) * ldb + k0 + lc4]);
      Bs[lc4 + 0][lrow] = bv.x; Bs[lc4 + 1][lrow] = bv.y;
      Bs[lc4 + 2][lrow] = bv.z; Bs[lc4 + 3][lrow] = bv.w;
    }
    __syncthreads();
#pragma unroll
    for (int kk = 0; kk < 16; ++kk) {
      float4 a = *reinterpret_cast<const float4*>(&As[kk][ty * 4]);
      float4 b = *reinterpret_cast<const float4*>(&Bs[kk][tx * 4]);
      float av[4] = {a.x, a.y, a.z, a.w};
      float bv[4] = {b.x, b.y, b.z, b.w};
#pragma unroll
      for (int i = 0; i < 4; ++i)
#pragma unroll
        for (int j = 0; j < 4; ++j) acc[i][j] = fmaf(av[i], bv[j], acc[i][j]);
    }
  }

#pragma unroll
  for (int i = 0; i < 4; ++i) {
    int m = m0 + ty * 4 + i;
    if (m >= M) continue;
#pragma unroll
    for (int j = 0; j < 4; ++j) {
      int n = n0 + tx * 4 + j;
      if (n < N) C[(size_t)m * ldc + n] = acc[i][j];
    }
  }
}

// ---------------- x_proj reduce ----------------
__global__ __launch_bounds__(256) void xproj_reduce(const float* __restrict__ Cpart,
                                                    float* __restrict__ x_dbl) {
  const int i = blockIdx.x * 256 + threadIdx.x;    // < BL * XP_N
  float s = 0.f;
#pragma unroll
  for (int z = 0; z < XP_KS; ++z) s += Cpart[(size_t)z * BL * XP_N + i];
  x_dbl[i] = s;
}

// ---------------- depthwise causal conv1d (w=4) + bias + silu, 8 d's/thread ----------
// Writes x_act fp32 (scan) AND x_act_bf bf16 (x_proj MFMA A-operand).
__global__ __launch_bounds__(256) void conv_silu_kernel(const __hip_bfloat16* __restrict__ xz_bf,
                                                        const float* __restrict__ conv_w,
                                                        const float* __restrict__ conv_b,
                                                        float* __restrict__ x_act,
                                                        __hip_bfloat16* __restrict__ x_act_bf) {
  const int idx = blockIdx.x * 256 + threadIdx.x;       // over BL * D_INNER / 8
  const int d8 = (idx << 3) & (D_INNER - 1);
  const int bl = idx >> 8;                               // (idx*8) >> 11
  const int l = bl & (SEQ - 1);

  float acc[8];
  {
    float4 cb0 = *reinterpret_cast<const float4*>(&conv_b[d8]);
    float4 cb1 = *reinterpret_cast<const float4*>(&conv_b[d8 + 4]);
    acc[0] = cb0.x; acc[1] = cb0.y; acc[2] = cb0.z; acc[3] = cb0.w;
    acc[4] = cb1.x; acc[5] = cb1.y; acc[6] = cb1.z; acc[7] = cb1.w;
  }
  float4 cw[8];
#pragma unroll
  for (int j = 0; j < 8; ++j)
    cw[j] = *reinterpret_cast<const float4*>(&conv_w[(d8 + j) * 4]);

#pragma unroll
  for (int k = 0; k < 4; ++k) {
    if (l + k - 3 >= 0) {
      short8 v = *reinterpret_cast<const short8*>(&xz_bf[(size_t)(bl + k - 3) * 4096 + d8]);
      const float w0[8] = {cw[0].x, cw[1].x, cw[2].x, cw[3].x, cw[4].x, cw[5].x, cw[6].x, cw[7].x};
      const float w1[8] = {cw[0].y, cw[1].y, cw[2].y, cw[3].y, cw[4].y, cw[5].y, cw[6].y, cw[7].y};
      const float w2[8] = {cw[0].z, cw[1].z, cw[2].z, cw[3].z, cw[4].z, cw[5].z, cw[6].z, cw[7].z};
      const float w3[8] = {cw[0].w, cw[1].w, cw[2].w, cw[3].w, cw[4].w, cw[5].w, cw[6].w, cw[7].w};
      const float* wk = (k == 0) ? w0 : (k == 1) ? w1 : (k == 2) ? w2 : w3;
#pragma unroll
      for (int j = 0; j < 8; ++j) acc[j] = fmaf(bf2f(v[j]), wk[j], acc[j]);
    }
  }

  float o[8];
  short8 ob;
#pragma unroll
  for (int j = 0; j < 8; ++j) {
    o[j] = siluf(acc[j]);
    ob[j] = f2bf_bits(o[j]);
  }
  const size_t oi = (size_t)bl * D_INNER + d8;
  *reinterpret_cast<float4*>(&x_act[oi])     = make_float4(o[0], o[1], o[2], o[3]);
  *reinterpret_cast<float4*>(&x_act[oi + 4]) = make_float4(o[4], o[5], o[6], o[7]);
  *reinterpret_cast<short8*>(&x_act_bf[oi])  = ob;
}

// ---------------- scan pass 1: lane owns d; 16 n-states in registers ----------------
__global__ __launch_bounds__(256) void scan_pass1(const float* __restrict__ delta_raw,
                                                  const float* __restrict__ x_act,
                                                  const float* __restrict__ x_dbl,
                                                  const float* __restrict__ A_log,
                                                  const float* __restrict__ dt_proj_b,
                                                  float* __restrict__ chunkS,
                                                  float* __restrict__ chunkH) {
  const int t = blockIdx.x * 256 + threadIdx.x;
  const int d = t & (D_INNER - 1);
  const int c = (t >> 11) & (NCHUNK - 1);
  const int b = t >> 18;
  const int base = b * SEQ + c * CHUNK;

  float Av[16];
#pragma unroll
  for (int q = 0; q < 4; ++q) {
    float4 a = *reinterpret_cast<const float4*>(&A_log[d * 16 + q * 4]);
    Av[q * 4 + 0] = -__expf(a.x); Av[q * 4 + 1] = -__expf(a.y);
    Av[q * 4 + 2] = -__expf(a.z); Av[q * 4 + 3] = -__expf(a.w);
  }
  const float bias = dt_proj_b[d];

  const float* dp = delta_raw + (size_t)base * D_INNER + d;
  const float* up = x_act + (size_t)base * D_INNER + d;
  const float* xb = x_dbl + (size_t)base * 96 + DT_RANK;   // B block (16 floats)

  float h[16];
#pragma unroll
  for (int n = 0; n < 16; ++n) h[n] = 0.f;
  float S = 0.f;

  float dvr = *dp, uvv = *up;
  float4 b0 = *reinterpret_cast<const float4*>(xb);
  float4 b1 = *reinterpret_cast<const float4*>(xb + 4);
  float4 b2 = *reinterpret_cast<const float4*>(xb + 8);
  float4 b3 = *reinterpret_cast<const float4*>(xb + 12);
  for (int l = 0; l < CHUNK; ++l) {
    dp += D_INNER; up += D_INNER; xb += 96;
    const float ndvr = *dp, nuv = *up;
    const float4 nb0 = *reinterpret_cast<const float4*>(xb);
    const float4 nb1 = *reinterpret_cast<const float4*>(xb + 4);
    const float4 nb2 = *reinterpret_cast<const float4*>(xb + 8);
    const float4 nb3 = *reinterpret_cast<const float4*>(xb + 12);

    const float dv = softplusf(dvr + bias);
    S += dv;
    const float du = dv * uvv;
    const float Bf[16] = {b0.x, b0.y, b0.z, b0.w, b1.x, b1.y, b1.z, b1.w,
                          b2.x, b2.y, b2.z, b2.w, b3.x, b3.y, b3.z, b3.w};
#pragma unroll
    for (int n = 0; n < 16; ++n) {
      const float dA = __expf(dv * Av[n]);
      h[n] = fmaf(dA, h[n], du * Bf[n]);
    }
    dvr = ndvr; uvv = nuv; b0 = nb0; b1 = nb1; b2 = nb2; b3 = nb3;
  }

  const size_t sidx = (size_t)(b * NCHUNK + c) * D_INNER + d;
  chunkS[sidx] = S;
  float* hp = chunkH + sidx * 16;
#pragma unroll
  for (int q = 0; q < 4; ++q)
    *reinterpret_cast<float4*>(hp + q * 4) =
        make_float4(h[q * 4 + 0], h[q * 4 + 1], h[q * 4 + 2], h[q * 4 + 3]);
}

// ---------------- scan pass 2: combine chunk prefixes; chunkH becomes h0 ----------------
__global__ __launch_bounds__(256) void scan_pass2(const float* __restrict__ chunkS,
                                                  const float* __restrict__ A_log,
                                                  float* chunkH) {
  const int s = blockIdx.x * 256 + threadIdx.x;   // 65536 = (b, d, n)
  const int n = s & 15;
  const int d = (s >> 4) & (D_INNER - 1);
  const int b = s >> 15;
  const float Aval = -__expf(A_log[d * 16 + n]);

  size_t sidx = (size_t)b * NCHUNK * D_INNER + d;
  float aS = chunkS[sidx];
  float hE = chunkH[sidx * 16 + n];
  float H = 0.f;
  for (int c = 0; c < NCHUNK; ++c) {
    const size_t sidx2 = sidx + D_INNER;
    const float naS = chunkS[sidx2];            // overread at c==NC-1: inside ws
    const float nhE = chunkH[sidx2 * 16 + n];
    const float aP = __expf(Aval * aS);
    chunkH[sidx * 16 + n] = H;                  // h0 for this chunk
    H = fmaf(aP, H, hE);
    sidx = sidx2; aS = naS; hE = nhE;
  }
}

// ---------------- scan pass 3: rescan with h0; fused D-skip + silu(z) gate -> bf16 ------
__global__ __launch_bounds__(256) void scan_pass3(const float* __restrict__ delta_raw,
                                                  const float* __restrict__ x_act,
                                                  const float* __restrict__ x_dbl,
                                                  const float* __restrict__ A_log,
                                                  const float* __restrict__ dt_proj_b,
                                                  const float* __restrict__ chunkH0,
                                                  const float* __restrict__ D_skip,
                                                  __hip_bfloat16* xz_bf) {
  const int t = blockIdx.x * 256 + threadIdx.x;
  const int d = t & (D_INNER - 1);
  const int c = (t >> 11) & (NCHUNK - 1);
  const int b = t >> 18;
  const int base = b * SEQ + c * CHUNK;

  float Av[16];
#pragma unroll
  for (int q = 0; q < 4; ++q) {
    float4 a = *reinterpret_cast<const float4*>(&A_log[d * 16 + q * 4]);
    Av[q * 4 + 0] = -__expf(a.x); Av[q * 4 + 1] = -__expf(a.y);
    Av[q * 4 + 2] = -__expf(a.z); Av[q * 4 + 3] = -__expf(a.w);
  }
  const float bias = dt_proj_b[d];
  const float Dv = D_skip[d];

  const float* dp = delta_raw + (size_t)base * D_INNER + d;
  const float* up = x_act + (size_t)base * D_INNER + d;
  const float* xb = x_dbl + (size_t)base * 96 + DT_RANK;      // B at [0..15], C at [16..31]
  __hip_bfloat16* zp = xz_bf + (size_t)base * 4096 + D_INNER + d;

  float h[16];
  {
    const float* hp = chunkH0 + ((size_t)(b * NCHUNK + c) * D_INNER + d) * 16;
#pragma unroll
    for (int q = 0; q < 4; ++q) {
      float4 v = *reinterpret_cast<const float4*>(hp + q * 4);
      h[q * 4 + 0] = v.x; h[q * 4 + 1] = v.y; h[q * 4 + 2] = v.z; h[q * 4 + 3] = v.w;
    }
  }

  float dvr = *dp, uvv = *up;
  float4 b0 = *reinterpret_cast<const float4*>(xb);
  float4 b1 = *reinterpret_cast<const float4*>(xb + 4);
  float4 b2 = *reinterpret_cast<const float4*>(xb + 8);
  float4 b3 = *reinterpret_cast<const float4*>(xb + 12);
  float4 c0 = *reinterpret_cast<const float4*>(xb + 16);
  float4 c1 = *reinterpret_cast<const float4*>(xb + 20);
  float4 c2 = *reinterpret_cast<const float4*>(xb + 24);
  float4 c3 = *reinterpret_cast<const float4*>(xb + 28);
  for (int l = 0; l < CHUNK; ++l) {
    dp += D_INNER; up += D_INNER; xb += 96;
    const float ndvr = *dp, nuv = *up;
    const float4 nb0 = *reinterpret_cast<const float4*>(xb);
    const float4 nb1 = *reinterpret_cast<const float4*>(xb + 4);
    const float4 nb2 = *reinterpret_cast<const float4*>(xb + 8);
    const float4 nb3 = *reinterpret_cast<const float4*>(xb + 12);
    const float4 nc0 = *reinterpret_cast<const float4*>(xb + 16);
    const float4 nc1 = *reinterpret_cast<const float4*>(xb + 20);
    const float4 nc2 = *reinterpret_cast<const float4*>(xb + 24);
    const float4 nc3 = *reinterpret_cast<const float4*>(xb + 28);

    const float dv = softplusf(dvr + bias);
    const float du = dv * uvv;
    const float Bf[16] = {b0.x, b0.y, b0.z, b0.w, b1.x, b1.y, b1.z, b1.w,
                          b2.x, b2.y, b2.z, b2.w, b3.x, b3.y, b3.z, b3.w};
    const float Cf[16] = {c0.x, c0.y, c0.z, c0.w, c1.x, c1.y, c1.z, c1.w,
                          c2.x, c2.y, c2.z, c2.w, c3.x, c3.y, c3.z, c3.w};
    float p = 0.f;
#pragma unroll
    for (int n = 0; n < 16; ++n) {
      const float dA = __expf(dv * Av[n]);
      h[n] = fmaf(dA, h[n], du * Bf[n]);
      p = fmaf(h[n], Cf[n], p);
    }
    const float zv = __bfloat162float(zp[0]);
    const float yv = fmaf(uvv, Dv, p) * siluf(zv);
    zp[-(int)D_INNER] = __float2bfloat16(yv);
    zp += 4096;

    dvr = ndvr; uvv = nuv;
    b0 = nb0; b1 = nb1; b2 = nb2; b3 = nb3;
    c0 = nc0; c1 = nc1; c2 = nc2; c3 = nc3;
  }
}

extern "C" void kernel_launch(void* const* d_in, const int* in_sizes, int n_in,
                              void* d_out, int out_size, void* d_ws, size_t ws_size,
                              hipStream_t stream) {
  const float* x          = (const float*)d_in[0];
  const float* in_proj_w  = (const float*)d_in[1];
  const float* conv_w     = (const float*)d_in[2];
  const float* conv_b     = (const float*)d_in[3];
  const float* x_proj_w   = (const float*)d_in[4];
  const float* dt_proj_w  = (const float*)d_in[5];
  const float* dt_proj_b  = (const float*)d_in[6];
  const float* A_log      = (const float*)d_in[7];
  const float* D_skip     = (const float*)d_in[8];
  const float* out_proj_w = (const float*)d_in[9];
  float* out = (float*)d_out;   // fp32 output

  // Workspace layout (peak ~132 MiB):
  //   xz_bf     @0          33,554,432  bf16 [4096][4096]
  //   x_act     @33554432   33,554,432  fp32 [4096][2048]
  //   delta_raw @67108864   33,554,432  (time-shared: x_bf/inw_bf -> Cpart -> delta_raw -> outw_bf)
  //   x_dbl     @100663296   1,572,864
  //   chunkH    @102236160  33,554,432  (time-shared: x_act_bf 16.7MB pre-scan)
  //   chunkS    @135790592   2,097,152
  //   wpad      @137887744     524,288  bf16 [128][2048] padded x_proj_w
  char* ws = (char*)d_ws;
  __hip_bfloat16* xz_bf    = (__hip_bfloat16*)(ws);
  float* x_act             = (float*)(ws + 33554432);
  float* delta_raw         = (float*)(ws + 67108864);
  __hip_bfloat16* x_bf     = (__hip_bfloat16*)(ws + 67108864);
  __hip_bfloat16* inw_bf   = (__hip_bfloat16*)(ws + 75497472);
  float* Cpart             = (float*)(ws + 67108864);   // 12.6 MB, pre-delta
  __hip_bfloat16* outw_bf  = (__hip_bfloat16*)(ws + 67108864);
  float* x_dbl             = (float*)(ws + 100663296);
  float* chunkH            = (float*)(ws + 102236160);
  __hip_bfloat16* x_act_bf = (__hip_bfloat16*)(ws + 102236160);  // aliases chunkH (pre-scan)
  float* chunkS            = (float*)(ws + 135790592);
  __hip_bfloat16* wpad     = (__hip_bfloat16*)(ws + 137887744);

  // 1-2. bf16 conversions for in_proj operands (8 elems/thread)
  f2bf_kernel<<<2048, 256, 0, stream>>>(x, x_bf);            // 4096x1024
  f2bf_kernel<<<2048, 256, 0, stream>>>(in_proj_w, inw_bf);  // 4096x1024

  // 3. xz = x @ in_proj_w^T  (M=4096, N=4096, K=1024), bf16 out, dbuf pipeline
  gemm_bt<128, 128, 128, false, __hip_bfloat16><<<dim3(32, 32), 256, 0, stream>>>(
      x_bf, inw_bf, xz_bf, 1024, 1024, 1024, 4096);

  // 4. depthwise causal conv + bias + silu -> x_act (fp32) + x_act_bf (bf16)
  conv_silu_kernel<<<(BL * D_INNER) / 8 / 256, 256, 0, stream>>>(
      xz_bf, conv_w, conv_b, x_act, x_act_bf);

  // 5. x_dbl = x_act @ x_proj_w^T via bf16 MFMA split-K (padded 96->128 weight) + reduce
  f2bf_kernel<<<96, 256, 0, stream>>>(x_proj_w, (__hip_bfloat16*)wpad);  // 96x2048
  gemm_bt<128, 128, XP_N, true, float><<<dim3(XP_KS, 32), 256, 0, stream>>>(
      x_act_bf, wpad, Cpart, 2048 / XP_KS, 2048, 2048, XP_N);
  xproj_reduce<<<(BL * XP_N) / 256, 256, 0, stream>>>(Cpart, x_dbl);

  // 6. delta_raw = dt_low @ dt_proj_w^T  (4096 x 2048, K=64); softplus fused into scan
  gemm64g<<<dim3(32, 64), 256, 0, stream>>>(x_dbl, dt_proj_w, delta_raw, BL, 2048, 64,
                                            96, 64, 2048);

  // 7-9. chunked selective scan, lane-owns-d, NCHUNK=128 (8 waves/SIMD)
  scan_pass1<<<2048, 256, 0, stream>>>(delta_raw, x_act, x_dbl, A_log, dt_proj_b,
                                       chunkS, chunkH);
  scan_pass2<<<256, 256, 0, stream>>>(chunkS, A_log, chunkH);
  scan_pass3<<<2048, 256, 0, stream>>>(delta_raw, x_act, x_dbl, A_log, dt_proj_b,
                                       chunkH, D_skip, xz_bf);

  // 10. out_proj weights -> bf16 (delta region dead now)
  f2bf_kernel<<<1024, 256, 0, stream>>>(out_proj_w, outw_bf); // 1024x2048

  // 11. out = y @ out_proj_w^T  (M=4096, N=1024, K=2048), fp32 out, 128x64 tile
  gemm_bt<128, 64, 64, false, float><<<dim3(16, 32), 256, 0, stream>>>(
      xz_bf, outw_bf, out, 2048, 4096, 2048, 1024);
}

// Round 13
// 259.090 us; speedup vs baseline: 6.3822x; 1.0380x over previous
//
#include <hip/hip_runtime.h>
#include <hip/hip_bf16.h>
#include <cstdint>

#define D_STATE 16
#define D_INNER 2048
#define DT_RANK 64
#define SEQ 2048
#define BL 4096      // B * L
#define NCHUNK 128
#define CHUNK 16     // SEQ / NCHUNK
#define XP_N 96      // dt_rank + 2*d_state
#define XP_KS 8      // x_proj K-splits

typedef short bf16x8 __attribute__((ext_vector_type(8)));
typedef short short8 __attribute__((ext_vector_type(8)));
typedef float f32x4 __attribute__((ext_vector_type(4)));

__device__ __forceinline__ float siluf(float x) {
  return __fdividef(x, 1.f + __expf(-x));
}

__device__ __forceinline__ float softplusf(float v) {
  return fmaxf(v, 0.f) + __logf(1.f + __expf(-fabsf(v)));
}

__device__ __forceinline__ unsigned short f2bf_bits(float x) {
  __hip_bfloat16 h = __float2bfloat16(x);
  return *reinterpret_cast<unsigned short*>(&h);
}

__device__ __forceinline__ float bf2f(short u) {
  return __int_as_float(((unsigned int)(unsigned short)u) << 16);
}

__device__ __forceinline__ void gload_lds16(const void* g, void* l) {
  __builtin_amdgcn_global_load_lds((const __attribute__((address_space(1))) unsigned int*)g,
                                   (__attribute__((address_space(3))) unsigned int*)l,
                                   16, 0, 0);
}

#define BARRIER() asm volatile("s_barrier" ::: "memory")
#define VMCNT(n)  asm volatile("s_waitcnt vmcnt(" #n ")" ::: "memory")

// ---------------- fp32 -> bf16 conversion, 8 elems/thread (n multiple of 2048) --------
__global__ __launch_bounds__(256) void f2bf_kernel(const float* __restrict__ in,
                                                   __hip_bfloat16* __restrict__ out) {
  const int i = (blockIdx.x * 256 + threadIdx.x) * 8;
  float4 v0 = *reinterpret_cast<const float4*>(&in[i]);
  float4 v1 = *reinterpret_cast<const float4*>(&in[i + 4]);
  short8 r;
  r[0] = f2bf_bits(v0.x); r[1] = f2bf_bits(v0.y); r[2] = f2bf_bits(v0.z); r[3] = f2bf_bits(v0.w);
  r[4] = f2bf_bits(v1.x); r[5] = f2bf_bits(v1.y); r[6] = f2bf_bits(v1.z); r[7] = f2bf_bits(v1.w);
  *reinterpret_cast<short8*>(&out[i]) = r;
}

// ============ 8-phase 256x256 bf16 GEMM (T2+T3+T4+T5): C = A[M,K] @ B[N,K]^T ============
// 512 thr = 8 waves (2M x 4N); per-wave out 128x64; BK=64; LDS 128KB dbuf, st-swizzled.
// Staging order per K-tile: B0,B1 | B2,B3 | A0,A2 | A1,A3 (64-row groups). Derived waits:
// vmcnt(2)@p0 (prev tile's A1,A3 land), vmcnt(2)@p3 (next tile's first 6 units land).
// K-accumulation order per output element identical to the 2-phase kernel (bitwise same C).
template <typename OutT>
__global__ __launch_bounds__(512, 1) void gemm256_8ph(const __hip_bfloat16* __restrict__ A,
                                                      const __hip_bfloat16* __restrict__ B,
                                                      OutT* __restrict__ C,
                                                      int K, int lda, int ldb, int ldc) {
  __shared__ __align__(16) unsigned short lds[65536];  // [2 buf][A 16384 | B 16384] shorts
  const int tid = threadIdx.x;
  const int wv = tid >> 6, lane = tid & 63;
  const int wr = wv >> 2, wc = wv & 3;              // wave grid 2(M) x 4(N)
  const int m0 = blockIdx.y * 256, n0 = blockIdx.x * 256;
  const int frow = lane & 15;                       // fragment row
  const int fu = lane >> 4;                         // 16B-unit index (k/8)
  const int rsw = frow & 7;                         // read-side swizzle key
  const int sr = lane >> 3;                         // staging row-in-8
  const int su = (lane & 7) ^ sr;                   // pre-swizzled source k-unit (rule 21)

  const unsigned short* Ag = (const unsigned short*)A;
  const unsigned short* Bg = (const unsigned short*)B;

  f32x4 acc[8][4];
#pragma unroll
  for (int i = 0; i < 8; ++i)
#pragma unroll
    for (int j = 0; j < 4; ++j) acc[i][j] = {0.f, 0.f, 0.f, 0.f};

  // stage one 64-row group (g) of A or B for K-offset kg into buf (1 gload/wave)
  auto stageA = [&](int buf, int g, int kg) {
    const int rowb = g * 64 + wv * 8;
    gload_lds16(&Ag[(size_t)(m0 + rowb + sr) * lda + kg + su * 8],
                &lds[buf * 32768 + rowb * 64]);
  };
  auto stageB = [&](int buf, int g, int kg) {
    const int rowb = g * 64 + wv * 8;
    gload_lds16(&Bg[(size_t)(n0 + rowb + sr) * ldb + kg + su * 8],
                &lds[buf * 32768 + 16384 + rowb * 64]);
  };
  auto fragA = [&](int buf, int mi, int kk) -> bf16x8 {
    const int row = wr * 128 + mi * 16 + frow;
    return *reinterpret_cast<const bf16x8*>(
        &lds[buf * 32768 + row * 64 + (((kk << 2) | fu) ^ rsw) * 8]);
  };
  auto fragB = [&](int buf, int ni, int kk) -> bf16x8 {
    const int row = wc * 64 + ni * 16 + frow;
    return *reinterpret_cast<const bf16x8*>(
        &lds[buf * 32768 + 16384 + row * 64 + (((kk << 2) | fu) ^ rsw) * 8]);
  };

#define QUAD(MB)                                                                        \
  _Pragma("unroll")                                                                     \
  for (int mi = 0; mi < 4; ++mi)                                                        \
    _Pragma("unroll")                                                                   \
    for (int ni = 0; ni < 4; ++ni)                                                      \
      acc[MB + mi][ni] =                                                                \
          __builtin_amdgcn_mfma_f32_16x16x32_bf16(af[mi], bfr[ni], acc[MB + mi][ni], 0, 0, 0);

  // prologue: stage tile 0 (canonical order), ensure its first 6 units before p0 reads
  stageB(0, 0, 0); stageB(0, 1, 0); stageB(0, 2, 0); stageB(0, 3, 0);
  stageA(0, 0, 0); stageA(0, 2, 0); stageA(0, 1, 0); stageA(0, 3, 0);
  VMCNT(2);
  BARRIER();

  const int NT = K >> 6;
  int cur = 0;
  for (int t = 0; t < NT - 1; ++t) {
    const int nxt = cur ^ 1;
    const int kn = (t + 1) << 6;
    bf16x8 af[4], bfr[4];
    // ---- phase 0: kk0, mi 0-3 (+ B frags kk0); stage next B0,B1; drain prev A1,A3
#pragma unroll
    for (int mi = 0; mi < 4; ++mi) af[mi] = fragA(cur, mi, 0);
#pragma unroll
    for (int ni = 0; ni < 4; ++ni) bfr[ni] = fragB(cur, ni, 0);
    stageB(nxt, 0, kn); stageB(nxt, 1, kn);
    VMCNT(2);
    BARRIER();
    __builtin_amdgcn_s_setprio(1);
    QUAD(0);
    __builtin_amdgcn_s_setprio(0);
    BARRIER();
    // ---- phase 1: kk0, mi 4-7; stage next B2,B3
#pragma unroll
    for (int mi = 0; mi < 4; ++mi) af[mi] = fragA(cur, 4 + mi, 0);
    stageB(nxt, 2, kn); stageB(nxt, 3, kn);
    BARRIER();
    __builtin_amdgcn_s_setprio(1);
    QUAD(4);
    __builtin_amdgcn_s_setprio(0);
    BARRIER();
    // ---- phase 2: kk1, mi 0-3 (+ B frags kk1); stage next A0,A2
#pragma unroll
    for (int mi = 0; mi < 4; ++mi) af[mi] = fragA(cur, mi, 1);
#pragma unroll
    for (int ni = 0; ni < 4; ++ni) bfr[ni] = fragB(cur, ni, 1);
    stageA(nxt, 0, kn); stageA(nxt, 2, kn);
    BARRIER();
    __builtin_amdgcn_s_setprio(1);
    QUAD(0);
    __builtin_amdgcn_s_setprio(0);
    BARRIER();
    // ---- phase 3: kk1, mi 4-7; stage next A1,A3; ensure next tile's first 6 units
#pragma unroll
    for (int mi = 0; mi < 4; ++mi) af[mi] = fragA(cur, 4 + mi, 1);
    stageA(nxt, 1, kn); stageA(nxt, 3, kn);
    VMCNT(2);
    BARRIER();
    __builtin_amdgcn_s_setprio(1);
    QUAD(4);
    __builtin_amdgcn_s_setprio(0);
    BARRIER();
    cur = nxt;
  }
  // ---- last tile (no staging): vmcnt(0)@p0 guarantees its A1,A3 landed
  {
    bf16x8 af[4], bfr[4];
#pragma unroll
    for (int mi = 0; mi < 4; ++mi) af[mi] = fragA(cur, mi, 0);
#pragma unroll
    for (int ni = 0; ni < 4; ++ni) bfr[ni] = fragB(cur, ni, 0);
    VMCNT(0);
    BARRIER();
    __builtin_amdgcn_s_setprio(1);
    QUAD(0);
    __builtin_amdgcn_s_setprio(0);
    BARRIER();
#pragma unroll
    for (int mi = 0; mi < 4; ++mi) af[mi] = fragA(cur, 4 + mi, 0);
    BARRIER();
    __builtin_amdgcn_s_setprio(1);
    QUAD(4);
    __builtin_amdgcn_s_setprio(0);
    BARRIER();
#pragma unroll
    for (int mi = 0; mi < 4; ++mi) af[mi] = fragA(cur, mi, 1);
#pragma unroll
    for (int ni = 0; ni < 4; ++ni) bfr[ni] = fragB(cur, ni, 1);
    BARRIER();
    __builtin_amdgcn_s_setprio(1);
    QUAD(0);
    __builtin_amdgcn_s_setprio(0);
    BARRIER();
#pragma unroll
    for (int mi = 0; mi < 4; ++mi) af[mi] = fragA(cur, 4 + mi, 1);
    __builtin_amdgcn_s_setprio(1);
    QUAD(4);
    __builtin_amdgcn_s_setprio(0);
  }
#undef QUAD

  // epilogue: C/D layout col=lane&15, row=(lane>>4)*4+reg (m89-verified)
  const int crow = fu * 4;
  const int ccol = frow;
#pragma unroll
  for (int mi = 0; mi < 8; ++mi)
#pragma unroll
    for (int ni = 0; ni < 4; ++ni) {
      const int gcol = n0 + wc * 64 + ni * 16 + ccol;
#pragma unroll
      for (int j = 0; j < 4; ++j) {
        const int grow = m0 + wr * 128 + mi * 16 + crow + j;
        if constexpr (sizeof(OutT) == 2) {
          C[(size_t)grow * ldc + gcol] = __float2bfloat16(acc[mi][ni][j]);
        } else {
          C[(size_t)grow * ldc + gcol] = acc[mi][ni][j];
        }
      }
    }
}

// ---------------- MFMA bf16 GEMM: C = A[M,K] * B[N,K]^T, double-buffered LDS ----------
// (2-phase structure; used for out_proj and x_proj split-K)
template <int BM, int BN>
__device__ __forceinline__ void stage_tiles(const unsigned short* __restrict__ Ag,
                                            const unsigned short* __restrict__ Bg,
                                            unsigned short* buf, int m0, int n0, int k0,
                                            int lda, int ldb, int sr, int sk, int wv) {
#pragma unroll
  for (int g = 0; g < BM / 64; ++g)
    gload_lds16(&Ag[(size_t)(m0 + g * 64 + sr) * lda + k0 + sk], &buf[g * 2048 + wv * 512]);
#pragma unroll
  for (int g = 0; g < BN / 64; ++g)
    gload_lds16(&Bg[(size_t)(n0 + g * 64 + sr) * ldb + k0 + sk], &buf[BM * 32 + g * 2048 + wv * 512]);
}

template <int BM, int BN, int NSTORE, bool SPLITK, typename OutT>
__global__ __launch_bounds__(256) void gemm_bt(const __hip_bfloat16* __restrict__ A,
                                               const __hip_bfloat16* __restrict__ B,
                                               OutT* __restrict__ C,
                                               int K, int lda, int ldb, int ldc) {
  constexpr int WM = BM / 2, WN = BN / 2;
  constexpr int MI = WM / 16, NI = WN / 16;
  constexpr int BUFS = (BM + BN) * 32;
  __shared__ __align__(16) unsigned short lds[2 * BUFS];
  const int tid = threadIdx.x;
  const int wv = tid >> 6, lane = tid & 63;
  const int wr = wv >> 1, wc = wv & 1;
  const int m0 = blockIdx.y * BM;
  int n0, koff;
  if constexpr (SPLITK) {
    n0 = 0;
    koff = blockIdx.x * K;
    C += (size_t)blockIdx.x * BL * NSTORE;
  } else {
    n0 = blockIdx.x * BN;
    koff = 0;
  }
  const int sr = tid >> 2;
  const int sk = (tid & 3) * 8;
  const int frow = lane & 15;
  const int fk = (lane >> 4) * 8;

  f32x4 acc[MI][NI];
#pragma unroll
  for (int i = 0; i < MI; ++i)
#pragma unroll
    for (int j = 0; j < NI; ++j) acc[i][j] = {0.f, 0.f, 0.f, 0.f};

  const unsigned short* Ag = (const unsigned short*)A;
  const unsigned short* Bg = (const unsigned short*)B;

  stage_tiles<BM, BN>(Ag, Bg, &lds[0], m0, n0, koff, lda, ldb, sr, sk, wv);
  __syncthreads();
  int sel = 0;
  for (int k0 = 0; k0 < K; k0 += 32) {
    if (k0 + 32 < K)
      stage_tiles<BM, BN>(Ag, Bg, &lds[(sel ^ 1) * BUFS], m0, n0, koff + k0 + 32, lda, ldb, sr, sk, wv);
    const unsigned short* Abuf = &lds[sel * BUFS];
    const unsigned short* Bbuf = &lds[sel * BUFS + BM * 32];
    bf16x8 af[MI], bfr[NI];
#pragma unroll
    for (int mi = 0; mi < MI; ++mi)
      af[mi] = *reinterpret_cast<const bf16x8*>(&Abuf[(wr * WM + mi * 16 + frow) * 32 + fk]);
#pragma unroll
    for (int ni = 0; ni < NI; ++ni)
      bfr[ni] = *reinterpret_cast<const bf16x8*>(&Bbuf[(wc * WN + ni * 16 + frow) * 32 + fk]);
#pragma unroll
    for (int mi = 0; mi < MI; ++mi)
#pragma unroll
      for (int ni = 0; ni < NI; ++ni)
        acc[mi][ni] = __builtin_amdgcn_mfma_f32_16x16x32_bf16(af[mi], bfr[ni], acc[mi][ni], 0, 0, 0);
    __syncthreads();
    sel ^= 1;
  }

  const int crow = (lane >> 4) * 4;
  const int ccol = lane & 15;
#pragma unroll
  for (int mi = 0; mi < MI; ++mi)
#pragma unroll
    for (int ni = 0; ni < NI; ++ni) {
      const int gcol = n0 + wc * WN + ni * 16 + ccol;
      if constexpr (NSTORE < BN) {
        if (gcol >= NSTORE) continue;
      }
#pragma unroll
      for (int j = 0; j < 4; ++j) {
        const int grow = m0 + wr * WM + mi * 16 + crow + j;
        if constexpr (sizeof(OutT) == 2) {
          C[(size_t)grow * ldc + gcol] = __float2bfloat16(acc[mi][ni][j]);
        } else {
          C[(size_t)grow * ldc + gcol] = acc[mi][ni][j];
        }
      }
    }
}

// ---------------- Guarded fp32 GEMM: 64x64 tile (dt_proj) ----------------
__global__ __launch_bounds__(256) void gemm64g(const float* __restrict__ A,
                                               const float* __restrict__ B,
                                               float* __restrict__ C,
                                               int M, int N, int K,
                                               int lda, int ldb, int ldc) {
  __shared__ __align__(16) float As[16][64];
  __shared__ __align__(16) float Bs[16][64];
  const int tid = threadIdx.x;
  const int tx = tid & 15, ty = tid >> 4;
  const int m0 = blockIdx.y * 64, n0 = blockIdx.x * 64;
  const int lrow = tid >> 2;
  const int lc4  = (tid & 3) * 4;

  float acc[4][4];
#pragma unroll
  for (int i = 0; i < 4; ++i)
#pragma unroll
    for (int j = 0; j < 4; ++j) acc[i][j] = 0.f;

  for (int k0 = 0; k0 < K; k0 += 16) {
    __syncthreads();
    {
      float4 av = make_float4(0.f, 0.f, 0.f, 0.f);
      if (m0 + lrow < M)
        av = *reinterpret_cast<const float4*>(&A[(size_t)(m0 + lrow) * lda + k0 + lc4]);
      As[lc4 + 0][lrow] = av.x; As[lc4 + 1][lrow] = av.y;
      As[lc4 + 2][lrow] = av.z; As[lc4 + 3][lrow] = av.w;
      float4 bv = make_float4(0.f, 0.f, 0.f, 0.f);
      if (n0 + lrow < N)
        bv = *reinterpret_cast<const float4*>(&B[(size_t)(n0 + lrow) * ldb + k0 + lc4]);
      Bs[lc4 + 0][lrow] = bv.x; Bs[lc4 + 1][lrow] = bv.y;
      Bs[lc4 + 2][lrow] = bv.z; Bs[lc4 + 3][lrow] = bv.w;
    }
    __syncthreads();
#pragma unroll
    for (int kk = 0; kk < 16; ++kk) {
      float4 a = *reinterpret_cast<const float4*>(&As[kk][ty * 4]);
      float4 b = *reinterpret_cast<const float4*>(&Bs[kk][tx * 4]);
      float av[4] = {a.x, a.y, a.z, a.w};
      float bv[4] = {b.x, b.y, b.z, b.w};
#pragma unroll
      for (int i = 0; i < 4; ++i)
#pragma unroll
        for (int j = 0; j < 4; ++j) acc[i][j] = fmaf(av[i], bv[j], acc[i][j]);
    }
  }

#pragma unroll
  for (int i = 0; i < 4; ++i) {
    int m = m0 + ty * 4 + i;
    if (m >= M) continue;
#pragma unroll
    for (int j = 0; j < 4; ++j) {
      int n = n0 + tx * 4 + j;
      if (n < N) C[(size_t)m * ldc + n] = acc[i][j];
    }
  }
}

// ---------------- x_proj reduce ----------------
__global__ __launch_bounds__(256) void xproj_reduce(const float* __restrict__ Cpart,
                                                    float* __restrict__ x_dbl) {
  const int i = blockIdx.x * 256 + threadIdx.x;    // < BL * XP_N
  float s = 0.f;
#pragma unroll
  for (int z = 0; z < XP_KS; ++z) s += Cpart[(size_t)z * BL * XP_N + i];
  x_dbl[i] = s;
}

// ---------------- depthwise causal conv1d (w=4) + bias + silu, 8 d's/thread ----------
__global__ __launch_bounds__(256) void conv_silu_kernel(const __hip_bfloat16* __restrict__ xz_bf,
                                                        const float* __restrict__ conv_w,
                                                        const float* __restrict__ conv_b,
                                                        float* __restrict__ x_act,
                                                        __hip_bfloat16* __restrict__ x_act_bf) {
  const int idx = blockIdx.x * 256 + threadIdx.x;       // over BL * D_INNER / 8
  const int d8 = (idx << 3) & (D_INNER - 1);
  const int bl = idx >> 8;
  const int l = bl & (SEQ - 1);

  float acc[8];
  {
    float4 cb0 = *reinterpret_cast<const float4*>(&conv_b[d8]);
    float4 cb1 = *reinterpret_cast<const float4*>(&conv_b[d8 + 4]);
    acc[0] = cb0.x; acc[1] = cb0.y; acc[2] = cb0.z; acc[3] = cb0.w;
    acc[4] = cb1.x; acc[5] = cb1.y; acc[6] = cb1.z; acc[7] = cb1.w;
  }
  float4 cw[8];
#pragma unroll
  for (int j = 0; j < 8; ++j)
    cw[j] = *reinterpret_cast<const float4*>(&conv_w[(d8 + j) * 4]);

#pragma unroll
  for (int k = 0; k < 4; ++k) {
    if (l + k - 3 >= 0) {
      short8 v = *reinterpret_cast<const short8*>(&xz_bf[(size_t)(bl + k - 3) * 4096 + d8]);
      const float w0[8] = {cw[0].x, cw[1].x, cw[2].x, cw[3].x, cw[4].x, cw[5].x, cw[6].x, cw[7].x};
      const float w1[8] = {cw[0].y, cw[1].y, cw[2].y, cw[3].y, cw[4].y, cw[5].y, cw[6].y, cw[7].y};
      const float w2[8] = {cw[0].z, cw[1].z, cw[2].z, cw[3].z, cw[4].z, cw[5].z, cw[6].z, cw[7].z};
      const float w3[8] = {cw[0].w, cw[1].w, cw[2].w, cw[3].w, cw[4].w, cw[5].w, cw[6].w, cw[7].w};
      const float* wk = (k == 0) ? w0 : (k == 1) ? w1 : (k == 2) ? w2 : w3;
#pragma unroll
      for (int j = 0; j < 8; ++j) acc[j] = fmaf(bf2f(v[j]), wk[j], acc[j]);
    }
  }

  float o[8];
  short8 ob;
#pragma unroll
  for (int j = 0; j < 8; ++j) {
    o[j] = siluf(acc[j]);
    ob[j] = f2bf_bits(o[j]);
  }
  const size_t oi = (size_t)bl * D_INNER + d8;
  *reinterpret_cast<float4*>(&x_act[oi])     = make_float4(o[0], o[1], o[2], o[3]);
  *reinterpret_cast<float4*>(&x_act[oi + 4]) = make_float4(o[4], o[5], o[6], o[7]);
  *reinterpret_cast<short8*>(&x_act_bf[oi])  = ob;
}

// ---------------- scan pass 1: lane owns d; 16 n-states in registers ----------------
__global__ __launch_bounds__(256) void scan_pass1(const float* __restrict__ delta_raw,
                                                  const float* __restrict__ x_act,
                                                  const float* __restrict__ x_dbl,
                                                  const float* __restrict__ A_log,
                                                  const float* __restrict__ dt_proj_b,
                                                  float* __restrict__ chunkS,
                                                  float* __restrict__ chunkH) {
  const int t = blockIdx.x * 256 + threadIdx.x;
  const int d = t & (D_INNER - 1);
  const int c = (t >> 11) & (NCHUNK - 1);
  const int b = t >> 18;
  const int base = b * SEQ + c * CHUNK;

  float Av[16];
#pragma unroll
  for (int q = 0; q < 4; ++q) {
    float4 a = *reinterpret_cast<const float4*>(&A_log[d * 16 + q * 4]);
    Av[q * 4 + 0] = -__expf(a.x); Av[q * 4 + 1] = -__expf(a.y);
    Av[q * 4 + 2] = -__expf(a.z); Av[q * 4 + 3] = -__expf(a.w);
  }
  const float bias = dt_proj_b[d];

  const float* dp = delta_raw + (size_t)base * D_INNER + d;
  const float* up = x_act + (size_t)base * D_INNER + d;
  const float* xb = x_dbl + (size_t)base * 96 + DT_RANK;

  float h[16];
#pragma unroll
  for (int n = 0; n < 16; ++n) h[n] = 0.f;
  float S = 0.f;

  float dvr = *dp, uvv = *up;
  float4 b0 = *reinterpret_cast<const float4*>(xb);
  float4 b1 = *reinterpret_cast<const float4*>(xb + 4);
  float4 b2 = *reinterpret_cast<const float4*>(xb + 8);
  float4 b3 = *reinterpret_cast<const float4*>(xb + 12);
  for (int l = 0; l < CHUNK; ++l) {
    dp += D_INNER; up += D_INNER; xb += 96;
    const float ndvr = *dp, nuv = *up;
    const float4 nb0 = *reinterpret_cast<const float4*>(xb);
    const float4 nb1 = *reinterpret_cast<const float4*>(xb + 4);
    const float4 nb2 = *reinterpret_cast<const float4*>(xb + 8);
    const float4 nb3 = *reinterpret_cast<const float4*>(xb + 12);

    const float dv = softplusf(dvr + bias);
    S += dv;
    const float du = dv * uvv;
    const float Bf[16] = {b0.x, b0.y, b0.z, b0.w, b1.x, b1.y, b1.z, b1.w,
                          b2.x, b2.y, b2.z, b2.w, b3.x, b3.y, b3.z, b3.w};
#pragma unroll
    for (int n = 0; n < 16; ++n) {
      const float dA = __expf(dv * Av[n]);
      h[n] = fmaf(dA, h[n], du * Bf[n]);
    }
    dvr = ndvr; uvv = nuv; b0 = nb0; b1 = nb1; b2 = nb2; b3 = nb3;
  }

  const size_t sidx = (size_t)(b * NCHUNK + c) * D_INNER + d;
  chunkS[sidx] = S;
  float* hp = chunkH + sidx * 16;
#pragma unroll
  for (int q = 0; q < 4; ++q)
    *reinterpret_cast<float4*>(hp + q * 4) =
        make_float4(h[q * 4 + 0], h[q * 4 + 1], h[q * 4 + 2], h[q * 4 + 3]);
}

// ---------------- scan pass 2: combine chunk prefixes; chunkH becomes h0 ----------------
__global__ __launch_bounds__(256) void scan_pass2(const float* __restrict__ chunkS,
                                                  const float* __restrict__ A_log,
                                                  float* chunkH) {
  const int s = blockIdx.x * 256 + threadIdx.x;   // 65536 = (b, d, n)
  const int n = s & 15;
  const int d = (s >> 4) & (D_INNER - 1);
  const int b = s >> 15;
  const float Aval = -__expf(A_log[d * 16 + n]);

  size_t sidx = (size_t)b * NCHUNK * D_INNER + d;
  float aS = chunkS[sidx];
  float hE = chunkH[sidx * 16 + n];
  float H = 0.f;
  for (int c = 0; c < NCHUNK; ++c) {
    const size_t sidx2 = sidx + D_INNER;
    const float naS = chunkS[sidx2];            // overread at c==NC-1: inside ws
    const float nhE = chunkH[sidx2 * 16 + n];
    const float aP = __expf(Aval * aS);
    chunkH[sidx * 16 + n] = H;                  // h0 for this chunk
    H = fmaf(aP, H, hE);
    sidx = sidx2; aS = naS; hE = nhE;
  }
}

// ---------------- scan pass 3: rescan with h0; fused D-skip + silu(z) gate -> bf16 ------
__global__ __launch_bounds__(256) void scan_pass3(const float* __restrict__ delta_raw,
                                                  const float* __restrict__ x_act,
                                                  const float* __restrict__ x_dbl,
                                                  const float* __restrict__ A_log,
                                                  const float* __restrict__ dt_proj_b,
                                                  const float* __restrict__ chunkH0,
                                                  const float* __restrict__ D_skip,
                                                  __hip_bfloat16* xz_bf) {
  const int t = blockIdx.x * 256 + threadIdx.x;
  const int d = t & (D_INNER - 1);
  const int c = (t >> 11) & (NCHUNK - 1);
  const int b = t >> 18;
  const int base = b * SEQ + c * CHUNK;

  float Av[16];
#pragma unroll
  for (int q = 0; q < 4; ++q) {
    float4 a = *reinterpret_cast<const float4*>(&A_log[d * 16 + q * 4]);
    Av[q * 4 + 0] = -__expf(a.x); Av[q * 4 + 1] = -__expf(a.y);
    Av[q * 4 + 2] = -__expf(a.z); Av[q * 4 + 3] = -__expf(a.w);
  }
  const float bias = dt_proj_b[d];
  const float Dv = D_skip[d];

  const float* dp = delta_raw + (size_t)base * D_INNER + d;
  const float* up = x_act + (size_t)base * D_INNER + d;
  const float* xb = x_dbl + (size_t)base * 96 + DT_RANK;      // B at [0..15], C at [16..31]
  __hip_bfloat16* zp = xz_bf + (size_t)base * 4096 + D_INNER + d;

  float h[16];
  {
    const float* hp = chunkH0 + ((size_t)(b * NCHUNK + c) * D_INNER + d) * 16;
#pragma unroll
    for (int q = 0; q < 4; ++q) {
      float4 v = *reinterpret_cast<const float4*>(hp + q * 4);
      h[q * 4 + 0] = v.x; h[q * 4 + 1] = v.y; h[q * 4 + 2] = v.z; h[q * 4 + 3] = v.w;
    }
  }

  float dvr = *dp, uvv = *up;
  float4 b0 = *reinterpret_cast<const float4*>(xb);
  float4 b1 = *reinterpret_cast<const float4*>(xb + 4);
  float4 b2 = *reinterpret_cast<const float4*>(xb + 8);
  float4 b3 = *reinterpret_cast<const float4*>(xb + 12);
  float4 c0 = *reinterpret_cast<const float4*>(xb + 16);
  float4 c1 = *reinterpret_cast<const float4*>(xb + 20);
  float4 c2 = *reinterpret_cast<const float4*>(xb + 24);
  float4 c3 = *reinterpret_cast<const float4*>(xb + 28);
  for (int l = 0; l < CHUNK; ++l) {
    dp += D_INNER; up += D_INNER; xb += 96;
    const float ndvr = *dp, nuv = *up;
    const float4 nb0 = *reinterpret_cast<const float4*>(xb);
    const float4 nb1 = *reinterpret_cast<const float4*>(xb + 4);
    const float4 nb2 = *reinterpret_cast<const float4*>(xb + 8);
    const float4 nb3 = *reinterpret_cast<const float4*>(xb + 12);
    const float4 nc0 = *reinterpret_cast<const float4*>(xb + 16);
    const float4 nc1 = *reinterpret_cast<const float4*>(xb + 20);
    const float4 nc2 = *reinterpret_cast<const float4*>(xb + 24);
    const float4 nc3 = *reinterpret_cast<const float4*>(xb + 28);

    const float dv = softplusf(dvr + bias);
    const float du = dv * uvv;
    const float Bf[16] = {b0.x, b0.y, b0.z, b0.w, b1.x, b1.y, b1.z, b1.w,
                          b2.x, b2.y, b2.z, b2.w, b3.x, b3.y, b3.z, b3.w};
    const float Cf[16] = {c0.x, c0.y, c0.z, c0.w, c1.x, c1.y, c1.z, c1.w,
                          c2.x, c2.y, c2.z, c2.w, c3.x, c3.y, c3.z, c3.w};
    float p = 0.f;
#pragma unroll
    for (int n = 0; n < 16; ++n) {
      const float dA = __expf(dv * Av[n]);
      h[n] = fmaf(dA, h[n], du * Bf[n]);
      p = fmaf(h[n], Cf[n], p);
    }
    const float zv = __bfloat162float(zp[0]);
    const float yv = fmaf(uvv, Dv, p) * siluf(zv);
    zp[-(int)D_INNER] = __float2bfloat16(yv);
    zp += 4096;

    dvr = ndvr; uvv = nuv;
    b0 = nb0; b1 = nb1; b2 = nb2; b3 = nb3;
    c0 = nc0; c1 = nc1; c2 = nc2; c3 = nc3;
  }
}

extern "C" void kernel_launch(void* const* d_in, const int* in_sizes, int n_in,
                              void* d_out, int out_size, void* d_ws, size_t ws_size,
                              hipStream_t stream) {
  const float* x          = (const float*)d_in[0];
  const float* in_proj_w  = (const float*)d_in[1];
  const float* conv_w     = (const float*)d_in[2];
  const float* conv_b     = (const float*)d_in[3];
  const float* x_proj_w   = (const float*)d_in[4];
  const float* dt_proj_w  = (const float*)d_in[5];
  const float* dt_proj_b  = (const float*)d_in[6];
  const float* A_log      = (const float*)d_in[7];
  const float* D_skip     = (const float*)d_in[8];
  const float* out_proj_w = (const float*)d_in[9];
  float* out = (float*)d_out;   // fp32 output

  // Workspace layout (peak ~132 MiB):
  //   xz_bf     @0          33,554,432  bf16 [4096][4096]
  //   x_act     @33554432   33,554,432  fp32 [4096][2048]
  //   delta_raw @67108864   33,554,432  (time-shared: x_bf/inw_bf -> Cpart -> delta_raw -> outw_bf)
  //   x_dbl     @100663296   1,572,864
  //   chunkH    @102236160  33,554,432  (time-shared: x_act_bf 16.7MB pre-scan)
  //   chunkS    @135790592   2,097,152
  //   wpad      @137887744     524,288  bf16 [128][2048] padded x_proj_w
  char* ws = (char*)d_ws;
  __hip_bfloat16* xz_bf    = (__hip_bfloat16*)(ws);
  float* x_act             = (float*)(ws + 33554432);
  float* delta_raw         = (float*)(ws + 67108864);
  __hip_bfloat16* x_bf     = (__hip_bfloat16*)(ws + 67108864);
  __hip_bfloat16* inw_bf   = (__hip_bfloat16*)(ws + 75497472);
  float* Cpart             = (float*)(ws + 67108864);   // 12.6 MB, pre-delta
  __hip_bfloat16* outw_bf  = (__hip_bfloat16*)(ws + 67108864);
  float* x_dbl             = (float*)(ws + 100663296);
  float* chunkH            = (float*)(ws + 102236160);
  __hip_bfloat16* x_act_bf = (__hip_bfloat16*)(ws + 102236160);  // aliases chunkH (pre-scan)
  float* chunkS            = (float*)(ws + 135790592);
  __hip_bfloat16* wpad     = (__hip_bfloat16*)(ws + 137887744);

  // 1-2. bf16 conversions for in_proj operands (8 elems/thread)
  f2bf_kernel<<<2048, 256, 0, stream>>>(x, x_bf);            // 4096x1024
  f2bf_kernel<<<2048, 256, 0, stream>>>(in_proj_w, inw_bf);  // 4096x1024

  // 3. xz = x @ in_proj_w^T  (M=4096, N=4096, K=1024), bf16 out, 8-phase 256^2 pipeline
  gemm256_8ph<__hip_bfloat16><<<dim3(16, 16), 512, 0, stream>>>(
      x_bf, inw_bf, xz_bf, 1024, 1024, 1024, 4096);

  // 4. depthwise causal conv + bias + silu -> x_act (fp32) + x_act_bf (bf16)
  conv_silu_kernel<<<(BL * D_INNER) / 8 / 256, 256, 0, stream>>>(
      xz_bf, conv_w, conv_b, x_act, x_act_bf);

  // 5. x_dbl = x_act @ x_proj_w^T via bf16 MFMA split-K (padded 96->128 weight) + reduce
  f2bf_kernel<<<96, 256, 0, stream>>>(x_proj_w, (__hip_bfloat16*)wpad);  // 96x2048
  gemm_bt<128, 128, XP_N, true, float><<<dim3(XP_KS, 32), 256, 0, stream>>>(
      x_act_bf, wpad, Cpart, 2048 / XP_KS, 2048, 2048, XP_N);
  xproj_reduce<<<(BL * XP_N) / 256, 256, 0, stream>>>(Cpart, x_dbl);

  // 6. delta_raw = dt_low @ dt_proj_w^T  (4096 x 2048, K=64); softplus fused into scan
  gemm64g<<<dim3(32, 64), 256, 0, stream>>>(x_dbl, dt_proj_w, delta_raw, BL, 2048, 64,
                                            96, 64, 2048);

  // 7-9. chunked selective scan, lane-owns-d, NCHUNK=128 (8 waves/SIMD)
  scan_pass1<<<2048, 256, 0, stream>>>(delta_raw, x_act, x_dbl, A_log, dt_proj_b,
                                       chunkS, chunkH);
  scan_pass2<<<256, 256, 0, stream>>>(chunkS, A_log, chunkH);
  scan_pass3<<<2048, 256, 0, stream>>>(delta_raw, x_act, x_dbl, A_log, dt_proj_b,
                                       chunkH, D_skip, xz_bf);

  // 10. out_proj weights -> bf16 (delta region dead now)
  f2bf_kernel<<<1024, 256, 0, stream>>>(out_proj_w, outw_bf); // 1024x2048

  // 11. out = y @ out_proj_w^T  (M=4096, N=1024, K=2048), fp32 out, 128x64 tile
  gemm_bt<128, 64, 64, false, float><<<dim3(16, 32), 256, 0, stream>>>(
      xz_bf, outw_bf, out, 2048, 4096, 2048, 1024);
}

// Round 14
// 249.827 us; speedup vs baseline: 6.6188x; 1.0371x over previous
//
#include <hip/hip_runtime.h>
#include <hip/hip_bf16.h>
#include <cstdint>

#define D_STATE 16
#define D_INNER 2048
#define DT_RANK 64
#define SEQ 2048
#define BL 4096      // B * L
#define NCHUNK 128
#define CHUNK 16     // SEQ / NCHUNK
#define XP_N 96      // dt_rank + 2*d_state
#define XP_KS 8      // x_proj K-splits
#define LOG2E 1.44269504088896340736f

typedef short bf16x8 __attribute__((ext_vector_type(8)));
typedef short short8 __attribute__((ext_vector_type(8)));
typedef float f32x4 __attribute__((ext_vector_type(4)));

__device__ __forceinline__ float siluf(float x) {
  return __fdividef(x, 1.f + __expf(-x));
}

__device__ __forceinline__ float softplusf(float v) {
  return fmaxf(v, 0.f) + __logf(1.f + __expf(-fabsf(v)));
}

__device__ __forceinline__ float exp2fast(float x) {
  return __builtin_amdgcn_exp2f(x);
}

__device__ __forceinline__ unsigned short f2bf_bits(float x) {
  __hip_bfloat16 h = __float2bfloat16(x);
  return *reinterpret_cast<unsigned short*>(&h);
}

__device__ __forceinline__ float bf2f(short u) {
  return __int_as_float(((unsigned int)(unsigned short)u) << 16);
}

__device__ __forceinline__ void gload_lds16(const void* g, void* l) {
  __builtin_amdgcn_global_load_lds((const __attribute__((address_space(1))) unsigned int*)g,
                                   (__attribute__((address_space(3))) unsigned int*)l,
                                   16, 0, 0);
}

#define BARRIER() asm volatile("s_barrier" ::: "memory")
#define VMCNT(n)  asm volatile("s_waitcnt vmcnt(" #n ")" ::: "memory")

// ---------------- fp32 -> bf16 conversion, 8 elems/thread (n multiple of 2048) --------
__global__ __launch_bounds__(256) void f2bf_kernel(const float* __restrict__ in,
                                                   __hip_bfloat16* __restrict__ out) {
  const int i = (blockIdx.x * 256 + threadIdx.x) * 8;
  float4 v0 = *reinterpret_cast<const float4*>(&in[i]);
  float4 v1 = *reinterpret_cast<const float4*>(&in[i + 4]);
  short8 r;
  r[0] = f2bf_bits(v0.x); r[1] = f2bf_bits(v0.y); r[2] = f2bf_bits(v0.z); r[3] = f2bf_bits(v0.w);
  r[4] = f2bf_bits(v1.x); r[5] = f2bf_bits(v1.y); r[6] = f2bf_bits(v1.z); r[7] = f2bf_bits(v1.w);
  *reinterpret_cast<short8*>(&out[i]) = r;
}

// ---------------- dt_low extract + bf16: x_dbl[:, 0:64] (stride 96) -> [4096][64] bf16 --
__global__ __launch_bounds__(256) void dtlow_bf_kernel(const float* __restrict__ x_dbl,
                                                       __hip_bfloat16* __restrict__ dtlow_bf) {
  const int i = blockIdx.x * 256 + threadIdx.x;   // 32768 threads
  const int row = i >> 3;
  const int c8 = (i & 7) * 8;
  float4 v0 = *reinterpret_cast<const float4*>(&x_dbl[(size_t)row * 96 + c8]);
  float4 v1 = *reinterpret_cast<const float4*>(&x_dbl[(size_t)row * 96 + c8 + 4]);
  short8 r;
  r[0] = f2bf_bits(v0.x); r[1] = f2bf_bits(v0.y); r[2] = f2bf_bits(v0.z); r[3] = f2bf_bits(v0.w);
  r[4] = f2bf_bits(v1.x); r[5] = f2bf_bits(v1.y); r[6] = f2bf_bits(v1.z); r[7] = f2bf_bits(v1.w);
  *reinterpret_cast<short8*>(&dtlow_bf[(size_t)row * 64 + c8]) = r;
}

// ============ 8-phase 256x256 bf16 GEMM (T2+T3+T4+T5): C = A[M,K] @ B[N,K]^T ============
// 512 thr = 8 waves (2M x 4N); per-wave out 128x64; BK=64; LDS 128KB dbuf, st-swizzled.
template <typename OutT>
__global__ __launch_bounds__(512, 1) void gemm256_8ph(const __hip_bfloat16* __restrict__ A,
                                                      const __hip_bfloat16* __restrict__ B,
                                                      OutT* __restrict__ C,
                                                      int K, int lda, int ldb, int ldc) {
  __shared__ __align__(16) unsigned short lds[65536];  // [2 buf][A 16384 | B 16384] shorts
  const int tid = threadIdx.x;
  const int wv = tid >> 6, lane = tid & 63;
  const int wr = wv >> 2, wc = wv & 3;              // wave grid 2(M) x 4(N)
  const int m0 = blockIdx.y * 256, n0 = blockIdx.x * 256;
  const int frow = lane & 15;                       // fragment row
  const int fu = lane >> 4;                         // 16B-unit index (k/8)
  const int rsw = frow & 7;                         // read-side swizzle key
  const int sr = lane >> 3;                         // staging row-in-8
  const int su = (lane & 7) ^ sr;                   // pre-swizzled source k-unit (rule 21)

  const unsigned short* Ag = (const unsigned short*)A;
  const unsigned short* Bg = (const unsigned short*)B;

  f32x4 acc[8][4];
#pragma unroll
  for (int i = 0; i < 8; ++i)
#pragma unroll
    for (int j = 0; j < 4; ++j) acc[i][j] = {0.f, 0.f, 0.f, 0.f};

  auto stageA = [&](int buf, int g, int kg) {
    const int rowb = g * 64 + wv * 8;
    gload_lds16(&Ag[(size_t)(m0 + rowb + sr) * lda + kg + su * 8],
                &lds[buf * 32768 + rowb * 64]);
  };
  auto stageB = [&](int buf, int g, int kg) {
    const int rowb = g * 64 + wv * 8;
    gload_lds16(&Bg[(size_t)(n0 + rowb + sr) * ldb + kg + su * 8],
                &lds[buf * 32768 + 16384 + rowb * 64]);
  };
  auto fragA = [&](int buf, int mi, int kk) -> bf16x8 {
    const int row = wr * 128 + mi * 16 + frow;
    return *reinterpret_cast<const bf16x8*>(
        &lds[buf * 32768 + row * 64 + (((kk << 2) | fu) ^ rsw) * 8]);
  };
  auto fragB = [&](int buf, int ni, int kk) -> bf16x8 {
    const int row = wc * 64 + ni * 16 + frow;
    return *reinterpret_cast<const bf16x8*>(
        &lds[buf * 32768 + 16384 + row * 64 + (((kk << 2) | fu) ^ rsw) * 8]);
  };

#define QUAD(MB)                                                                        \
  _Pragma("unroll")                                                                     \
  for (int mi = 0; mi < 4; ++mi)                                                        \
    _Pragma("unroll")                                                                   \
    for (int ni = 0; ni < 4; ++ni)                                                      \
      acc[MB + mi][ni] =                                                                \
          __builtin_amdgcn_mfma_f32_16x16x32_bf16(af[mi], bfr[ni], acc[MB + mi][ni], 0, 0, 0);

  stageB(0, 0, 0); stageB(0, 1, 0); stageB(0, 2, 0); stageB(0, 3, 0);
  stageA(0, 0, 0); stageA(0, 2, 0); stageA(0, 1, 0); stageA(0, 3, 0);
  VMCNT(2);
  BARRIER();

  const int NT = K >> 6;
  int cur = 0;
  for (int t = 0; t < NT - 1; ++t) {
    const int nxt = cur ^ 1;
    const int kn = (t + 1) << 6;
    bf16x8 af[4], bfr[4];
    // ---- phase 0
#pragma unroll
    for (int mi = 0; mi < 4; ++mi) af[mi] = fragA(cur, mi, 0);
#pragma unroll
    for (int ni = 0; ni < 4; ++ni) bfr[ni] = fragB(cur, ni, 0);
    stageB(nxt, 0, kn); stageB(nxt, 1, kn);
    VMCNT(2);
    BARRIER();
    __builtin_amdgcn_s_setprio(1);
    QUAD(0);
    __builtin_amdgcn_s_setprio(0);
    BARRIER();
    // ---- phase 1
#pragma unroll
    for (int mi = 0; mi < 4; ++mi) af[mi] = fragA(cur, 4 + mi, 0);
    stageB(nxt, 2, kn); stageB(nxt, 3, kn);
    BARRIER();
    __builtin_amdgcn_s_setprio(1);
    QUAD(4);
    __builtin_amdgcn_s_setprio(0);
    BARRIER();
    // ---- phase 2
#pragma unroll
    for (int mi = 0; mi < 4; ++mi) af[mi] = fragA(cur, mi, 1);
#pragma unroll
    for (int ni = 0; ni < 4; ++ni) bfr[ni] = fragB(cur, ni, 1);
    stageA(nxt, 0, kn); stageA(nxt, 2, kn);
    BARRIER();
    __builtin_amdgcn_s_setprio(1);
    QUAD(0);
    __builtin_amdgcn_s_setprio(0);
    BARRIER();
    // ---- phase 3
#pragma unroll
    for (int mi = 0; mi < 4; ++mi) af[mi] = fragA(cur, 4 + mi, 1);
    stageA(nxt, 1, kn); stageA(nxt, 3, kn);
    VMCNT(2);
    BARRIER();
    __builtin_amdgcn_s_setprio(1);
    QUAD(4);
    __builtin_amdgcn_s_setprio(0);
    BARRIER();
    cur = nxt;
  }
  // ---- last tile
  {
    bf16x8 af[4], bfr[4];
#pragma unroll
    for (int mi = 0; mi < 4; ++mi) af[mi] = fragA(cur, mi, 0);
#pragma unroll
    for (int ni = 0; ni < 4; ++ni) bfr[ni] = fragB(cur, ni, 0);
    VMCNT(0);
    BARRIER();
    __builtin_amdgcn_s_setprio(1);
    QUAD(0);
    __builtin_amdgcn_s_setprio(0);
    BARRIER();
#pragma unroll
    for (int mi = 0; mi < 4; ++mi) af[mi] = fragA(cur, 4 + mi, 0);
    BARRIER();
    __builtin_amdgcn_s_setprio(1);
    QUAD(4);
    __builtin_amdgcn_s_setprio(0);
    BARRIER();
#pragma unroll
    for (int mi = 0; mi < 4; ++mi) af[mi] = fragA(cur, mi, 1);
#pragma unroll
    for (int ni = 0; ni < 4; ++ni) bfr[ni] = fragB(cur, ni, 1);
    BARRIER();
    __builtin_amdgcn_s_setprio(1);
    QUAD(0);
    __builtin_amdgcn_s_setprio(0);
    BARRIER();
#pragma unroll
    for (int mi = 0; mi < 4; ++mi) af[mi] = fragA(cur, 4 + mi, 1);
    __builtin_amdgcn_s_setprio(1);
    QUAD(4);
    __builtin_amdgcn_s_setprio(0);
  }
#undef QUAD

  const int crow = fu * 4;
  const int ccol = frow;
#pragma unroll
  for (int mi = 0; mi < 8; ++mi)
#pragma unroll
    for (int ni = 0; ni < 4; ++ni) {
      const int gcol = n0 + wc * 64 + ni * 16 + ccol;
#pragma unroll
      for (int j = 0; j < 4; ++j) {
        const int grow = m0 + wr * 128 + mi * 16 + crow + j;
        if constexpr (sizeof(OutT) == 2) {
          C[(size_t)grow * ldc + gcol] = __float2bfloat16(acc[mi][ni][j]);
        } else {
          C[(size_t)grow * ldc + gcol] = acc[mi][ni][j];
        }
      }
    }
}

// ---------------- MFMA bf16 GEMM: C = A[M,K] * B[N,K]^T, double-buffered LDS ----------
template <int BM, int BN>
__device__ __forceinline__ void stage_tiles(const unsigned short* __restrict__ Ag,
                                            const unsigned short* __restrict__ Bg,
                                            unsigned short* buf, int m0, int n0, int k0,
                                            int lda, int ldb, int sr, int sk, int wv) {
#pragma unroll
  for (int g = 0; g < BM / 64; ++g)
    gload_lds16(&Ag[(size_t)(m0 + g * 64 + sr) * lda + k0 + sk], &buf[g * 2048 + wv * 512]);
#pragma unroll
  for (int g = 0; g < BN / 64; ++g)
    gload_lds16(&Bg[(size_t)(n0 + g * 64 + sr) * ldb + k0 + sk], &buf[BM * 32 + g * 2048 + wv * 512]);
}

template <int BM, int BN, int NSTORE, bool SPLITK, typename OutT>
__global__ __launch_bounds__(256) void gemm_bt(const __hip_bfloat16* __restrict__ A,
                                               const __hip_bfloat16* __restrict__ B,
                                               OutT* __restrict__ C,
                                               int K, int lda, int ldb, int ldc) {
  constexpr int WM = BM / 2, WN = BN / 2;
  constexpr int MI = WM / 16, NI = WN / 16;
  constexpr int BUFS = (BM + BN) * 32;
  __shared__ __align__(16) unsigned short lds[2 * BUFS];
  const int tid = threadIdx.x;
  const int wv = tid >> 6, lane = tid & 63;
  const int wr = wv >> 1, wc = wv & 1;
  const int m0 = blockIdx.y * BM;
  int n0, koff;
  if constexpr (SPLITK) {
    n0 = 0;
    koff = blockIdx.x * K;
    C += (size_t)blockIdx.x * BL * NSTORE;
  } else {
    n0 = blockIdx.x * BN;
    koff = 0;
  }
  const int sr = tid >> 2;
  const int sk = (tid & 3) * 8;
  const int frow = lane & 15;
  const int fk = (lane >> 4) * 8;

  f32x4 acc[MI][NI];
#pragma unroll
  for (int i = 0; i < MI; ++i)
#pragma unroll
    for (int j = 0; j < NI; ++j) acc[i][j] = {0.f, 0.f, 0.f, 0.f};

  const unsigned short* Ag = (const unsigned short*)A;
  const unsigned short* Bg = (const unsigned short*)B;

  stage_tiles<BM, BN>(Ag, Bg, &lds[0], m0, n0, koff, lda, ldb, sr, sk, wv);
  __syncthreads();
  int sel = 0;
  for (int k0 = 0; k0 < K; k0 += 32) {
    if (k0 + 32 < K)
      stage_tiles<BM, BN>(Ag, Bg, &lds[(sel ^ 1) * BUFS], m0, n0, koff + k0 + 32, lda, ldb, sr, sk, wv);
    const unsigned short* Abuf = &lds[sel * BUFS];
    const unsigned short* Bbuf = &lds[sel * BUFS + BM * 32];
    bf16x8 af[MI], bfr[NI];
#pragma unroll
    for (int mi = 0; mi < MI; ++mi)
      af[mi] = *reinterpret_cast<const bf16x8*>(&Abuf[(wr * WM + mi * 16 + frow) * 32 + fk]);
#pragma unroll
    for (int ni = 0; ni < NI; ++ni)
      bfr[ni] = *reinterpret_cast<const bf16x8*>(&Bbuf[(wc * WN + ni * 16 + frow) * 32 + fk]);
#pragma unroll
    for (int mi = 0; mi < MI; ++mi)
#pragma unroll
      for (int ni = 0; ni < NI; ++ni)
        acc[mi][ni] = __builtin_amdgcn_mfma_f32_16x16x32_bf16(af[mi], bfr[ni], acc[mi][ni], 0, 0, 0);
    __syncthreads();
    sel ^= 1;
  }

  const int crow = (lane >> 4) * 4;
  const int ccol = lane & 15;
#pragma unroll
  for (int mi = 0; mi < MI; ++mi)
#pragma unroll
    for (int ni = 0; ni < NI; ++ni) {
      const int gcol = n0 + wc * WN + ni * 16 + ccol;
      if constexpr (NSTORE < BN) {
        if (gcol >= NSTORE) continue;
      }
#pragma unroll
      for (int j = 0; j < 4; ++j) {
        const int grow = m0 + wr * WM + mi * 16 + crow + j;
        if constexpr (sizeof(OutT) == 2) {
          C[(size_t)grow * ldc + gcol] = __float2bfloat16(acc[mi][ni][j]);
        } else {
          C[(size_t)grow * ldc + gcol] = acc[mi][ni][j];
        }
      }
    }
}

// ---------------- x_proj reduce ----------------
__global__ __launch_bounds__(256) void xproj_reduce(const float* __restrict__ Cpart,
                                                    float* __restrict__ x_dbl) {
  const int i = blockIdx.x * 256 + threadIdx.x;    // < BL * XP_N
  float s = 0.f;
#pragma unroll
  for (int z = 0; z < XP_KS; ++z) s += Cpart[(size_t)z * BL * XP_N + i];
  x_dbl[i] = s;
}

// ---------------- depthwise causal conv1d (w=4) + bias + silu, 8 d's/thread ----------
__global__ __launch_bounds__(256) void conv_silu_kernel(const __hip_bfloat16* __restrict__ xz_bf,
                                                        const float* __restrict__ conv_w,
                                                        const float* __restrict__ conv_b,
                                                        float* __restrict__ x_act,
                                                        __hip_bfloat16* __restrict__ x_act_bf) {
  const int idx = blockIdx.x * 256 + threadIdx.x;       // over BL * D_INNER / 8
  const int d8 = (idx << 3) & (D_INNER - 1);
  const int bl = idx >> 8;
  const int l = bl & (SEQ - 1);

  float acc[8];
  {
    float4 cb0 = *reinterpret_cast<const float4*>(&conv_b[d8]);
    float4 cb1 = *reinterpret_cast<const float4*>(&conv_b[d8 + 4]);
    acc[0] = cb0.x; acc[1] = cb0.y; acc[2] = cb0.z; acc[3] = cb0.w;
    acc[4] = cb1.x; acc[5] = cb1.y; acc[6] = cb1.z; acc[7] = cb1.w;
  }
  float4 cw[8];
#pragma unroll
  for (int j = 0; j < 8; ++j)
    cw[j] = *reinterpret_cast<const float4*>(&conv_w[(d8 + j) * 4]);

#pragma unroll
  for (int k = 0; k < 4; ++k) {
    if (l + k - 3 >= 0) {
      short8 v = *reinterpret_cast<const short8*>(&xz_bf[(size_t)(bl + k - 3) * 4096 + d8]);
      const float w0[8] = {cw[0].x, cw[1].x, cw[2].x, cw[3].x, cw[4].x, cw[5].x, cw[6].x, cw[7].x};
      const float w1[8] = {cw[0].y, cw[1].y, cw[2].y, cw[3].y, cw[4].y, cw[5].y, cw[6].y, cw[7].y};
      const float w2[8] = {cw[0].z, cw[1].z, cw[2].z, cw[3].z, cw[4].z, cw[5].z, cw[6].z, cw[7].z};
      const float w3[8] = {cw[0].w, cw[1].w, cw[2].w, cw[3].w, cw[4].w, cw[5].w, cw[6].w, cw[7].w};
      const float* wk = (k == 0) ? w0 : (k == 1) ? w1 : (k == 2) ? w2 : w3;
#pragma unroll
      for (int j = 0; j < 8; ++j) acc[j] = fmaf(bf2f(v[j]), wk[j], acc[j]);
    }
  }

  float o[8];
  short8 ob;
#pragma unroll
  for (int j = 0; j < 8; ++j) {
    o[j] = siluf(acc[j]);
    ob[j] = f2bf_bits(o[j]);
  }
  const size_t oi = (size_t)bl * D_INNER + d8;
  *reinterpret_cast<float4*>(&x_act[oi])     = make_float4(o[0], o[1], o[2], o[3]);
  *reinterpret_cast<float4*>(&x_act[oi + 4]) = make_float4(o[4], o[5], o[6], o[7]);
  *reinterpret_cast<short8*>(&x_act_bf[oi])  = ob;
}

// ---------------- scan pass 1: lane owns d; 16 n-states in registers ----------------
// Av prescaled by log2e: dA = exp2(dv * Av2[n]).
__global__ __launch_bounds__(256) void scan_pass1(const float* __restrict__ delta_raw,
                                                  const float* __restrict__ x_act,
                                                  const float* __restrict__ x_dbl,
                                                  const float* __restrict__ A_log,
                                                  const float* __restrict__ dt_proj_b,
                                                  float* __restrict__ chunkS,
                                                  float* __restrict__ chunkH) {
  const int t = blockIdx.x * 256 + threadIdx.x;
  const int d = t & (D_INNER - 1);
  const int c = (t >> 11) & (NCHUNK - 1);
  const int b = t >> 18;
  const int base = b * SEQ + c * CHUNK;

  float Av[16];
#pragma unroll
  for (int q = 0; q < 4; ++q) {
    float4 a = *reinterpret_cast<const float4*>(&A_log[d * 16 + q * 4]);
    Av[q * 4 + 0] = -__expf(a.x) * LOG2E; Av[q * 4 + 1] = -__expf(a.y) * LOG2E;
    Av[q * 4 + 2] = -__expf(a.z) * LOG2E; Av[q * 4 + 3] = -__expf(a.w) * LOG2E;
  }
  const float bias = dt_proj_b[d];

  const float* dp = delta_raw + (size_t)base * D_INNER + d;
  const float* up = x_act + (size_t)base * D_INNER + d;
  const float* xb = x_dbl + (size_t)base * 96 + DT_RANK;

  float h[16];
#pragma unroll
  for (int n = 0; n < 16; ++n) h[n] = 0.f;
  float S = 0.f;

  float dvr = *dp, uvv = *up;
  float4 b0 = *reinterpret_cast<const float4*>(xb);
  float4 b1 = *reinterpret_cast<const float4*>(xb + 4);
  float4 b2 = *reinterpret_cast<const float4*>(xb + 8);
  float4 b3 = *reinterpret_cast<const float4*>(xb + 12);
  for (int l = 0; l < CHUNK; ++l) {
    dp += D_INNER; up += D_INNER; xb += 96;
    const float ndvr = *dp, nuv = *up;
    const float4 nb0 = *reinterpret_cast<const float4*>(xb);
    const float4 nb1 = *reinterpret_cast<const float4*>(xb + 4);
    const float4 nb2 = *reinterpret_cast<const float4*>(xb + 8);
    const float4 nb3 = *reinterpret_cast<const float4*>(xb + 12);

    const float dv = softplusf(dvr + bias);
    S += dv;
    const float du = dv * uvv;
    const float Bf[16] = {b0.x, b0.y, b0.z, b0.w, b1.x, b1.y, b1.z, b1.w,
                          b2.x, b2.y, b2.z, b2.w, b3.x, b3.y, b3.z, b3.w};
#pragma unroll
    for (int n = 0; n < 16; ++n) {
      const float dA = exp2fast(dv * Av[n]);
      h[n] = fmaf(dA, h[n], du * Bf[n]);
    }
    dvr = ndvr; uvv = nuv; b0 = nb0; b1 = nb1; b2 = nb2; b3 = nb3;
  }

  const size_t sidx = (size_t)(b * NCHUNK + c) * D_INNER + d;
  chunkS[sidx] = S;
  float* hp = chunkH + sidx * 16;
#pragma unroll
  for (int q = 0; q < 4; ++q)
    *reinterpret_cast<float4*>(hp + q * 4) =
        make_float4(h[q * 4 + 0], h[q * 4 + 1], h[q * 4 + 2], h[q * 4 + 3]);
}

// ---------------- scan pass 2: combine chunk prefixes; chunkH becomes h0 ----------------
__global__ __launch_bounds__(256) void scan_pass2(const float* __restrict__ chunkS,
                                                  const float* __restrict__ A_log,
                                                  float* chunkH) {
  const int s = blockIdx.x * 256 + threadIdx.x;   // 65536 = (b, d, n)
  const int n = s & 15;
  const int d = (s >> 4) & (D_INNER - 1);
  const int b = s >> 15;
  const float Aval = -__expf(A_log[d * 16 + n]) * LOG2E;

  size_t sidx = (size_t)b * NCHUNK * D_INNER + d;
  float aS = chunkS[sidx];
  float hE = chunkH[sidx * 16 + n];
  float H = 0.f;
  for (int c = 0; c < NCHUNK; ++c) {
    const size_t sidx2 = sidx + D_INNER;
    const float naS = chunkS[sidx2];            // overread at c==NC-1: inside ws
    const float nhE = chunkH[sidx2 * 16 + n];
    const float aP = exp2fast(Aval * aS);
    chunkH[sidx * 16 + n] = H;                  // h0 for this chunk
    H = fmaf(aP, H, hE);
    sidx = sidx2; aS = naS; hE = nhE;
  }
}

// ---------------- scan pass 3: rescan with h0; fused D-skip + silu(z) gate -> bf16 ------
__global__ __launch_bounds__(256) void scan_pass3(const float* __restrict__ delta_raw,
                                                  const float* __restrict__ x_act,
                                                  const float* __restrict__ x_dbl,
                                                  const float* __restrict__ A_log,
                                                  const float* __restrict__ dt_proj_b,
                                                  const float* __restrict__ chunkH0,
                                                  const float* __restrict__ D_skip,
                                                  __hip_bfloat16* xz_bf) {
  const int t = blockIdx.x * 256 + threadIdx.x;
  const int d = t & (D_INNER - 1);
  const int c = (t >> 11) & (NCHUNK - 1);
  const int b = t >> 18;
  const int base = b * SEQ + c * CHUNK;

  float Av[16];
#pragma unroll
  for (int q = 0; q < 4; ++q) {
    float4 a = *reinterpret_cast<const float4*>(&A_log[d * 16 + q * 4]);
    Av[q * 4 + 0] = -__expf(a.x) * LOG2E; Av[q * 4 + 1] = -__expf(a.y) * LOG2E;
    Av[q * 4 + 2] = -__expf(a.z) * LOG2E; Av[q * 4 + 3] = -__expf(a.w) * LOG2E;
  }
  const float bias = dt_proj_b[d];
  const float Dv = D_skip[d];

  const float* dp = delta_raw + (size_t)base * D_INNER + d;
  const float* up = x_act + (size_t)base * D_INNER + d;
  const float* xb = x_dbl + (size_t)base * 96 + DT_RANK;      // B at [0..15], C at [16..31]
  __hip_bfloat16* zp = xz_bf + (size_t)base * 4096 + D_INNER + d;

  float h[16];
  {
    const float* hp = chunkH0 + ((size_t)(b * NCHUNK + c) * D_INNER + d) * 16;
#pragma unroll
    for (int q = 0; q < 4; ++q) {
      float4 v = *reinterpret_cast<const float4*>(hp + q * 4);
      h[q * 4 + 0] = v.x; h[q * 4 + 1] = v.y; h[q * 4 + 2] = v.z; h[q * 4 + 3] = v.w;
    }
  }

  float dvr = *dp, uvv = *up;
  float4 b0 = *reinterpret_cast<const float4*>(xb);
  float4 b1 = *reinterpret_cast<const float4*>(xb + 4);
  float4 b2 = *reinterpret_cast<const float4*>(xb + 8);
  float4 b3 = *reinterpret_cast<const float4*>(xb + 12);
  float4 c0 = *reinterpret_cast<const float4*>(xb + 16);
  float4 c1 = *reinterpret_cast<const float4*>(xb + 20);
  float4 c2 = *reinterpret_cast<const float4*>(xb + 24);
  float4 c3 = *reinterpret_cast<const float4*>(xb + 28);
  for (int l = 0; l < CHUNK; ++l) {
    dp += D_INNER; up += D_INNER; xb += 96;
    const float ndvr = *dp, nuv = *up;
    const float4 nb0 = *reinterpret_cast<const float4*>(xb);
    const float4 nb1 = *reinterpret_cast<const float4*>(xb + 4);
    const float4 nb2 = *reinterpret_cast<const float4*>(xb + 8);
    const float4 nb3 = *reinterpret_cast<const float4*>(xb + 12);
    const float4 nc0 = *reinterpret_cast<const float4*>(xb + 16);
    const float4 nc1 = *reinterpret_cast<const float4*>(xb + 20);
    const float4 nc2 = *reinterpret_cast<const float4*>(xb + 24);
    const float4 nc3 = *reinterpret_cast<const float4*>(xb + 28);

    const float dv = softplusf(dvr + bias);
    const float du = dv * uvv;
    const float Bf[16] = {b0.x, b0.y, b0.z, b0.w, b1.x, b1.y, b1.z, b1.w,
                          b2.x, b2.y, b2.z, b2.w, b3.x, b3.y, b3.z, b3.w};
    const float Cf[16] = {c0.x, c0.y, c0.z, c0.w, c1.x, c1.y, c1.z, c1.w,
                          c2.x, c2.y, c2.z, c2.w, c3.x, c3.y, c3.z, c3.w};
    float p = 0.f;
#pragma unroll
    for (int n = 0; n < 16; ++n) {
      const float dA = exp2fast(dv * Av[n]);
      h[n] = fmaf(dA, h[n], du * Bf[n]);
      p = fmaf(h[n], Cf[n], p);
    }
    const float zv = __bfloat162float(zp[0]);
    const float yv = fmaf(uvv, Dv, p) * siluf(zv);
    zp[-(int)D_INNER] = __float2bfloat16(yv);
    zp += 4096;

    dvr = ndvr; uvv = nuv;
    b0 = nb0; b1 = nb1; b2 = nb2; b3 = nb3;
    c0 = nc0; c1 = nc1; c2 = nc2; c3 = nc3;
  }
}

extern "C" void kernel_launch(void* const* d_in, const int* in_sizes, int n_in,
                              void* d_out, int out_size, void* d_ws, size_t ws_size,
                              hipStream_t stream) {
  const float* x          = (const float*)d_in[0];
  const float* in_proj_w  = (const float*)d_in[1];
  const float* conv_w     = (const float*)d_in[2];
  const float* conv_b     = (const float*)d_in[3];
  const float* x_proj_w   = (const float*)d_in[4];
  const float* dt_proj_w  = (const float*)d_in[5];
  const float* dt_proj_b  = (const float*)d_in[6];
  const float* A_log      = (const float*)d_in[7];
  const float* D_skip     = (const float*)d_in[8];
  const float* out_proj_w = (const float*)d_in[9];
  float* out = (float*)d_out;   // fp32 output

  // Workspace layout (peak ~133 MiB):
  //   xz_bf     @0          33,554,432  bf16 [4096][4096]
  //   x_act     @33554432   33,554,432  fp32 [4096][2048]
  //   delta_raw @67108864   33,554,432  (time-shared: x_bf/inw_bf -> Cpart -> delta_raw -> outw_bf)
  //   x_dbl     @100663296   1,572,864
  //   chunkH    @102236160  33,554,432  (time-shared: x_act_bf 16.7MB pre-scan)
  //   chunkS    @135790592   2,097,152
  //   wpad      @137887744     524,288  bf16 [128][2048] padded x_proj_w
  //   dtlow_bf  @138412032     524,288  bf16 [4096][64]
  //   dtw_bf    @138936320     262,144  bf16 [2048][64]
  char* ws = (char*)d_ws;
  __hip_bfloat16* xz_bf    = (__hip_bfloat16*)(ws);
  float* x_act             = (float*)(ws + 33554432);
  float* delta_raw         = (float*)(ws + 67108864);
  __hip_bfloat16* x_bf     = (__hip_bfloat16*)(ws + 67108864);
  __hip_bfloat16* inw_bf   = (__hip_bfloat16*)(ws + 75497472);
  float* Cpart             = (float*)(ws + 67108864);   // 12.6 MB, pre-delta
  __hip_bfloat16* outw_bf  = (__hip_bfloat16*)(ws + 67108864);
  float* x_dbl             = (float*)(ws + 100663296);
  float* chunkH            = (float*)(ws + 102236160);
  __hip_bfloat16* x_act_bf = (__hip_bfloat16*)(ws + 102236160);  // aliases chunkH (pre-scan)
  float* chunkS            = (float*)(ws + 135790592);
  __hip_bfloat16* wpad     = (__hip_bfloat16*)(ws + 137887744);
  __hip_bfloat16* dtlow_bf = (__hip_bfloat16*)(ws + 138412032);
  __hip_bfloat16* dtw_bf   = (__hip_bfloat16*)(ws + 138936320);

  // 1-2. bf16 conversions for in_proj operands (8 elems/thread)
  f2bf_kernel<<<2048, 256, 0, stream>>>(x, x_bf);            // 4096x1024
  f2bf_kernel<<<2048, 256, 0, stream>>>(in_proj_w, inw_bf);  // 4096x1024

  // 3. xz = x @ in_proj_w^T  (M=4096, N=4096, K=1024), bf16 out, 8-phase 256^2 pipeline
  gemm256_8ph<__hip_bfloat16><<<dim3(16, 16), 512, 0, stream>>>(
      x_bf, inw_bf, xz_bf, 1024, 1024, 1024, 4096);

  // 4. depthwise causal conv + bias + silu -> x_act (fp32) + x_act_bf (bf16)
  conv_silu_kernel<<<(BL * D_INNER) / 8 / 256, 256, 0, stream>>>(
      xz_bf, conv_w, conv_b, x_act, x_act_bf);

  // 5. x_dbl = x_act @ x_proj_w^T via bf16 MFMA split-K (padded 96->128 weight) + reduce
  f2bf_kernel<<<96, 256, 0, stream>>>(x_proj_w, (__hip_bfloat16*)wpad);  // 96x2048
  gemm_bt<128, 128, XP_N, true, float><<<dim3(XP_KS, 32), 256, 0, stream>>>(
      x_act_bf, wpad, Cpart, 2048 / XP_KS, 2048, 2048, XP_N);
  xproj_reduce<<<(BL * XP_N) / 256, 256, 0, stream>>>(Cpart, x_dbl);

  // 6. delta_raw = dt_low @ dt_proj_w^T  (4096 x 2048, K=64) via bf16 MFMA
  dtlow_bf_kernel<<<128, 256, 0, stream>>>(x_dbl, dtlow_bf);
  f2bf_kernel<<<64, 256, 0, stream>>>(dt_proj_w, dtw_bf);    // 2048x64
  gemm_bt<128, 128, 128, false, float><<<dim3(16, 32), 256, 0, stream>>>(
      dtlow_bf, dtw_bf, delta_raw, 64, 64, 64, 2048);

  // 7-9. chunked selective scan, lane-owns-d, NCHUNK=128 (8 waves/SIMD)
  scan_pass1<<<2048, 256, 0, stream>>>(delta_raw, x_act, x_dbl, A_log, dt_proj_b,
                                       chunkS, chunkH);
  scan_pass2<<<256, 256, 0, stream>>>(chunkS, A_log, chunkH);
  scan_pass3<<<2048, 256, 0, stream>>>(delta_raw, x_act, x_dbl, A_log, dt_proj_b,
                                       chunkH, D_skip, xz_bf);

  // 10. out_proj weights -> bf16 (delta region dead now)
  f2bf_kernel<<<1024, 256, 0, stream>>>(out_proj_w, outw_bf); // 1024x2048

  // 11. out = y @ out_proj_w^T  (M=4096, N=1024, K=2048), fp32 out, 128x64 tile
  gemm_bt<128, 64, 64, false, float><<<dim3(16, 32), 256, 0, stream>>>(
      xz_bf, outw_bf, out, 2048, 4096, 2048, 1024);
}

// Round 15
// 240.893 us; speedup vs baseline: 6.8642x; 1.0371x over previous
//
#include <hip/hip_runtime.h>
#include <hip/hip_bf16.h>
#include <cstdint>

#define D_STATE 16
#define D_INNER 2048
#define DT_RANK 64
#define SEQ 2048
#define BL 4096      // B * L
#define NCHUNK 128
#define CHUNK 16     // SEQ / NCHUNK
#define XP_N 96      // dt_rank + 2*d_state
#define XP_KS 8      // x_proj K-splits
#define LOG2E 1.44269504088896340736f

typedef short bf16x8 __attribute__((ext_vector_type(8)));
typedef short short8 __attribute__((ext_vector_type(8)));
typedef float f32x4 __attribute__((ext_vector_type(4)));

__device__ __forceinline__ float siluf(float x) {
  return __fdividef(x, 1.f + __expf(-x));
}

__device__ __forceinline__ float softplusf(float v) {
  return fmaxf(v, 0.f) + __logf(1.f + __expf(-fabsf(v)));
}

__device__ __forceinline__ float exp2fast(float x) {
  return __builtin_amdgcn_exp2f(x);
}

__device__ __forceinline__ unsigned short f2bf_bits(float x) {
  __hip_bfloat16 h = __float2bfloat16(x);
  return *reinterpret_cast<unsigned short*>(&h);
}

__device__ __forceinline__ float bf2f(unsigned short u) {
  return __int_as_float(((unsigned int)u) << 16);
}

__device__ __forceinline__ void gload_lds16(const void* g, void* l) {
  __builtin_amdgcn_global_load_lds((const __attribute__((address_space(1))) unsigned int*)g,
                                   (__attribute__((address_space(3))) unsigned int*)l,
                                   16, 0, 0);
}

#define BARRIER() asm volatile("s_barrier" ::: "memory")
#define VMCNT(n)  asm volatile("s_waitcnt vmcnt(" #n ")" ::: "memory")

// ---------------- fp32 -> bf16 conversion, 8 elems/thread (n multiple of 2048) --------
__global__ __launch_bounds__(256) void f2bf_kernel(const float* __restrict__ in,
                                                   __hip_bfloat16* __restrict__ out) {
  const int i = (blockIdx.x * 256 + threadIdx.x) * 8;
  float4 v0 = *reinterpret_cast<const float4*>(&in[i]);
  float4 v1 = *reinterpret_cast<const float4*>(&in[i + 4]);
  short8 r;
  r[0] = f2bf_bits(v0.x); r[1] = f2bf_bits(v0.y); r[2] = f2bf_bits(v0.z); r[3] = f2bf_bits(v0.w);
  r[4] = f2bf_bits(v1.x); r[5] = f2bf_bits(v1.y); r[6] = f2bf_bits(v1.z); r[7] = f2bf_bits(v1.w);
  *reinterpret_cast<short8*>(&out[i]) = r;
}

// ---------------- dt_low extract + bf16: x_dbl[:, 0:64] (stride 96) -> [4096][64] bf16 --
__global__ __launch_bounds__(256) void dtlow_bf_kernel(const float* __restrict__ x_dbl,
                                                       __hip_bfloat16* __restrict__ dtlow_bf) {
  const int i = blockIdx.x * 256 + threadIdx.x;   // 32768 threads
  const int row = i >> 3;
  const int c8 = (i & 7) * 8;
  float4 v0 = *reinterpret_cast<const float4*>(&x_dbl[(size_t)row * 96 + c8]);
  float4 v1 = *reinterpret_cast<const float4*>(&x_dbl[(size_t)row * 96 + c8 + 4]);
  short8 r;
  r[0] = f2bf_bits(v0.x); r[1] = f2bf_bits(v0.y); r[2] = f2bf_bits(v0.z); r[3] = f2bf_bits(v0.w);
  r[4] = f2bf_bits(v1.x); r[5] = f2bf_bits(v1.y); r[6] = f2bf_bits(v1.z); r[7] = f2bf_bits(v1.w);
  *reinterpret_cast<short8*>(&dtlow_bf[(size_t)row * 64 + c8]) = r;
}

// ============ 8-phase 256x256 bf16 GEMM (T2+T3+T4+T5): C = A[M,K] @ B[N,K]^T ============
template <typename OutT>
__global__ __launch_bounds__(512, 1) void gemm256_8ph(const __hip_bfloat16* __restrict__ A,
                                                      const __hip_bfloat16* __restrict__ B,
                                                      OutT* __restrict__ C,
                                                      int K, int lda, int ldb, int ldc) {
  __shared__ __align__(16) unsigned short lds[65536];  // [2 buf][A 16384 | B 16384] shorts
  const int tid = threadIdx.x;
  const int wv = tid >> 6, lane = tid & 63;
  const int wr = wv >> 2, wc = wv & 3;              // wave grid 2(M) x 4(N)
  const int m0 = blockIdx.y * 256, n0 = blockIdx.x * 256;
  const int frow = lane & 15;
  const int fu = lane >> 4;
  const int rsw = frow & 7;
  const int sr = lane >> 3;
  const int su = (lane & 7) ^ sr;

  const unsigned short* Ag = (const unsigned short*)A;
  const unsigned short* Bg = (const unsigned short*)B;

  f32x4 acc[8][4];
#pragma unroll
  for (int i = 0; i < 8; ++i)
#pragma unroll
    for (int j = 0; j < 4; ++j) acc[i][j] = {0.f, 0.f, 0.f, 0.f};

  auto stageA = [&](int buf, int g, int kg) {
    const int rowb = g * 64 + wv * 8;
    gload_lds16(&Ag[(size_t)(m0 + rowb + sr) * lda + kg + su * 8],
                &lds[buf * 32768 + rowb * 64]);
  };
  auto stageB = [&](int buf, int g, int kg) {
    const int rowb = g * 64 + wv * 8;
    gload_lds16(&Bg[(size_t)(n0 + rowb + sr) * ldb + kg + su * 8],
                &lds[buf * 32768 + 16384 + rowb * 64]);
  };
  auto fragA = [&](int buf, int mi, int kk) -> bf16x8 {
    const int row = wr * 128 + mi * 16 + frow;
    return *reinterpret_cast<const bf16x8*>(
        &lds[buf * 32768 + row * 64 + (((kk << 2) | fu) ^ rsw) * 8]);
  };
  auto fragB = [&](int buf, int ni, int kk) -> bf16x8 {
    const int row = wc * 64 + ni * 16 + frow;
    return *reinterpret_cast<const bf16x8*>(
        &lds[buf * 32768 + 16384 + row * 64 + (((kk << 2) | fu) ^ rsw) * 8]);
  };

#define QUAD(MB)                                                                        \
  _Pragma("unroll")                                                                     \
  for (int mi = 0; mi < 4; ++mi)                                                        \
    _Pragma("unroll")                                                                   \
    for (int ni = 0; ni < 4; ++ni)                                                      \
      acc[MB + mi][ni] =                                                                \
          __builtin_amdgcn_mfma_f32_16x16x32_bf16(af[mi], bfr[ni], acc[MB + mi][ni], 0, 0, 0);

  stageB(0, 0, 0); stageB(0, 1, 0); stageB(0, 2, 0); stageB(0, 3, 0);
  stageA(0, 0, 0); stageA(0, 2, 0); stageA(0, 1, 0); stageA(0, 3, 0);
  VMCNT(2);
  BARRIER();

  const int NT = K >> 6;
  int cur = 0;
  for (int t = 0; t < NT - 1; ++t) {
    const int nxt = cur ^ 1;
    const int kn = (t + 1) << 6;
    bf16x8 af[4], bfr[4];
    // ---- phase 0
#pragma unroll
    for (int mi = 0; mi < 4; ++mi) af[mi] = fragA(cur, mi, 0);
#pragma unroll
    for (int ni = 0; ni < 4; ++ni) bfr[ni] = fragB(cur, ni, 0);
    stageB(nxt, 0, kn); stageB(nxt, 1, kn);
    VMCNT(2);
    BARRIER();
    __builtin_amdgcn_s_setprio(1);
    QUAD(0);
    __builtin_amdgcn_s_setprio(0);
    BARRIER();
    // ---- phase 1
#pragma unroll
    for (int mi = 0; mi < 4; ++mi) af[mi] = fragA(cur, 4 + mi, 0);
    stageB(nxt, 2, kn); stageB(nxt, 3, kn);
    BARRIER();
    __builtin_amdgcn_s_setprio(1);
    QUAD(4);
    __builtin_amdgcn_s_setprio(0);
    BARRIER();
    // ---- phase 2
#pragma unroll
    for (int mi = 0; mi < 4; ++mi) af[mi] = fragA(cur, mi, 1);
#pragma unroll
    for (int ni = 0; ni < 4; ++ni) bfr[ni] = fragB(cur, ni, 1);
    stageA(nxt, 0, kn); stageA(nxt, 2, kn);
    BARRIER();
    __builtin_amdgcn_s_setprio(1);
    QUAD(0);
    __builtin_amdgcn_s_setprio(0);
    BARRIER();
    // ---- phase 3
#pragma unroll
    for (int mi = 0; mi < 4; ++mi) af[mi] = fragA(cur, 4 + mi, 1);
    stageA(nxt, 1, kn); stageA(nxt, 3, kn);
    VMCNT(2);
    BARRIER();
    __builtin_amdgcn_s_setprio(1);
    QUAD(4);
    __builtin_amdgcn_s_setprio(0);
    BARRIER();
    cur = nxt;
  }
  // ---- last tile
  {
    bf16x8 af[4], bfr[4];
#pragma unroll
    for (int mi = 0; mi < 4; ++mi) af[mi] = fragA(cur, mi, 0);
#pragma unroll
    for (int ni = 0; ni < 4; ++ni) bfr[ni] = fragB(cur, ni, 0);
    VMCNT(0);
    BARRIER();
    __builtin_amdgcn_s_setprio(1);
    QUAD(0);
    __builtin_amdgcn_s_setprio(0);
    BARRIER();
#pragma unroll
    for (int mi = 0; mi < 4; ++mi) af[mi] = fragA(cur, 4 + mi, 0);
    BARRIER();
    __builtin_amdgcn_s_setprio(1);
    QUAD(4);
    __builtin_amdgcn_s_setprio(0);
    BARRIER();
#pragma unroll
    for (int mi = 0; mi < 4; ++mi) af[mi] = fragA(cur, mi, 1);
#pragma unroll
    for (int ni = 0; ni < 4; ++ni) bfr[ni] = fragB(cur, ni, 1);
    BARRIER();
    __builtin_amdgcn_s_setprio(1);
    QUAD(0);
    __builtin_amdgcn_s_setprio(0);
    BARRIER();
#pragma unroll
    for (int mi = 0; mi < 4; ++mi) af[mi] = fragA(cur, 4 + mi, 1);
    __builtin_amdgcn_s_setprio(1);
    QUAD(4);
    __builtin_amdgcn_s_setprio(0);
  }
#undef QUAD

  const int crow = fu * 4;
  const int ccol = frow;
#pragma unroll
  for (int mi = 0; mi < 8; ++mi)
#pragma unroll
    for (int ni = 0; ni < 4; ++ni) {
      const int gcol = n0 + wc * 64 + ni * 16 + ccol;
#pragma unroll
      for (int j = 0; j < 4; ++j) {
        const int grow = m0 + wr * 128 + mi * 16 + crow + j;
        if constexpr (sizeof(OutT) == 2) {
          C[(size_t)grow * ldc + gcol] = __float2bfloat16(acc[mi][ni][j]);
        } else {
          C[(size_t)grow * ldc + gcol] = acc[mi][ni][j];
        }
      }
    }
}

// ---------------- MFMA bf16 GEMM: C = A[M,K] * B[N,K]^T, double-buffered LDS ----------
template <int BM, int BN>
__device__ __forceinline__ void stage_tiles(const unsigned short* __restrict__ Ag,
                                            const unsigned short* __restrict__ Bg,
                                            unsigned short* buf, int m0, int n0, int k0,
                                            int lda, int ldb, int sr, int sk, int wv) {
#pragma unroll
  for (int g = 0; g < BM / 64; ++g)
    gload_lds16(&Ag[(size_t)(m0 + g * 64 + sr) * lda + k0 + sk], &buf[g * 2048 + wv * 512]);
#pragma unroll
  for (int g = 0; g < BN / 64; ++g)
    gload_lds16(&Bg[(size_t)(n0 + g * 64 + sr) * ldb + k0 + sk], &buf[BM * 32 + g * 2048 + wv * 512]);
}

template <int BM, int BN, int NSTORE, bool SPLITK, typename OutT>
__global__ __launch_bounds__(256) void gemm_bt(const __hip_bfloat16* __restrict__ A,
                                               const __hip_bfloat16* __restrict__ B,
                                               OutT* __restrict__ C,
                                               int K, int lda, int ldb, int ldc) {
  constexpr int WM = BM / 2, WN = BN / 2;
  constexpr int MI = WM / 16, NI = WN / 16;
  constexpr int BUFS = (BM + BN) * 32;
  __shared__ __align__(16) unsigned short lds[2 * BUFS];
  const int tid = threadIdx.x;
  const int wv = tid >> 6, lane = tid & 63;
  const int wr = wv >> 1, wc = wv & 1;
  const int m0 = blockIdx.y * BM;
  int n0, koff;
  if constexpr (SPLITK) {
    n0 = 0;
    koff = blockIdx.x * K;
    C += (size_t)blockIdx.x * BL * NSTORE;
  } else {
    n0 = blockIdx.x * BN;
    koff = 0;
  }
  const int sr = tid >> 2;
  const int sk = (tid & 3) * 8;
  const int frow = lane & 15;
  const int fk = (lane >> 4) * 8;

  f32x4 acc[MI][NI];
#pragma unroll
  for (int i = 0; i < MI; ++i)
#pragma unroll
    for (int j = 0; j < NI; ++j) acc[i][j] = {0.f, 0.f, 0.f, 0.f};

  const unsigned short* Ag = (const unsigned short*)A;
  const unsigned short* Bg = (const unsigned short*)B;

  stage_tiles<BM, BN>(Ag, Bg, &lds[0], m0, n0, koff, lda, ldb, sr, sk, wv);
  __syncthreads();
  int sel = 0;
  for (int k0 = 0; k0 < K; k0 += 32) {
    if (k0 + 32 < K)
      stage_tiles<BM, BN>(Ag, Bg, &lds[(sel ^ 1) * BUFS], m0, n0, koff + k0 + 32, lda, ldb, sr, sk, wv);
    const unsigned short* Abuf = &lds[sel * BUFS];
    const unsigned short* Bbuf = &lds[sel * BUFS + BM * 32];
    bf16x8 af[MI], bfr[NI];
#pragma unroll
    for (int mi = 0; mi < MI; ++mi)
      af[mi] = *reinterpret_cast<const bf16x8*>(&Abuf[(wr * WM + mi * 16 + frow) * 32 + fk]);
#pragma unroll
    for (int ni = 0; ni < NI; ++ni)
      bfr[ni] = *reinterpret_cast<const bf16x8*>(&Bbuf[(wc * WN + ni * 16 + frow) * 32 + fk]);
#pragma unroll
    for (int mi = 0; mi < MI; ++mi)
#pragma unroll
      for (int ni = 0; ni < NI; ++ni)
        acc[mi][ni] = __builtin_amdgcn_mfma_f32_16x16x32_bf16(af[mi], bfr[ni], acc[mi][ni], 0, 0, 0);
    __syncthreads();
    sel ^= 1;
  }

  const int crow = (lane >> 4) * 4;
  const int ccol = lane & 15;
#pragma unroll
  for (int mi = 0; mi < MI; ++mi)
#pragma unroll
    for (int ni = 0; ni < NI; ++ni) {
      const int gcol = n0 + wc * WN + ni * 16 + ccol;
      if constexpr (NSTORE < BN) {
        if (gcol >= NSTORE) continue;
      }
#pragma unroll
      for (int j = 0; j < 4; ++j) {
        const int grow = m0 + wr * WM + mi * 16 + crow + j;
        if constexpr (sizeof(OutT) == 2) {
          C[(size_t)grow * ldc + gcol] = __float2bfloat16(acc[mi][ni][j]);
        } else {
          C[(size_t)grow * ldc + gcol] = acc[mi][ni][j];
        }
      }
    }
}

// ---------------- x_proj reduce ----------------
__global__ __launch_bounds__(256) void xproj_reduce(const float* __restrict__ Cpart,
                                                    float* __restrict__ x_dbl) {
  const int i = blockIdx.x * 256 + threadIdx.x;    // < BL * XP_N
  float s = 0.f;
#pragma unroll
  for (int z = 0; z < XP_KS; ++z) s += Cpart[(size_t)z * BL * XP_N + i];
  x_dbl[i] = s;
}

// ---------------- depthwise causal conv1d (w=4) + bias + silu, 8 d's/thread ----------
// Writes x_act only as bf16 (feeds x_proj MFMA A-operand and the scan's u-loads).
__global__ __launch_bounds__(256) void conv_silu_kernel(const __hip_bfloat16* __restrict__ xz_bf,
                                                        const float* __restrict__ conv_w,
                                                        const float* __restrict__ conv_b,
                                                        __hip_bfloat16* __restrict__ x_act_bf) {
  const int idx = blockIdx.x * 256 + threadIdx.x;       // over BL * D_INNER / 8
  const int d8 = (idx << 3) & (D_INNER - 1);
  const int bl = idx >> 8;
  const int l = bl & (SEQ - 1);

  float acc[8];
  {
    float4 cb0 = *reinterpret_cast<const float4*>(&conv_b[d8]);
    float4 cb1 = *reinterpret_cast<const float4*>(&conv_b[d8 + 4]);
    acc[0] = cb0.x; acc[1] = cb0.y; acc[2] = cb0.z; acc[3] = cb0.w;
    acc[4] = cb1.x; acc[5] = cb1.y; acc[6] = cb1.z; acc[7] = cb1.w;
  }
  float4 cw[8];
#pragma unroll
  for (int j = 0; j < 8; ++j)
    cw[j] = *reinterpret_cast<const float4*>(&conv_w[(d8 + j) * 4]);

#pragma unroll
  for (int k = 0; k < 4; ++k) {
    if (l + k - 3 >= 0) {
      short8 v = *reinterpret_cast<const short8*>(&xz_bf[(size_t)(bl + k - 3) * 4096 + d8]);
      const float w0[8] = {cw[0].x, cw[1].x, cw[2].x, cw[3].x, cw[4].x, cw[5].x, cw[6].x, cw[7].x};
      const float w1[8] = {cw[0].y, cw[1].y, cw[2].y, cw[3].y, cw[4].y, cw[5].y, cw[6].y, cw[7].y};
      const float w2[8] = {cw[0].z, cw[1].z, cw[2].z, cw[3].z, cw[4].z, cw[5].z, cw[6].z, cw[7].z};
      const float w3[8] = {cw[0].w, cw[1].w, cw[2].w, cw[3].w, cw[4].w, cw[5].w, cw[6].w, cw[7].w};
      const float* wk = (k == 0) ? w0 : (k == 1) ? w1 : (k == 2) ? w2 : w3;
#pragma unroll
      for (int j = 0; j < 8; ++j) acc[j] = fmaf(bf2f((unsigned short)v[j]), wk[j], acc[j]);
    }
  }

  short8 ob;
#pragma unroll
  for (int j = 0; j < 8; ++j) ob[j] = f2bf_bits(siluf(acc[j]));
  *reinterpret_cast<short8*>(&x_act_bf[(size_t)bl * D_INNER + d8]) = ob;
}

// ---------------- scan pass 1: lane owns d; 16 n-states in registers (bf16 dv/uv) -------
__global__ __launch_bounds__(256) void scan_pass1(const __hip_bfloat16* __restrict__ delta_bf,
                                                  const __hip_bfloat16* __restrict__ x_act_bf,
                                                  const float* __restrict__ x_dbl,
                                                  const float* __restrict__ A_log,
                                                  const float* __restrict__ dt_proj_b,
                                                  float* __restrict__ chunkS,
                                                  float* __restrict__ chunkH) {
  const int t = blockIdx.x * 256 + threadIdx.x;
  const int d = t & (D_INNER - 1);
  const int c = (t >> 11) & (NCHUNK - 1);
  const int b = t >> 18;
  const int base = b * SEQ + c * CHUNK;

  float Av[16];
#pragma unroll
  for (int q = 0; q < 4; ++q) {
    float4 a = *reinterpret_cast<const float4*>(&A_log[d * 16 + q * 4]);
    Av[q * 4 + 0] = -__expf(a.x) * LOG2E; Av[q * 4 + 1] = -__expf(a.y) * LOG2E;
    Av[q * 4 + 2] = -__expf(a.z) * LOG2E; Av[q * 4 + 3] = -__expf(a.w) * LOG2E;
  }
  const float bias = dt_proj_b[d];

  const unsigned short* dp = (const unsigned short*)delta_bf + (size_t)base * D_INNER + d;
  const unsigned short* up = (const unsigned short*)x_act_bf + (size_t)base * D_INNER + d;
  const float* xb = x_dbl + (size_t)base * 96 + DT_RANK;

  float h[16];
#pragma unroll
  for (int n = 0; n < 16; ++n) h[n] = 0.f;
  float S = 0.f;

  float dvr = bf2f(*dp), uvv = bf2f(*up);
  float4 b0 = *reinterpret_cast<const float4*>(xb);
  float4 b1 = *reinterpret_cast<const float4*>(xb + 4);
  float4 b2 = *reinterpret_cast<const float4*>(xb + 8);
  float4 b3 = *reinterpret_cast<const float4*>(xb + 12);
  for (int l = 0; l < CHUNK; ++l) {
    dp += D_INNER; up += D_INNER; xb += 96;
    const float ndvr = bf2f(*dp), nuv = bf2f(*up);
    const float4 nb0 = *reinterpret_cast<const float4*>(xb);
    const float4 nb1 = *reinterpret_cast<const float4*>(xb + 4);
    const float4 nb2 = *reinterpret_cast<const float4*>(xb + 8);
    const float4 nb3 = *reinterpret_cast<const float4*>(xb + 12);

    const float dv = softplusf(dvr + bias);
    S += dv;
    const float du = dv * uvv;
    const float Bf[16] = {b0.x, b0.y, b0.z, b0.w, b1.x, b1.y, b1.z, b1.w,
                          b2.x, b2.y, b2.z, b2.w, b3.x, b3.y, b3.z, b3.w};
#pragma unroll
    for (int n = 0; n < 16; ++n) {
      const float dA = exp2fast(dv * Av[n]);
      h[n] = fmaf(dA, h[n], du * Bf[n]);
    }
    dvr = ndvr; uvv = nuv; b0 = nb0; b1 = nb1; b2 = nb2; b3 = nb3;
  }

  const size_t sidx = (size_t)(b * NCHUNK + c) * D_INNER + d;
  chunkS[sidx] = S;
  float* hp = chunkH + sidx * 16;
#pragma unroll
  for (int q = 0; q < 4; ++q)
    *reinterpret_cast<float4*>(hp + q * 4) =
        make_float4(h[q * 4 + 0], h[q * 4 + 1], h[q * 4 + 2], h[q * 4 + 3]);
}

// ---------------- scan pass 2: combine chunk prefixes; chunkH becomes h0 ----------------
__global__ __launch_bounds__(256) void scan_pass2(const float* __restrict__ chunkS,
                                                  const float* __restrict__ A_log,
                                                  float* chunkH) {
  const int s = blockIdx.x * 256 + threadIdx.x;   // 65536 = (b, d, n)
  const int n = s & 15;
  const int d = (s >> 4) & (D_INNER - 1);
  const int b = s >> 15;
  const float Aval = -__expf(A_log[d * 16 + n]) * LOG2E;

  size_t sidx = (size_t)b * NCHUNK * D_INNER + d;
  float aS = chunkS[sidx];
  float hE = chunkH[sidx * 16 + n];
  float H = 0.f;
  for (int c = 0; c < NCHUNK; ++c) {
    const size_t sidx2 = sidx + D_INNER;
    const float naS = chunkS[sidx2];            // overread at c==NC-1: inside ws
    const float nhE = chunkH[sidx2 * 16 + n];
    const float aP = exp2fast(Aval * aS);
    chunkH[sidx * 16 + n] = H;                  // h0 for this chunk
    H = fmaf(aP, H, hE);
    sidx = sidx2; aS = naS; hE = nhE;
  }
}

// ---------------- scan pass 3: rescan with h0; fused D-skip + silu(z) gate -> bf16 ------
__global__ __launch_bounds__(256) void scan_pass3(const __hip_bfloat16* __restrict__ delta_bf,
                                                  const __hip_bfloat16* __restrict__ x_act_bf,
                                                  const float* __restrict__ x_dbl,
                                                  const float* __restrict__ A_log,
                                                  const float* __restrict__ dt_proj_b,
                                                  const float* __restrict__ chunkH0,
                                                  const float* __restrict__ D_skip,
                                                  __hip_bfloat16* xz_bf) {
  const int t = blockIdx.x * 256 + threadIdx.x;
  const int d = t & (D_INNER - 1);
  const int c = (t >> 11) & (NCHUNK - 1);
  const int b = t >> 18;
  const int base = b * SEQ + c * CHUNK;

  float Av[16];
#pragma unroll
  for (int q = 0; q < 4; ++q) {
    float4 a = *reinterpret_cast<const float4*>(&A_log[d * 16 + q * 4]);
    Av[q * 4 + 0] = -__expf(a.x) * LOG2E; Av[q * 4 + 1] = -__expf(a.y) * LOG2E;
    Av[q * 4 + 2] = -__expf(a.z) * LOG2E; Av[q * 4 + 3] = -__expf(a.w) * LOG2E;
  }
  const float bias = dt_proj_b[d];
  const float Dv = D_skip[d];

  const unsigned short* dp = (const unsigned short*)delta_bf + (size_t)base * D_INNER + d;
  const unsigned short* up = (const unsigned short*)x_act_bf + (size_t)base * D_INNER + d;
  const float* xb = x_dbl + (size_t)base * 96 + DT_RANK;      // B at [0..15], C at [16..31]
  __hip_bfloat16* zp = xz_bf + (size_t)base * 4096 + D_INNER + d;

  float h[16];
  {
    const float* hp = chunkH0 + ((size_t)(b * NCHUNK + c) * D_INNER + d) * 16;
#pragma unroll
    for (int q = 0; q < 4; ++q) {
      float4 v = *reinterpret_cast<const float4*>(hp + q * 4);
      h[q * 4 + 0] = v.x; h[q * 4 + 1] = v.y; h[q * 4 + 2] = v.z; h[q * 4 + 3] = v.w;
    }
  }

  float dvr = bf2f(*dp), uvv = bf2f(*up);
  float4 b0 = *reinterpret_cast<const float4*>(xb);
  float4 b1 = *reinterpret_cast<const float4*>(xb + 4);
  float4 b2 = *reinterpret_cast<const float4*>(xb + 8);
  float4 b3 = *reinterpret_cast<const float4*>(xb + 12);
  float4 c0 = *reinterpret_cast<const float4*>(xb + 16);
  float4 c1 = *reinterpret_cast<const float4*>(xb + 20);
  float4 c2 = *reinterpret_cast<const float4*>(xb + 24);
  float4 c3 = *reinterpret_cast<const float4*>(xb + 28);
  for (int l = 0; l < CHUNK; ++l) {
    dp += D_INNER; up += D_INNER; xb += 96;
    const float ndvr = bf2f(*dp), nuv = bf2f(*up);
    const float4 nb0 = *reinterpret_cast<const float4*>(xb);
    const float4 nb1 = *reinterpret_cast<const float4*>(xb + 4);
    const float4 nb2 = *reinterpret_cast<const float4*>(xb + 8);
    const float4 nb3 = *reinterpret_cast<const float4*>(xb + 12);
    const float4 nc0 = *reinterpret_cast<const float4*>(xb + 16);
    const float4 nc1 = *reinterpret_cast<const float4*>(xb + 20);
    const float4 nc2 = *reinterpret_cast<const float4*>(xb + 24);
    const float4 nc3 = *reinterpret_cast<const float4*>(xb + 28);

    const float dv = softplusf(dvr + bias);
    const float du = dv * uvv;
    const float Bf[16] = {b0.x, b0.y, b0.z, b0.w, b1.x, b1.y, b1.z, b1.w,
                          b2.x, b2.y, b2.z, b2.w, b3.x, b3.y, b3.z, b3.w};
    const float Cf[16] = {c0.x, c0.y, c0.z, c0.w, c1.x, c1.y, c1.z, c1.w,
                          c2.x, c2.y, c2.z, c2.w, c3.x, c3.y, c3.z, c3.w};
    float p = 0.f;
#pragma unroll
    for (int n = 0; n < 16; ++n) {
      const float dA = exp2fast(dv * Av[n]);
      h[n] = fmaf(dA, h[n], du * Bf[n]);
      p = fmaf(h[n], Cf[n], p);
    }
    const float zv = __bfloat162float(zp[0]);
    const float yv = fmaf(uvv, Dv, p) * siluf(zv);
    zp[-(int)D_INNER] = __float2bfloat16(yv);
    zp += 4096;

    dvr = ndvr; uvv = nuv;
    b0 = nb0; b1 = nb1; b2 = nb2; b3 = nb3;
    c0 = nc0; c1 = nc1; c2 = nc2; c3 = nc3;
  }
}

extern "C" void kernel_launch(void* const* d_in, const int* in_sizes, int n_in,
                              void* d_out, int out_size, void* d_ws, size_t ws_size,
                              hipStream_t stream) {
  const float* x          = (const float*)d_in[0];
  const float* in_proj_w  = (const float*)d_in[1];
  const float* conv_w     = (const float*)d_in[2];
  const float* conv_b     = (const float*)d_in[3];
  const float* x_proj_w   = (const float*)d_in[4];
  const float* dt_proj_w  = (const float*)d_in[5];
  const float* dt_proj_b  = (const float*)d_in[6];
  const float* A_log      = (const float*)d_in[7];
  const float* D_skip     = (const float*)d_in[8];
  const float* out_proj_w = (const float*)d_in[9];
  float* out = (float*)d_out;   // fp32 output

  // Workspace layout (peak ~133 MiB):
  //   xz_bf     @0          33,554,432  bf16 [4096][4096]
  //   x_act_bf  @33554432   16,777,216  bf16 [4096][2048]
  //   delta_bf  @50331648   16,777,216  bf16 [4096][2048]
  //   x_bf      @67108864    8,388,608  (pre-conv; region reused: Cpart -> outw_bf)
  //   inw_bf    @75497472    8,388,608
  //   Cpart     @67108864   12,582,912  (post-conv, pre-dt)
  //   outw_bf   @67108864    4,194,304  (post-scan)
  //   x_dbl     @100663296   1,572,864
  //   chunkH    @102236160  33,554,432
  //   chunkS    @135790592   2,097,152
  //   wpad      @137887744     524,288
  //   dtlow_bf  @138412032     524,288
  //   dtw_bf    @138936320     262,144
  char* ws = (char*)d_ws;
  __hip_bfloat16* xz_bf    = (__hip_bfloat16*)(ws);
  __hip_bfloat16* x_act_bf = (__hip_bfloat16*)(ws + 33554432);
  __hip_bfloat16* delta_bf = (__hip_bfloat16*)(ws + 50331648);
  __hip_bfloat16* x_bf     = (__hip_bfloat16*)(ws + 67108864);
  __hip_bfloat16* inw_bf   = (__hip_bfloat16*)(ws + 75497472);
  float* Cpart             = (float*)(ws + 67108864);
  __hip_bfloat16* outw_bf  = (__hip_bfloat16*)(ws + 67108864);
  float* x_dbl             = (float*)(ws + 100663296);
  float* chunkH            = (float*)(ws + 102236160);
  float* chunkS            = (float*)(ws + 135790592);
  __hip_bfloat16* wpad     = (__hip_bfloat16*)(ws + 137887744);
  __hip_bfloat16* dtlow_bf = (__hip_bfloat16*)(ws + 138412032);
  __hip_bfloat16* dtw_bf   = (__hip_bfloat16*)(ws + 138936320);

  // 1-2. bf16 conversions for in_proj operands (8 elems/thread)
  f2bf_kernel<<<2048, 256, 0, stream>>>(x, x_bf);            // 4096x1024
  f2bf_kernel<<<2048, 256, 0, stream>>>(in_proj_w, inw_bf);  // 4096x1024

  // 3. xz = x @ in_proj_w^T  (M=4096, N=4096, K=1024), bf16 out, 8-phase 256^2 pipeline
  gemm256_8ph<__hip_bfloat16><<<dim3(16, 16), 512, 0, stream>>>(
      x_bf, inw_bf, xz_bf, 1024, 1024, 1024, 4096);

  // 4. depthwise causal conv + bias + silu -> x_act_bf (bf16 only)
  conv_silu_kernel<<<(BL * D_INNER) / 8 / 256, 256, 0, stream>>>(
      xz_bf, conv_w, conv_b, x_act_bf);

  // 5. x_dbl = x_act @ x_proj_w^T via bf16 MFMA split-K (padded 96->128 weight) + reduce
  f2bf_kernel<<<96, 256, 0, stream>>>(x_proj_w, (__hip_bfloat16*)wpad);  // 96x2048
  gemm_bt<128, 128, XP_N, true, float><<<dim3(XP_KS, 32), 256, 0, stream>>>(
      x_act_bf, wpad, Cpart, 2048 / XP_KS, 2048, 2048, XP_N);
  xproj_reduce<<<(BL * XP_N) / 256, 256, 0, stream>>>(Cpart, x_dbl);

  // 6. delta_raw = dt_low @ dt_proj_w^T  (4096 x 2048, K=64) via bf16 MFMA, bf16 out
  dtlow_bf_kernel<<<128, 256, 0, stream>>>(x_dbl, dtlow_bf);
  f2bf_kernel<<<64, 256, 0, stream>>>(dt_proj_w, dtw_bf);    // 2048x64
  gemm_bt<128, 128, 128, false, __hip_bfloat16><<<dim3(16, 32), 256, 0, stream>>>(
      dtlow_bf, dtw_bf, delta_bf, 64, 64, 64, 2048);

  // 7-9. chunked selective scan, lane-owns-d, NCHUNK=128 (8 waves/SIMD), bf16 streams
  scan_pass1<<<2048, 256, 0, stream>>>(delta_bf, x_act_bf, x_dbl, A_log, dt_proj_b,
                                       chunkS, chunkH);
  scan_pass2<<<256, 256, 0, stream>>>(chunkS, A_log, chunkH);
  scan_pass3<<<2048, 256, 0, stream>>>(delta_bf, x_act_bf, x_dbl, A_log, dt_proj_b,
                                       chunkH, D_skip, xz_bf);

  // 10. out_proj weights -> bf16 (Cpart region dead now)
  f2bf_kernel<<<1024, 256, 0, stream>>>(out_proj_w, outw_bf); // 1024x2048

  // 11. out = y @ out_proj_w^T  (M=4096, N=1024, K=2048), fp32 out, 128x64 tile
  gemm_bt<128, 64, 64, false, float><<<dim3(16, 32), 256, 0, stream>>>(
      xz_bf, outw_bf, out, 2048, 4096, 2048, 1024);
}

// Round 16
// 226.662 us; speedup vs baseline: 7.2952x; 1.0628x over previous
//
#include <hip/hip_runtime.h>
#include <hip/hip_bf16.h>
#include <cstdint>

#define D_STATE 16
#define D_INNER 2048
#define DT_RANK 64
#define SEQ 2048
#define BL 4096      // B * L
#define NCHUNK 128
#define CHUNK 16     // SEQ / NCHUNK
#define XP_N 96      // dt_rank + 2*d_state
#define XP_KS 8      // x_proj K-splits
#define LOG2E 1.44269504088896340736f

typedef short bf16x8 __attribute__((ext_vector_type(8)));
typedef short short8 __attribute__((ext_vector_type(8)));
typedef float f32x4 __attribute__((ext_vector_type(4)));

__device__ __forceinline__ float siluf(float x) {
  return __fdividef(x, 1.f + __expf(-x));
}

__device__ __forceinline__ float softplusf(float v) {
  return fmaxf(v, 0.f) + __logf(1.f + __expf(-fabsf(v)));
}

__device__ __forceinline__ float exp2fast(float x) {
  return __builtin_amdgcn_exp2f(x);
}

__device__ __forceinline__ unsigned short f2bf_bits(float x) {
  __hip_bfloat16 h = __float2bfloat16(x);
  return *reinterpret_cast<unsigned short*>(&h);
}

__device__ __forceinline__ float bf2f(unsigned short u) {
  return __int_as_float(((unsigned int)u) << 16);
}

__device__ __forceinline__ void gload_lds16(const void* g, void* l) {
  __builtin_amdgcn_global_load_lds((const __attribute__((address_space(1))) unsigned int*)g,
                                   (__attribute__((address_space(3))) unsigned int*)l,
                                   16, 0, 0);
}

#define BARRIER() asm volatile("s_barrier" ::: "memory")
#define VMCNT(n)  asm volatile("s_waitcnt vmcnt(" #n ")" ::: "memory")

// ---------------- fused fp32 -> bf16 conversions of all inputs (one launch) ----------
// blocks: [0,2048) x -> x_bf | [2048,4096) in_proj_w -> inw_bf | [4096,4192) x_proj_w ->
// wpad | [4192,4256) dt_proj_w -> dtw_bf | [4256,5280) out_proj_w -> outw_bf.
__global__ __launch_bounds__(256) void f2bf_multi(const float* __restrict__ x, __hip_bfloat16* __restrict__ x_bf,
                                                  const float* __restrict__ inw, __hip_bfloat16* __restrict__ inw_bf,
                                                  const float* __restrict__ xpw, __hip_bfloat16* __restrict__ wpad,
                                                  const float* __restrict__ dtw, __hip_bfloat16* __restrict__ dtw_bf,
                                                  const float* __restrict__ outw, __hip_bfloat16* __restrict__ outw_bf) {
  const int blk = blockIdx.x;
  const float* src;
  __hip_bfloat16* dst;
  int base;
  if (blk < 2048)      { src = x;    dst = x_bf;    base = blk; }
  else if (blk < 4096) { src = inw;  dst = inw_bf;  base = blk - 2048; }
  else if (blk < 4192) { src = xpw;  dst = wpad;    base = blk - 4096; }
  else if (blk < 4256) { src = dtw;  dst = dtw_bf;  base = blk - 4192; }
  else                 { src = outw; dst = outw_bf; base = blk - 4256; }
  const int i = (base * 256 + threadIdx.x) * 8;
  float4 v0 = *reinterpret_cast<const float4*>(&src[i]);
  float4 v1 = *reinterpret_cast<const float4*>(&src[i + 4]);
  short8 r;
  r[0] = f2bf_bits(v0.x); r[1] = f2bf_bits(v0.y); r[2] = f2bf_bits(v0.z); r[3] = f2bf_bits(v0.w);
  r[4] = f2bf_bits(v1.x); r[5] = f2bf_bits(v1.y); r[6] = f2bf_bits(v1.z); r[7] = f2bf_bits(v1.w);
  *reinterpret_cast<short8*>(&dst[i]) = r;
}

// ---------------- dt_low extract + bf16: x_dbl[:, 0:64] (stride 96) -> [4096][64] bf16 --
__global__ __launch_bounds__(256) void dtlow_bf_kernel(const float* __restrict__ x_dbl,
                                                       __hip_bfloat16* __restrict__ dtlow_bf) {
  const int i = blockIdx.x * 256 + threadIdx.x;   // 32768 threads
  const int row = i >> 3;
  const int c8 = (i & 7) * 8;
  float4 v0 = *reinterpret_cast<const float4*>(&x_dbl[(size_t)row * 96 + c8]);
  float4 v1 = *reinterpret_cast<const float4*>(&x_dbl[(size_t)row * 96 + c8 + 4]);
  short8 r;
  r[0] = f2bf_bits(v0.x); r[1] = f2bf_bits(v0.y); r[2] = f2bf_bits(v0.z); r[3] = f2bf_bits(v0.w);
  r[4] = f2bf_bits(v1.x); r[5] = f2bf_bits(v1.y); r[6] = f2bf_bits(v1.z); r[7] = f2bf_bits(v1.w);
  *reinterpret_cast<short8*>(&dtlow_bf[(size_t)row * 64 + c8]) = r;
}

// ============ 8-phase 256x256 bf16 GEMM (T2+T3+T4+T5): C = A[M,K] @ B[N,K]^T ============
template <typename OutT>
__global__ __launch_bounds__(512, 1) void gemm256_8ph(const __hip_bfloat16* __restrict__ A,
                                                      const __hip_bfloat16* __restrict__ B,
                                                      OutT* __restrict__ C,
                                                      int K, int lda, int ldb, int ldc) {
  __shared__ __align__(16) unsigned short lds[65536];  // [2 buf][A 16384 | B 16384] shorts
  const int tid = threadIdx.x;
  const int wv = tid >> 6, lane = tid & 63;
  const int wr = wv >> 2, wc = wv & 3;              // wave grid 2(M) x 4(N)
  const int m0 = blockIdx.y * 256, n0 = blockIdx.x * 256;
  const int frow = lane & 15;
  const int fu = lane >> 4;
  const int rsw = frow & 7;
  const int sr = lane >> 3;
  const int su = (lane & 7) ^ sr;

  const unsigned short* Ag = (const unsigned short*)A;
  const unsigned short* Bg = (const unsigned short*)B;

  f32x4 acc[8][4];
#pragma unroll
  for (int i = 0; i < 8; ++i)
#pragma unroll
    for (int j = 0; j < 4; ++j) acc[i][j] = {0.f, 0.f, 0.f, 0.f};

  auto stageA = [&](int buf, int g, int kg) {
    const int rowb = g * 64 + wv * 8;
    gload_lds16(&Ag[(size_t)(m0 + rowb + sr) * lda + kg + su * 8],
                &lds[buf * 32768 + rowb * 64]);
  };
  auto stageB = [&](int buf, int g, int kg) {
    const int rowb = g * 64 + wv * 8;
    gload_lds16(&Bg[(size_t)(n0 + rowb + sr) * ldb + kg + su * 8],
                &lds[buf * 32768 + 16384 + rowb * 64]);
  };
  auto fragA = [&](int buf, int mi, int kk) -> bf16x8 {
    const int row = wr * 128 + mi * 16 + frow;
    return *reinterpret_cast<const bf16x8*>(
        &lds[buf * 32768 + row * 64 + (((kk << 2) | fu) ^ rsw) * 8]);
  };
  auto fragB = [&](int buf, int ni, int kk) -> bf16x8 {
    const int row = wc * 64 + ni * 16 + frow;
    return *reinterpret_cast<const bf16x8*>(
        &lds[buf * 32768 + 16384 + row * 64 + (((kk << 2) | fu) ^ rsw) * 8]);
  };

#define QUAD(MB)                                                                        \
  _Pragma("unroll")                                                                     \
  for (int mi = 0; mi < 4; ++mi)                                                        \
    _Pragma("unroll")                                                                   \
    for (int ni = 0; ni < 4; ++ni)                                                      \
      acc[MB + mi][ni] =                                                                \
          __builtin_amdgcn_mfma_f32_16x16x32_bf16(af[mi], bfr[ni], acc[MB + mi][ni], 0, 0, 0);

  stageB(0, 0, 0); stageB(0, 1, 0); stageB(0, 2, 0); stageB(0, 3, 0);
  stageA(0, 0, 0); stageA(0, 2, 0); stageA(0, 1, 0); stageA(0, 3, 0);
  VMCNT(2);
  BARRIER();

  const int NT = K >> 6;
  int cur = 0;
  for (int t = 0; t < NT - 1; ++t) {
    const int nxt = cur ^ 1;
    const int kn = (t + 1) << 6;
    bf16x8 af[4], bfr[4];
    // ---- phase 0
#pragma unroll
    for (int mi = 0; mi < 4; ++mi) af[mi] = fragA(cur, mi, 0);
#pragma unroll
    for (int ni = 0; ni < 4; ++ni) bfr[ni] = fragB(cur, ni, 0);
    stageB(nxt, 0, kn); stageB(nxt, 1, kn);
    VMCNT(2);
    BARRIER();
    __builtin_amdgcn_s_setprio(1);
    QUAD(0);
    __builtin_amdgcn_s_setprio(0);
    BARRIER();
    // ---- phase 1
#pragma unroll
    for (int mi = 0; mi < 4; ++mi) af[mi] = fragA(cur, 4 + mi, 0);
    stageB(nxt, 2, kn); stageB(nxt, 3, kn);
    BARRIER();
    __builtin_amdgcn_s_setprio(1);
    QUAD(4);
    __builtin_amdgcn_s_setprio(0);
    BARRIER();
    // ---- phase 2
#pragma unroll
    for (int mi = 0; mi < 4; ++mi) af[mi] = fragA(cur, mi, 1);
#pragma unroll
    for (int ni = 0; ni < 4; ++ni) bfr[ni] = fragB(cur, ni, 1);
    stageA(nxt, 0, kn); stageA(nxt, 2, kn);
    BARRIER();
    __builtin_amdgcn_s_setprio(1);
    QUAD(0);
    __builtin_amdgcn_s_setprio(0);
    BARRIER();
    // ---- phase 3
#pragma unroll
    for (int mi = 0; mi < 4; ++mi) af[mi] = fragA(cur, 4 + mi, 1);
    stageA(nxt, 1, kn); stageA(nxt, 3, kn);
    VMCNT(2);
    BARRIER();
    __builtin_amdgcn_s_setprio(1);
    QUAD(4);
    __builtin_amdgcn_s_setprio(0);
    BARRIER();
    cur = nxt;
  }
  // ---- last tile
  {
    bf16x8 af[4], bfr[4];
#pragma unroll
    for (int mi = 0; mi < 4; ++mi) af[mi] = fragA(cur, mi, 0);
#pragma unroll
    for (int ni = 0; ni < 4; ++ni) bfr[ni] = fragB(cur, ni, 0);
    VMCNT(0);
    BARRIER();
    __builtin_amdgcn_s_setprio(1);
    QUAD(0);
    __builtin_amdgcn_s_setprio(0);
    BARRIER();
#pragma unroll
    for (int mi = 0; mi < 4; ++mi) af[mi] = fragA(cur, 4 + mi, 0);
    BARRIER();
    __builtin_amdgcn_s_setprio(1);
    QUAD(4);
    __builtin_amdgcn_s_setprio(0);
    BARRIER();
#pragma unroll
    for (int mi = 0; mi < 4; ++mi) af[mi] = fragA(cur, mi, 1);
#pragma unroll
    for (int ni = 0; ni < 4; ++ni) bfr[ni] = fragB(cur, ni, 1);
    BARRIER();
    __builtin_amdgcn_s_setprio(1);
    QUAD(0);
    __builtin_amdgcn_s_setprio(0);
    BARRIER();
#pragma unroll
    for (int mi = 0; mi < 4; ++mi) af[mi] = fragA(cur, 4 + mi, 1);
    __builtin_amdgcn_s_setprio(1);
    QUAD(4);
    __builtin_amdgcn_s_setprio(0);
  }
#undef QUAD

  const int crow = fu * 4;
  const int ccol = frow;
#pragma unroll
  for (int mi = 0; mi < 8; ++mi)
#pragma unroll
    for (int ni = 0; ni < 4; ++ni) {
      const int gcol = n0 + wc * 64 + ni * 16 + ccol;
#pragma unroll
      for (int j = 0; j < 4; ++j) {
        const int grow = m0 + wr * 128 + mi * 16 + crow + j;
        if constexpr (sizeof(OutT) == 2) {
          C[(size_t)grow * ldc + gcol] = __float2bfloat16(acc[mi][ni][j]);
        } else {
          C[(size_t)grow * ldc + gcol] = acc[mi][ni][j];
        }
      }
    }
}

// ---------------- MFMA bf16 GEMM: C = A[M,K] * B[N,K]^T, double-buffered LDS ----------
template <int BM, int BN>
__device__ __forceinline__ void stage_tiles(const unsigned short* __restrict__ Ag,
                                            const unsigned short* __restrict__ Bg,
                                            unsigned short* buf, int m0, int n0, int k0,
                                            int lda, int ldb, int sr, int sk, int wv) {
#pragma unroll
  for (int g = 0; g < BM / 64; ++g)
    gload_lds16(&Ag[(size_t)(m0 + g * 64 + sr) * lda + k0 + sk], &buf[g * 2048 + wv * 512]);
#pragma unroll
  for (int g = 0; g < BN / 64; ++g)
    gload_lds16(&Bg[(size_t)(n0 + g * 64 + sr) * ldb + k0 + sk], &buf[BM * 32 + g * 2048 + wv * 512]);
}

template <int BM, int BN, int NSTORE, bool SPLITK, typename OutT>
__global__ __launch_bounds__(256) void gemm_bt(const __hip_bfloat16* __restrict__ A,
                                               const __hip_bfloat16* __restrict__ B,
                                               OutT* __restrict__ C,
                                               int K, int lda, int ldb, int ldc) {
  constexpr int WM = BM / 2, WN = BN / 2;
  constexpr int MI = WM / 16, NI = WN / 16;
  constexpr int BUFS = (BM + BN) * 32;
  __shared__ __align__(16) unsigned short lds[2 * BUFS];
  const int tid = threadIdx.x;
  const int wv = tid >> 6, lane = tid & 63;
  const int wr = wv >> 1, wc = wv & 1;
  const int m0 = blockIdx.y * BM;
  int n0, koff;
  if constexpr (SPLITK) {
    n0 = 0;
    koff = blockIdx.x * K;
    C += (size_t)blockIdx.x * BL * NSTORE;
  } else {
    n0 = blockIdx.x * BN;
    koff = 0;
  }
  const int sr = tid >> 2;
  const int sk = (tid & 3) * 8;
  const int frow = lane & 15;
  const int fk = (lane >> 4) * 8;

  f32x4 acc[MI][NI];
#pragma unroll
  for (int i = 0; i < MI; ++i)
#pragma unroll
    for (int j = 0; j < NI; ++j) acc[i][j] = {0.f, 0.f, 0.f, 0.f};

  const unsigned short* Ag = (const unsigned short*)A;
  const unsigned short* Bg = (const unsigned short*)B;

  stage_tiles<BM, BN>(Ag, Bg, &lds[0], m0, n0, koff, lda, ldb, sr, sk, wv);
  __syncthreads();
  int sel = 0;
  for (int k0 = 0; k0 < K; k0 += 32) {
    if (k0 + 32 < K)
      stage_tiles<BM, BN>(Ag, Bg, &lds[(sel ^ 1) * BUFS], m0, n0, koff + k0 + 32, lda, ldb, sr, sk, wv);
    const unsigned short* Abuf = &lds[sel * BUFS];
    const unsigned short* Bbuf = &lds[sel * BUFS + BM * 32];
    bf16x8 af[MI], bfr[NI];
#pragma unroll
    for (int mi = 0; mi < MI; ++mi)
      af[mi] = *reinterpret_cast<const bf16x8*>(&Abuf[(wr * WM + mi * 16 + frow) * 32 + fk]);
#pragma unroll
    for (int ni = 0; ni < NI; ++ni)
      bfr[ni] = *reinterpret_cast<const bf16x8*>(&Bbuf[(wc * WN + ni * 16 + frow) * 32 + fk]);
#pragma unroll
    for (int mi = 0; mi < MI; ++mi)
#pragma unroll
      for (int ni = 0; ni < NI; ++ni)
        acc[mi][ni] = __builtin_amdgcn_mfma_f32_16x16x32_bf16(af[mi], bfr[ni], acc[mi][ni], 0, 0, 0);
    __syncthreads();
    sel ^= 1;
  }

  const int crow = (lane >> 4) * 4;
  const int ccol = lane & 15;
#pragma unroll
  for (int mi = 0; mi < MI; ++mi)
#pragma unroll
    for (int ni = 0; ni < NI; ++ni) {
      const int gcol = n0 + wc * WN + ni * 16 + ccol;
      if constexpr (NSTORE < BN) {
        if (gcol >= NSTORE) continue;
      }
#pragma unroll
      for (int j = 0; j < 4; ++j) {
        const int grow = m0 + wr * WM + mi * 16 + crow + j;
        if constexpr (sizeof(OutT) == 2) {
          C[(size_t)grow * ldc + gcol] = __float2bfloat16(acc[mi][ni][j]);
        } else {
          C[(size_t)grow * ldc + gcol] = acc[mi][ni][j];
        }
      }
    }
}

// ---------------- x_proj reduce ----------------
__global__ __launch_bounds__(256) void xproj_reduce(const float* __restrict__ Cpart,
                                                    float* __restrict__ x_dbl) {
  const int i = blockIdx.x * 256 + threadIdx.x;    // < BL * XP_N
  float s = 0.f;
#pragma unroll
  for (int z = 0; z < XP_KS; ++z) s += Cpart[(size_t)z * BL * XP_N + i];
  x_dbl[i] = s;
}

// ---------------- depthwise causal conv1d (w=4) + bias + silu, 8 d's/thread ----------
__global__ __launch_bounds__(256) void conv_silu_kernel(const __hip_bfloat16* __restrict__ xz_bf,
                                                        const float* __restrict__ conv_w,
                                                        const float* __restrict__ conv_b,
                                                        __hip_bfloat16* __restrict__ x_act_bf) {
  const int idx = blockIdx.x * 256 + threadIdx.x;       // over BL * D_INNER / 8
  const int d8 = (idx << 3) & (D_INNER - 1);
  const int bl = idx >> 8;
  const int l = bl & (SEQ - 1);

  float acc[8];
  {
    float4 cb0 = *reinterpret_cast<const float4*>(&conv_b[d8]);
    float4 cb1 = *reinterpret_cast<const float4*>(&conv_b[d8 + 4]);
    acc[0] = cb0.x; acc[1] = cb0.y; acc[2] = cb0.z; acc[3] = cb0.w;
    acc[4] = cb1.x; acc[5] = cb1.y; acc[6] = cb1.z; acc[7] = cb1.w;
  }
  float4 cw[8];
#pragma unroll
  for (int j = 0; j < 8; ++j)
    cw[j] = *reinterpret_cast<const float4*>(&conv_w[(d8 + j) * 4]);

#pragma unroll
  for (int k = 0; k < 4; ++k) {
    if (l + k - 3 >= 0) {
      short8 v = *reinterpret_cast<const short8*>(&xz_bf[(size_t)(bl + k - 3) * 4096 + d8]);
      const float w0[8] = {cw[0].x, cw[1].x, cw[2].x, cw[3].x, cw[4].x, cw[5].x, cw[6].x, cw[7].x};
      const float w1[8] = {cw[0].y, cw[1].y, cw[2].y, cw[3].y, cw[4].y, cw[5].y, cw[6].y, cw[7].y};
      const float w2[8] = {cw[0].z, cw[1].z, cw[2].z, cw[3].z, cw[4].z, cw[5].z, cw[6].z, cw[7].z};
      const float w3[8] = {cw[0].w, cw[1].w, cw[2].w, cw[3].w, cw[4].w, cw[5].w, cw[6].w, cw[7].w};
      const float* wk = (k == 0) ? w0 : (k == 1) ? w1 : (k == 2) ? w2 : w3;
#pragma unroll
      for (int j = 0; j < 8; ++j) acc[j] = fmaf(bf2f((unsigned short)v[j]), wk[j], acc[j]);
    }
  }

  short8 ob;
#pragma unroll
  for (int j = 0; j < 8; ++j) ob[j] = f2bf_bits(siluf(acc[j]));
  *reinterpret_cast<short8*>(&x_act_bf[(size_t)bl * D_INNER + d8]) = ob;
}

// ---------------- scan pass 1: lane owns d; explicit pipeline (dv/uv depth-2) ----------
__global__ __launch_bounds__(256) void scan_pass1(const __hip_bfloat16* __restrict__ delta_bf,
                                                  const __hip_bfloat16* __restrict__ x_act_bf,
                                                  const float* __restrict__ x_dbl,
                                                  const float* __restrict__ A_log,
                                                  const float* __restrict__ dt_proj_b,
                                                  float* __restrict__ chunkS,
                                                  __hip_bfloat16* __restrict__ chunkH) {
  const int t = blockIdx.x * 256 + threadIdx.x;
  const int d = t & (D_INNER - 1);
  const int c = (t >> 11) & (NCHUNK - 1);
  const int b = t >> 18;
  const int base = b * SEQ + c * CHUNK;

  float Av[16];
#pragma unroll
  for (int q = 0; q < 4; ++q) {
    float4 a = *reinterpret_cast<const float4*>(&A_log[d * 16 + q * 4]);
    Av[q * 4 + 0] = -__expf(a.x) * LOG2E; Av[q * 4 + 1] = -__expf(a.y) * LOG2E;
    Av[q * 4 + 2] = -__expf(a.z) * LOG2E; Av[q * 4 + 3] = -__expf(a.w) * LOG2E;
  }
  const float bias = dt_proj_b[d];

  const unsigned short* dp = (const unsigned short*)delta_bf + (size_t)base * D_INNER + d;
  const unsigned short* up = (const unsigned short*)x_act_bf + (size_t)base * D_INNER + d;
  const float* xb = x_dbl + (size_t)base * 96 + DT_RANK;

  float h[16];
#pragma unroll
  for (int n = 0; n < 16; ++n) h[n] = 0.f;
  float S = 0.f;

  // prime: dv/uv at depth-2, B at depth-1
  float dv0 = bf2f(dp[0]), uv0 = bf2f(up[0]);
  float dv1 = bf2f(dp[D_INNER]), uv1 = bf2f(up[D_INNER]);
  dp += 2 * D_INNER; up += 2 * D_INNER;
  float4 b0 = *reinterpret_cast<const float4*>(xb);
  float4 b1 = *reinterpret_cast<const float4*>(xb + 4);
  float4 b2 = *reinterpret_cast<const float4*>(xb + 8);
  float4 b3 = *reinterpret_cast<const float4*>(xb + 12);
  for (int l = 0; l < CHUNK; ++l) {
    const float dv2 = bf2f(*dp), uv2 = bf2f(*up);   // l+2 (overread tail stays in ws)
    dp += D_INNER; up += D_INNER; xb += 96;
    const float4 nb0 = *reinterpret_cast<const float4*>(xb);
    const float4 nb1 = *reinterpret_cast<const float4*>(xb + 4);
    const float4 nb2 = *reinterpret_cast<const float4*>(xb + 8);
    const float4 nb3 = *reinterpret_cast<const float4*>(xb + 12);

    const float dv = softplusf(dv0 + bias);
    S += dv;
    const float du = dv * uv0;
    const float Bf[16] = {b0.x, b0.y, b0.z, b0.w, b1.x, b1.y, b1.z, b1.w,
                          b2.x, b2.y, b2.z, b2.w, b3.x, b3.y, b3.z, b3.w};
#pragma unroll
    for (int n = 0; n < 16; ++n) {
      const float dA = exp2fast(dv * Av[n]);
      h[n] = fmaf(dA, h[n], du * Bf[n]);
    }
    dv0 = dv1; uv0 = uv1; dv1 = dv2; uv1 = uv2;
    b0 = nb0; b1 = nb1; b2 = nb2; b3 = nb3;
  }

  const size_t sidx = (size_t)(b * NCHUNK + c) * D_INNER + d;
  chunkS[sidx] = S;
  unsigned short* hp = (unsigned short*)chunkH + sidx * 16;
  short8 h0v, h1v;
#pragma unroll
  for (int n = 0; n < 8; ++n) { h0v[n] = f2bf_bits(h[n]); h1v[n] = f2bf_bits(h[8 + n]); }
  *reinterpret_cast<short8*>(hp) = h0v;
  *reinterpret_cast<short8*>(hp + 8) = h1v;
}

// ---------------- scan pass 2: combine chunk prefixes; chunkH (bf16) becomes h0 --------
__global__ __launch_bounds__(256) void scan_pass2(const float* __restrict__ chunkS,
                                                  const float* __restrict__ A_log,
                                                  __hip_bfloat16* chunkH) {
  const int s = blockIdx.x * 256 + threadIdx.x;   // 65536 = (b, d, n)
  const int n = s & 15;
  const int d = (s >> 4) & (D_INNER - 1);
  const int b = s >> 15;
  const float Aval = -__expf(A_log[d * 16 + n]) * LOG2E;

  unsigned short* hb = (unsigned short*)chunkH;
  size_t sidx = (size_t)b * NCHUNK * D_INNER + d;
  float aS = chunkS[sidx];
  float hE = bf2f(hb[sidx * 16 + n]);
  float H = 0.f;
  for (int c = 0; c < NCHUNK; ++c) {
    const size_t sidx2 = sidx + D_INNER;
    const float naS = chunkS[sidx2];            // overread at c==NC-1: inside ws
    const float nhE = bf2f(hb[sidx2 * 16 + n]);
    const float aP = exp2fast(Aval * aS);
    hb[sidx * 16 + n] = f2bf_bits(H);           // h0 for this chunk
    H = fmaf(aP, H, hE);
    sidx = sidx2; aS = naS; hE = nhE;
  }
}

// ---------------- scan pass 3: explicit pipeline; z prefetched BEFORE y-store ----------
__global__ __launch_bounds__(256) void scan_pass3(const __hip_bfloat16* __restrict__ delta_bf,
                                                  const __hip_bfloat16* __restrict__ x_act_bf,
                                                  const float* __restrict__ x_dbl,
                                                  const float* __restrict__ A_log,
                                                  const float* __restrict__ dt_proj_b,
                                                  const __hip_bfloat16* __restrict__ chunkH0,
                                                  const float* __restrict__ D_skip,
                                                  __hip_bfloat16* xz_bf) {
  const int t = blockIdx.x * 256 + threadIdx.x;
  const int d = t & (D_INNER - 1);
  const int c = (t >> 11) & (NCHUNK - 1);
  const int b = t >> 18;
  const int base = b * SEQ + c * CHUNK;

  float Av[16];
#pragma unroll
  for (int q = 0; q < 4; ++q) {
    float4 a = *reinterpret_cast<const float4*>(&A_log[d * 16 + q * 4]);
    Av[q * 4 + 0] = -__expf(a.x) * LOG2E; Av[q * 4 + 1] = -__expf(a.y) * LOG2E;
    Av[q * 4 + 2] = -__expf(a.z) * LOG2E; Av[q * 4 + 3] = -__expf(a.w) * LOG2E;
  }
  const float bias = dt_proj_b[d];
  const float Dv = D_skip[d];

  const unsigned short* dp = (const unsigned short*)delta_bf + (size_t)base * D_INNER + d;
  const unsigned short* up = (const unsigned short*)x_act_bf + (size_t)base * D_INNER + d;
  const float* xb = x_dbl + (size_t)base * 96 + DT_RANK;      // B at [0..15], C at [16..31]
  const unsigned short* zr = (const unsigned short*)xz_bf + (size_t)base * 4096 + D_INNER + d;
  __hip_bfloat16* yp = xz_bf + (size_t)base * 4096 + d;

  float h[16];
  {
    const unsigned short* hp = (const unsigned short*)chunkH0 +
                               ((size_t)(b * NCHUNK + c) * D_INNER + d) * 16;
    short8 a8 = *reinterpret_cast<const short8*>(hp);
    short8 b8 = *reinterpret_cast<const short8*>(hp + 8);
#pragma unroll
    for (int n = 0; n < 8; ++n) {
      h[n] = bf2f((unsigned short)a8[n]);
      h[8 + n] = bf2f((unsigned short)b8[n]);
    }
  }

  // prime: dv/uv depth-2, B/C depth-1, z depth-1
  float dv0 = bf2f(dp[0]), uv0 = bf2f(up[0]);
  float dv1 = bf2f(dp[D_INNER]), uv1 = bf2f(up[D_INNER]);
  dp += 2 * D_INNER; up += 2 * D_INNER;
  float4 b0 = *reinterpret_cast<const float4*>(xb);
  float4 b1 = *reinterpret_cast<const float4*>(xb + 4);
  float4 b2 = *reinterpret_cast<const float4*>(xb + 8);
  float4 b3 = *reinterpret_cast<const float4*>(xb + 12);
  float4 c0 = *reinterpret_cast<const float4*>(xb + 16);
  float4 c1 = *reinterpret_cast<const float4*>(xb + 20);
  float4 c2 = *reinterpret_cast<const float4*>(xb + 24);
  float4 c3 = *reinterpret_cast<const float4*>(xb + 28);
  float zv = bf2f(zr[0]);
  zr += 4096;
  for (int l = 0; l < CHUNK; ++l) {
    const float dv2 = bf2f(*dp), uv2 = bf2f(*up);   // l+2
    dp += D_INNER; up += D_INNER; xb += 96;
    const float4 nb0 = *reinterpret_cast<const float4*>(xb);
    const float4 nb1 = *reinterpret_cast<const float4*>(xb + 4);
    const float4 nb2 = *reinterpret_cast<const float4*>(xb + 8);
    const float4 nb3 = *reinterpret_cast<const float4*>(xb + 12);
    const float4 nc0 = *reinterpret_cast<const float4*>(xb + 16);
    const float4 nc1 = *reinterpret_cast<const float4*>(xb + 20);
    const float4 nc2 = *reinterpret_cast<const float4*>(xb + 24);
    const float4 nc3 = *reinterpret_cast<const float4*>(xb + 28);
    const float nzv = bf2f(*zr);                    // z(l+1), issued BEFORE y(l) store
    zr += 4096;

    const float dv = softplusf(dv0 + bias);
    const float du = dv * uv0;
    const float Bf[16] = {b0.x, b0.y, b0.z, b0.w, b1.x, b1.y, b1.z, b1.w,
                          b2.x, b2.y, b2.z, b2.w, b3.x, b3.y, b3.z, b3.w};
    const float Cf[16] = {c0.x, c0.y, c0.z, c0.w, c1.x, c1.y, c1.z, c1.w,
                          c2.x, c2.y, c2.z, c2.w, c3.x, c3.y, c3.z, c3.w};
    float p = 0.f;
#pragma unroll
    for (int n = 0; n < 16; ++n) {
      const float dA = exp2fast(dv * Av[n]);
      h[n] = fmaf(dA, h[n], du * Bf[n]);
      p = fmaf(h[n], Cf[n], p);
    }
    const float yv = fmaf(uv0, Dv, p) * siluf(zv);
    yp[0] = __float2bfloat16(yv);
    yp += 4096;

    dv0 = dv1; uv0 = uv1; dv1 = dv2; uv1 = uv2; zv = nzv;
    b0 = nb0; b1 = nb1; b2 = nb2; b3 = nb3;
    c0 = nc0; c1 = nc1; c2 = nc2; c3 = nc3;
  }
}

extern "C" void kernel_launch(void* const* d_in, const int* in_sizes, int n_in,
                              void* d_out, int out_size, void* d_ws, size_t ws_size,
                              hipStream_t stream) {
  const float* x          = (const float*)d_in[0];
  const float* in_proj_w  = (const float*)d_in[1];
  const float* conv_w     = (const float*)d_in[2];
  const float* conv_b     = (const float*)d_in[3];
  const float* x_proj_w   = (const float*)d_in[4];
  const float* dt_proj_w  = (const float*)d_in[5];
  const float* dt_proj_b  = (const float*)d_in[6];
  const float* A_log      = (const float*)d_in[7];
  const float* D_skip     = (const float*)d_in[8];
  const float* out_proj_w = (const float*)d_in[9];
  float* out = (float*)d_out;   // fp32 output

  // Workspace layout (peak ~137 MiB; ws evidence >= 169 MB from r1/r2):
  //   xz_bf     @0          33,554,432  bf16 [4096][4096]
  //   x_act_bf  @33554432   16,777,216  bf16 [4096][2048]
  //   delta_bf  @50331648   16,777,216  bf16 [4096][2048]
  //   x_bf      @67108864    8,388,608  (pre-in_proj; region reused by Cpart after conv)
  //   inw_bf    @75497472    8,388,608
  //   Cpart     @67108864   12,582,912  (post-conv)
  //   x_dbl     @100663296   1,572,864
  //   chunkH    @102236160  16,777,216  bf16 [B*NC*D][16]
  //   chunkS    @135790592   2,097,152
  //   wpad      @137887744     524,288
  //   dtlow_bf  @138412032     524,288
  //   dtw_bf    @138936320     262,144
  //   outw_bf   @139198464   4,194,304
  char* ws = (char*)d_ws;
  __hip_bfloat16* xz_bf    = (__hip_bfloat16*)(ws);
  __hip_bfloat16* x_act_bf = (__hip_bfloat16*)(ws + 33554432);
  __hip_bfloat16* delta_bf = (__hip_bfloat16*)(ws + 50331648);
  __hip_bfloat16* x_bf     = (__hip_bfloat16*)(ws + 67108864);
  __hip_bfloat16* inw_bf   = (__hip_bfloat16*)(ws + 75497472);
  float* Cpart             = (float*)(ws + 67108864);
  float* x_dbl             = (float*)(ws + 100663296);
  __hip_bfloat16* chunkH   = (__hip_bfloat16*)(ws + 102236160);
  float* chunkS            = (float*)(ws + 135790592);
  __hip_bfloat16* wpad     = (__hip_bfloat16*)(ws + 137887744);
  __hip_bfloat16* dtlow_bf = (__hip_bfloat16*)(ws + 138412032);
  __hip_bfloat16* dtw_bf   = (__hip_bfloat16*)(ws + 138936320);
  __hip_bfloat16* outw_bf  = (__hip_bfloat16*)(ws + 139198464);

  // 1. all input conversions in one launch
  f2bf_multi<<<5280, 256, 0, stream>>>(x, x_bf, in_proj_w, inw_bf, x_proj_w, wpad,
                                       dt_proj_w, dtw_bf, out_proj_w, outw_bf);

  // 2. xz = x @ in_proj_w^T  (M=4096, N=4096, K=1024), bf16 out, 8-phase 256^2 pipeline
  gemm256_8ph<__hip_bfloat16><<<dim3(16, 16), 512, 0, stream>>>(
      x_bf, inw_bf, xz_bf, 1024, 1024, 1024, 4096);

  // 3. depthwise causal conv + bias + silu -> x_act_bf
  conv_silu_kernel<<<(BL * D_INNER) / 8 / 256, 256, 0, stream>>>(
      xz_bf, conv_w, conv_b, x_act_bf);

  // 4. x_dbl = x_act @ x_proj_w^T via bf16 MFMA split-K (padded 96->128 weight) + reduce
  gemm_bt<128, 128, XP_N, true, float><<<dim3(XP_KS, 32), 256, 0, stream>>>(
      x_act_bf, wpad, Cpart, 2048 / XP_KS, 2048, 2048, XP_N);
  xproj_reduce<<<(BL * XP_N) / 256, 256, 0, stream>>>(Cpart, x_dbl);

  // 5. delta_raw = dt_low @ dt_proj_w^T  (4096 x 2048, K=64) via bf16 MFMA, bf16 out
  dtlow_bf_kernel<<<128, 256, 0, stream>>>(x_dbl, dtlow_bf);
  gemm_bt<128, 128, 128, false, __hip_bfloat16><<<dim3(16, 32), 256, 0, stream>>>(
      dtlow_bf, dtw_bf, delta_bf, 64, 64, 64, 2048);

  // 6-8. chunked selective scan, lane-owns-d, NCHUNK=128, explicit pipelines
  scan_pass1<<<2048, 256, 0, stream>>>(delta_bf, x_act_bf, x_dbl, A_log, dt_proj_b,
                                       chunkS, chunkH);
  scan_pass2<<<256, 256, 0, stream>>>(chunkS, A_log, chunkH);
  scan_pass3<<<2048, 256, 0, stream>>>(delta_bf, x_act_bf, x_dbl, A_log, dt_proj_b,
                                       chunkH, D_skip, xz_bf);

  // 9. out = y @ out_proj_w^T  (M=4096, N=1024, K=2048), fp32 out, 128x64 tile
  gemm_bt<128, 64, 64, false, float><<<dim3(16, 32), 256, 0, stream>>>(
      xz_bf, outw_bf, out, 2048, 4096, 2048, 1024);
}

// Round 17
// 212.231 us; speedup vs baseline: 7.7913x; 1.0680x over previous
//
#include <hip/hip_runtime.h>
#include <hip/hip_bf16.h>
#include <cstdint>

#define D_STATE 16
#define D_INNER 2048
#define DT_RANK 64
#define SEQ 2048
#define BL 4096      // B * L
#define NCHUNK 128
#define CHUNK 16     // SEQ / NCHUNK
#define XP_N 96      // dt_rank + 2*d_state
#define XP_KS 8      // x_proj K-splits
#define LOG2E 1.44269504088896340736f

typedef short bf16x8 __attribute__((ext_vector_type(8)));
typedef short short8 __attribute__((ext_vector_type(8)));
typedef float f32x4 __attribute__((ext_vector_type(4)));

__device__ __forceinline__ float siluf(float x) {
  return __fdividef(x, 1.f + __expf(-x));
}

__device__ __forceinline__ float softplusf(float v) {
  return fmaxf(v, 0.f) + __logf(1.f + __expf(-fabsf(v)));
}

__device__ __forceinline__ float exp2fast(float x) {
  return __builtin_amdgcn_exp2f(x);
}

__device__ __forceinline__ unsigned short f2bf_bits(float x) {
  __hip_bfloat16 h = __float2bfloat16(x);
  return *reinterpret_cast<unsigned short*>(&h);
}

__device__ __forceinline__ float bf2f(unsigned short u) {
  return __int_as_float(((unsigned int)u) << 16);
}

__device__ __forceinline__ void gload_lds16(const void* g, void* l) {
  __builtin_amdgcn_global_load_lds((const __attribute__((address_space(1))) unsigned int*)g,
                                   (__attribute__((address_space(3))) unsigned int*)l,
                                   16, 0, 0);
}

#define BARRIER() asm volatile("s_barrier" ::: "memory")
#define VMCNT(n)  asm volatile("s_waitcnt vmcnt(" #n ")" ::: "memory")

// ---------------- fused fp32 -> bf16 conversions of all inputs (one launch) ----------
__global__ __launch_bounds__(256) void f2bf_multi(const float* __restrict__ x, __hip_bfloat16* __restrict__ x_bf,
                                                  const float* __restrict__ inw, __hip_bfloat16* __restrict__ inw_bf,
                                                  const float* __restrict__ xpw, __hip_bfloat16* __restrict__ wpad,
                                                  const float* __restrict__ dtw, __hip_bfloat16* __restrict__ dtw_bf,
                                                  const float* __restrict__ outw, __hip_bfloat16* __restrict__ outw_bf) {
  const int blk = blockIdx.x;
  const float* src;
  __hip_bfloat16* dst;
  int base;
  if (blk < 2048)      { src = x;    dst = x_bf;    base = blk; }
  else if (blk < 4096) { src = inw;  dst = inw_bf;  base = blk - 2048; }
  else if (blk < 4192) { src = xpw;  dst = wpad;    base = blk - 4096; }
  else if (blk < 4256) { src = dtw;  dst = dtw_bf;  base = blk - 4192; }
  else                 { src = outw; dst = outw_bf; base = blk - 4256; }
  const int i = (base * 256 + threadIdx.x) * 8;
  float4 v0 = *reinterpret_cast<const float4*>(&src[i]);
  float4 v1 = *reinterpret_cast<const float4*>(&src[i + 4]);
  short8 r;
  r[0] = f2bf_bits(v0.x); r[1] = f2bf_bits(v0.y); r[2] = f2bf_bits(v0.z); r[3] = f2bf_bits(v0.w);
  r[4] = f2bf_bits(v1.x); r[5] = f2bf_bits(v1.y); r[6] = f2bf_bits(v1.z); r[7] = f2bf_bits(v1.w);
  *reinterpret_cast<short8*>(&dst[i]) = r;
}

// ---------------- dt_low extract + bf16: x_dbl[:, 0:64] (stride 96) -> [4096][64] bf16 --
__global__ __launch_bounds__(256) void dtlow_bf_kernel(const float* __restrict__ x_dbl,
                                                       __hip_bfloat16* __restrict__ dtlow_bf) {
  const int i = blockIdx.x * 256 + threadIdx.x;   // 32768 threads
  const int row = i >> 3;
  const int c8 = (i & 7) * 8;
  float4 v0 = *reinterpret_cast<const float4*>(&x_dbl[(size_t)row * 96 + c8]);
  float4 v1 = *reinterpret_cast<const float4*>(&x_dbl[(size_t)row * 96 + c8 + 4]);
  short8 r;
  r[0] = f2bf_bits(v0.x); r[1] = f2bf_bits(v0.y); r[2] = f2bf_bits(v0.z); r[3] = f2bf_bits(v0.w);
  r[4] = f2bf_bits(v1.x); r[5] = f2bf_bits(v1.y); r[6] = f2bf_bits(v1.z); r[7] = f2bf_bits(v1.w);
  *reinterpret_cast<short8*>(&dtlow_bf[(size_t)row * 64 + c8]) = r;
}

// ============ 8-phase 256x256 bf16 GEMM (T2+T3+T4+T5): C = A[M,K] @ B[N,K]^T ============
template <typename OutT>
__global__ __launch_bounds__(512, 1) void gemm256_8ph(const __hip_bfloat16* __restrict__ A,
                                                      const __hip_bfloat16* __restrict__ B,
                                                      OutT* __restrict__ C,
                                                      int K, int lda, int ldb, int ldc) {
  __shared__ __align__(16) unsigned short lds[65536];  // [2 buf][A 16384 | B 16384] shorts
  const int tid = threadIdx.x;
  const int wv = tid >> 6, lane = tid & 63;
  const int wr = wv >> 2, wc = wv & 3;              // wave grid 2(M) x 4(N)
  const int m0 = blockIdx.y * 256, n0 = blockIdx.x * 256;
  const int frow = lane & 15;
  const int fu = lane >> 4;
  const int rsw = frow & 7;
  const int sr = lane >> 3;
  const int su = (lane & 7) ^ sr;

  const unsigned short* Ag = (const unsigned short*)A;
  const unsigned short* Bg = (const unsigned short*)B;

  f32x4 acc[8][4];
#pragma unroll
  for (int i = 0; i < 8; ++i)
#pragma unroll
    for (int j = 0; j < 4; ++j) acc[i][j] = {0.f, 0.f, 0.f, 0.f};

  auto stageA = [&](int buf, int g, int kg) {
    const int rowb = g * 64 + wv * 8;
    gload_lds16(&Ag[(size_t)(m0 + rowb + sr) * lda + kg + su * 8],
                &lds[buf * 32768 + rowb * 64]);
  };
  auto stageB = [&](int buf, int g, int kg) {
    const int rowb = g * 64 + wv * 8;
    gload_lds16(&Bg[(size_t)(n0 + rowb + sr) * ldb + kg + su * 8],
                &lds[buf * 32768 + 16384 + rowb * 64]);
  };
  auto fragA = [&](int buf, int mi, int kk) -> bf16x8 {
    const int row = wr * 128 + mi * 16 + frow;
    return *reinterpret_cast<const bf16x8*>(
        &lds[buf * 32768 + row * 64 + (((kk << 2) | fu) ^ rsw) * 8]);
  };
  auto fragB = [&](int buf, int ni, int kk) -> bf16x8 {
    const int row = wc * 64 + ni * 16 + frow;
    return *reinterpret_cast<const bf16x8*>(
        &lds[buf * 32768 + 16384 + row * 64 + (((kk << 2) | fu) ^ rsw) * 8]);
  };

#define QUAD(MB)                                                                        \
  _Pragma("unroll")                                                                     \
  for (int mi = 0; mi < 4; ++mi)                                                        \
    _Pragma("unroll")                                                                   \
    for (int ni = 0; ni < 4; ++ni)                                                      \
      acc[MB + mi][ni] =                                                                \
          __builtin_amdgcn_mfma_f32_16x16x32_bf16(af[mi], bfr[ni], acc[MB + mi][ni], 0, 0, 0);

  stageB(0, 0, 0); stageB(0, 1, 0); stageB(0, 2, 0); stageB(0, 3, 0);
  stageA(0, 0, 0); stageA(0, 2, 0); stageA(0, 1, 0); stageA(0, 3, 0);
  VMCNT(2);
  BARRIER();

  const int NT = K >> 6;
  int cur = 0;
  for (int t = 0; t < NT - 1; ++t) {
    const int nxt = cur ^ 1;
    const int kn = (t + 1) << 6;
    bf16x8 af[4], bfr[4];
    // ---- phase 0
#pragma unroll
    for (int mi = 0; mi < 4; ++mi) af[mi] = fragA(cur, mi, 0);
#pragma unroll
    for (int ni = 0; ni < 4; ++ni) bfr[ni] = fragB(cur, ni, 0);
    stageB(nxt, 0, kn); stageB(nxt, 1, kn);
    VMCNT(2);
    BARRIER();
    __builtin_amdgcn_s_setprio(1);
    QUAD(0);
    __builtin_amdgcn_s_setprio(0);
    BARRIER();
    // ---- phase 1
#pragma unroll
    for (int mi = 0; mi < 4; ++mi) af[mi] = fragA(cur, 4 + mi, 0);
    stageB(nxt, 2, kn); stageB(nxt, 3, kn);
    BARRIER();
    __builtin_amdgcn_s_setprio(1);
    QUAD(4);
    __builtin_amdgcn_s_setprio(0);
    BARRIER();
    // ---- phase 2
#pragma unroll
    for (int mi = 0; mi < 4; ++mi) af[mi] = fragA(cur, mi, 1);
#pragma unroll
    for (int ni = 0; ni < 4; ++ni) bfr[ni] = fragB(cur, ni, 1);
    stageA(nxt, 0, kn); stageA(nxt, 2, kn);
    BARRIER();
    __builtin_amdgcn_s_setprio(1);
    QUAD(0);
    __builtin_amdgcn_s_setprio(0);
    BARRIER();
    // ---- phase 3
#pragma unroll
    for (int mi = 0; mi < 4; ++mi) af[mi] = fragA(cur, 4 + mi, 1);
    stageA(nxt, 1, kn); stageA(nxt, 3, kn);
    VMCNT(2);
    BARRIER();
    __builtin_amdgcn_s_setprio(1);
    QUAD(4);
    __builtin_amdgcn_s_setprio(0);
    BARRIER();
    cur = nxt;
  }
  // ---- last tile
  {
    bf16x8 af[4], bfr[4];
#pragma unroll
    for (int mi = 0; mi < 4; ++mi) af[mi] = fragA(cur, mi, 0);
#pragma unroll
    for (int ni = 0; ni < 4; ++ni) bfr[ni] = fragB(cur, ni, 0);
    VMCNT(0);
    BARRIER();
    __builtin_amdgcn_s_setprio(1);
    QUAD(0);
    __builtin_amdgcn_s_setprio(0);
    BARRIER();
#pragma unroll
    for (int mi = 0; mi < 4; ++mi) af[mi] = fragA(cur, 4 + mi, 0);
    BARRIER();
    __builtin_amdgcn_s_setprio(1);
    QUAD(4);
    __builtin_amdgcn_s_setprio(0);
    BARRIER();
#pragma unroll
    for (int mi = 0; mi < 4; ++mi) af[mi] = fragA(cur, mi, 1);
#pragma unroll
    for (int ni = 0; ni < 4; ++ni) bfr[ni] = fragB(cur, ni, 1);
    BARRIER();
    __builtin_amdgcn_s_setprio(1);
    QUAD(0);
    __builtin_amdgcn_s_setprio(0);
    BARRIER();
#pragma unroll
    for (int mi = 0; mi < 4; ++mi) af[mi] = fragA(cur, 4 + mi, 1);
    __builtin_amdgcn_s_setprio(1);
    QUAD(4);
    __builtin_amdgcn_s_setprio(0);
  }
#undef QUAD

  const int crow = fu * 4;
  const int ccol = frow;
#pragma unroll
  for (int mi = 0; mi < 8; ++mi)
#pragma unroll
    for (int ni = 0; ni < 4; ++ni) {
      const int gcol = n0 + wc * 64 + ni * 16 + ccol;
#pragma unroll
      for (int j = 0; j < 4; ++j) {
        const int grow = m0 + wr * 128 + mi * 16 + crow + j;
        if constexpr (sizeof(OutT) == 2) {
          C[(size_t)grow * ldc + gcol] = __float2bfloat16(acc[mi][ni][j]);
        } else {
          C[(size_t)grow * ldc + gcol] = acc[mi][ni][j];
        }
      }
    }
}

// ---------------- MFMA bf16 GEMM: C = A[M,K] * B[N,K]^T, double-buffered LDS ----------
template <int BM, int BN>
__device__ __forceinline__ void stage_tiles(const unsigned short* __restrict__ Ag,
                                            const unsigned short* __restrict__ Bg,
                                            unsigned short* buf, int m0, int n0, int k0,
                                            int lda, int ldb, int sr, int sk, int wv) {
#pragma unroll
  for (int g = 0; g < BM / 64; ++g)
    gload_lds16(&Ag[(size_t)(m0 + g * 64 + sr) * lda + k0 + sk], &buf[g * 2048 + wv * 512]);
#pragma unroll
  for (int g = 0; g < BN / 64; ++g)
    gload_lds16(&Bg[(size_t)(n0 + g * 64 + sr) * ldb + k0 + sk], &buf[BM * 32 + g * 2048 + wv * 512]);
}

template <int BM, int BN, int NSTORE, bool SPLITK, typename OutT>
__global__ __launch_bounds__(256) void gemm_bt(const __hip_bfloat16* __restrict__ A,
                                               const __hip_bfloat16* __restrict__ B,
                                               OutT* __restrict__ C,
                                               int K, int lda, int ldb, int ldc) {
  constexpr int WM = BM / 2, WN = BN / 2;
  constexpr int MI = WM / 16, NI = WN / 16;
  constexpr int BUFS = (BM + BN) * 32;
  __shared__ __align__(16) unsigned short lds[2 * BUFS];
  const int tid = threadIdx.x;
  const int wv = tid >> 6, lane = tid & 63;
  const int wr = wv >> 1, wc = wv & 1;
  const int m0 = blockIdx.y * BM;
  int n0, koff;
  if constexpr (SPLITK) {
    n0 = 0;
    koff = blockIdx.x * K;
    C += (size_t)blockIdx.x * BL * NSTORE;
  } else {
    n0 = blockIdx.x * BN;
    koff = 0;
  }
  const int sr = tid >> 2;
  const int sk = (tid & 3) * 8;
  const int frow = lane & 15;
  const int fk = (lane >> 4) * 8;

  f32x4 acc[MI][NI];
#pragma unroll
  for (int i = 0; i < MI; ++i)
#pragma unroll
    for (int j = 0; j < NI; ++j) acc[i][j] = {0.f, 0.f, 0.f, 0.f};

  const unsigned short* Ag = (const unsigned short*)A;
  const unsigned short* Bg = (const unsigned short*)B;

  stage_tiles<BM, BN>(Ag, Bg, &lds[0], m0, n0, koff, lda, ldb, sr, sk, wv);
  __syncthreads();
  int sel = 0;
  for (int k0 = 0; k0 < K; k0 += 32) {
    if (k0 + 32 < K)
      stage_tiles<BM, BN>(Ag, Bg, &lds[(sel ^ 1) * BUFS], m0, n0, koff + k0 + 32, lda, ldb, sr, sk, wv);
    const unsigned short* Abuf = &lds[sel * BUFS];
    const unsigned short* Bbuf = &lds[sel * BUFS + BM * 32];
    bf16x8 af[MI], bfr[NI];
#pragma unroll
    for (int mi = 0; mi < MI; ++mi)
      af[mi] = *reinterpret_cast<const bf16x8*>(&Abuf[(wr * WM + mi * 16 + frow) * 32 + fk]);
#pragma unroll
    for (int ni = 0; ni < NI; ++ni)
      bfr[ni] = *reinterpret_cast<const bf16x8*>(&Bbuf[(wc * WN + ni * 16 + frow) * 32 + fk]);
#pragma unroll
    for (int mi = 0; mi < MI; ++mi)
#pragma unroll
      for (int ni = 0; ni < NI; ++ni)
        acc[mi][ni] = __builtin_amdgcn_mfma_f32_16x16x32_bf16(af[mi], bfr[ni], acc[mi][ni], 0, 0, 0);
    __syncthreads();
    sel ^= 1;
  }

  const int crow = (lane >> 4) * 4;
  const int ccol = lane & 15;
#pragma unroll
  for (int mi = 0; mi < MI; ++mi)
#pragma unroll
    for (int ni = 0; ni < NI; ++ni) {
      const int gcol = n0 + wc * WN + ni * 16 + ccol;
      if constexpr (NSTORE < BN) {
        if (gcol >= NSTORE) continue;
      }
#pragma unroll
      for (int j = 0; j < 4; ++j) {
        const int grow = m0 + wr * WM + mi * 16 + crow + j;
        if constexpr (sizeof(OutT) == 2) {
          C[(size_t)grow * ldc + gcol] = __float2bfloat16(acc[mi][ni][j]);
        } else {
          C[(size_t)grow * ldc + gcol] = acc[mi][ni][j];
        }
      }
    }
}

// ---------------- x_proj reduce ----------------
__global__ __launch_bounds__(256) void xproj_reduce(const float* __restrict__ Cpart,
                                                    float* __restrict__ x_dbl) {
  const int i = blockIdx.x * 256 + threadIdx.x;    // < BL * XP_N
  float s = 0.f;
#pragma unroll
  for (int z = 0; z < XP_KS; ++z) s += Cpart[(size_t)z * BL * XP_N + i];
  x_dbl[i] = s;
}

// ---------------- depthwise causal conv1d (w=4) + bias + silu, 8 d's/thread ----------
__global__ __launch_bounds__(256) void conv_silu_kernel(const __hip_bfloat16* __restrict__ xz_bf,
                                                        const float* __restrict__ conv_w,
                                                        const float* __restrict__ conv_b,
                                                        __hip_bfloat16* __restrict__ x_act_bf) {
  const int idx = blockIdx.x * 256 + threadIdx.x;       // over BL * D_INNER / 8
  const int d8 = (idx << 3) & (D_INNER - 1);
  const int bl = idx >> 8;
  const int l = bl & (SEQ - 1);

  float acc[8];
  {
    float4 cb0 = *reinterpret_cast<const float4*>(&conv_b[d8]);
    float4 cb1 = *reinterpret_cast<const float4*>(&conv_b[d8 + 4]);
    acc[0] = cb0.x; acc[1] = cb0.y; acc[2] = cb0.z; acc[3] = cb0.w;
    acc[4] = cb1.x; acc[5] = cb1.y; acc[6] = cb1.z; acc[7] = cb1.w;
  }
  float4 cw[8];
#pragma unroll
  for (int j = 0; j < 8; ++j)
    cw[j] = *reinterpret_cast<const float4*>(&conv_w[(d8 + j) * 4]);

#pragma unroll
  for (int k = 0; k < 4; ++k) {
    if (l + k - 3 >= 0) {
      short8 v = *reinterpret_cast<const short8*>(&xz_bf[(size_t)(bl + k - 3) * 4096 + d8]);
      const float w0[8] = {cw[0].x, cw[1].x, cw[2].x, cw[3].x, cw[4].x, cw[5].x, cw[6].x, cw[7].x};
      const float w1[8] = {cw[0].y, cw[1].y, cw[2].y, cw[3].y, cw[4].y, cw[5].y, cw[6].y, cw[7].y};
      const float w2[8] = {cw[0].z, cw[1].z, cw[2].z, cw[3].z, cw[4].z, cw[5].z, cw[6].z, cw[7].z};
      const float w3[8] = {cw[0].w, cw[1].w, cw[2].w, cw[3].w, cw[4].w, cw[5].w, cw[6].w, cw[7].w};
      const float* wk = (k == 0) ? w0 : (k == 1) ? w1 : (k == 2) ? w2 : w3;
#pragma unroll
      for (int j = 0; j < 8; ++j) acc[j] = fmaf(bf2f((unsigned short)v[j]), wk[j], acc[j]);
    }
  }

  short8 ob;
#pragma unroll
  for (int j = 0; j < 8; ++j) ob[j] = f2bf_bits(siluf(acc[j]));
  *reinterpret_cast<short8*>(&x_act_bf[(size_t)bl * D_INNER + d8]) = ob;
}

// ---------------- scan pass 1: block-uniform (b,c); B loads scalarize to SGPR ----------
// blk bits: [0:3) d-group, [3:10) c, [10] b. All 256 threads share (b,c) -> xb uniform.
__global__ __launch_bounds__(256) void scan_pass1(const __hip_bfloat16* __restrict__ delta_bf,
                                                  const __hip_bfloat16* __restrict__ x_act_bf,
                                                  const float* __restrict__ x_dbl,
                                                  const float* __restrict__ A_log,
                                                  const float* __restrict__ dt_proj_b,
                                                  float* __restrict__ chunkS,
                                                  __hip_bfloat16* __restrict__ chunkH) {
  const int blk = blockIdx.x;
  const int d = ((blk & 7) << 8) + threadIdx.x;
  const int c = (blk >> 3) & (NCHUNK - 1);
  const int b = blk >> 10;
  const int base = b * SEQ + c * CHUNK;      // block-uniform

  float Av[16];
#pragma unroll
  for (int q = 0; q < 4; ++q) {
    float4 a = *reinterpret_cast<const float4*>(&A_log[d * 16 + q * 4]);
    Av[q * 4 + 0] = -__expf(a.x) * LOG2E; Av[q * 4 + 1] = -__expf(a.y) * LOG2E;
    Av[q * 4 + 2] = -__expf(a.z) * LOG2E; Av[q * 4 + 3] = -__expf(a.w) * LOG2E;
  }
  const float bias = dt_proj_b[d];

  const unsigned short* dp = (const unsigned short*)delta_bf + (size_t)base * D_INNER + d;
  const unsigned short* up = (const unsigned short*)x_act_bf + (size_t)base * D_INNER + d;
  const float* xb = x_dbl + (size_t)base * 96 + DT_RANK;   // uniform address

  float h[16];
#pragma unroll
  for (int n = 0; n < 16; ++n) h[n] = 0.f;
  float S = 0.f;

  float dv0 = bf2f(dp[0]), uv0 = bf2f(up[0]);
  float dv1 = bf2f(dp[D_INNER]), uv1 = bf2f(up[D_INNER]);
  dp += 2 * D_INNER; up += 2 * D_INNER;
  for (int l = 0; l < CHUNK; ++l) {
    const float dv2 = bf2f(*dp), uv2 = bf2f(*up);   // l+2 (overread tail stays in ws)
    dp += D_INNER; up += D_INNER;

    const float dv = softplusf(dv0 + bias);
    S += dv;
    const float du = dv * uv0;
#pragma unroll
    for (int n = 0; n < 16; ++n) {
      const float dA = exp2fast(dv * Av[n]);
      h[n] = fmaf(dA, h[n], du * xb[n]);            // xb[n] uniform -> SGPR operand
    }
    xb += 96;
    dv0 = dv1; uv0 = uv1; dv1 = dv2; uv1 = uv2;
  }

  const size_t sidx = (size_t)(b * NCHUNK + c) * D_INNER + d;
  chunkS[sidx] = S;
  unsigned short* hp = (unsigned short*)chunkH + sidx * 16;
  short8 h0v, h1v;
#pragma unroll
  for (int n = 0; n < 8; ++n) { h0v[n] = f2bf_bits(h[n]); h1v[n] = f2bf_bits(h[8 + n]); }
  *reinterpret_cast<short8*>(hp) = h0v;
  *reinterpret_cast<short8*>(hp + 8) = h1v;
}

// ---------------- scan pass 2: combine chunk prefixes; chunkH (bf16) becomes h0 --------
__global__ __launch_bounds__(256) void scan_pass2(const float* __restrict__ chunkS,
                                                  const float* __restrict__ A_log,
                                                  __hip_bfloat16* chunkH) {
  const int s = blockIdx.x * 256 + threadIdx.x;   // 65536 = (b, d, n)
  const int n = s & 15;
  const int d = (s >> 4) & (D_INNER - 1);
  const int b = s >> 15;
  const float Aval = -__expf(A_log[d * 16 + n]) * LOG2E;

  unsigned short* hb = (unsigned short*)chunkH;
  size_t sidx = (size_t)b * NCHUNK * D_INNER + d;
  float aS = chunkS[sidx];
  float hE = bf2f(hb[sidx * 16 + n]);
  float H = 0.f;
  for (int c = 0; c < NCHUNK; ++c) {
    const size_t sidx2 = sidx + D_INNER;
    const float naS = chunkS[sidx2];            // overread at c==NC-1: inside ws
    const float nhE = bf2f(hb[sidx2 * 16 + n]);
    const float aP = exp2fast(Aval * aS);
    hb[sidx * 16 + n] = f2bf_bits(H);           // h0 for this chunk
    H = fmaf(aP, H, hE);
    sidx = sidx2; aS = naS; hE = nhE;
  }
}

// ---------------- scan pass 3: block-uniform (b,c); B/C scalarized; z before y-store ---
__global__ __launch_bounds__(256) void scan_pass3(const __hip_bfloat16* __restrict__ delta_bf,
                                                  const __hip_bfloat16* __restrict__ x_act_bf,
                                                  const float* __restrict__ x_dbl,
                                                  const float* __restrict__ A_log,
                                                  const float* __restrict__ dt_proj_b,
                                                  const __hip_bfloat16* __restrict__ chunkH0,
                                                  const float* __restrict__ D_skip,
                                                  __hip_bfloat16* xz_bf) {
  const int blk = blockIdx.x;
  const int d = ((blk & 7) << 8) + threadIdx.x;
  const int c = (blk >> 3) & (NCHUNK - 1);
  const int b = blk >> 10;
  const int base = b * SEQ + c * CHUNK;      // block-uniform

  float Av[16];
#pragma unroll
  for (int q = 0; q < 4; ++q) {
    float4 a = *reinterpret_cast<const float4*>(&A_log[d * 16 + q * 4]);
    Av[q * 4 + 0] = -__expf(a.x) * LOG2E; Av[q * 4 + 1] = -__expf(a.y) * LOG2E;
    Av[q * 4 + 2] = -__expf(a.z) * LOG2E; Av[q * 4 + 3] = -__expf(a.w) * LOG2E;
  }
  const float bias = dt_proj_b[d];
  const float Dv = D_skip[d];

  const unsigned short* dp = (const unsigned short*)delta_bf + (size_t)base * D_INNER + d;
  const unsigned short* up = (const unsigned short*)x_act_bf + (size_t)base * D_INNER + d;
  const float* xb = x_dbl + (size_t)base * 96 + DT_RANK;      // uniform; B [0..15], C [16..31]
  const unsigned short* zr = (const unsigned short*)xz_bf + (size_t)base * 4096 + D_INNER + d;
  __hip_bfloat16* yp = xz_bf + (size_t)base * 4096 + d;

  float h[16];
  {
    const unsigned short* hp = (const unsigned short*)chunkH0 +
                               ((size_t)(b * NCHUNK + c) * D_INNER + d) * 16;
    short8 a8 = *reinterpret_cast<const short8*>(hp);
    short8 b8 = *reinterpret_cast<const short8*>(hp + 8);
#pragma unroll
    for (int n = 0; n < 8; ++n) {
      h[n] = bf2f((unsigned short)a8[n]);
      h[8 + n] = bf2f((unsigned short)b8[n]);
    }
  }

  float dv0 = bf2f(dp[0]), uv0 = bf2f(up[0]);
  float dv1 = bf2f(dp[D_INNER]), uv1 = bf2f(up[D_INNER]);
  dp += 2 * D_INNER; up += 2 * D_INNER;
  float zv = bf2f(zr[0]);
  zr += 4096;
  for (int l = 0; l < CHUNK; ++l) {
    const float dv2 = bf2f(*dp), uv2 = bf2f(*up);   // l+2
    dp += D_INNER; up += D_INNER;
    const float nzv = bf2f(*zr);                    // z(l+1), issued BEFORE y(l) store
    zr += 4096;

    const float dv = softplusf(dv0 + bias);
    const float du = dv * uv0;
    float p = 0.f;
#pragma unroll
    for (int n = 0; n < 16; ++n) {
      const float dA = exp2fast(dv * Av[n]);
      h[n] = fmaf(dA, h[n], du * xb[n]);            // B uniform -> SGPR
      p = fmaf(h[n], xb[16 + n], p);                // C uniform -> SGPR
    }
    xb += 96;
    const float yv = fmaf(uv0, Dv, p) * siluf(zv);
    yp[0] = __float2bfloat16(yv);
    yp += 4096;

    dv0 = dv1; uv0 = uv1; dv1 = dv2; uv1 = uv2; zv = nzv;
  }
}

extern "C" void kernel_launch(void* const* d_in, const int* in_sizes, int n_in,
                              void* d_out, int out_size, void* d_ws, size_t ws_size,
                              hipStream_t stream) {
  const float* x          = (const float*)d_in[0];
  const float* in_proj_w  = (const float*)d_in[1];
  const float* conv_w     = (const float*)d_in[2];
  const float* conv_b     = (const float*)d_in[3];
  const float* x_proj_w   = (const float*)d_in[4];
  const float* dt_proj_w  = (const float*)d_in[5];
  const float* dt_proj_b  = (const float*)d_in[6];
  const float* A_log      = (const float*)d_in[7];
  const float* D_skip     = (const float*)d_in[8];
  const float* out_proj_w = (const float*)d_in[9];
  float* out = (float*)d_out;   // fp32 output

  // Workspace layout (peak ~137 MiB; ws evidence >= 169 MB from r1/r2):
  //   xz_bf     @0          33,554,432  bf16 [4096][4096]
  //   x_act_bf  @33554432   16,777,216  bf16 [4096][2048]
  //   delta_bf  @50331648   16,777,216  bf16 [4096][2048]
  //   x_bf      @67108864    8,388,608  (pre-in_proj; region reused by Cpart after conv)
  //   inw_bf    @75497472    8,388,608
  //   Cpart     @67108864   12,582,912  (post-conv)
  //   x_dbl     @100663296   1,572,864
  //   chunkH    @102236160  16,777,216  bf16 [B*NC*D][16]
  //   chunkS    @135790592   2,097,152
  //   wpad      @137887744     524,288
  //   dtlow_bf  @138412032     524,288
  //   dtw_bf    @138936320     262,144
  //   outw_bf   @139198464   4,194,304
  char* ws = (char*)d_ws;
  __hip_bfloat16* xz_bf    = (__hip_bfloat16*)(ws);
  __hip_bfloat16* x_act_bf = (__hip_bfloat16*)(ws + 33554432);
  __hip_bfloat16* delta_bf = (__hip_bfloat16*)(ws + 50331648);
  __hip_bfloat16* x_bf     = (__hip_bfloat16*)(ws + 67108864);
  __hip_bfloat16* inw_bf   = (__hip_bfloat16*)(ws + 75497472);
  float* Cpart             = (float*)(ws + 67108864);
  float* x_dbl             = (float*)(ws + 100663296);
  __hip_bfloat16* chunkH   = (__hip_bfloat16*)(ws + 102236160);
  float* chunkS            = (float*)(ws + 135790592);
  __hip_bfloat16* wpad     = (__hip_bfloat16*)(ws + 137887744);
  __hip_bfloat16* dtlow_bf = (__hip_bfloat16*)(ws + 138412032);
  __hip_bfloat16* dtw_bf   = (__hip_bfloat16*)(ws + 138936320);
  __hip_bfloat16* outw_bf  = (__hip_bfloat16*)(ws + 139198464);

  // 1. all input conversions in one launch
  f2bf_multi<<<5280, 256, 0, stream>>>(x, x_bf, in_proj_w, inw_bf, x_proj_w, wpad,
                                       dt_proj_w, dtw_bf, out_proj_w, outw_bf);

  // 2. xz = x @ in_proj_w^T  (M=4096, N=4096, K=1024), bf16 out, 8-phase 256^2 pipeline
  gemm256_8ph<__hip_bfloat16><<<dim3(16, 16), 512, 0, stream>>>(
      x_bf, inw_bf, xz_bf, 1024, 1024, 1024, 4096);

  // 3. depthwise causal conv + bias + silu -> x_act_bf
  conv_silu_kernel<<<(BL * D_INNER) / 8 / 256, 256, 0, stream>>>(
      xz_bf, conv_w, conv_b, x_act_bf);

  // 4. x_dbl = x_act @ x_proj_w^T via bf16 MFMA split-K (padded 96->128 weight) + reduce
  gemm_bt<128, 128, XP_N, true, float><<<dim3(XP_KS, 32), 256, 0, stream>>>(
      x_act_bf, wpad, Cpart, 2048 / XP_KS, 2048, 2048, XP_N);
  xproj_reduce<<<(BL * XP_N) / 256, 256, 0, stream>>>(Cpart, x_dbl);

  // 5. delta_raw = dt_low @ dt_proj_w^T  (4096 x 2048, K=64) via bf16 MFMA, bf16 out
  dtlow_bf_kernel<<<128, 256, 0, stream>>>(x_dbl, dtlow_bf);
  gemm_bt<128, 128, 128, false, __hip_bfloat16><<<dim3(16, 32), 256, 0, stream>>>(
      dtlow_bf, dtw_bf, delta_bf, 64, 64, 64, 2048);

  // 6-8. chunked selective scan, block-uniform (b,c) for scalarized B/C loads
  scan_pass1<<<2048, 256, 0, stream>>>(delta_bf, x_act_bf, x_dbl, A_log, dt_proj_b,
                                       chunkS, chunkH);
  scan_pass2<<<256, 256, 0, stream>>>(chunkS, A_log, chunkH);
  scan_pass3<<<2048, 256, 0, stream>>>(delta_bf, x_act_bf, x_dbl, A_log, dt_proj_b,
                                       chunkH, D_skip, xz_bf);

  // 9. out = y @ out_proj_w^T  (M=4096, N=1024, K=2048), fp32 out, 128x64 tile
  gemm_bt<128, 64, 64, false, float><<<dim3(16, 32), 256, 0, stream>>>(
      xz_bf, outw_bf, out, 2048, 4096, 2048, 1024);
}

// Round 18
// 207.556 us; speedup vs baseline: 7.9668x; 1.0225x over previous
//
#include <hip/hip_runtime.h>
#include <hip/hip_bf16.h>
#include <cstdint>

#define D_STATE 16
#define D_INNER 2048
#define DT_RANK 64
#define SEQ 2048
#define BL 4096      // B * L
#define NCHUNK 128
#define CHUNK 16     // SEQ / NCHUNK
#define XP_N 96      // dt_rank + 2*d_state
#define XP_KS 8      // x_proj K-splits
#define LOG2E 1.44269504088896340736f

typedef short bf16x8 __attribute__((ext_vector_type(8)));
typedef short short8 __attribute__((ext_vector_type(8)));
typedef float f32x4 __attribute__((ext_vector_type(4)));

__device__ __forceinline__ float siluf(float x) {
  return __fdividef(x, 1.f + __expf(-x));
}

__device__ __forceinline__ float softplusf(float v) {
  return fmaxf(v, 0.f) + __logf(1.f + __expf(-fabsf(v)));
}

__device__ __forceinline__ float exp2fast(float x) {
  return __builtin_amdgcn_exp2f(x);
}

__device__ __forceinline__ unsigned short f2bf_bits(float x) {
  __hip_bfloat16 h = __float2bfloat16(x);
  return *reinterpret_cast<unsigned short*>(&h);
}

__device__ __forceinline__ float bf2f(unsigned short u) {
  return __int_as_float(((unsigned int)u) << 16);
}

__device__ __forceinline__ void gload_lds16(const void* g, void* l) {
  __builtin_amdgcn_global_load_lds((const __attribute__((address_space(1))) unsigned int*)g,
                                   (__attribute__((address_space(3))) unsigned int*)l,
                                   16, 0, 0);
}

#define BARRIER() asm volatile("s_barrier" ::: "memory")
#define VMCNT(n)  asm volatile("s_waitcnt vmcnt(" #n ")" ::: "memory")

// ---------------- fused fp32 -> bf16 conversions of all inputs (one launch) ----------
__global__ __launch_bounds__(256) void f2bf_multi(const float* __restrict__ x, __hip_bfloat16* __restrict__ x_bf,
                                                  const float* __restrict__ inw, __hip_bfloat16* __restrict__ inw_bf,
                                                  const float* __restrict__ xpw, __hip_bfloat16* __restrict__ wpad,
                                                  const float* __restrict__ dtw, __hip_bfloat16* __restrict__ dtw_bf,
                                                  const float* __restrict__ outw, __hip_bfloat16* __restrict__ outw_bf) {
  const int blk = blockIdx.x;
  const float* src;
  __hip_bfloat16* dst;
  int base;
  if (blk < 2048)      { src = x;    dst = x_bf;    base = blk; }
  else if (blk < 4096) { src = inw;  dst = inw_bf;  base = blk - 2048; }
  else if (blk < 4192) { src = xpw;  dst = wpad;    base = blk - 4096; }
  else if (blk < 4256) { src = dtw;  dst = dtw_bf;  base = blk - 4192; }
  else                 { src = outw; dst = outw_bf; base = blk - 4256; }
  const int i = (base * 256 + threadIdx.x) * 8;
  float4 v0 = *reinterpret_cast<const float4*>(&src[i]);
  float4 v1 = *reinterpret_cast<const float4*>(&src[i + 4]);
  short8 r;
  r[0] = f2bf_bits(v0.x); r[1] = f2bf_bits(v0.y); r[2] = f2bf_bits(v0.z); r[3] = f2bf_bits(v0.w);
  r[4] = f2bf_bits(v1.x); r[5] = f2bf_bits(v1.y); r[6] = f2bf_bits(v1.z); r[7] = f2bf_bits(v1.w);
  *reinterpret_cast<short8*>(&dst[i]) = r;
}

// ============ 8-phase 256x256 bf16 GEMM (T2+T3+T4+T5+T1): C = A[M,K] @ B[N,K]^T ========
template <typename OutT>
__global__ __launch_bounds__(512, 1) void gemm256_8ph(const __hip_bfloat16* __restrict__ A,
                                                      const __hip_bfloat16* __restrict__ B,
                                                      OutT* __restrict__ C,
                                                      int K, int lda, int ldb, int ldc) {
  __shared__ __align__(16) unsigned short lds[65536];  // [2 buf][A 16384 | B 16384] shorts
  const int tid = threadIdx.x;
  const int wv = tid >> 6, lane = tid & 63;
  const int wr = wv >> 2, wc = wv & 3;              // wave grid 2(M) x 4(N)
  // XCD-aware bijective swizzle (nwg % 8 == 0)
  const int nwg = gridDim.x * gridDim.y;
  const int bid = blockIdx.y * gridDim.x + blockIdx.x;
  const int swz = (bid & 7) * (nwg >> 3) + (bid >> 3);
  const int m0 = (swz / gridDim.x) * 256, n0 = (swz % gridDim.x) * 256;
  const int frow = lane & 15;
  const int fu = lane >> 4;
  const int rsw = frow & 7;
  const int sr = lane >> 3;
  const int su = (lane & 7) ^ sr;

  const unsigned short* Ag = (const unsigned short*)A;
  const unsigned short* Bg = (const unsigned short*)B;

  f32x4 acc[8][4];
#pragma unroll
  for (int i = 0; i < 8; ++i)
#pragma unroll
    for (int j = 0; j < 4; ++j) acc[i][j] = {0.f, 0.f, 0.f, 0.f};

  auto stageA = [&](int buf, int g, int kg) {
    const int rowb = g * 64 + wv * 8;
    gload_lds16(&Ag[(size_t)(m0 + rowb + sr) * lda + kg + su * 8],
                &lds[buf * 32768 + rowb * 64]);
  };
  auto stageB = [&](int buf, int g, int kg) {
    const int rowb = g * 64 + wv * 8;
    gload_lds16(&Bg[(size_t)(n0 + rowb + sr) * ldb + kg + su * 8],
                &lds[buf * 32768 + 16384 + rowb * 64]);
  };
  auto fragA = [&](int buf, int mi, int kk) -> bf16x8 {
    const int row = wr * 128 + mi * 16 + frow;
    return *reinterpret_cast<const bf16x8*>(
        &lds[buf * 32768 + row * 64 + (((kk << 2) | fu) ^ rsw) * 8]);
  };
  auto fragB = [&](int buf, int ni, int kk) -> bf16x8 {
    const int row = wc * 64 + ni * 16 + frow;
    return *reinterpret_cast<const bf16x8*>(
        &lds[buf * 32768 + 16384 + row * 64 + (((kk << 2) | fu) ^ rsw) * 8]);
  };

#define QUAD(MB)                                                                        \
  _Pragma("unroll")                                                                     \
  for (int mi = 0; mi < 4; ++mi)                                                        \
    _Pragma("unroll")                                                                   \
    for (int ni = 0; ni < 4; ++ni)                                                      \
      acc[MB + mi][ni] =                                                                \
          __builtin_amdgcn_mfma_f32_16x16x32_bf16(af[mi], bfr[ni], acc[MB + mi][ni], 0, 0, 0);

  stageB(0, 0, 0); stageB(0, 1, 0); stageB(0, 2, 0); stageB(0, 3, 0);
  stageA(0, 0, 0); stageA(0, 2, 0); stageA(0, 1, 0); stageA(0, 3, 0);
  VMCNT(2);
  BARRIER();

  const int NT = K >> 6;
  int cur = 0;
  for (int t = 0; t < NT - 1; ++t) {
    const int nxt = cur ^ 1;
    const int kn = (t + 1) << 6;
    bf16x8 af[4], bfr[4];
    // ---- phase 0
#pragma unroll
    for (int mi = 0; mi < 4; ++mi) af[mi] = fragA(cur, mi, 0);
#pragma unroll
    for (int ni = 0; ni < 4; ++ni) bfr[ni] = fragB(cur, ni, 0);
    stageB(nxt, 0, kn); stageB(nxt, 1, kn);
    VMCNT(2);
    BARRIER();
    __builtin_amdgcn_s_setprio(1);
    QUAD(0);
    __builtin_amdgcn_s_setprio(0);
    BARRIER();
    // ---- phase 1
#pragma unroll
    for (int mi = 0; mi < 4; ++mi) af[mi] = fragA(cur, 4 + mi, 0);
    stageB(nxt, 2, kn); stageB(nxt, 3, kn);
    BARRIER();
    __builtin_amdgcn_s_setprio(1);
    QUAD(4);
    __builtin_amdgcn_s_setprio(0);
    BARRIER();
    // ---- phase 2
#pragma unroll
    for (int mi = 0; mi < 4; ++mi) af[mi] = fragA(cur, mi, 1);
#pragma unroll
    for (int ni = 0; ni < 4; ++ni) bfr[ni] = fragB(cur, ni, 1);
    stageA(nxt, 0, kn); stageA(nxt, 2, kn);
    BARRIER();
    __builtin_amdgcn_s_setprio(1);
    QUAD(0);
    __builtin_amdgcn_s_setprio(0);
    BARRIER();
    // ---- phase 3
#pragma unroll
    for (int mi = 0; mi < 4; ++mi) af[mi] = fragA(cur, 4 + mi, 1);
    stageA(nxt, 1, kn); stageA(nxt, 3, kn);
    VMCNT(2);
    BARRIER();
    __builtin_amdgcn_s_setprio(1);
    QUAD(4);
    __builtin_amdgcn_s_setprio(0);
    BARRIER();
    cur = nxt;
  }
  // ---- last tile
  {
    bf16x8 af[4], bfr[4];
#pragma unroll
    for (int mi = 0; mi < 4; ++mi) af[mi] = fragA(cur, mi, 0);
#pragma unroll
    for (int ni = 0; ni < 4; ++ni) bfr[ni] = fragB(cur, ni, 0);
    VMCNT(0);
    BARRIER();
    __builtin_amdgcn_s_setprio(1);
    QUAD(0);
    __builtin_amdgcn_s_setprio(0);
    BARRIER();
#pragma unroll
    for (int mi = 0; mi < 4; ++mi) af[mi] = fragA(cur, 4 + mi, 0);
    BARRIER();
    __builtin_amdgcn_s_setprio(1);
    QUAD(4);
    __builtin_amdgcn_s_setprio(0);
    BARRIER();
#pragma unroll
    for (int mi = 0; mi < 4; ++mi) af[mi] = fragA(cur, mi, 1);
#pragma unroll
    for (int ni = 0; ni < 4; ++ni) bfr[ni] = fragB(cur, ni, 1);
    BARRIER();
    __builtin_amdgcn_s_setprio(1);
    QUAD(0);
    __builtin_amdgcn_s_setprio(0);
    BARRIER();
#pragma unroll
    for (int mi = 0; mi < 4; ++mi) af[mi] = fragA(cur, 4 + mi, 1);
    __builtin_amdgcn_s_setprio(1);
    QUAD(4);
    __builtin_amdgcn_s_setprio(0);
  }
#undef QUAD

  const int crow = fu * 4;
  const int ccol = frow;
#pragma unroll
  for (int mi = 0; mi < 8; ++mi)
#pragma unroll
    for (int ni = 0; ni < 4; ++ni) {
      const int gcol = n0 + wc * 64 + ni * 16 + ccol;
#pragma unroll
      for (int j = 0; j < 4; ++j) {
        const int grow = m0 + wr * 128 + mi * 16 + crow + j;
        if constexpr (sizeof(OutT) == 2) {
          C[(size_t)grow * ldc + gcol] = __float2bfloat16(acc[mi][ni][j]);
        } else {
          C[(size_t)grow * ldc + gcol] = acc[mi][ni][j];
        }
      }
    }
}

// ---------------- MFMA bf16 GEMM: C = A[M,K] * B[N,K]^T, double-buffered LDS ----------
template <int BM, int BN>
__device__ __forceinline__ void stage_tiles(const unsigned short* __restrict__ Ag,
                                            const unsigned short* __restrict__ Bg,
                                            unsigned short* buf, int m0, int n0, int k0,
                                            int lda, int ldb, int sr, int sk, int wv) {
#pragma unroll
  for (int g = 0; g < BM / 64; ++g)
    gload_lds16(&Ag[(size_t)(m0 + g * 64 + sr) * lda + k0 + sk], &buf[g * 2048 + wv * 512]);
#pragma unroll
  for (int g = 0; g < BN / 64; ++g)
    gload_lds16(&Bg[(size_t)(n0 + g * 64 + sr) * ldb + k0 + sk], &buf[BM * 32 + g * 2048 + wv * 512]);
}

template <int BM, int BN, int NSTORE, bool SPLITK, bool XSWZ, typename OutT>
__global__ __launch_bounds__(256) void gemm_bt(const __hip_bfloat16* __restrict__ A,
                                               const __hip_bfloat16* __restrict__ B,
                                               OutT* __restrict__ C,
                                               int K, int lda, int ldb, int ldc) {
  constexpr int WM = BM / 2, WN = BN / 2;
  constexpr int MI = WM / 16, NI = WN / 16;
  constexpr int BUFS = (BM + BN) * 32;
  __shared__ __align__(16) unsigned short lds[2 * BUFS];
  const int tid = threadIdx.x;
  const int wv = tid >> 6, lane = tid & 63;
  const int wr = wv >> 1, wc = wv & 1;
  int m0, n0, koff;
  if constexpr (SPLITK) {
    m0 = blockIdx.y * BM;
    n0 = 0;
    koff = blockIdx.x * K;
    C += (size_t)blockIdx.x * BL * NSTORE;
  } else if constexpr (XSWZ) {
    const int nwg = gridDim.x * gridDim.y;
    const int bid = blockIdx.y * gridDim.x + blockIdx.x;
    const int swz = (bid & 7) * (nwg >> 3) + (bid >> 3);
    m0 = (swz / gridDim.x) * BM;
    n0 = (swz % gridDim.x) * BN;
    koff = 0;
  } else {
    m0 = blockIdx.y * BM;
    n0 = blockIdx.x * BN;
    koff = 0;
  }
  const int sr = tid >> 2;
  const int sk = (tid & 3) * 8;
  const int frow = lane & 15;
  const int fk = (lane >> 4) * 8;

  f32x4 acc[MI][NI];
#pragma unroll
  for (int i = 0; i < MI; ++i)
#pragma unroll
    for (int j = 0; j < NI; ++j) acc[i][j] = {0.f, 0.f, 0.f, 0.f};

  const unsigned short* Ag = (const unsigned short*)A;
  const unsigned short* Bg = (const unsigned short*)B;

  stage_tiles<BM, BN>(Ag, Bg, &lds[0], m0, n0, koff, lda, ldb, sr, sk, wv);
  __syncthreads();
  int sel = 0;
  for (int k0 = 0; k0 < K; k0 += 32) {
    if (k0 + 32 < K)
      stage_tiles<BM, BN>(Ag, Bg, &lds[(sel ^ 1) * BUFS], m0, n0, koff + k0 + 32, lda, ldb, sr, sk, wv);
    const unsigned short* Abuf = &lds[sel * BUFS];
    const unsigned short* Bbuf = &lds[sel * BUFS + BM * 32];
    bf16x8 af[MI], bfr[NI];
#pragma unroll
    for (int mi = 0; mi < MI; ++mi)
      af[mi] = *reinterpret_cast<const bf16x8*>(&Abuf[(wr * WM + mi * 16 + frow) * 32 + fk]);
#pragma unroll
    for (int ni = 0; ni < NI; ++ni)
      bfr[ni] = *reinterpret_cast<const bf16x8*>(&Bbuf[(wc * WN + ni * 16 + frow) * 32 + fk]);
#pragma unroll
    for (int mi = 0; mi < MI; ++mi)
#pragma unroll
      for (int ni = 0; ni < NI; ++ni)
        acc[mi][ni] = __builtin_amdgcn_mfma_f32_16x16x32_bf16(af[mi], bfr[ni], acc[mi][ni], 0, 0, 0);
    __syncthreads();
    sel ^= 1;
  }

  const int crow = (lane >> 4) * 4;
  const int ccol = lane & 15;
#pragma unroll
  for (int mi = 0; mi < MI; ++mi)
#pragma unroll
    for (int ni = 0; ni < NI; ++ni) {
      const int gcol = n0 + wc * WN + ni * 16 + ccol;
      if constexpr (NSTORE < BN) {
        if (gcol >= NSTORE) continue;
      }
#pragma unroll
      for (int j = 0; j < 4; ++j) {
        const int grow = m0 + wr * WM + mi * 16 + crow + j;
        if constexpr (sizeof(OutT) == 2) {
          C[(size_t)grow * ldc + gcol] = __float2bfloat16(acc[mi][ni][j]);
        } else {
          C[(size_t)grow * ldc + gcol] = acc[mi][ni][j];
        }
      }
    }
}

// ---------------- x_proj reduce (+ fused dt_low bf16 extraction) ----------------
__global__ __launch_bounds__(256) void xproj_reduce(const float* __restrict__ Cpart,
                                                    float* __restrict__ x_dbl,
                                                    __hip_bfloat16* __restrict__ dtlow_bf) {
  const int i = blockIdx.x * 256 + threadIdx.x;    // < BL * XP_N
  float s = 0.f;
#pragma unroll
  for (int z = 0; z < XP_KS; ++z) s += Cpart[(size_t)z * BL * XP_N + i];
  x_dbl[i] = s;
  const int row = i / XP_N;
  const int col = i - row * XP_N;
  if (col < DT_RANK) dtlow_bf[(size_t)row * DT_RANK + col] = __float2bfloat16(s);
}

// ---------------- depthwise causal conv1d (w=4) + bias + silu, 8 d's/thread ----------
__global__ __launch_bounds__(256) void conv_silu_kernel(const __hip_bfloat16* __restrict__ xz_bf,
                                                        const float* __restrict__ conv_w,
                                                        const float* __restrict__ conv_b,
                                                        __hip_bfloat16* __restrict__ x_act_bf) {
  const int idx = blockIdx.x * 256 + threadIdx.x;       // over BL * D_INNER / 8
  const int d8 = (idx << 3) & (D_INNER - 1);
  const int bl = idx >> 8;
  const int l = bl & (SEQ - 1);

  float acc[8];
  {
    float4 cb0 = *reinterpret_cast<const float4*>(&conv_b[d8]);
    float4 cb1 = *reinterpret_cast<const float4*>(&conv_b[d8 + 4]);
    acc[0] = cb0.x; acc[1] = cb0.y; acc[2] = cb0.z; acc[3] = cb0.w;
    acc[4] = cb1.x; acc[5] = cb1.y; acc[6] = cb1.z; acc[7] = cb1.w;
  }
  float4 cw[8];
#pragma unroll
  for (int j = 0; j < 8; ++j)
    cw[j] = *reinterpret_cast<const float4*>(&conv_w[(d8 + j) * 4]);

#pragma unroll
  for (int k = 0; k < 4; ++k) {
    if (l + k - 3 >= 0) {
      short8 v = *reinterpret_cast<const short8*>(&xz_bf[(size_t)(bl + k - 3) * 4096 + d8]);
      const float w0[8] = {cw[0].x, cw[1].x, cw[2].x, cw[3].x, cw[4].x, cw[5].x, cw[6].x, cw[7].x};
      const float w1[8] = {cw[0].y, cw[1].y, cw[2].y, cw[3].y, cw[4].y, cw[5].y, cw[6].y, cw[7].y};
      const float w2[8] = {cw[0].z, cw[1].z, cw[2].z, cw[3].z, cw[4].z, cw[5].z, cw[6].z, cw[7].z};
      const float w3[8] = {cw[0].w, cw[1].w, cw[2].w, cw[3].w, cw[4].w, cw[5].w, cw[6].w, cw[7].w};
      const float* wk = (k == 0) ? w0 : (k == 1) ? w1 : (k == 2) ? w2 : w3;
#pragma unroll
      for (int j = 0; j < 8; ++j) acc[j] = fmaf(bf2f((unsigned short)v[j]), wk[j], acc[j]);
    }
  }

  short8 ob;
#pragma unroll
  for (int j = 0; j < 8; ++j) ob[j] = f2bf_bits(siluf(acc[j]));
  *reinterpret_cast<short8*>(&x_act_bf[(size_t)bl * D_INNER + d8]) = ob;
}

// ---------------- scan pass 1: block-uniform (b,c); B loads scalarize to SGPR ----------
__global__ __launch_bounds__(256) void scan_pass1(const __hip_bfloat16* __restrict__ delta_bf,
                                                  const __hip_bfloat16* __restrict__ x_act_bf,
                                                  const float* __restrict__ x_dbl,
                                                  const float* __restrict__ A_log,
                                                  const float* __restrict__ dt_proj_b,
                                                  float* __restrict__ chunkS,
                                                  __hip_bfloat16* __restrict__ chunkH) {
  const int blk = blockIdx.x;
  const int d = ((blk & 7) << 8) + threadIdx.x;
  const int c = (blk >> 3) & (NCHUNK - 1);
  const int b = blk >> 10;
  const int base = b * SEQ + c * CHUNK;      // block-uniform

  float Av[16];
#pragma unroll
  for (int q = 0; q < 4; ++q) {
    float4 a = *reinterpret_cast<const float4*>(&A_log[d * 16 + q * 4]);
    Av[q * 4 + 0] = -__expf(a.x) * LOG2E; Av[q * 4 + 1] = -__expf(a.y) * LOG2E;
    Av[q * 4 + 2] = -__expf(a.z) * LOG2E; Av[q * 4 + 3] = -__expf(a.w) * LOG2E;
  }
  const float bias = dt_proj_b[d];

  const unsigned short* dp = (const unsigned short*)delta_bf + (size_t)base * D_INNER + d;
  const unsigned short* up = (const unsigned short*)x_act_bf + (size_t)base * D_INNER + d;
  const float* xb = x_dbl + (size_t)base * 96 + DT_RANK;   // uniform address

  float h[16];
#pragma unroll
  for (int n = 0; n < 16; ++n) h[n] = 0.f;
  float S = 0.f;

  float dv0 = bf2f(dp[0]), uv0 = bf2f(up[0]);
  float dv1 = bf2f(dp[D_INNER]), uv1 = bf2f(up[D_INNER]);
  dp += 2 * D_INNER; up += 2 * D_INNER;
  for (int l = 0; l < CHUNK; ++l) {
    const float dv2 = bf2f(*dp), uv2 = bf2f(*up);   // l+2 (overread tail stays in ws)
    dp += D_INNER; up += D_INNER;

    const float dv = softplusf(dv0 + bias);
    S += dv;
    const float du = dv * uv0;
#pragma unroll
    for (int n = 0; n < 16; ++n) {
      const float dA = exp2fast(dv * Av[n]);
      h[n] = fmaf(dA, h[n], du * xb[n]);            // xb[n] uniform -> SGPR operand
    }
    xb += 96;
    dv0 = dv1; uv0 = uv1; dv1 = dv2; uv1 = uv2;
  }

  const size_t sidx = (size_t)(b * NCHUNK + c) * D_INNER + d;
  chunkS[sidx] = S;
  unsigned short* hp = (unsigned short*)chunkH + sidx * 16;
  short8 h0v, h1v;
#pragma unroll
  for (int n = 0; n < 8; ++n) { h0v[n] = f2bf_bits(h[n]); h1v[n] = f2bf_bits(h[8 + n]); }
  *reinterpret_cast<short8*>(hp) = h0v;
  *reinterpret_cast<short8*>(hp + 8) = h1v;
}

// ---------------- scan pass 2: depth-4 prefetch over the serial chunk chain ----------
__global__ __launch_bounds__(256) void scan_pass2(const float* __restrict__ chunkS,
                                                  const float* __restrict__ A_log,
                                                  __hip_bfloat16* chunkH) {
  const int s = blockIdx.x * 256 + threadIdx.x;   // 65536 = (b, d, n)
  const int n = s & 15;
  const int d = (s >> 4) & (D_INNER - 1);
  const int b = s >> 15;
  const float Aval = -__expf(A_log[d * 16 + n]) * LOG2E;

  unsigned short* hb = (unsigned short*)chunkH;
  size_t s0 = (size_t)b * NCHUNK * D_INNER + d;
  float aSq[4], hEq[4];
#pragma unroll
  for (int j = 0; j < 4; ++j) {
    aSq[j] = chunkS[s0 + (size_t)j * D_INNER];
    hEq[j] = bf2f(hb[(s0 + (size_t)j * D_INNER) * 16 + n]);
  }
  float H = 0.f;
  for (int c = 0; c < NCHUNK; c += 4) {
#pragma unroll
    for (int j = 0; j < 4; ++j) {
      const size_t scur = s0 + (size_t)j * D_INNER;
      const size_t snext = scur + 4 * (size_t)D_INNER;   // overread tail: inside ws
      const float naS = chunkS[snext];
      const float nhE = bf2f(hb[snext * 16 + n]);
      const float aP = exp2fast(Aval * aSq[j]);
      hb[scur * 16 + n] = f2bf_bits(H);                  // h0 for this chunk
      H = fmaf(aP, H, hEq[j]);
      aSq[j] = naS; hEq[j] = nhE;
    }
    s0 += 4 * (size_t)D_INNER;
  }
}

// ---------------- scan pass 3: block-uniform (b,c); B/C scalarized; z before y-store ---
__global__ __launch_bounds__(256) void scan_pass3(const __hip_bfloat16* __restrict__ delta_bf,
                                                  const __hip_bfloat16* __restrict__ x_act_bf,
                                                  const float* __restrict__ x_dbl,
                                                  const float* __restrict__ A_log,
                                                  const float* __restrict__ dt_proj_b,
                                                  const __hip_bfloat16* __restrict__ chunkH0,
                                                  const float* __restrict__ D_skip,
                                                  __hip_bfloat16* xz_bf) {
  const int blk = blockIdx.x;
  const int d = ((blk & 7) << 8) + threadIdx.x;
  const int c = (blk >> 3) & (NCHUNK - 1);
  const int b = blk >> 10;
  const int base = b * SEQ + c * CHUNK;      // block-uniform

  float Av[16];
#pragma unroll
  for (int q = 0; q < 4; ++q) {
    float4 a = *reinterpret_cast<const float4*>(&A_log[d * 16 + q * 4]);
    Av[q * 4 + 0] = -__expf(a.x) * LOG2E; Av[q * 4 + 1] = -__expf(a.y) * LOG2E;
    Av[q * 4 + 2] = -__expf(a.z) * LOG2E; Av[q * 4 + 3] = -__expf(a.w) * LOG2E;
  }
  const float bias = dt_proj_b[d];
  const float Dv = D_skip[d];

  const unsigned short* dp = (const unsigned short*)delta_bf + (size_t)base * D_INNER + d;
  const unsigned short* up = (const unsigned short*)x_act_bf + (size_t)base * D_INNER + d;
  const float* xb = x_dbl + (size_t)base * 96 + DT_RANK;      // uniform; B [0..15], C [16..31]
  const unsigned short* zr = (const unsigned short*)xz_bf + (size_t)base * 4096 + D_INNER + d;
  __hip_bfloat16* yp = xz_bf + (size_t)base * 4096 + d;

  float h[16];
  {
    const unsigned short* hp = (const unsigned short*)chunkH0 +
                               ((size_t)(b * NCHUNK + c) * D_INNER + d) * 16;
    short8 a8 = *reinterpret_cast<const short8*>(hp);
    short8 b8 = *reinterpret_cast<const short8*>(hp + 8);
#pragma unroll
    for (int n = 0; n < 8; ++n) {
      h[n] = bf2f((unsigned short)a8[n]);
      h[8 + n] = bf2f((unsigned short)b8[n]);
    }
  }

  float dv0 = bf2f(dp[0]), uv0 = bf2f(up[0]);
  float dv1 = bf2f(dp[D_INNER]), uv1 = bf2f(up[D_INNER]);
  dp += 2 * D_INNER; up += 2 * D_INNER;
  float zv = bf2f(zr[0]);
  zr += 4096;
  for (int l = 0; l < CHUNK; ++l) {
    const float dv2 = bf2f(*dp), uv2 = bf2f(*up);   // l+2
    dp += D_INNER; up += D_INNER;
    const float nzv = bf2f(*zr);                    // z(l+1), issued BEFORE y(l) store
    zr += 4096;

    const float dv = softplusf(dv0 + bias);
    const float du = dv * uv0;
    float p = 0.f;
#pragma unroll
    for (int n = 0; n < 16; ++n) {
      const float dA = exp2fast(dv * Av[n]);
      h[n] = fmaf(dA, h[n], du * xb[n]);            // B uniform -> SGPR
      p = fmaf(h[n], xb[16 + n], p);                // C uniform -> SGPR
    }
    xb += 96;
    const float yv = fmaf(uv0, Dv, p) * siluf(zv);
    yp[0] = __float2bfloat16(yv);
    yp += 4096;

    dv0 = dv1; uv0 = uv1; dv1 = dv2; uv1 = uv2; zv = nzv;
  }
}

extern "C" void kernel_launch(void* const* d_in, const int* in_sizes, int n_in,
                              void* d_out, int out_size, void* d_ws, size_t ws_size,
                              hipStream_t stream) {
  const float* x          = (const float*)d_in[0];
  const float* in_proj_w  = (const float*)d_in[1];
  const float* conv_w     = (const float*)d_in[2];
  const float* conv_b     = (const float*)d_in[3];
  const float* x_proj_w   = (const float*)d_in[4];
  const float* dt_proj_w  = (const float*)d_in[5];
  const float* dt_proj_b  = (const float*)d_in[6];
  const float* A_log      = (const float*)d_in[7];
  const float* D_skip     = (const float*)d_in[8];
  const float* out_proj_w = (const float*)d_in[9];
  float* out = (float*)d_out;   // fp32 output

  // Workspace layout (peak ~137 MiB; ws evidence >= 169 MB from r1/r2):
  //   xz_bf     @0          33,554,432  bf16 [4096][4096]
  //   x_act_bf  @33554432   16,777,216  bf16 [4096][2048]
  //   delta_bf  @50331648   16,777,216  bf16 [4096][2048]
  //   x_bf      @67108864    8,388,608  (pre-in_proj; region reused by Cpart after conv)
  //   inw_bf    @75497472    8,388,608
  //   Cpart     @67108864   12,582,912  (post-conv)
  //   x_dbl     @100663296   1,572,864
  //   chunkH    @102236160  16,777,216  bf16 [B*NC*D][16]
  //   chunkS    @135790592   2,097,152
  //   wpad      @137887744     524,288
  //   dtlow_bf  @138412032     524,288
  //   dtw_bf    @138936320     262,144
  //   outw_bf   @139198464   4,194,304
  char* ws = (char*)d_ws;
  __hip_bfloat16* xz_bf    = (__hip_bfloat16*)(ws);
  __hip_bfloat16* x_act_bf = (__hip_bfloat16*)(ws + 33554432);
  __hip_bfloat16* delta_bf = (__hip_bfloat16*)(ws + 50331648);
  __hip_bfloat16* x_bf     = (__hip_bfloat16*)(ws + 67108864);
  __hip_bfloat16* inw_bf   = (__hip_bfloat16*)(ws + 75497472);
  float* Cpart             = (float*)(ws + 67108864);
  float* x_dbl             = (float*)(ws + 100663296);
  __hip_bfloat16* chunkH   = (__hip_bfloat16*)(ws + 102236160);
  float* chunkS            = (float*)(ws + 135790592);
  __hip_bfloat16* wpad     = (__hip_bfloat16*)(ws + 137887744);
  __hip_bfloat16* dtlow_bf = (__hip_bfloat16*)(ws + 138412032);
  __hip_bfloat16* dtw_bf   = (__hip_bfloat16*)(ws + 138936320);
  __hip_bfloat16* outw_bf  = (__hip_bfloat16*)(ws + 139198464);

  // 1. all input conversions in one launch
  f2bf_multi<<<5280, 256, 0, stream>>>(x, x_bf, in_proj_w, inw_bf, x_proj_w, wpad,
                                       dt_proj_w, dtw_bf, out_proj_w, outw_bf);

  // 2. xz = x @ in_proj_w^T  (M=4096, N=4096, K=1024), 8-phase 256^2, XCD-swizzled
  gemm256_8ph<__hip_bfloat16><<<dim3(16, 16), 512, 0, stream>>>(
      x_bf, inw_bf, xz_bf, 1024, 1024, 1024, 4096);

  // 3. depthwise causal conv + bias + silu -> x_act_bf
  conv_silu_kernel<<<(BL * D_INNER) / 8 / 256, 256, 0, stream>>>(
      xz_bf, conv_w, conv_b, x_act_bf);

  // 4. x_dbl = x_act @ x_proj_w^T via bf16 MFMA split-K + reduce (fused dtlow extract)
  gemm_bt<128, 128, XP_N, true, false, float><<<dim3(XP_KS, 32), 256, 0, stream>>>(
      x_act_bf, wpad, Cpart, 2048 / XP_KS, 2048, 2048, XP_N);
  xproj_reduce<<<(BL * XP_N) / 256, 256, 0, stream>>>(Cpart, x_dbl, dtlow_bf);

  // 5. delta_raw = dt_low @ dt_proj_w^T  (4096 x 2048, K=64), bf16 out, XCD-swizzled
  gemm_bt<128, 128, 128, false, true, __hip_bfloat16><<<dim3(16, 32), 256, 0, stream>>>(
      dtlow_bf, dtw_bf, delta_bf, 64, 64, 64, 2048);

  // 6-8. chunked selective scan, block-uniform (b,c), depth-4 pass2
  scan_pass1<<<2048, 256, 0, stream>>>(delta_bf, x_act_bf, x_dbl, A_log, dt_proj_b,
                                       chunkS, chunkH);
  scan_pass2<<<256, 256, 0, stream>>>(chunkS, A_log, chunkH);
  scan_pass3<<<2048, 256, 0, stream>>>(delta_bf, x_act_bf, x_dbl, A_log, dt_proj_b,
                                       chunkH, D_skip, xz_bf);

  // 9. out = y @ out_proj_w^T  (M=4096, N=1024, K=2048), fp32 out, XCD-swizzled
  gemm_bt<128, 64, 64, false, true, float><<<dim3(16, 32), 256, 0, stream>>>(
      xz_bf, outw_bf, out, 2048, 4096, 2048, 1024);
}